// Round 2
// baseline (11368.371 us; speedup 1.0000x reference)
//
#include <hip/hip_runtime.h>
#include <math.h>

// ---------------- problem constants ----------------
constexpr int BB   = 512;
constexpr int TSEQ = 24;
constexpr int NF   = 81;
constexpr int DD   = 64;
constexpr int MTOT = BB * TSEQ;      // 12288
constexpr int FDIM = NF * DD;        // 5184
constexpr int MC   = 1536;           // M-chunk for VSN phase (8 chunks)
constexpr float LN_EPS = 1e-5f;

static __device__ __forceinline__ float sigmoidf_(float x) { return 1.f / (1.f + expf(-x)); }
static __device__ __forceinline__ float eluf_(float x)     { return x > 0.f ? x : (expf(x) - 1.f); }

// =====================================================================
// Kernel 1: VSN — 81 per-feature GRNs -> stacked chunk [MC, NF*64]
// grid (NF, MC/64), 256 threads. Thread tile 4x4 of a 64x64 output tile.
// x points at the chunk's first row ([MC, NF]).
// =====================================================================
__global__ __launch_bounds__(256) void vsn_kernel(
    const float* __restrict__ x,
    const float* __restrict__ f_w1,  const float* __restrict__ f_b1,
    const float* __restrict__ f_w2,  const float* __restrict__ f_b2,
    const float* __restrict__ f_g1w, const float* __restrict__ f_g1b,
    const float* __restrict__ f_g2w, const float* __restrict__ f_g2b,
    const float* __restrict__ f_skw, const float* __restrict__ f_skb,
    const float* __restrict__ f_lng, const float* __restrict__ f_lnb,
    float* __restrict__ stacked)
{
    const int f  = blockIdx.x;
    const int m0 = blockIdx.y * 64;
    const int t  = threadIdx.x;
    const int tr = t >> 4;      // 0..15 row group
    const int tc = t & 15;      // 0..15 col group

    __shared__ __align__(16) float hA[64 * 68];   // h buffer (h0, then h1)
    __shared__ __align__(16) float Wt[64 * 68];   // transposed weight: Wt[c][i]
    __shared__ float vw1[64], vb1[64], vb2[64], vg1b[64], vg2b[64];
    __shared__ float vskw[64], vskb[64], vlng[64], vlnb[64], xv[64];

    if (t < 64) {
        vw1[t]  = f_w1 [f*64 + t];  vb1[t]  = f_b1 [f*64 + t];
        vb2[t]  = f_b2 [f*64 + t];
        vg1b[t] = f_g1b[f*64 + t];  vg2b[t] = f_g2b[f*64 + t];
        vskw[t] = f_skw[f*64 + t];  vskb[t] = f_skb[f*64 + t];
        vlng[t] = f_lng[f*64 + t];  vlnb[t] = f_lnb[f*64 + t];
        xv[t]   = x[(size_t)(m0 + t) * NF + f];
    }
    // stage Wt = f_w2[f] transposed
    {
        const float* w2p = f_w2 + (size_t)f * 4096;
        #pragma unroll
        for (int p = 0; p < 16; ++p) {
            int e = t + 256 * p; int i = e >> 6, c = e & 63;
            Wt[c*68 + i] = w2p[i*64 + c];
        }
    }
    __syncthreads();
    // h0 = elu(x*w1 + b1)
    #pragma unroll
    for (int p = 0; p < 16; ++p) {
        int e = t + 256 * p; int r = e >> 6, d = e & 63;
        hA[r*68 + d] = eluf_(xv[r] * vw1[d] + vb1[d]);
    }
    __syncthreads();

    // ---- matmul1: h1 = h0 @ w2 (+b2 at write) ----
    float acc1[4][4] = {};
    for (int i = 0; i < 64; i += 4) {
        float4 av[4], wv[4];
        #pragma unroll
        for (int j = 0; j < 4; ++j) av[j] = *(const float4*)&hA[(tr + 16*j)*68 + i];
        #pragma unroll
        for (int j = 0; j < 4; ++j) wv[j] = *(const float4*)&Wt[(tc + 16*j)*68 + i];
        #pragma unroll
        for (int a = 0; a < 4; ++a)
            #pragma unroll
            for (int b = 0; b < 4; ++b)
                acc1[a][b] += av[a].x*wv[b].x + av[a].y*wv[b].y + av[a].z*wv[b].z + av[a].w*wv[b].w;
    }
    __syncthreads();
    // write h1 back into hA ; stage g1w
    #pragma unroll
    for (int a = 0; a < 4; ++a)
        #pragma unroll
        for (int b = 0; b < 4; ++b)
            hA[(tr + 16*a)*68 + (tc + 16*b)] = acc1[a][b] + vb2[tc + 16*b];
    {
        const float* g1p = f_g1w + (size_t)f * 4096;
        #pragma unroll
        for (int p = 0; p < 16; ++p) {
            int e = t + 256 * p; int i = e >> 6, c = e & 63;
            Wt[c*68 + i] = g1p[i*64 + c];
        }
    }
    __syncthreads();

    // ---- matmul2: g1 = h1 @ g1w ----
    float accA[4][4] = {};
    for (int i = 0; i < 64; i += 4) {
        float4 av[4], wv[4];
        #pragma unroll
        for (int j = 0; j < 4; ++j) av[j] = *(const float4*)&hA[(tr + 16*j)*68 + i];
        #pragma unroll
        for (int j = 0; j < 4; ++j) wv[j] = *(const float4*)&Wt[(tc + 16*j)*68 + i];
        #pragma unroll
        for (int a = 0; a < 4; ++a)
            #pragma unroll
            for (int b = 0; b < 4; ++b)
                accA[a][b] += av[a].x*wv[b].x + av[a].y*wv[b].y + av[a].z*wv[b].z + av[a].w*wv[b].w;
    }
    __syncthreads();
    {
        const float* g2p = f_g2w + (size_t)f * 4096;
        #pragma unroll
        for (int p = 0; p < 16; ++p) {
            int e = t + 256 * p; int i = e >> 6, c = e & 63;
            Wt[c*68 + i] = g2p[i*64 + c];
        }
    }
    __syncthreads();

    // ---- matmul3: g2 = h1 @ g2w ----
    float accB[4][4] = {};
    for (int i = 0; i < 64; i += 4) {
        float4 av[4], wv[4];
        #pragma unroll
        for (int j = 0; j < 4; ++j) av[j] = *(const float4*)&hA[(tr + 16*j)*68 + i];
        #pragma unroll
        for (int j = 0; j < 4; ++j) wv[j] = *(const float4*)&Wt[(tc + 16*j)*68 + i];
        #pragma unroll
        for (int a = 0; a < 4; ++a)
            #pragma unroll
            for (int b = 0; b < 4; ++b)
                accB[a][b] += av[a].x*wv[b].x + av[a].y*wv[b].y + av[a].z*wv[b].z + av[a].w*wv[b].w;
    }

    // ---- GLU + skip + LayerNorm(64) + store ----
    #pragma unroll
    for (int a = 0; a < 4; ++a) {
        const int r = tr + 16*a;
        float vals[4];
        float partial = 0.f;
        #pragma unroll
        for (int b = 0; b < 4; ++b) {
            const int c = tc + 16*b;
            float sg = sigmoidf_(accA[a][b] + vg1b[c]);
            float y  = sg * (accB[a][b] + vg2b[c]) + xv[r] * vskw[c] + vskb[c];
            vals[b] = y; partial += y;
        }
        #pragma unroll
        for (int off = 1; off < 16; off <<= 1) partial += __shfl_xor(partial, off);
        const float mean = partial * (1.f / 64.f);
        float vp = 0.f;
        #pragma unroll
        for (int b = 0; b < 4; ++b) { float d = vals[b] - mean; vp += d * d; }
        #pragma unroll
        for (int off = 1; off < 16; off <<= 1) vp += __shfl_xor(vp, off);
        const float inv = rsqrtf(vp * (1.f / 64.f) + LN_EPS);
        const size_t base = (size_t)(m0 + r) * FDIM + (size_t)f * 64;
        #pragma unroll
        for (int b = 0; b < 4; ++b) {
            const int c = tc + 16*b;
            stacked[base + c] = (vals[b] - mean) * inv * vlng[c] + vlnb[c];
        }
    }
}

// =====================================================================
// Generic tiled fp32 GEMM: C[M,N] = act(A[M,K] @ W[K,N] + bias)
// 32x64 tile per block, 256 threads, thread tile 2x4. act: 0 none, 1 elu, 2 relu
// =====================================================================
__global__ __launch_bounds__(256) void gemm_kernel(
    const float* __restrict__ A, const float* __restrict__ W,
    const float* __restrict__ bias, float* __restrict__ C,
    int M, int K, int N, int act)
{
    __shared__ __align__(16) float As[32 * 68];
    __shared__ __align__(16) float Ws[64 * 68];   // transposed: Ws[c][i]
    const int t  = threadIdx.x;
    const int m0 = blockIdx.x * 32;
    const int n0 = blockIdx.y * 64;
    const int tr = t >> 4, tc = t & 15;

    float acc[2][4] = {};
    for (int k0 = 0; k0 < K; k0 += 64) {
        #pragma unroll
        for (int p = 0; p < 8; ++p) {
            int e = t + 256 * p; int r = e >> 6, i = e & 63;
            int gm = m0 + r, gk = k0 + i;
            As[r*68 + i] = (gm < M && gk < K) ? A[(size_t)gm * K + gk] : 0.f;
        }
        #pragma unroll
        for (int p = 0; p < 16; ++p) {
            int e = t + 256 * p; int i = e >> 6, c = e & 63;
            int gk = k0 + i, gn = n0 + c;
            Ws[c*68 + i] = (gk < K && gn < N) ? W[(size_t)gk * N + gn] : 0.f;
        }
        __syncthreads();
        for (int i = 0; i < 64; i += 4) {
            float4 av[2], wv[4];
            av[0] = *(const float4*)&As[tr*68 + i];
            av[1] = *(const float4*)&As[(tr + 16)*68 + i];
            #pragma unroll
            for (int j = 0; j < 4; ++j) wv[j] = *(const float4*)&Ws[(tc + 16*j)*68 + i];
            #pragma unroll
            for (int a = 0; a < 2; ++a)
                #pragma unroll
                for (int b = 0; b < 4; ++b)
                    acc[a][b] += av[a].x*wv[b].x + av[a].y*wv[b].y + av[a].z*wv[b].z + av[a].w*wv[b].w;
        }
        __syncthreads();
    }
    #pragma unroll
    for (int a = 0; a < 2; ++a) {
        int gm = m0 + tr + 16*a; if (gm >= M) continue;
        #pragma unroll
        for (int b = 0; b < 4; ++b) {
            int gn = n0 + tc + 16*b; if (gn >= N) continue;
            float v = acc[a][b] + bias[gn];
            if (act == 1) v = eluf_(v);
            else if (act == 2) v = fmaxf(v, 0.f);
            C[(size_t)gm * N + gn] = v;
        }
    }
}

// =====================================================================
// Weight-GRN tail: wh2 -> GLU -> +skip -> LN(81) -> softmax -> w81
// one wave per row; grid Mc/4, 256 threads
// =====================================================================
__global__ __launch_bounds__(256) void wtail_kernel(
    const float* __restrict__ wh1, const float* __restrict__ sk81,
    const float* __restrict__ w_w2,  const float* __restrict__ w_b2,
    const float* __restrict__ w_g1w, const float* __restrict__ w_g1b,
    const float* __restrict__ w_g2w, const float* __restrict__ w_g2b,
    const float* __restrict__ w_lng, const float* __restrict__ w_lnb,
    float* __restrict__ w81)
{
    __shared__ float sWh[4][64];
    __shared__ float sW2[4][96];
    const int wv = threadIdx.x >> 6, l = threadIdx.x & 63;
    const int m = blockIdx.x * 4 + wv;
    sWh[wv][l] = wh1[(size_t)m * 64 + l];
    __syncthreads();

    const bool v1 = (l < 17);
    float acc0 = w_b2[l], acc1 = v1 ? w_b2[64 + l] : 0.f;
    for (int i = 0; i < 64; ++i) {
        float h = sWh[wv][i];
        acc0 += h * w_w2[i*81 + l];
        if (v1) acc1 += h * w_w2[i*81 + 64 + l];
    }
    sW2[wv][l] = acc0; if (v1) sW2[wv][64 + l] = acc1;
    __syncthreads();

    float g10 = w_g1b[l], g20 = w_g2b[l];
    float g11 = v1 ? w_g1b[64 + l] : 0.f, g21 = v1 ? w_g2b[64 + l] : 0.f;
    for (int i = 0; i < 81; ++i) {
        float h = sW2[wv][i];
        g10 += h * w_g1w[i*81 + l];
        g20 += h * w_g2w[i*81 + l];
        if (v1) { g11 += h * w_g1w[i*81 + 64 + l]; g21 += h * w_g2w[i*81 + 64 + l]; }
    }
    float y0 = sigmoidf_(g10) * g20 + sk81[(size_t)m * 81 + l];
    float y1 = v1 ? (sigmoidf_(g11) * g21 + sk81[(size_t)m * 81 + 64 + l]) : 0.f;

    float s = y0 + (v1 ? y1 : 0.f);
    #pragma unroll
    for (int off = 32; off; off >>= 1) s += __shfl_xor(s, off);
    const float mean = s / 81.f;
    float d0 = y0 - mean, d1 = v1 ? (y1 - mean) : 0.f;
    float vs = d0*d0 + (v1 ? d1*d1 : 0.f);
    #pragma unroll
    for (int off = 32; off; off >>= 1) vs += __shfl_xor(vs, off);
    const float inv = rsqrtf(vs / 81.f + LN_EPS);
    float wn0 = d0 * inv * w_lng[l] + w_lnb[l];
    float wn1 = v1 ? (d1 * inv * w_lng[64 + l] + w_lnb[64 + l]) : -1e30f;

    float mx = fmaxf(wn0, wn1);
    #pragma unroll
    for (int off = 32; off; off >>= 1) mx = fmaxf(mx, __shfl_xor(mx, off));
    float e0 = expf(wn0 - mx), e1 = v1 ? expf(wn1 - mx) : 0.f;
    float es = e0 + e1;
    #pragma unroll
    for (int off = 32; off; off >>= 1) es += __shfl_xor(es, off);
    const float r = 1.f / es;
    w81[(size_t)m * 81 + l] = e0 * r;
    if (v1) w81[(size_t)m * 81 + 64 + l] = e1 * r;
}

// =====================================================================
// selected[m,d] = sum_f stacked[m,f,d] * w81[m,f]     grid Mc, 256 thr
// =====================================================================
__global__ __launch_bounds__(256) void selected_kernel(
    const float* __restrict__ stacked, const float* __restrict__ w81,
    float* __restrict__ sel)
{
    const int m = blockIdx.x;
    const int d = threadIdx.x & 63, fg = threadIdx.x >> 6;
    __shared__ float red[4][64];
    __shared__ float wsh[81];
    if (threadIdx.x < 81) wsh[threadIdx.x] = w81[(size_t)m * 81 + threadIdx.x];
    __syncthreads();
    float acc = 0.f;
    for (int f = fg; f < 81; f += 4)
        acc += stacked[(size_t)m * FDIM + f*64 + d] * wsh[f];
    red[fg][d] = acc;
    __syncthreads();
    if (fg == 0) sel[(size_t)m * 64 + d] = red[0][d] + red[1][d] + red[2][d] + red[3][d];
}

// =====================================================================
// LSTM prep: transpose wih/whh (torch [4H,in] -> [in,4H]), bias sum
// =====================================================================
__global__ void lstm_prep_kernel(
    const float* __restrict__ wih, const float* __restrict__ whh,
    const float* __restrict__ bih, const float* __restrict__ bhh,
    float* __restrict__ wihT, float* __restrict__ whhT, float* __restrict__ bsum)
{
    int id = blockIdx.x * 256 + threadIdx.x;
    if (id < 16384) {
        int i = id >> 8, j = id & 255;
        wihT[id] = wih[j*64 + i];
        whhT[id] = whh[j*64 + i];
    }
    if (id < 256) bsum[id] = bih[id] + bhh[id];
}

// =====================================================================
// LSTM recurrence: 4 batch rows per block, grid 128, 256 threads
// =====================================================================
__global__ __launch_bounds__(256) void lstm_kernel(
    const float* __restrict__ xW, const float* __restrict__ whhT,
    float* __restrict__ out)
{
    __shared__ float sh[4][64];
    __shared__ float sg[4][256];
    const int t = threadIdx.x;
    const int b0 = blockIdx.x * 4;
    const int rr = t >> 6, dd = t & 63;
    sh[rr][dd] = 0.f;
    float c_reg = 0.f;
    __syncthreads();
    for (int tt = 0; tt < TSEQ; ++tt) {
        float acc[4];
        #pragma unroll
        for (int r = 0; r < 4; ++r)
            acc[r] = xW[((size_t)(b0 + r) * TSEQ + tt) * 256 + t];
        for (int i = 0; i < 64; ++i) {
            float wvv = whhT[i*256 + t];
            #pragma unroll
            for (int r = 0; r < 4; ++r) acc[r] += sh[r][i] * wvv;
        }
        __syncthreads();
        #pragma unroll
        for (int r = 0; r < 4; ++r) sg[r][t] = acc[r];
        __syncthreads();
        {
            float gi = sg[rr][dd], gf = sg[rr][64 + dd], gg = sg[rr][128 + dd], go = sg[rr][192 + dd];
            c_reg = sigmoidf_(gf) * c_reg + sigmoidf_(gi) * tanhf(gg);
            float hn = sigmoidf_(go) * tanhf(c_reg);
            sh[rr][dd] = hn;
            out[((size_t)(b0 + rr) * TSEQ + tt) * 64 + dd] = hn;
        }
        __syncthreads();
    }
}

// =====================================================================
// out = LN( sigmoid(g1)*g2 + res )  per 64-wide row; one wave per row
// =====================================================================
__global__ __launch_bounds__(256) void glu_res_ln_kernel(
    const float* __restrict__ g1, const float* __restrict__ g2,
    const float* __restrict__ res,
    const float* __restrict__ gamma, const float* __restrict__ beta,
    float* __restrict__ out, int Mtot)
{
    const int wv = threadIdx.x >> 6, l = threadIdx.x & 63;
    const int m = blockIdx.x * 4 + wv;
    if (m >= Mtot) return;
    float a = g1[(size_t)m*64 + l], b = g2[(size_t)m*64 + l];
    float y = sigmoidf_(a) * b + res[(size_t)m*64 + l];
    float s = y;
    #pragma unroll
    for (int off = 32; off; off >>= 1) s += __shfl_xor(s, off);
    float mean = s * (1.f / 64.f);
    float d = y - mean, vs = d * d;
    #pragma unroll
    for (int off = 32; off; off >>= 1) vs += __shfl_xor(vs, off);
    float inv = rsqrtf(vs * (1.f / 64.f) + LN_EPS);
    out[(size_t)m*64 + l] = d * inv * gamma[l] + beta[l];
}

// =====================================================================
// MHA core: per batch block, wave per head (T=24, HD=16)
// =====================================================================
__global__ __launch_bounds__(256) void attn_kernel(
    const float* __restrict__ qkv, float* __restrict__ ao)
{
    const int b = blockIdx.x;
    const int h = threadIdx.x >> 6, l = threadIdx.x & 63;
    __shared__ float sq[4][24][16], sk[4][24][16], sv[4][24][16], sp[4][24][24];
    #pragma unroll
    for (int p = 0; p < 6; ++p) {
        int e = l + 64 * p; int ti = e >> 4, d = e & 15;
        size_t base = ((size_t)(b * TSEQ + ti)) * 192 + h * 16 + d;
        sq[h][ti][d] = qkv[base];
        sk[h][ti][d] = qkv[base + 64];
        sv[h][ti][d] = qkv[base + 128];
    }
    __syncthreads();
    #pragma unroll
    for (int p = 0; p < 9; ++p) {
        int e = l + 64 * p; int i = e / 24, j = e - i * 24;
        float s = 0.f;
        #pragma unroll
        for (int d = 0; d < 16; ++d) s += sq[h][i][d] * sk[h][j][d];
        sp[h][i][j] = s * 0.25f;   // 1/sqrt(16)
    }
    __syncthreads();
    if (l < 24) {
        float mx = -1e30f;
        for (int j = 0; j < 24; ++j) mx = fmaxf(mx, sp[h][l][j]);
        float s = 0.f;
        for (int j = 0; j < 24; ++j) { float e = expf(sp[h][l][j] - mx); sp[h][l][j] = e; s += e; }
        float inv = 1.f / s;
        for (int j = 0; j < 24; ++j) sp[h][l][j] *= inv;
    }
    __syncthreads();
    #pragma unroll
    for (int p = 0; p < 6; ++p) {
        int e = l + 64 * p; int ti = e >> 4, d = e & 15;
        float s = 0.f;
        #pragma unroll
        for (int j = 0; j < 24; ++j) s += sp[h][ti][j] * sv[h][j][d];
        ao[((size_t)(b * TSEQ + ti)) * 64 + h * 16 + d] = s;
    }
}

// =====================================================================
// mean over T
// =====================================================================
__global__ void pool_kernel(const float* __restrict__ outln, float* __restrict__ pooled)
{
    int id = blockIdx.x * 256 + threadIdx.x;
    if (id >= BB * 64) return;
    int b = id >> 6, d = id & 63;
    float s = 0.f;
    #pragma unroll
    for (int tt = 0; tt < TSEQ; ++tt) s += outln[((size_t)(b * TSEQ + tt)) * 64 + d];
    pooled[id] = s * (1.f / 24.f);
}

__global__ __launch_bounds__(64) void fc2_kernel(
    const float* __restrict__ fc1o, const float* __restrict__ w,
    const float* __restrict__ bias, float* __restrict__ out)
{
    const int b = blockIdx.x, l = threadIdx.x;
    float v = fc1o[(size_t)b * 64 + l];
    #pragma unroll
    for (int j = 0; j < 6; ++j) {
        float p = v * w[l * 6 + j];
        #pragma unroll
        for (int off = 32; off; off >>= 1) p += __shfl_xor(p, off);
        if (l == 0) out[b * 6 + j] = p + bias[j];
    }
}

// =====================================================================
extern "C" void kernel_launch(void* const* d_in, const int* in_sizes, int n_in,
                              void* d_out, int out_size, void* d_ws, size_t ws_size,
                              hipStream_t stream)
{
    const float* x        = (const float*)d_in[0];
    const float* f_w1     = (const float*)d_in[1];
    const float* f_b1     = (const float*)d_in[2];
    const float* f_w2     = (const float*)d_in[3];
    const float* f_b2     = (const float*)d_in[4];
    const float* f_g1w    = (const float*)d_in[5];
    const float* f_g1b    = (const float*)d_in[6];
    const float* f_g2w    = (const float*)d_in[7];
    const float* f_g2b    = (const float*)d_in[8];
    const float* f_skw    = (const float*)d_in[9];
    const float* f_skb    = (const float*)d_in[10];
    const float* f_lng    = (const float*)d_in[11];
    const float* f_lnb    = (const float*)d_in[12];
    const float* w_w1     = (const float*)d_in[13];
    const float* w_b1     = (const float*)d_in[14];
    const float* w_w2     = (const float*)d_in[15];
    const float* w_b2     = (const float*)d_in[16];
    const float* w_g1w    = (const float*)d_in[17];
    const float* w_g1b    = (const float*)d_in[18];
    const float* w_g2w    = (const float*)d_in[19];
    const float* w_g2b    = (const float*)d_in[20];
    const float* w_skw    = (const float*)d_in[21];
    const float* w_skb    = (const float*)d_in[22];
    const float* w_lng    = (const float*)d_in[23];
    const float* w_lnb    = (const float*)d_in[24];
    const float* lstm_wih = (const float*)d_in[25];
    const float* lstm_whh = (const float*)d_in[26];
    const float* lstm_bih = (const float*)d_in[27];
    const float* lstm_bhh = (const float*)d_in[28];
    const float* pl_g1w   = (const float*)d_in[29];
    const float* pl_g1b   = (const float*)d_in[30];
    const float* pl_g2w   = (const float*)d_in[31];
    const float* pl_g2b   = (const float*)d_in[32];
    const float* pl_lng   = (const float*)d_in[33];
    const float* pl_lnb   = (const float*)d_in[34];
    const float* attn_in_w  = (const float*)d_in[35];
    const float* attn_in_b  = (const float*)d_in[36];
    const float* attn_out_w = (const float*)d_in[37];
    const float* attn_out_b = (const float*)d_in[38];
    const float* pa_g1w   = (const float*)d_in[39];
    const float* pa_g1b   = (const float*)d_in[40];
    const float* pa_g2w   = (const float*)d_in[41];
    const float* pa_g2b   = (const float*)d_in[42];
    const float* pa_lng   = (const float*)d_in[43];
    const float* pa_lnb   = (const float*)d_in[44];
    const float* ff_w1    = (const float*)d_in[45];
    const float* ff_b1    = (const float*)d_in[46];
    const float* ff_w2    = (const float*)d_in[47];
    const float* ff_b2    = (const float*)d_in[48];
    const float* ff_g1w   = (const float*)d_in[49];
    const float* ff_g1b   = (const float*)d_in[50];
    const float* ff_g2w   = (const float*)d_in[51];
    const float* ff_g2b   = (const float*)d_in[52];
    const float* ff_lng   = (const float*)d_in[53];
    const float* ff_lnb   = (const float*)d_in[54];
    const float* fc1_w    = (const float*)d_in[55];
    const float* fc1_b    = (const float*)d_in[56];
    const float* fc2_w    = (const float*)d_in[57];
    const float* fc2_b    = (const float*)d_in[58];

    float* ws = (float*)d_ws;

    // ---------------- workspace layout (UNION region, slot-reused) -------
    // later-phase slots (laid out first; chunk buffer overlays the same region)
    size_t o = 0;
    const size_t o_S0   = o; o += (size_t)MTOT * 256;   // xW / qkv
    const size_t o_A    = o; o += (size_t)MTOT * 64;
    const size_t o_Bf   = o; o += (size_t)MTOT * 64;
    const size_t o_Cf   = o; o += (size_t)MTOT * 64;
    const size_t o_Df   = o; o += (size_t)MTOT * 64;
    const size_t o_F    = o; o += (size_t)MTOT * 128;   // ff 128-wide
    const size_t o_wihT = o; o += 16384;
    const size_t o_whhT = o; o += 16384;
    const size_t o_bsum = o; o += 256;
    const size_t o_pool = o; o += (size_t)BB * 64;
    const size_t o_fc1  = o; o += (size_t)BB * 64;
    const size_t union_end = o;                          // 7,962,880 floats
    // chunk-phase buffer overlays [0, union_end):  MC*FDIM = 7,962,624  (fits)
    const size_t o_chunk = 0;
    static_assert((size_t)MC * FDIM <= 7962880, "chunk must fit union");
    // persistent region after the union
    o = union_end;
    const size_t o_wh1c = o; o += (size_t)MC * 64;
    const size_t o_skc  = o; o += (size_t)MC * 81;
    const size_t o_w81c = o; o += (size_t)MC * 81;
    const size_t o_sel  = o; o += (size_t)MTOT * 64;
    const size_t need   = o;                             // ~9.10M floats = 36.4 MB
    if (ws_size < need * sizeof(float)) return;          // diagnostic guard

    const dim3 blk(256);

    // ---------------- phase 1: VSN + weight-GRN, chunked over M ----------
    for (int mb = 0; mb < MTOT; mb += MC) {
        // 1) VSN -> stacked chunk [MC, 5184]
        vsn_kernel<<<dim3(NF, MC / 64), blk, 0, stream>>>(
            x + (size_t)mb * NF, f_w1, f_b1, f_w2, f_b2, f_g1w, f_g1b,
            f_g2w, f_g2b, f_skw, f_skb, f_lng, f_lnb, ws + o_chunk);
        // 2) wh1 = elu(flat @ w_w1 + b1)
        gemm_kernel<<<dim3(MC / 32, 1), blk, 0, stream>>>(
            ws + o_chunk, w_w1, w_b1, ws + o_wh1c, MC, FDIM, 64, 1);
        // 3) sk81 = flat @ w_skw + skb
        gemm_kernel<<<dim3(MC / 32, 2), blk, 0, stream>>>(
            ws + o_chunk, w_skw, w_skb, ws + o_skc, MC, FDIM, 81, 0);
        // 4) weight-GRN tail -> softmax weights
        wtail_kernel<<<dim3(MC / 4), blk, 0, stream>>>(
            ws + o_wh1c, ws + o_skc, w_w2, w_b2, w_g1w, w_g1b, w_g2w, w_g2b,
            w_lng, w_lnb, ws + o_w81c);
        // 5) selected rows [mb, mb+MC)
        selected_kernel<<<dim3(MC), blk, 0, stream>>>(
            ws + o_chunk, ws + o_w81c, ws + o_sel + (size_t)mb * 64);
    }

    // ---------------- phase 2: LSTM -> attention -> head -----------------
    // 6) LSTM weight transpose + bias sum
    lstm_prep_kernel<<<dim3(64), blk, 0, stream>>>(
        lstm_wih, lstm_whh, lstm_bih, lstm_bhh,
        ws + o_wihT, ws + o_whhT, ws + o_bsum);
    // 7) xW = selected @ wihT + (bih+bhh)   -> S0
    gemm_kernel<<<dim3(MTOT / 32, 4), blk, 0, stream>>>(
        ws + o_sel, ws + o_wihT, ws + o_bsum, ws + o_S0, MTOT, 64, 256, 0);
    // 8) LSTM recurrence -> A
    lstm_kernel<<<dim3(BB / 4), blk, 0, stream>>>(
        ws + o_S0, ws + o_whhT, ws + o_A);
    // 9-11) post-LSTM GLU + residual(selected) + LN -> temporal (Df)
    gemm_kernel<<<dim3(MTOT / 32, 1), blk, 0, stream>>>(
        ws + o_A, pl_g1w, pl_g1b, ws + o_Bf, MTOT, 64, 64, 0);
    gemm_kernel<<<dim3(MTOT / 32, 1), blk, 0, stream>>>(
        ws + o_A, pl_g2w, pl_g2b, ws + o_Cf, MTOT, 64, 64, 0);
    glu_res_ln_kernel<<<dim3(MTOT / 4), blk, 0, stream>>>(
        ws + o_Bf, ws + o_Cf, ws + o_sel, pl_lng, pl_lnb, ws + o_Df, MTOT);
    // 12) qkv projection -> S0
    gemm_kernel<<<dim3(MTOT / 32, 3), blk, 0, stream>>>(
        ws + o_Df, attn_in_w, attn_in_b, ws + o_S0, MTOT, 64, 192, 0);
    // 13) attention core -> A
    attn_kernel<<<dim3(BB), blk, 0, stream>>>(ws + o_S0, ws + o_A);
    // 14) output projection -> Bf
    gemm_kernel<<<dim3(MTOT / 32, 1), blk, 0, stream>>>(
        ws + o_A, attn_out_w, attn_out_b, ws + o_Bf, MTOT, 64, 64, 0);
    // 15-17) post-attn GLU + residual(temporal=Df) + LN -> enriched (Bf)
    gemm_kernel<<<dim3(MTOT / 32, 1), blk, 0, stream>>>(
        ws + o_Bf, pa_g1w, pa_g1b, ws + o_A, MTOT, 64, 64, 0);
    gemm_kernel<<<dim3(MTOT / 32, 1), blk, 0, stream>>>(
        ws + o_Bf, pa_g2w, pa_g2b, ws + o_Cf, MTOT, 64, 64, 0);
    glu_res_ln_kernel<<<dim3(MTOT / 4), blk, 0, stream>>>(
        ws + o_A, ws + o_Cf, ws + o_Df, pa_lng, pa_lnb, ws + o_Bf, MTOT);
    // 18-22) FF GRN (identity skip): enriched = Bf
    gemm_kernel<<<dim3(MTOT / 32, 2), blk, 0, stream>>>(
        ws + o_Bf, ff_w1, ff_b1, ws + o_F, MTOT, 64, 128, 1);
    gemm_kernel<<<dim3(MTOT / 32, 1), blk, 0, stream>>>(
        ws + o_F, ff_w2, ff_b2, ws + o_A, MTOT, 128, 64, 0);
    gemm_kernel<<<dim3(MTOT / 32, 1), blk, 0, stream>>>(
        ws + o_A, ff_g1w, ff_g1b, ws + o_Cf, MTOT, 64, 64, 0);
    gemm_kernel<<<dim3(MTOT / 32, 1), blk, 0, stream>>>(
        ws + o_A, ff_g2w, ff_g2b, ws + o_Df, MTOT, 64, 64, 0);
    glu_res_ln_kernel<<<dim3(MTOT / 4), blk, 0, stream>>>(
        ws + o_Cf, ws + o_Df, ws + o_Bf, ff_lng, ff_lnb, ws + o_A, MTOT);
    // 23) temporal mean pool
    pool_kernel<<<dim3((BB * 64 + 255) / 256), blk, 0, stream>>>(
        ws + o_A, ws + o_pool);
    // 24) fc1 + relu
    gemm_kernel<<<dim3(BB / 32, 1), blk, 0, stream>>>(
        ws + o_pool, fc1_w, fc1_b, ws + o_fc1, BB, 64, 64, 2);
    // 25) fc2 -> output [512, 6]
    fc2_kernel<<<dim3(BB), dim3(64), 0, stream>>>(
        ws + o_fc1, fc2_w, fc2_b, (float*)d_out);
}

// Round 3
// 2022.459 us; speedup vs baseline: 5.6211x; 5.6211x over previous
//
#include <hip/hip_runtime.h>
#include <hip/hip_bf16.h>
#include <math.h>

// ---------------- problem constants ----------------
constexpr int BB   = 512;
constexpr int TSEQ = 24;
constexpr int NF   = 81;
constexpr int DD   = 64;
constexpr int MTOT = BB * TSEQ;      // 12288
constexpr int FDIM = NF * DD;        // 5184
constexpr int MC   = 1536;           // M-chunk for VSN phase (8 chunks)
constexpr int KS   = 9;              // split-K groups for weight-head GEMM
constexpr int FPG  = 9;              // features per group (9*9 = 81)
constexpr int PH   = 145;            // partial width: 64 (wh1) + 81 (sk)
constexpr float LN_EPS = 1e-5f;

static __device__ __forceinline__ float sigmoidf_(float x) { return 1.f / (1.f + expf(-x)); }
static __device__ __forceinline__ float eluf_(float x)     { return x > 0.f ? x : (expf(x) - 1.f); }

// =====================================================================
// Kernel 1: VSN — 81 per-feature GRNs -> stacked chunk [MC, NF*64] (bf16)
// grid (NF, MC/64), 256 threads. Thread tile 4x4 of a 64x64 output tile.
// =====================================================================
__global__ __launch_bounds__(256) void vsn_kernel(
    const float* __restrict__ x,
    const float* __restrict__ f_w1,  const float* __restrict__ f_b1,
    const float* __restrict__ f_w2,  const float* __restrict__ f_b2,
    const float* __restrict__ f_g1w, const float* __restrict__ f_g1b,
    const float* __restrict__ f_g2w, const float* __restrict__ f_g2b,
    const float* __restrict__ f_skw, const float* __restrict__ f_skb,
    const float* __restrict__ f_lng, const float* __restrict__ f_lnb,
    __hip_bfloat16* __restrict__ stacked)
{
    const int f  = blockIdx.x;
    const int m0 = blockIdx.y * 64;
    const int t  = threadIdx.x;
    const int tr = t >> 4;      // 0..15 row group
    const int tc = t & 15;      // 0..15 col group

    __shared__ __align__(16) float hA[64 * 68];   // h buffer (h0, then h1)
    __shared__ __align__(16) float Wt[64 * 68];   // transposed weight: Wt[c][i]
    __shared__ float vw1[64], vb1[64], vb2[64], vg1b[64], vg2b[64];
    __shared__ float vskw[64], vskb[64], vlng[64], vlnb[64], xv[64];

    if (t < 64) {
        vw1[t]  = f_w1 [f*64 + t];  vb1[t]  = f_b1 [f*64 + t];
        vb2[t]  = f_b2 [f*64 + t];
        vg1b[t] = f_g1b[f*64 + t];  vg2b[t] = f_g2b[f*64 + t];
        vskw[t] = f_skw[f*64 + t];  vskb[t] = f_skb[f*64 + t];
        vlng[t] = f_lng[f*64 + t];  vlnb[t] = f_lnb[f*64 + t];
        xv[t]   = x[(size_t)(m0 + t) * NF + f];
    }
    // stage Wt = f_w2[f] transposed
    {
        const float* w2p = f_w2 + (size_t)f * 4096;
        #pragma unroll
        for (int p = 0; p < 16; ++p) {
            int e = t + 256 * p; int i = e >> 6, c = e & 63;
            Wt[c*68 + i] = w2p[i*64 + c];
        }
    }
    __syncthreads();
    // h0 = elu(x*w1 + b1)
    #pragma unroll
    for (int p = 0; p < 16; ++p) {
        int e = t + 256 * p; int r = e >> 6, d = e & 63;
        hA[r*68 + d] = eluf_(xv[r] * vw1[d] + vb1[d]);
    }
    __syncthreads();

    // ---- matmul1: h1 = h0 @ w2 (+b2 at write) ----
    float acc1[4][4] = {};
    for (int i = 0; i < 64; i += 4) {
        float4 av[4], wv[4];
        #pragma unroll
        for (int j = 0; j < 4; ++j) av[j] = *(const float4*)&hA[(tr + 16*j)*68 + i];
        #pragma unroll
        for (int j = 0; j < 4; ++j) wv[j] = *(const float4*)&Wt[(tc + 16*j)*68 + i];
        #pragma unroll
        for (int a = 0; a < 4; ++a)
            #pragma unroll
            for (int b = 0; b < 4; ++b)
                acc1[a][b] += av[a].x*wv[b].x + av[a].y*wv[b].y + av[a].z*wv[b].z + av[a].w*wv[b].w;
    }
    __syncthreads();
    // write h1 back into hA ; stage g1w
    #pragma unroll
    for (int a = 0; a < 4; ++a)
        #pragma unroll
        for (int b = 0; b < 4; ++b)
            hA[(tr + 16*a)*68 + (tc + 16*b)] = acc1[a][b] + vb2[tc + 16*b];
    {
        const float* g1p = f_g1w + (size_t)f * 4096;
        #pragma unroll
        for (int p = 0; p < 16; ++p) {
            int e = t + 256 * p; int i = e >> 6, c = e & 63;
            Wt[c*68 + i] = g1p[i*64 + c];
        }
    }
    __syncthreads();

    // ---- matmul2: g1 = h1 @ g1w ----
    float accA[4][4] = {};
    for (int i = 0; i < 64; i += 4) {
        float4 av[4], wv[4];
        #pragma unroll
        for (int j = 0; j < 4; ++j) av[j] = *(const float4*)&hA[(tr + 16*j)*68 + i];
        #pragma unroll
        for (int j = 0; j < 4; ++j) wv[j] = *(const float4*)&Wt[(tc + 16*j)*68 + i];
        #pragma unroll
        for (int a = 0; a < 4; ++a)
            #pragma unroll
            for (int b = 0; b < 4; ++b)
                accA[a][b] += av[a].x*wv[b].x + av[a].y*wv[b].y + av[a].z*wv[b].z + av[a].w*wv[b].w;
    }
    __syncthreads();
    {
        const float* g2p = f_g2w + (size_t)f * 4096;
        #pragma unroll
        for (int p = 0; p < 16; ++p) {
            int e = t + 256 * p; int i = e >> 6, c = e & 63;
            Wt[c*68 + i] = g2p[i*64 + c];
        }
    }
    __syncthreads();

    // ---- matmul3: g2 = h1 @ g2w ----
    float accB[4][4] = {};
    for (int i = 0; i < 64; i += 4) {
        float4 av[4], wv[4];
        #pragma unroll
        for (int j = 0; j < 4; ++j) av[j] = *(const float4*)&hA[(tr + 16*j)*68 + i];
        #pragma unroll
        for (int j = 0; j < 4; ++j) wv[j] = *(const float4*)&Wt[(tc + 16*j)*68 + i];
        #pragma unroll
        for (int a = 0; a < 4; ++a)
            #pragma unroll
            for (int b = 0; b < 4; ++b)
                accB[a][b] += av[a].x*wv[b].x + av[a].y*wv[b].y + av[a].z*wv[b].z + av[a].w*wv[b].w;
    }

    // ---- GLU + skip + LayerNorm(64) + store (bf16) ----
    #pragma unroll
    for (int a = 0; a < 4; ++a) {
        const int r = tr + 16*a;
        float vals[4];
        float partial = 0.f;
        #pragma unroll
        for (int b = 0; b < 4; ++b) {
            const int c = tc + 16*b;
            float sg = sigmoidf_(accA[a][b] + vg1b[c]);
            float y  = sg * (accB[a][b] + vg2b[c]) + xv[r] * vskw[c] + vskb[c];
            vals[b] = y; partial += y;
        }
        #pragma unroll
        for (int off = 1; off < 16; off <<= 1) partial += __shfl_xor(partial, off);
        const float mean = partial * (1.f / 64.f);
        float vp = 0.f;
        #pragma unroll
        for (int b = 0; b < 4; ++b) { float d = vals[b] - mean; vp += d * d; }
        #pragma unroll
        for (int off = 1; off < 16; off <<= 1) vp += __shfl_xor(vp, off);
        const float inv = rsqrtf(vp * (1.f / 64.f) + LN_EPS);
        const size_t base = (size_t)(m0 + r) * FDIM + (size_t)f * 64;
        #pragma unroll
        for (int b = 0; b < 4; ++b) {
            const int c = tc + 16*b;
            stacked[base + c] = __float2bfloat16((vals[b] - mean) * inv * vlng[c] + vlnb[c]);
        }
    }
}

// =====================================================================
// Split-K fused weight-head GEMM:
// partial[ks][m][0:64]   = stacked[m, ks-slice] @ w_w1[ks-slice, :]
// partial[ks][m][64:145] = stacked[m, ks-slice] @ w_skw[ks-slice, :]
// grid (MC/32, KS), 256 threads. Thread tile 2x10 of a 32x160 output tile.
// =====================================================================
__global__ __launch_bounds__(256) void wgemm_kernel(
    const __hip_bfloat16* __restrict__ stacked,  // [MC, FDIM]
    const float* __restrict__ w_w1,              // [FDIM, 64]
    const float* __restrict__ w_skw,             // [FDIM, 81]
    float* __restrict__ partial)                 // [KS, MC, PH]
{
    __shared__ __align__(16) float As[32 * 68];
    __shared__ __align__(16) float Ws[160 * 68];  // transposed: Ws[c][i]
    const int t  = threadIdx.x;
    const int m0 = blockIdx.x * 32;
    const int ks = blockIdx.y;
    const int tr = t >> 4, tc = t & 15;

    float acc[2][10] = {};
    for (int f = ks * FPG; f < ks * FPG + FPG; ++f) {
        // stage A tile (32x64, bf16 -> f32)
        #pragma unroll
        for (int p = 0; p < 8; ++p) {
            int e = t + 256 * p; int r = e >> 6, i = e & 63;
            As[r*68 + i] = __bfloat162float(stacked[(size_t)(m0 + r) * FDIM + f*64 + i]);
        }
        // stage w_w1 slice (64x64) transposed -> rows 0..63
        #pragma unroll
        for (int p = 0; p < 16; ++p) {
            int e = t + 256 * p; int i = e >> 6, c = e & 63;
            Ws[c*68 + i] = w_w1[(size_t)(f*64 + i) * 64 + c];
        }
        // stage w_skw slice (64x81) transposed -> rows 64..144
        for (int e = t; e < 5184; e += 256) {
            int i = e / 81, c = e - i * 81;
            Ws[(64 + c)*68 + i] = w_skw[(size_t)(f*64 + i) * 81 + c];
        }
        __syncthreads();
        for (int i = 0; i < 64; i += 4) {
            float4 av[2], wv[10];
            av[0] = *(const float4*)&As[tr*68 + i];
            av[1] = *(const float4*)&As[(tr + 16)*68 + i];
            #pragma unroll
            for (int b = 0; b < 10; ++b) wv[b] = *(const float4*)&Ws[(tc + 16*b)*68 + i];
            #pragma unroll
            for (int a = 0; a < 2; ++a)
                #pragma unroll
                for (int b = 0; b < 10; ++b)
                    acc[a][b] += av[a].x*wv[b].x + av[a].y*wv[b].y + av[a].z*wv[b].z + av[a].w*wv[b].w;
        }
        __syncthreads();
    }
    #pragma unroll
    for (int a = 0; a < 2; ++a) {
        int m = m0 + tr + 16*a;
        #pragma unroll
        for (int b = 0; b < 10; ++b) {
            int c = tc + 16*b;
            if (c < PH) partial[((size_t)ks * MC + m) * PH + c] = acc[a][b];
        }
    }
}

// =====================================================================
// Weight-GRN tail: reduce split-K partials -> wh1(elu)/sk81, then
// wh2 -> GLU -> +skip -> LN(81) -> softmax -> w81.  One wave per row.
// =====================================================================
__global__ __launch_bounds__(256) void wtail_kernel(
    const float* __restrict__ partial,           // [KS, MC, PH]
    const float* __restrict__ w_b1,  const float* __restrict__ w_skb,
    const float* __restrict__ w_w2,  const float* __restrict__ w_b2,
    const float* __restrict__ w_g1w, const float* __restrict__ w_g1b,
    const float* __restrict__ w_g2w, const float* __restrict__ w_g2b,
    const float* __restrict__ w_lng, const float* __restrict__ w_lnb,
    float* __restrict__ w81)
{
    __shared__ float sWh[4][64];
    __shared__ float sW2[4][96];
    const int wv = threadIdx.x >> 6, l = threadIdx.x & 63;
    const int m = blockIdx.x * 4 + wv;
    const bool v1 = (l < 17);

    // ---- reduce split-K partials ----
    float s0  = w_b1[l];                    // wh1 pre-act, col l
    float sk0 = w_skb[l];                   // sk col l
    float sk1 = v1 ? w_skb[64 + l] : 0.f;   // sk col 64+l
    for (int ks = 0; ks < KS; ++ks) {
        const float* pr = partial + ((size_t)ks * MC + m) * PH;
        s0  += pr[l];
        sk0 += pr[64 + l];
        if (v1) sk1 += pr[128 + l];
    }
    sWh[wv][l] = eluf_(s0);
    __syncthreads();

    // ---- wh2 = wh1 @ w_w2 + b2  (64 -> 81) ----
    float acc0 = w_b2[l], acc1 = v1 ? w_b2[64 + l] : 0.f;
    for (int i = 0; i < 64; ++i) {
        float h = sWh[wv][i];
        acc0 += h * w_w2[i*81 + l];
        if (v1) acc1 += h * w_w2[i*81 + 64 + l];
    }
    sW2[wv][l] = acc0; if (v1) sW2[wv][64 + l] = acc1;
    __syncthreads();

    // ---- GLU (81 -> 81, two mats) ----
    float g10 = w_g1b[l], g20 = w_g2b[l];
    float g11 = v1 ? w_g1b[64 + l] : 0.f, g21 = v1 ? w_g2b[64 + l] : 0.f;
    for (int i = 0; i < 81; ++i) {
        float h = sW2[wv][i];
        g10 += h * w_g1w[i*81 + l];
        g20 += h * w_g2w[i*81 + l];
        if (v1) { g11 += h * w_g1w[i*81 + 64 + l]; g21 += h * w_g2w[i*81 + 64 + l]; }
    }
    float y0 = sigmoidf_(g10) * g20 + sk0;
    float y1 = v1 ? (sigmoidf_(g11) * g21 + sk1) : 0.f;

    // ---- LN(81) + softmax(81) ----
    float s = y0 + (v1 ? y1 : 0.f);
    #pragma unroll
    for (int off = 32; off; off >>= 1) s += __shfl_xor(s, off);
    const float mean = s / 81.f;
    float d0 = y0 - mean, d1 = v1 ? (y1 - mean) : 0.f;
    float vs = d0*d0 + (v1 ? d1*d1 : 0.f);
    #pragma unroll
    for (int off = 32; off; off >>= 1) vs += __shfl_xor(vs, off);
    const float inv = rsqrtf(vs / 81.f + LN_EPS);
    float wn0 = d0 * inv * w_lng[l] + w_lnb[l];
    float wn1 = v1 ? (d1 * inv * w_lng[64 + l] + w_lnb[64 + l]) : -1e30f;

    float mx = fmaxf(wn0, wn1);
    #pragma unroll
    for (int off = 32; off; off >>= 1) mx = fmaxf(mx, __shfl_xor(mx, off));
    float e0 = expf(wn0 - mx), e1 = v1 ? expf(wn1 - mx) : 0.f;
    float es = e0 + e1;
    #pragma unroll
    for (int off = 32; off; off >>= 1) es += __shfl_xor(es, off);
    const float r = 1.f / es;
    w81[(size_t)m * 81 + l] = e0 * r;
    if (v1) w81[(size_t)m * 81 + 64 + l] = e1 * r;
}

// =====================================================================
// selected[m,d] = sum_f stacked[m,f,d] * w81[m,f]     grid Mc, 256 thr
// =====================================================================
__global__ __launch_bounds__(256) void selected_kernel(
    const __hip_bfloat16* __restrict__ stacked, const float* __restrict__ w81,
    float* __restrict__ sel)
{
    const int m = blockIdx.x;
    const int d = threadIdx.x & 63, fg = threadIdx.x >> 6;
    __shared__ float red[4][64];
    __shared__ float wsh[81];
    if (threadIdx.x < 81) wsh[threadIdx.x] = w81[(size_t)m * 81 + threadIdx.x];
    __syncthreads();
    float acc = 0.f;
    for (int f = fg; f < 81; f += 4)
        acc += __bfloat162float(stacked[(size_t)m * FDIM + f*64 + d]) * wsh[f];
    red[fg][d] = acc;
    __syncthreads();
    if (fg == 0) sel[(size_t)m * 64 + d] = red[0][d] + red[1][d] + red[2][d] + red[3][d];
}

// =====================================================================
// Generic tiled fp32 GEMM: C[M,N] = act(A[M,K] @ W[K,N] + bias)
// 32x64 tile per block, 256 threads, thread tile 2x4. act: 0 none, 1 elu, 2 relu
// =====================================================================
__global__ __launch_bounds__(256) void gemm_kernel(
    const float* __restrict__ A, const float* __restrict__ W,
    const float* __restrict__ bias, float* __restrict__ C,
    int M, int K, int N, int act)
{
    __shared__ __align__(16) float As[32 * 68];
    __shared__ __align__(16) float Ws[64 * 68];   // transposed: Ws[c][i]
    const int t  = threadIdx.x;
    const int m0 = blockIdx.x * 32;
    const int n0 = blockIdx.y * 64;
    const int tr = t >> 4, tc = t & 15;

    float acc[2][4] = {};
    for (int k0 = 0; k0 < K; k0 += 64) {
        #pragma unroll
        for (int p = 0; p < 8; ++p) {
            int e = t + 256 * p; int r = e >> 6, i = e & 63;
            int gm = m0 + r, gk = k0 + i;
            As[r*68 + i] = (gm < M && gk < K) ? A[(size_t)gm * K + gk] : 0.f;
        }
        #pragma unroll
        for (int p = 0; p < 16; ++p) {
            int e = t + 256 * p; int i = e >> 6, c = e & 63;
            int gk = k0 + i, gn = n0 + c;
            Ws[c*68 + i] = (gk < K && gn < N) ? W[(size_t)gk * N + gn] : 0.f;
        }
        __syncthreads();
        for (int i = 0; i < 64; i += 4) {
            float4 av[2], wv[4];
            av[0] = *(const float4*)&As[tr*68 + i];
            av[1] = *(const float4*)&As[(tr + 16)*68 + i];
            #pragma unroll
            for (int j = 0; j < 4; ++j) wv[j] = *(const float4*)&Ws[(tc + 16*j)*68 + i];
            #pragma unroll
            for (int a = 0; a < 2; ++a)
                #pragma unroll
                for (int b = 0; b < 4; ++b)
                    acc[a][b] += av[a].x*wv[b].x + av[a].y*wv[b].y + av[a].z*wv[b].z + av[a].w*wv[b].w;
        }
        __syncthreads();
    }
    #pragma unroll
    for (int a = 0; a < 2; ++a) {
        int gm = m0 + tr + 16*a; if (gm >= M) continue;
        #pragma unroll
        for (int b = 0; b < 4; ++b) {
            int gn = n0 + tc + 16*b; if (gn >= N) continue;
            float v = acc[a][b] + bias[gn];
            if (act == 1) v = eluf_(v);
            else if (act == 2) v = fmaxf(v, 0.f);
            C[(size_t)gm * N + gn] = v;
        }
    }
}

// =====================================================================
// LSTM prep: transpose wih/whh (torch [4H,in] -> [in,4H]), bias sum
// =====================================================================
__global__ void lstm_prep_kernel(
    const float* __restrict__ wih, const float* __restrict__ whh,
    const float* __restrict__ bih, const float* __restrict__ bhh,
    float* __restrict__ wihT, float* __restrict__ whhT, float* __restrict__ bsum)
{
    int id = blockIdx.x * 256 + threadIdx.x;
    if (id < 16384) {
        int i = id >> 8, j = id & 255;
        wihT[id] = wih[j*64 + i];
        whhT[id] = whh[j*64 + i];
    }
    if (id < 256) bsum[id] = bih[id] + bhh[id];
}

// =====================================================================
// LSTM recurrence: 4 batch rows per block, grid 128, 256 threads
// =====================================================================
__global__ __launch_bounds__(256) void lstm_kernel(
    const float* __restrict__ xW, const float* __restrict__ whhT,
    float* __restrict__ out)
{
    __shared__ float sh[4][64];
    __shared__ float sg[4][256];
    const int t = threadIdx.x;
    const int b0 = blockIdx.x * 4;
    const int rr = t >> 6, dd = t & 63;
    sh[rr][dd] = 0.f;
    float c_reg = 0.f;
    __syncthreads();
    for (int tt = 0; tt < TSEQ; ++tt) {
        float acc[4];
        #pragma unroll
        for (int r = 0; r < 4; ++r)
            acc[r] = xW[((size_t)(b0 + r) * TSEQ + tt) * 256 + t];
        for (int i = 0; i < 64; ++i) {
            float wvv = whhT[i*256 + t];
            #pragma unroll
            for (int r = 0; r < 4; ++r) acc[r] += sh[r][i] * wvv;
        }
        __syncthreads();
        #pragma unroll
        for (int r = 0; r < 4; ++r) sg[r][t] = acc[r];
        __syncthreads();
        {
            float gi = sg[rr][dd], gf = sg[rr][64 + dd], gg = sg[rr][128 + dd], go = sg[rr][192 + dd];
            c_reg = sigmoidf_(gf) * c_reg + sigmoidf_(gi) * tanhf(gg);
            float hn = sigmoidf_(go) * tanhf(c_reg);
            sh[rr][dd] = hn;
            out[((size_t)(b0 + rr) * TSEQ + tt) * 64 + dd] = hn;
        }
        __syncthreads();
    }
}

// =====================================================================
// out = LN( sigmoid(g1)*g2 + res )  per 64-wide row; one wave per row
// =====================================================================
__global__ __launch_bounds__(256) void glu_res_ln_kernel(
    const float* __restrict__ g1, const float* __restrict__ g2,
    const float* __restrict__ res,
    const float* __restrict__ gamma, const float* __restrict__ beta,
    float* __restrict__ out, int Mtot)
{
    const int wv = threadIdx.x >> 6, l = threadIdx.x & 63;
    const int m = blockIdx.x * 4 + wv;
    if (m >= Mtot) return;
    float a = g1[(size_t)m*64 + l], b = g2[(size_t)m*64 + l];
    float y = sigmoidf_(a) * b + res[(size_t)m*64 + l];
    float s = y;
    #pragma unroll
    for (int off = 32; off; off >>= 1) s += __shfl_xor(s, off);
    float mean = s * (1.f / 64.f);
    float d = y - mean, vs = d * d;
    #pragma unroll
    for (int off = 32; off; off >>= 1) vs += __shfl_xor(vs, off);
    float inv = rsqrtf(vs * (1.f / 64.f) + LN_EPS);
    out[(size_t)m*64 + l] = d * inv * gamma[l] + beta[l];
}

// =====================================================================
// MHA core: per batch block, wave per head (T=24, HD=16)
// =====================================================================
__global__ __launch_bounds__(256) void attn_kernel(
    const float* __restrict__ qkv, float* __restrict__ ao)
{
    const int b = blockIdx.x;
    const int h = threadIdx.x >> 6, l = threadIdx.x & 63;
    __shared__ float sq[4][24][16], sk[4][24][16], sv[4][24][16], sp[4][24][24];
    #pragma unroll
    for (int p = 0; p < 6; ++p) {
        int e = l + 64 * p; int ti = e >> 4, d = e & 15;
        size_t base = ((size_t)(b * TSEQ + ti)) * 192 + h * 16 + d;
        sq[h][ti][d] = qkv[base];
        sk[h][ti][d] = qkv[base + 64];
        sv[h][ti][d] = qkv[base + 128];
    }
    __syncthreads();
    #pragma unroll
    for (int p = 0; p < 9; ++p) {
        int e = l + 64 * p; int i = e / 24, j = e - i * 24;
        float s = 0.f;
        #pragma unroll
        for (int d = 0; d < 16; ++d) s += sq[h][i][d] * sk[h][j][d];
        sp[h][i][j] = s * 0.25f;   // 1/sqrt(16)
    }
    __syncthreads();
    if (l < 24) {
        float mx = -1e30f;
        for (int j = 0; j < 24; ++j) mx = fmaxf(mx, sp[h][l][j]);
        float s = 0.f;
        for (int j = 0; j < 24; ++j) { float e = expf(sp[h][l][j] - mx); sp[h][l][j] = e; s += e; }
        float inv = 1.f / s;
        for (int j = 0; j < 24; ++j) sp[h][l][j] *= inv;
    }
    __syncthreads();
    #pragma unroll
    for (int p = 0; p < 6; ++p) {
        int e = l + 64 * p; int ti = e >> 4, d = e & 15;
        float s = 0.f;
        #pragma unroll
        for (int j = 0; j < 24; ++j) s += sp[h][ti][j] * sv[h][j][d];
        ao[((size_t)(b * TSEQ + ti)) * 64 + h * 16 + d] = s;
    }
}

// =====================================================================
// mean over T
// =====================================================================
__global__ void pool_kernel(const float* __restrict__ outln, float* __restrict__ pooled)
{
    int id = blockIdx.x * 256 + threadIdx.x;
    if (id >= BB * 64) return;
    int b = id >> 6, d = id & 63;
    float s = 0.f;
    #pragma unroll
    for (int tt = 0; tt < TSEQ; ++tt) s += outln[((size_t)(b * TSEQ + tt)) * 64 + d];
    pooled[id] = s * (1.f / 24.f);
}

__global__ __launch_bounds__(64) void fc2_kernel(
    const float* __restrict__ fc1o, const float* __restrict__ w,
    const float* __restrict__ bias, float* __restrict__ out)
{
    const int b = blockIdx.x, l = threadIdx.x;
    float v = fc1o[(size_t)b * 64 + l];
    #pragma unroll
    for (int j = 0; j < 6; ++j) {
        float p = v * w[l * 6 + j];
        #pragma unroll
        for (int off = 32; off; off >>= 1) p += __shfl_xor(p, off);
        if (l == 0) out[b * 6 + j] = p + bias[j];
    }
}

// =====================================================================
extern "C" void kernel_launch(void* const* d_in, const int* in_sizes, int n_in,
                              void* d_out, int out_size, void* d_ws, size_t ws_size,
                              hipStream_t stream)
{
    const float* x        = (const float*)d_in[0];
    const float* f_w1     = (const float*)d_in[1];
    const float* f_b1     = (const float*)d_in[2];
    const float* f_w2     = (const float*)d_in[3];
    const float* f_b2     = (const float*)d_in[4];
    const float* f_g1w    = (const float*)d_in[5];
    const float* f_g1b    = (const float*)d_in[6];
    const float* f_g2w    = (const float*)d_in[7];
    const float* f_g2b    = (const float*)d_in[8];
    const float* f_skw    = (const float*)d_in[9];
    const float* f_skb    = (const float*)d_in[10];
    const float* f_lng    = (const float*)d_in[11];
    const float* f_lnb    = (const float*)d_in[12];
    const float* w_w1     = (const float*)d_in[13];
    const float* w_b1     = (const float*)d_in[14];
    const float* w_w2     = (const float*)d_in[15];
    const float* w_b2     = (const float*)d_in[16];
    const float* w_g1w    = (const float*)d_in[17];
    const float* w_g1b    = (const float*)d_in[18];
    const float* w_g2w    = (const float*)d_in[19];
    const float* w_g2b    = (const float*)d_in[20];
    const float* w_skw    = (const float*)d_in[21];
    const float* w_skb    = (const float*)d_in[22];
    const float* w_lng    = (const float*)d_in[23];
    const float* w_lnb    = (const float*)d_in[24];
    const float* lstm_wih = (const float*)d_in[25];
    const float* lstm_whh = (const float*)d_in[26];
    const float* lstm_bih = (const float*)d_in[27];
    const float* lstm_bhh = (const float*)d_in[28];
    const float* pl_g1w   = (const float*)d_in[29];
    const float* pl_g1b   = (const float*)d_in[30];
    const float* pl_g2w   = (const float*)d_in[31];
    const float* pl_g2b   = (const float*)d_in[32];
    const float* pl_lng   = (const float*)d_in[33];
    const float* pl_lnb   = (const float*)d_in[34];
    const float* attn_in_w  = (const float*)d_in[35];
    const float* attn_in_b  = (const float*)d_in[36];
    const float* attn_out_w = (const float*)d_in[37];
    const float* attn_out_b = (const float*)d_in[38];
    const float* pa_g1w   = (const float*)d_in[39];
    const float* pa_g1b   = (const float*)d_in[40];
    const float* pa_g2w   = (const float*)d_in[41];
    const float* pa_g2b   = (const float*)d_in[42];
    const float* pa_lng   = (const float*)d_in[43];
    const float* pa_lnb   = (const float*)d_in[44];
    const float* ff_w1    = (const float*)d_in[45];
    const float* ff_b1    = (const float*)d_in[46];
    const float* ff_w2    = (const float*)d_in[47];
    const float* ff_b2    = (const float*)d_in[48];
    const float* ff_g1w   = (const float*)d_in[49];
    const float* ff_g1b   = (const float*)d_in[50];
    const float* ff_g2w   = (const float*)d_in[51];
    const float* ff_g2b   = (const float*)d_in[52];
    const float* ff_lng   = (const float*)d_in[53];
    const float* ff_lnb   = (const float*)d_in[54];
    const float* fc1_w    = (const float*)d_in[55];
    const float* fc1_b    = (const float*)d_in[56];
    const float* fc2_w    = (const float*)d_in[57];
    const float* fc2_b    = (const float*)d_in[58];

    float* ws = (float*)d_ws;

    // ---------------- workspace layout (UNION region, slot-reused) -------
    // phase-2 slots (the chunk-phase buffers overlay the same region)
    size_t o = 0;
    const size_t o_S0   = o; o += (size_t)MTOT * 256;   // xW / qkv
    const size_t o_A    = o; o += (size_t)MTOT * 64;
    const size_t o_Bf   = o; o += (size_t)MTOT * 64;
    const size_t o_Cf   = o; o += (size_t)MTOT * 64;
    const size_t o_Df   = o; o += (size_t)MTOT * 64;
    const size_t o_F    = o; o += (size_t)MTOT * 128;   // ff 128-wide
    const size_t o_wihT = o; o += 16384;
    const size_t o_whhT = o; o += 16384;
    const size_t o_bsum = o; o += 256;
    const size_t o_pool = o; o += (size_t)BB * 64;
    const size_t o_fc1  = o; o += (size_t)BB * 64;
    const size_t union_end = o;                          // 7,962,880 floats

    // chunk-phase overlay (inside the union):
    //   bf16 stacked chunk  [MC, FDIM]  = 3,981,312 float-equivalents
    //   split-K partials    [KS,MC,PH]  = 2,004,480 floats
    //   w81 chunk           [MC, 81]    =   124,416 floats
    const size_t o_partial = ((size_t)MC * FDIM) / 2;           // 3,981,312
    const size_t o_w81c    = o_partial + (size_t)KS * MC * PH;  // 5,985,792
    static_assert(((size_t)MC * FDIM) % 2 == 0, "bf16 chunk alignment");
    static_assert(5985792 + (size_t)MC * 81 <= 7962880, "chunk phase must fit union");

    // persistent region after the union
    o = union_end;
    const size_t o_sel  = o; o += (size_t)MTOT * 64;
    const size_t need   = o;                             // 8,749,312 floats = 35.0 MB
    if (ws_size < need * sizeof(float)) return;          // diagnostic guard

    const dim3 blk(256);

    // ---------------- phase 1: VSN + weight-GRN, chunked over M ----------
    for (int mb = 0; mb < MTOT; mb += MC) {
        __hip_bfloat16* chunk = (__hip_bfloat16*)ws;
        // 1) VSN -> stacked chunk [MC, 5184] bf16
        vsn_kernel<<<dim3(NF, MC / 64), blk, 0, stream>>>(
            x + (size_t)mb * NF, f_w1, f_b1, f_w2, f_b2, f_g1w, f_g1b,
            f_g2w, f_g2b, f_skw, f_skb, f_lng, f_lnb, chunk);
        // 2) split-K fused weight-head GEMM -> partials
        wgemm_kernel<<<dim3(MC / 32, KS), blk, 0, stream>>>(
            chunk, w_w1, w_skw, ws + o_partial);
        // 3) reduce + weight-GRN tail -> softmax weights
        wtail_kernel<<<dim3(MC / 4), blk, 0, stream>>>(
            ws + o_partial, w_b1, w_skb, w_w2, w_b2, w_g1w, w_g1b,
            w_g2w, w_g2b, w_lng, w_lnb, ws + o_w81c);
        // 4) selected rows [mb, mb+MC)
        selected_kernel<<<dim3(MC), blk, 0, stream>>>(
            chunk, ws + o_w81c, ws + o_sel + (size_t)mb * 64);
    }

    // ---------------- phase 2: LSTM -> attention -> head -----------------
    lstm_prep_kernel<<<dim3(64), blk, 0, stream>>>(
        lstm_wih, lstm_whh, lstm_bih, lstm_bhh,
        ws + o_wihT, ws + o_whhT, ws + o_bsum);
    gemm_kernel<<<dim3(MTOT / 32, 4), blk, 0, stream>>>(
        ws + o_sel, ws + o_wihT, ws + o_bsum, ws + o_S0, MTOT, 64, 256, 0);
    lstm_kernel<<<dim3(BB / 4), blk, 0, stream>>>(
        ws + o_S0, ws + o_whhT, ws + o_A);
    gemm_kernel<<<dim3(MTOT / 32, 1), blk, 0, stream>>>(
        ws + o_A, pl_g1w, pl_g1b, ws + o_Bf, MTOT, 64, 64, 0);
    gemm_kernel<<<dim3(MTOT / 32, 1), blk, 0, stream>>>(
        ws + o_A, pl_g2w, pl_g2b, ws + o_Cf, MTOT, 64, 64, 0);
    glu_res_ln_kernel<<<dim3(MTOT / 4), blk, 0, stream>>>(
        ws + o_Bf, ws + o_Cf, ws + o_sel, pl_lng, pl_lnb, ws + o_Df, MTOT);
    gemm_kernel<<<dim3(MTOT / 32, 3), blk, 0, stream>>>(
        ws + o_Df, attn_in_w, attn_in_b, ws + o_S0, MTOT, 64, 192, 0);
    attn_kernel<<<dim3(BB), blk, 0, stream>>>(ws + o_S0, ws + o_A);
    gemm_kernel<<<dim3(MTOT / 32, 1), blk, 0, stream>>>(
        ws + o_A, attn_out_w, attn_out_b, ws + o_Bf, MTOT, 64, 64, 0);
    gemm_kernel<<<dim3(MTOT / 32, 1), blk, 0, stream>>>(
        ws + o_Bf, pa_g1w, pa_g1b, ws + o_A, MTOT, 64, 64, 0);
    gemm_kernel<<<dim3(MTOT / 32, 1), blk, 0, stream>>>(
        ws + o_Bf, pa_g2w, pa_g2b, ws + o_Cf, MTOT, 64, 64, 0);
    glu_res_ln_kernel<<<dim3(MTOT / 4), blk, 0, stream>>>(
        ws + o_A, ws + o_Cf, ws + o_Df, pa_lng, pa_lnb, ws + o_Bf, MTOT);
    gemm_kernel<<<dim3(MTOT / 32, 2), blk, 0, stream>>>(
        ws + o_Bf, ff_w1, ff_b1, ws + o_F, MTOT, 64, 128, 1);
    gemm_kernel<<<dim3(MTOT / 32, 1), blk, 0, stream>>>(
        ws + o_F, ff_w2, ff_b2, ws + o_A, MTOT, 128, 64, 0);
    gemm_kernel<<<dim3(MTOT / 32, 1), blk, 0, stream>>>(
        ws + o_A, ff_g1w, ff_g1b, ws + o_Cf, MTOT, 64, 64, 0);
    gemm_kernel<<<dim3(MTOT / 32, 1), blk, 0, stream>>>(
        ws + o_A, ff_g2w, ff_g2b, ws + o_Df, MTOT, 64, 64, 0);
    glu_res_ln_kernel<<<dim3(MTOT / 4), blk, 0, stream>>>(
        ws + o_Cf, ws + o_Df, ws + o_Bf, ff_lng, ff_lnb, ws + o_A, MTOT);
    pool_kernel<<<dim3((BB * 64 + 255) / 256), blk, 0, stream>>>(
        ws + o_A, ws + o_pool);
    gemm_kernel<<<dim3(BB / 32, 1), blk, 0, stream>>>(
        ws + o_pool, fc1_w, fc1_b, ws + o_fc1, BB, 64, 64, 2);
    fc2_kernel<<<dim3(BB), dim3(64), 0, stream>>>(
        ws + o_fc1, fc2_w, fc2_b, (float*)d_out);
}

// Round 4
// 1373.193 us; speedup vs baseline: 8.2788x; 1.4728x over previous
//
#include <hip/hip_runtime.h>
#include <hip/hip_bf16.h>
#include <math.h>

// ---------------- problem constants ----------------
constexpr int BB   = 512;
constexpr int TSEQ = 24;
constexpr int NF   = 81;
constexpr int DD   = 64;
constexpr int MTOT = BB * TSEQ;      // 12288
constexpr int FDIM = NF * DD;        // 5184
constexpr int MC   = 1536;           // M-chunk for VSN phase (8 chunks)
constexpr int KS   = 9;              // split-K groups for weight-head GEMM
constexpr int NW   = 160;            // padded combined N: 64 (wh1) + 81 (sk) + 15 pad
constexpr float LN_EPS = 1e-5f;

typedef __attribute__((ext_vector_type(8))) short short8v;   // 8 bf16 (4 VGPRs)
typedef __attribute__((ext_vector_type(4))) float f32x4;     // MFMA C/D

static __device__ __forceinline__ float sigmoidf_(float x) { return 1.f / (1.f + expf(-x)); }
static __device__ __forceinline__ float eluf_(float x)     { return x > 0.f ? x : (expf(x) - 1.f); }
static __device__ __forceinline__ unsigned short f2bf(float x) {
    __hip_bfloat16 h = __float2bfloat16(x);
    return *reinterpret_cast<unsigned short*>(&h);
}

// =====================================================================
// Kernel 1: VSN — 81 per-feature GRNs -> stacked chunk [MC, NF*64] (bf16)
// grid (NF, MC/64), 256 threads = 4 waves.
// MFMA 16x16x32 bf16; wave w owns cols [w*16, w*16+16), 4 row-frags.
// Layouts (HW-verified): A[r=l&15][k=(l>>4)*8+j]; B[k=(l>>4)*8+j][c=l&15];
//                        D[r=(l>>4)*4+j][c=l&15].
// =====================================================================
__global__ __launch_bounds__(256) void vsn_kernel(
    const float* __restrict__ x,
    const float* __restrict__ f_w1,  const float* __restrict__ f_b1,
    const float* __restrict__ f_w2,  const float* __restrict__ f_b2,
    const float* __restrict__ f_g1w, const float* __restrict__ f_g1b,
    const float* __restrict__ f_g2w, const float* __restrict__ f_g2b,
    const float* __restrict__ f_skw, const float* __restrict__ f_skb,
    const float* __restrict__ f_lng, const float* __restrict__ f_lnb,
    __hip_bfloat16* __restrict__ stacked)
{
    const int f  = blockIdx.x;
    const int m0 = blockIdx.y * 64;
    const int t  = threadIdx.x;
    const int w  = t >> 6;       // wave 0..3  -> col-frag
    const int l  = t & 63;       // lane
    const int lr = l & 15;       // row/col within fragment
    const int lg = l >> 4;       // k-group / D-row-group

    __shared__ __align__(16) unsigned short hA[64 * 72];   // h0 then h1 (bf16, pitch 72)
    __shared__ __align__(16) unsigned char  uS[18432];     // Wt0[9216] + Wt1[9216]  OR  yA[64*68 f32]
    __shared__ float vw1[64], vb1[64], vb2[64], vg1b[64], vg2b[64];
    __shared__ float vskw[64], vskb[64], vlng[64], vlnb[64], xv[64];

    unsigned short* Wt0 = (unsigned short*)uS;             // [64][72]
    unsigned short* Wt1 = (unsigned short*)(uS + 9216);    // [64][72]
    float*          yA  = (float*)uS;                      // [64][68] (after matmuls)

    if (t < 64) {
        vw1[t]  = f_w1 [f*64 + t];  vb1[t]  = f_b1 [f*64 + t];
        vb2[t]  = f_b2 [f*64 + t];
        vg1b[t] = f_g1b[f*64 + t];  vg2b[t] = f_g2b[f*64 + t];
        vskw[t] = f_skw[f*64 + t];  vskb[t] = f_skb[f*64 + t];
        vlng[t] = f_lng[f*64 + t];  vlnb[t] = f_lnb[f*64 + t];
        xv[t]   = x[(size_t)(m0 + t) * NF + f];
    }
    __syncthreads();   // xv ready (needed by h0)

    // stage Wt0 <- w2^T (bf16) ; h0 = elu(x*w1 + b1) -> hA (bf16)
    {
        const float* w2p = f_w2 + (size_t)f * 4096;
        #pragma unroll
        for (int p = 0; p < 16; ++p) {
            int e = t + 256 * p; int k = e >> 6, c = e & 63;
            Wt0[c*72 + k] = f2bf(w2p[k*64 + c]);
        }
        #pragma unroll
        for (int p = 0; p < 16; ++p) {
            int e = t + 256 * p; int r = e >> 6, d = e & 63;
            hA[r*72 + d] = f2bf(eluf_(xv[r] * vw1[d] + vb1[d]));
        }
    }
    __syncthreads();   // hA(h0), Wt0(w2t) ready

    // ---- mm1: h1 = h0 @ w2 ----
    f32x4 acc1[4];
    #pragma unroll
    for (int rg = 0; rg < 4; ++rg) acc1[rg] = (f32x4){0.f, 0.f, 0.f, 0.f};
    #pragma unroll
    for (int ks = 0; ks < 2; ++ks) {
        short8v bf = *(const short8v*)&Wt0[(w*16 + lr)*72 + ks*32 + lg*8];
        #pragma unroll
        for (int rg = 0; rg < 4; ++rg) {
            short8v af = *(const short8v*)&hA[(rg*16 + lr)*72 + ks*32 + lg*8];
            acc1[rg] = __builtin_amdgcn_mfma_f32_16x16x32_bf16(af, bf, acc1[rg], 0, 0, 0);
        }
    }
    // stage Wt1 <- g1w^T (independent of mm1 operands)
    {
        const float* g1p = f_g1w + (size_t)f * 4096;
        #pragma unroll
        for (int p = 0; p < 16; ++p) {
            int e = t + 256 * p; int k = e >> 6, c = e & 63;
            Wt1[c*72 + k] = f2bf(g1p[k*64 + c]);
        }
    }
    __syncthreads();   // all reads of hA(h0)/Wt0 done; Wt1 ready

    // write h1 (+b2) -> hA (bf16) ; stage Wt0 <- g2w^T
    #pragma unroll
    for (int rg = 0; rg < 4; ++rg)
        #pragma unroll
        for (int j = 0; j < 4; ++j) {
            int r = rg*16 + lg*4 + j, c = w*16 + lr;
            hA[r*72 + c] = f2bf(acc1[rg][j] + vb2[c]);
        }
    {
        const float* g2p = f_g2w + (size_t)f * 4096;
        #pragma unroll
        for (int p = 0; p < 16; ++p) {
            int e = t + 256 * p; int k = e >> 6, c = e & 63;
            Wt0[c*72 + k] = f2bf(g2p[k*64 + c]);
        }
    }
    __syncthreads();   // hA(h1), Wt0(g2wt), Wt1(g1wt) ready

    // ---- mm2: g1 = h1 @ g1w ; mm3: g2 = h1 @ g2w ----
    f32x4 aA[4], aB[4];
    #pragma unroll
    for (int rg = 0; rg < 4; ++rg) { aA[rg] = (f32x4){0.f,0.f,0.f,0.f}; aB[rg] = (f32x4){0.f,0.f,0.f,0.f}; }
    #pragma unroll
    for (int ks = 0; ks < 2; ++ks) {
        short8v b1f = *(const short8v*)&Wt1[(w*16 + lr)*72 + ks*32 + lg*8];
        short8v b2f = *(const short8v*)&Wt0[(w*16 + lr)*72 + ks*32 + lg*8];
        #pragma unroll
        for (int rg = 0; rg < 4; ++rg) {
            short8v af = *(const short8v*)&hA[(rg*16 + lr)*72 + ks*32 + lg*8];
            aA[rg] = __builtin_amdgcn_mfma_f32_16x16x32_bf16(af, b1f, aA[rg], 0, 0, 0);
            aB[rg] = __builtin_amdgcn_mfma_f32_16x16x32_bf16(af, b2f, aB[rg], 0, 0, 0);
        }
    }
    __syncthreads();   // Wt buffers dead -> reuse as yA

    // ---- GLU + skip -> yA (f32) ----
    #pragma unroll
    for (int rg = 0; rg < 4; ++rg)
        #pragma unroll
        for (int j = 0; j < 4; ++j) {
            int r = rg*16 + lg*4 + j, c = w*16 + lr;
            float sg = sigmoidf_(aA[rg][j] + vg1b[c]);
            float y  = sg * (aB[rg][j] + vg2b[c]) + xv[r] * vskw[c] + vskb[c];
            yA[r*68 + c] = y;
        }
    __syncthreads();

    // ---- LayerNorm(64) + bf16 store ----
    const int tr = t >> 4, tc = t & 15;
    #pragma unroll
    for (int a = 0; a < 4; ++a) {
        const int r = tr + 16*a;
        float vals[4];
        float part = 0.f;
        #pragma unroll
        for (int b = 0; b < 4; ++b) { vals[b] = yA[r*68 + tc + 16*b]; part += vals[b]; }
        #pragma unroll
        for (int off = 1; off < 16; off <<= 1) part += __shfl_xor(part, off);
        const float mean = part * (1.f / 64.f);
        float vp = 0.f;
        #pragma unroll
        for (int b = 0; b < 4; ++b) { float d = vals[b] - mean; vp += d * d; }
        #pragma unroll
        for (int off = 1; off < 16; off <<= 1) vp += __shfl_xor(vp, off);
        const float inv = rsqrtf(vp * (1.f / 64.f) + LN_EPS);
        const size_t base = (size_t)(m0 + r) * FDIM + (size_t)f * 64;
        #pragma unroll
        for (int b = 0; b < 4; ++b) {
            const int c = tc + 16*b;
            stacked[base + c] = __float2bfloat16((vals[b] - mean) * inv * vlng[c] + vlnb[c]);
        }
    }
}

// =====================================================================
// Pack w_w1 (FDIM x 64) and w_skw (FDIM x 81) into bf16 WcatT[160][FDIM]
// (transposed so B-fragments are contiguous in K). cols 145..159 = 0.
// =====================================================================
__global__ void wprep_kernel(
    const float* __restrict__ w_w1, const float* __restrict__ w_skw,
    unsigned short* __restrict__ WcatT)
{
    const int c = blockIdx.y;
    const int k = blockIdx.x * 256 + threadIdx.x;
    if (k >= FDIM) return;
    float v = 0.f;
    if (c < 64)       v = w_w1[(size_t)k * 64 + c];
    else if (c < 145) v = w_skw[(size_t)k * 81 + (c - 64)];
    WcatT[(size_t)c * FDIM + k] = f2bf(v);
}

// =====================================================================
// Split-K fused weight-head GEMM (MFMA, LDS-free):
// partial[ks][m][c] = stacked[m, ks-slice] @ Wcat[ks-slice, c]
// grid (MC/16, KS), 64 threads (1 wave). Wave: 16 rows x 160 cols, K=576.
// =====================================================================
__global__ __launch_bounds__(64) void wgemm_kernel(
    const __hip_bfloat16* __restrict__ stacked,  // [MC][FDIM] bf16
    const unsigned short* __restrict__ WcatT,    // [160][FDIM] bf16
    float* __restrict__ partial)                 // [KS][MC][160]
{
    const int m0 = blockIdx.x * 16;
    const int ks = blockIdx.y;
    const int l  = threadIdx.x;
    const int lr = l & 15, lg = l >> 4;

    f32x4 acc[10];
    #pragma unroll
    for (int n = 0; n < 10; ++n) acc[n] = (f32x4){0.f, 0.f, 0.f, 0.f};

    const size_t arow = (size_t)(m0 + lr) * FDIM;
    const int k0base = ks * 576;
    for (int kk = 0; kk < 576; kk += 32) {
        const int k = k0base + kk + lg * 8;
        short8v af = *(const short8v*)(stacked + arow + k);
        #pragma unroll
        for (int n = 0; n < 10; ++n) {
            short8v bf = *(const short8v*)(WcatT + (size_t)(n*16 + lr) * FDIM + k);
            acc[n] = __builtin_amdgcn_mfma_f32_16x16x32_bf16(af, bf, acc[n], 0, 0, 0);
        }
    }
    #pragma unroll
    for (int n = 0; n < 10; ++n)
        #pragma unroll
        for (int j = 0; j < 4; ++j) {
            const int m = m0 + lg*4 + j;
            partial[((size_t)ks * MC + m) * NW + n*16 + lr] = acc[n][j];
        }
}

// =====================================================================
// Weight-GRN tail: reduce split-K partials -> wh1(elu)/sk81, then
// wh2 -> GLU -> +skip -> LN(81) -> softmax -> w81.  One wave per row.
// =====================================================================
__global__ __launch_bounds__(256) void wtail_kernel(
    const float* __restrict__ partial,           // [KS, MC, NW]
    const float* __restrict__ w_b1,  const float* __restrict__ w_skb,
    const float* __restrict__ w_w2,  const float* __restrict__ w_b2,
    const float* __restrict__ w_g1w, const float* __restrict__ w_g1b,
    const float* __restrict__ w_g2w, const float* __restrict__ w_g2b,
    const float* __restrict__ w_lng, const float* __restrict__ w_lnb,
    float* __restrict__ w81)
{
    __shared__ float sWh[4][64];
    __shared__ float sW2[4][96];
    const int wv = threadIdx.x >> 6, l = threadIdx.x & 63;
    const int m = blockIdx.x * 4 + wv;
    const bool v1 = (l < 17);

    // ---- reduce split-K partials ----
    float s0  = w_b1[l];
    float sk0 = w_skb[l];
    float sk1 = v1 ? w_skb[64 + l] : 0.f;
    for (int ks = 0; ks < KS; ++ks) {
        const float* pr = partial + ((size_t)ks * MC + m) * NW;
        s0  += pr[l];
        sk0 += pr[64 + l];
        if (v1) sk1 += pr[128 + l];
    }
    sWh[wv][l] = eluf_(s0);
    __syncthreads();

    // ---- wh2 = wh1 @ w_w2 + b2  (64 -> 81) ----
    float acc0 = w_b2[l], acc1 = v1 ? w_b2[64 + l] : 0.f;
    for (int i = 0; i < 64; ++i) {
        float h = sWh[wv][i];
        acc0 += h * w_w2[i*81 + l];
        if (v1) acc1 += h * w_w2[i*81 + 64 + l];
    }
    sW2[wv][l] = acc0; if (v1) sW2[wv][64 + l] = acc1;
    __syncthreads();

    // ---- GLU (81 -> 81, two mats) ----
    float g10 = w_g1b[l], g20 = w_g2b[l];
    float g11 = v1 ? w_g1b[64 + l] : 0.f, g21 = v1 ? w_g2b[64 + l] : 0.f;
    for (int i = 0; i < 81; ++i) {
        float h = sW2[wv][i];
        g10 += h * w_g1w[i*81 + l];
        g20 += h * w_g2w[i*81 + l];
        if (v1) { g11 += h * w_g1w[i*81 + 64 + l]; g21 += h * w_g2w[i*81 + 64 + l]; }
    }
    float y0 = sigmoidf_(g10) * g20 + sk0;
    float y1 = v1 ? (sigmoidf_(g11) * g21 + sk1) : 0.f;

    // ---- LN(81) + softmax(81) ----
    float s = y0 + (v1 ? y1 : 0.f);
    #pragma unroll
    for (int off = 32; off; off >>= 1) s += __shfl_xor(s, off);
    const float mean = s / 81.f;
    float d0 = y0 - mean, d1 = v1 ? (y1 - mean) : 0.f;
    float vs = d0*d0 + (v1 ? d1*d1 : 0.f);
    #pragma unroll
    for (int off = 32; off; off >>= 1) vs += __shfl_xor(vs, off);
    const float inv = rsqrtf(vs / 81.f + LN_EPS);
    float wn0 = d0 * inv * w_lng[l] + w_lnb[l];
    float wn1 = v1 ? (d1 * inv * w_lng[64 + l] + w_lnb[64 + l]) : -1e30f;

    float mx = fmaxf(wn0, wn1);
    #pragma unroll
    for (int off = 32; off; off >>= 1) mx = fmaxf(mx, __shfl_xor(mx, off));
    float e0 = expf(wn0 - mx), e1 = v1 ? expf(wn1 - mx) : 0.f;
    float es = e0 + e1;
    #pragma unroll
    for (int off = 32; off; off >>= 1) es += __shfl_xor(es, off);
    const float r = 1.f / es;
    w81[(size_t)m * 81 + l] = e0 * r;
    if (v1) w81[(size_t)m * 81 + 64 + l] = e1 * r;
}

// =====================================================================
// selected[m,d] = sum_f stacked[m,f,d] * w81[m,f]     grid Mc, 256 thr
// =====================================================================
__global__ __launch_bounds__(256) void selected_kernel(
    const __hip_bfloat16* __restrict__ stacked, const float* __restrict__ w81,
    float* __restrict__ sel)
{
    const int m = blockIdx.x;
    const int d = threadIdx.x & 63, fg = threadIdx.x >> 6;
    __shared__ float red[4][64];
    __shared__ float wsh[81];
    if (threadIdx.x < 81) wsh[threadIdx.x] = w81[(size_t)m * 81 + threadIdx.x];
    __syncthreads();
    float acc = 0.f;
    for (int f = fg; f < 81; f += 4)
        acc += __bfloat162float(stacked[(size_t)m * FDIM + f*64 + d]) * wsh[f];
    red[fg][d] = acc;
    __syncthreads();
    if (fg == 0) sel[(size_t)m * 64 + d] = red[0][d] + red[1][d] + red[2][d] + red[3][d];
}

// =====================================================================
// Generic tiled fp32 GEMM: C[M,N] = act(A[M,K] @ W[K,N] + bias)
// =====================================================================
__global__ __launch_bounds__(256) void gemm_kernel(
    const float* __restrict__ A, const float* __restrict__ W,
    const float* __restrict__ bias, float* __restrict__ C,
    int M, int K, int N, int act)
{
    __shared__ __align__(16) float As[32 * 68];
    __shared__ __align__(16) float Ws[64 * 68];   // transposed: Ws[c][i]
    const int t  = threadIdx.x;
    const int m0 = blockIdx.x * 32;
    const int n0 = blockIdx.y * 64;
    const int tr = t >> 4, tc = t & 15;

    float acc[2][4] = {};
    for (int k0 = 0; k0 < K; k0 += 64) {
        #pragma unroll
        for (int p = 0; p < 8; ++p) {
            int e = t + 256 * p; int r = e >> 6, i = e & 63;
            int gm = m0 + r, gk = k0 + i;
            As[r*68 + i] = (gm < M && gk < K) ? A[(size_t)gm * K + gk] : 0.f;
        }
        #pragma unroll
        for (int p = 0; p < 16; ++p) {
            int e = t + 256 * p; int i = e >> 6, c = e & 63;
            int gk = k0 + i, gn = n0 + c;
            Ws[c*68 + i] = (gk < K && gn < N) ? W[(size_t)gk * N + gn] : 0.f;
        }
        __syncthreads();
        for (int i = 0; i < 64; i += 4) {
            float4 av[2], wv[4];
            av[0] = *(const float4*)&As[tr*68 + i];
            av[1] = *(const float4*)&As[(tr + 16)*68 + i];
            #pragma unroll
            for (int j = 0; j < 4; ++j) wv[j] = *(const float4*)&Ws[(tc + 16*j)*68 + i];
            #pragma unroll
            for (int a = 0; a < 2; ++a)
                #pragma unroll
                for (int b = 0; b < 4; ++b)
                    acc[a][b] += av[a].x*wv[b].x + av[a].y*wv[b].y + av[a].z*wv[b].z + av[a].w*wv[b].w;
        }
        __syncthreads();
    }
    #pragma unroll
    for (int a = 0; a < 2; ++a) {
        int gm = m0 + tr + 16*a; if (gm >= M) continue;
        #pragma unroll
        for (int b = 0; b < 4; ++b) {
            int gn = n0 + tc + 16*b; if (gn >= N) continue;
            float v = acc[a][b] + bias[gn];
            if (act == 1) v = eluf_(v);
            else if (act == 2) v = fmaxf(v, 0.f);
            C[(size_t)gm * N + gn] = v;
        }
    }
}

// =====================================================================
// LSTM prep: transpose wih/whh (torch [4H,in] -> [in,4H]), bias sum
// =====================================================================
__global__ void lstm_prep_kernel(
    const float* __restrict__ wih, const float* __restrict__ whh,
    const float* __restrict__ bih, const float* __restrict__ bhh,
    float* __restrict__ wihT, float* __restrict__ whhT, float* __restrict__ bsum)
{
    int id = blockIdx.x * 256 + threadIdx.x;
    if (id < 16384) {
        int i = id >> 8, j = id & 255;
        wihT[id] = wih[j*64 + i];
        whhT[id] = whh[j*64 + i];
    }
    if (id < 256) bsum[id] = bih[id] + bhh[id];
}

// =====================================================================
// LSTM recurrence: 4 batch rows per block, grid 128, 256 threads
// =====================================================================
__global__ __launch_bounds__(256) void lstm_kernel(
    const float* __restrict__ xW, const float* __restrict__ whhT,
    float* __restrict__ out)
{
    __shared__ float sh[4][64];
    __shared__ float sg[4][256];
    const int t = threadIdx.x;
    const int b0 = blockIdx.x * 4;
    const int rr = t >> 6, dd = t & 63;
    sh[rr][dd] = 0.f;
    float c_reg = 0.f;
    __syncthreads();
    for (int tt = 0; tt < TSEQ; ++tt) {
        float acc[4];
        #pragma unroll
        for (int r = 0; r < 4; ++r)
            acc[r] = xW[((size_t)(b0 + r) * TSEQ + tt) * 256 + t];
        for (int i = 0; i < 64; ++i) {
            float wvv = whhT[i*256 + t];
            #pragma unroll
            for (int r = 0; r < 4; ++r) acc[r] += sh[r][i] * wvv;
        }
        __syncthreads();
        #pragma unroll
        for (int r = 0; r < 4; ++r) sg[r][t] = acc[r];
        __syncthreads();
        {
            float gi = sg[rr][dd], gf = sg[rr][64 + dd], gg = sg[rr][128 + dd], go = sg[rr][192 + dd];
            c_reg = sigmoidf_(gf) * c_reg + sigmoidf_(gi) * tanhf(gg);
            float hn = sigmoidf_(go) * tanhf(c_reg);
            sh[rr][dd] = hn;
            out[((size_t)(b0 + rr) * TSEQ + tt) * 64 + dd] = hn;
        }
        __syncthreads();
    }
}

// =====================================================================
// out = LN( sigmoid(g1)*g2 + res )  per 64-wide row; one wave per row
// =====================================================================
__global__ __launch_bounds__(256) void glu_res_ln_kernel(
    const float* __restrict__ g1, const float* __restrict__ g2,
    const float* __restrict__ res,
    const float* __restrict__ gamma, const float* __restrict__ beta,
    float* __restrict__ out, int Mtot)
{
    const int wv = threadIdx.x >> 6, l = threadIdx.x & 63;
    const int m = blockIdx.x * 4 + wv;
    if (m >= Mtot) return;
    float a = g1[(size_t)m*64 + l], b = g2[(size_t)m*64 + l];
    float y = sigmoidf_(a) * b + res[(size_t)m*64 + l];
    float s = y;
    #pragma unroll
    for (int off = 32; off; off >>= 1) s += __shfl_xor(s, off);
    float mean = s * (1.f / 64.f);
    float d = y - mean, vs = d * d;
    #pragma unroll
    for (int off = 32; off; off >>= 1) vs += __shfl_xor(vs, off);
    float inv = rsqrtf(vs * (1.f / 64.f) + LN_EPS);
    out[(size_t)m*64 + l] = d * inv * gamma[l] + beta[l];
}

// =====================================================================
// MHA core: per batch block, wave per head (T=24, HD=16)
// =====================================================================
__global__ __launch_bounds__(256) void attn_kernel(
    const float* __restrict__ qkv, float* __restrict__ ao)
{
    const int b = blockIdx.x;
    const int h = threadIdx.x >> 6, l = threadIdx.x & 63;
    __shared__ float sq[4][24][16], sk[4][24][16], sv[4][24][16], sp[4][24][24];
    #pragma unroll
    for (int p = 0; p < 6; ++p) {
        int e = l + 64 * p; int ti = e >> 4, d = e & 15;
        size_t base = ((size_t)(b * TSEQ + ti)) * 192 + h * 16 + d;
        sq[h][ti][d] = qkv[base];
        sk[h][ti][d] = qkv[base + 64];
        sv[h][ti][d] = qkv[base + 128];
    }
    __syncthreads();
    #pragma unroll
    for (int p = 0; p < 9; ++p) {
        int e = l + 64 * p; int i = e / 24, j = e - i * 24;
        float s = 0.f;
        #pragma unroll
        for (int d = 0; d < 16; ++d) s += sq[h][i][d] * sk[h][j][d];
        sp[h][i][j] = s * 0.25f;   // 1/sqrt(16)
    }
    __syncthreads();
    if (l < 24) {
        float mx = -1e30f;
        for (int j = 0; j < 24; ++j) mx = fmaxf(mx, sp[h][l][j]);
        float s = 0.f;
        for (int j = 0; j < 24; ++j) { float e = expf(sp[h][l][j] - mx); sp[h][l][j] = e; s += e; }
        float inv = 1.f / s;
        for (int j = 0; j < 24; ++j) sp[h][l][j] *= inv;
    }
    __syncthreads();
    #pragma unroll
    for (int p = 0; p < 6; ++p) {
        int e = l + 64 * p; int ti = e >> 4, d = e & 15;
        float s = 0.f;
        #pragma unroll
        for (int j = 0; j < 24; ++j) s += sp[h][ti][j] * sv[h][j][d];
        ao[((size_t)(b * TSEQ + ti)) * 64 + h * 16 + d] = s;
    }
}

// =====================================================================
// mean over T
// =====================================================================
__global__ void pool_kernel(const float* __restrict__ outln, float* __restrict__ pooled)
{
    int id = blockIdx.x * 256 + threadIdx.x;
    if (id >= BB * 64) return;
    int b = id >> 6, d = id & 63;
    float s = 0.f;
    #pragma unroll
    for (int tt = 0; tt < TSEQ; ++tt) s += outln[((size_t)(b * TSEQ + tt)) * 64 + d];
    pooled[id] = s * (1.f / 24.f);
}

__global__ __launch_bounds__(64) void fc2_kernel(
    const float* __restrict__ fc1o, const float* __restrict__ w,
    const float* __restrict__ bias, float* __restrict__ out)
{
    const int b = blockIdx.x, l = threadIdx.x;
    float v = fc1o[(size_t)b * 64 + l];
    #pragma unroll
    for (int j = 0; j < 6; ++j) {
        float p = v * w[l * 6 + j];
        #pragma unroll
        for (int off = 32; off; off >>= 1) p += __shfl_xor(p, off);
        if (l == 0) out[b * 6 + j] = p + bias[j];
    }
}

// =====================================================================
extern "C" void kernel_launch(void* const* d_in, const int* in_sizes, int n_in,
                              void* d_out, int out_size, void* d_ws, size_t ws_size,
                              hipStream_t stream)
{
    const float* x        = (const float*)d_in[0];
    const float* f_w1     = (const float*)d_in[1];
    const float* f_b1     = (const float*)d_in[2];
    const float* f_w2     = (const float*)d_in[3];
    const float* f_b2     = (const float*)d_in[4];
    const float* f_g1w    = (const float*)d_in[5];
    const float* f_g1b    = (const float*)d_in[6];
    const float* f_g2w    = (const float*)d_in[7];
    const float* f_g2b    = (const float*)d_in[8];
    const float* f_skw    = (const float*)d_in[9];
    const float* f_skb    = (const float*)d_in[10];
    const float* f_lng    = (const float*)d_in[11];
    const float* f_lnb    = (const float*)d_in[12];
    const float* w_w1     = (const float*)d_in[13];
    const float* w_b1     = (const float*)d_in[14];
    const float* w_w2     = (const float*)d_in[15];
    const float* w_b2     = (const float*)d_in[16];
    const float* w_g1w    = (const float*)d_in[17];
    const float* w_g1b    = (const float*)d_in[18];
    const float* w_g2w    = (const float*)d_in[19];
    const float* w_g2b    = (const float*)d_in[20];
    const float* w_skw    = (const float*)d_in[21];
    const float* w_skb    = (const float*)d_in[22];
    const float* w_lng    = (const float*)d_in[23];
    const float* w_lnb    = (const float*)d_in[24];
    const float* lstm_wih = (const float*)d_in[25];
    const float* lstm_whh = (const float*)d_in[26];
    const float* lstm_bih = (const float*)d_in[27];
    const float* lstm_bhh = (const float*)d_in[28];
    const float* pl_g1w   = (const float*)d_in[29];
    const float* pl_g1b   = (const float*)d_in[30];
    const float* pl_g2w   = (const float*)d_in[31];
    const float* pl_g2b   = (const float*)d_in[32];
    const float* pl_lng   = (const float*)d_in[33];
    const float* pl_lnb   = (const float*)d_in[34];
    const float* attn_in_w  = (const float*)d_in[35];
    const float* attn_in_b  = (const float*)d_in[36];
    const float* attn_out_w = (const float*)d_in[37];
    const float* attn_out_b = (const float*)d_in[38];
    const float* pa_g1w   = (const float*)d_in[39];
    const float* pa_g1b   = (const float*)d_in[40];
    const float* pa_g2w   = (const float*)d_in[41];
    const float* pa_g2b   = (const float*)d_in[42];
    const float* pa_lng   = (const float*)d_in[43];
    const float* pa_lnb   = (const float*)d_in[44];
    const float* ff_w1    = (const float*)d_in[45];
    const float* ff_b1    = (const float*)d_in[46];
    const float* ff_w2    = (const float*)d_in[47];
    const float* ff_b2    = (const float*)d_in[48];
    const float* ff_g1w   = (const float*)d_in[49];
    const float* ff_g1b   = (const float*)d_in[50];
    const float* ff_g2w   = (const float*)d_in[51];
    const float* ff_g2b   = (const float*)d_in[52];
    const float* ff_lng   = (const float*)d_in[53];
    const float* ff_lnb   = (const float*)d_in[54];
    const float* fc1_w    = (const float*)d_in[55];
    const float* fc1_b    = (const float*)d_in[56];
    const float* fc2_w    = (const float*)d_in[57];
    const float* fc2_b    = (const float*)d_in[58];

    float* ws = (float*)d_ws;

    // ---------------- workspace layout (UNION region, slot-reused) -------
    size_t o = 0;
    const size_t o_S0   = o; o += (size_t)MTOT * 256;   // xW / qkv
    const size_t o_A    = o; o += (size_t)MTOT * 64;
    const size_t o_Bf   = o; o += (size_t)MTOT * 64;
    const size_t o_Cf   = o; o += (size_t)MTOT * 64;
    const size_t o_Df   = o; o += (size_t)MTOT * 64;
    const size_t o_F    = o; o += (size_t)MTOT * 128;   // ff 128-wide
    const size_t o_wihT = o; o += 16384;
    const size_t o_whhT = o; o += 16384;
    const size_t o_bsum = o; o += 256;
    const size_t o_pool = o; o += (size_t)BB * 64;
    const size_t o_fc1  = o; o += (size_t)BB * 64;
    const size_t union_end = o;                          // 7,962,880 floats

    // chunk-phase overlay (inside the union):
    //   bf16 stacked chunk  [MC, FDIM]    = 3,981,312 float-equivalents
    //   split-K partials    [KS,MC,NW]    = 2,211,840 floats
    //   w81 chunk           [MC, 81]      =   124,416 floats
    //   WcatT bf16          [NW, FDIM]    =   414,720 float-equivalents
    const size_t o_partial = ((size_t)MC * FDIM) / 2;             // 3,981,312
    const size_t o_w81c    = o_partial + (size_t)KS * MC * NW;    // 6,193,152
    const size_t o_wcat    = o_w81c + (size_t)MC * 81;            // 6,317,568
    static_assert(6317568 + ((size_t)NW * FDIM) / 2 <= 7962880, "chunk phase must fit union");

    // persistent region after the union
    o = union_end;
    const size_t o_sel  = o; o += (size_t)MTOT * 64;
    const size_t need   = o;                             // 8,749,312 floats = 35.0 MB
    if (ws_size < need * sizeof(float)) return;          // diagnostic guard

    const dim3 blk(256);

    // 0) pack weight-head matrices to bf16 (transposed)
    wprep_kernel<<<dim3((FDIM + 255) / 256, NW), blk, 0, stream>>>(
        w_w1, w_skw, (unsigned short*)(ws + o_wcat));

    // ---------------- phase 1: VSN + weight-GRN, chunked over M ----------
    for (int mb = 0; mb < MTOT; mb += MC) {
        __hip_bfloat16* chunk = (__hip_bfloat16*)ws;
        // 1) VSN -> stacked chunk [MC, 5184] bf16 (MFMA)
        vsn_kernel<<<dim3(NF, MC / 64), blk, 0, stream>>>(
            x + (size_t)mb * NF, f_w1, f_b1, f_w2, f_b2, f_g1w, f_g1b,
            f_g2w, f_g2b, f_skw, f_skb, f_lng, f_lnb, chunk);
        // 2) split-K fused weight-head GEMM (MFMA) -> partials
        wgemm_kernel<<<dim3(MC / 16, KS), dim3(64), 0, stream>>>(
            chunk, (const unsigned short*)(ws + o_wcat), ws + o_partial);
        // 3) reduce + weight-GRN tail -> softmax weights
        wtail_kernel<<<dim3(MC / 4), blk, 0, stream>>>(
            ws + o_partial, w_b1, w_skb, w_w2, w_b2, w_g1w, w_g1b,
            w_g2w, w_g2b, w_lng, w_lnb, ws + o_w81c);
        // 4) selected rows [mb, mb+MC)
        selected_kernel<<<dim3(MC), blk, 0, stream>>>(
            chunk, ws + o_w81c, ws + o_sel + (size_t)mb * 64);
    }

    // ---------------- phase 2: LSTM -> attention -> head -----------------
    lstm_prep_kernel<<<dim3(64), blk, 0, stream>>>(
        lstm_wih, lstm_whh, lstm_bih, lstm_bhh,
        ws + o_wihT, ws + o_whhT, ws + o_bsum);
    gemm_kernel<<<dim3(MTOT / 32, 4), blk, 0, stream>>>(
        ws + o_sel, ws + o_wihT, ws + o_bsum, ws + o_S0, MTOT, 64, 256, 0);
    lstm_kernel<<<dim3(BB / 4), blk, 0, stream>>>(
        ws + o_S0, ws + o_whhT, ws + o_A);
    gemm_kernel<<<dim3(MTOT / 32, 1), blk, 0, stream>>>(
        ws + o_A, pl_g1w, pl_g1b, ws + o_Bf, MTOT, 64, 64, 0);
    gemm_kernel<<<dim3(MTOT / 32, 1), blk, 0, stream>>>(
        ws + o_A, pl_g2w, pl_g2b, ws + o_Cf, MTOT, 64, 64, 0);
    glu_res_ln_kernel<<<dim3(MTOT / 4), blk, 0, stream>>>(
        ws + o_Bf, ws + o_Cf, ws + o_sel, pl_lng, pl_lnb, ws + o_Df, MTOT);
    gemm_kernel<<<dim3(MTOT / 32, 3), blk, 0, stream>>>(
        ws + o_Df, attn_in_w, attn_in_b, ws + o_S0, MTOT, 64, 192, 0);
    attn_kernel<<<dim3(BB), blk, 0, stream>>>(ws + o_S0, ws + o_A);
    gemm_kernel<<<dim3(MTOT / 32, 1), blk, 0, stream>>>(
        ws + o_A, attn_out_w, attn_out_b, ws + o_Bf, MTOT, 64, 64, 0);
    gemm_kernel<<<dim3(MTOT / 32, 1), blk, 0, stream>>>(
        ws + o_Bf, pa_g1w, pa_g1b, ws + o_A, MTOT, 64, 64, 0);
    gemm_kernel<<<dim3(MTOT / 32, 1), blk, 0, stream>>>(
        ws + o_Bf, pa_g2w, pa_g2b, ws + o_Cf, MTOT, 64, 64, 0);
    glu_res_ln_kernel<<<dim3(MTOT / 4), blk, 0, stream>>>(
        ws + o_A, ws + o_Cf, ws + o_Df, pa_lng, pa_lnb, ws + o_Bf, MTOT);
    gemm_kernel<<<dim3(MTOT / 32, 2), blk, 0, stream>>>(
        ws + o_Bf, ff_w1, ff_b1, ws + o_F, MTOT, 64, 128, 1);
    gemm_kernel<<<dim3(MTOT / 32, 1), blk, 0, stream>>>(
        ws + o_F, ff_w2, ff_b2, ws + o_A, MTOT, 128, 64, 0);
    gemm_kernel<<<dim3(MTOT / 32, 1), blk, 0, stream>>>(
        ws + o_A, ff_g1w, ff_g1b, ws + o_Cf, MTOT, 64, 64, 0);
    gemm_kernel<<<dim3(MTOT / 32, 1), blk, 0, stream>>>(
        ws + o_A, ff_g2w, ff_g2b, ws + o_Df, MTOT, 64, 64, 0);
    glu_res_ln_kernel<<<dim3(MTOT / 4), blk, 0, stream>>>(
        ws + o_Cf, ws + o_Df, ws + o_Bf, ff_lng, ff_lnb, ws + o_A, MTOT);
    pool_kernel<<<dim3((BB * 64 + 255) / 256), blk, 0, stream>>>(
        ws + o_A, ws + o_pool);
    gemm_kernel<<<dim3(BB / 32, 1), blk, 0, stream>>>(
        ws + o_pool, fc1_w, fc1_b, ws + o_fc1, BB, 64, 64, 2);
    fc2_kernel<<<dim3(BB), dim3(64), 0, stream>>>(
        ws + o_fc1, fc2_w, fc2_b, (float*)d_out);
}

// Round 5
// 1163.876 us; speedup vs baseline: 9.7677x; 1.1798x over previous
//
#include <hip/hip_runtime.h>
#include <hip/hip_bf16.h>
#include <math.h>

// ---------------- problem constants ----------------
constexpr int BB   = 512;
constexpr int TSEQ = 24;
constexpr int NF   = 81;
constexpr int DD   = 64;
constexpr int MTOT = BB * TSEQ;      // 12288
constexpr int FDIM = NF * DD;        // 5184
constexpr int MC   = 1536;           // M-chunk for VSN phase (8 chunks)
constexpr int KS   = 9;              // split-K groups for weight-head GEMM
constexpr int NW   = 160;            // padded combined N: 64 (wh1) + 81 (sk) + 15 pad
constexpr float LN_EPS = 1e-5f;

typedef __attribute__((ext_vector_type(8))) short short8v;   // 8 bf16 (4 VGPRs)
typedef __attribute__((ext_vector_type(4))) float f32x4;     // MFMA C/D

static __device__ __forceinline__ float sigmoidf_(float x) { return 1.f / (1.f + expf(-x)); }
static __device__ __forceinline__ float eluf_(float x)     { return x > 0.f ? x : (expf(x) - 1.f); }
static __device__ __forceinline__ unsigned short f2bf(float x) {
    __hip_bfloat16 h = __float2bfloat16(x);
    return *reinterpret_cast<unsigned short*>(&h);
}

// =====================================================================
// Kernel 1: VSN — 81 per-feature GRNs -> stacked chunk [MC, NF*64] (bf16)
// (unchanged from round 4 — verified)
// =====================================================================
__global__ __launch_bounds__(256) void vsn_kernel(
    const float* __restrict__ x,
    const float* __restrict__ f_w1,  const float* __restrict__ f_b1,
    const float* __restrict__ f_w2,  const float* __restrict__ f_b2,
    const float* __restrict__ f_g1w, const float* __restrict__ f_g1b,
    const float* __restrict__ f_g2w, const float* __restrict__ f_g2b,
    const float* __restrict__ f_skw, const float* __restrict__ f_skb,
    const float* __restrict__ f_lng, const float* __restrict__ f_lnb,
    __hip_bfloat16* __restrict__ stacked)
{
    const int f  = blockIdx.x;
    const int m0 = blockIdx.y * 64;
    const int t  = threadIdx.x;
    const int w  = t >> 6;
    const int l  = t & 63;
    const int lr = l & 15;
    const int lg = l >> 4;

    __shared__ __align__(16) unsigned short hA[64 * 72];
    __shared__ __align__(16) unsigned char  uS[18432];
    __shared__ float vw1[64], vb1[64], vb2[64], vg1b[64], vg2b[64];
    __shared__ float vskw[64], vskb[64], vlng[64], vlnb[64], xv[64];

    unsigned short* Wt0 = (unsigned short*)uS;
    unsigned short* Wt1 = (unsigned short*)(uS + 9216);
    float*          yA  = (float*)uS;

    if (t < 64) {
        vw1[t]  = f_w1 [f*64 + t];  vb1[t]  = f_b1 [f*64 + t];
        vb2[t]  = f_b2 [f*64 + t];
        vg1b[t] = f_g1b[f*64 + t];  vg2b[t] = f_g2b[f*64 + t];
        vskw[t] = f_skw[f*64 + t];  vskb[t] = f_skb[f*64 + t];
        vlng[t] = f_lng[f*64 + t];  vlnb[t] = f_lnb[f*64 + t];
        xv[t]   = x[(size_t)(m0 + t) * NF + f];
    }
    __syncthreads();

    {
        const float* w2p = f_w2 + (size_t)f * 4096;
        #pragma unroll
        for (int p = 0; p < 16; ++p) {
            int e = t + 256 * p; int k = e >> 6, c = e & 63;
            Wt0[c*72 + k] = f2bf(w2p[k*64 + c]);
        }
        #pragma unroll
        for (int p = 0; p < 16; ++p) {
            int e = t + 256 * p; int r = e >> 6, d = e & 63;
            hA[r*72 + d] = f2bf(eluf_(xv[r] * vw1[d] + vb1[d]));
        }
    }
    __syncthreads();

    f32x4 acc1[4];
    #pragma unroll
    for (int rg = 0; rg < 4; ++rg) acc1[rg] = (f32x4){0.f, 0.f, 0.f, 0.f};
    #pragma unroll
    for (int ks = 0; ks < 2; ++ks) {
        short8v bf = *(const short8v*)&Wt0[(w*16 + lr)*72 + ks*32 + lg*8];
        #pragma unroll
        for (int rg = 0; rg < 4; ++rg) {
            short8v af = *(const short8v*)&hA[(rg*16 + lr)*72 + ks*32 + lg*8];
            acc1[rg] = __builtin_amdgcn_mfma_f32_16x16x32_bf16(af, bf, acc1[rg], 0, 0, 0);
        }
    }
    {
        const float* g1p = f_g1w + (size_t)f * 4096;
        #pragma unroll
        for (int p = 0; p < 16; ++p) {
            int e = t + 256 * p; int k = e >> 6, c = e & 63;
            Wt1[c*72 + k] = f2bf(g1p[k*64 + c]);
        }
    }
    __syncthreads();

    #pragma unroll
    for (int rg = 0; rg < 4; ++rg)
        #pragma unroll
        for (int j = 0; j < 4; ++j) {
            int r = rg*16 + lg*4 + j, c = w*16 + lr;
            hA[r*72 + c] = f2bf(acc1[rg][j] + vb2[c]);
        }
    {
        const float* g2p = f_g2w + (size_t)f * 4096;
        #pragma unroll
        for (int p = 0; p < 16; ++p) {
            int e = t + 256 * p; int k = e >> 6, c = e & 63;
            Wt0[c*72 + k] = f2bf(g2p[k*64 + c]);
        }
    }
    __syncthreads();

    f32x4 aA[4], aB[4];
    #pragma unroll
    for (int rg = 0; rg < 4; ++rg) { aA[rg] = (f32x4){0.f,0.f,0.f,0.f}; aB[rg] = (f32x4){0.f,0.f,0.f,0.f}; }
    #pragma unroll
    for (int ks = 0; ks < 2; ++ks) {
        short8v b1f = *(const short8v*)&Wt1[(w*16 + lr)*72 + ks*32 + lg*8];
        short8v b2f = *(const short8v*)&Wt0[(w*16 + lr)*72 + ks*32 + lg*8];
        #pragma unroll
        for (int rg = 0; rg < 4; ++rg) {
            short8v af = *(const short8v*)&hA[(rg*16 + lr)*72 + ks*32 + lg*8];
            aA[rg] = __builtin_amdgcn_mfma_f32_16x16x32_bf16(af, b1f, aA[rg], 0, 0, 0);
            aB[rg] = __builtin_amdgcn_mfma_f32_16x16x32_bf16(af, b2f, aB[rg], 0, 0, 0);
        }
    }
    __syncthreads();

    #pragma unroll
    for (int rg = 0; rg < 4; ++rg)
        #pragma unroll
        for (int j = 0; j < 4; ++j) {
            int r = rg*16 + lg*4 + j, c = w*16 + lr;
            float sg = sigmoidf_(aA[rg][j] + vg1b[c]);
            float y  = sg * (aB[rg][j] + vg2b[c]) + xv[r] * vskw[c] + vskb[c];
            yA[r*68 + c] = y;
        }
    __syncthreads();

    const int tr = t >> 4, tc = t & 15;
    #pragma unroll
    for (int a = 0; a < 4; ++a) {
        const int r = tr + 16*a;
        float vals[4];
        float part = 0.f;
        #pragma unroll
        for (int b = 0; b < 4; ++b) { vals[b] = yA[r*68 + tc + 16*b]; part += vals[b]; }
        #pragma unroll
        for (int off = 1; off < 16; off <<= 1) part += __shfl_xor(part, off);
        const float mean = part * (1.f / 64.f);
        float vp = 0.f;
        #pragma unroll
        for (int b = 0; b < 4; ++b) { float d = vals[b] - mean; vp += d * d; }
        #pragma unroll
        for (int off = 1; off < 16; off <<= 1) vp += __shfl_xor(vp, off);
        const float inv = rsqrtf(vp * (1.f / 64.f) + LN_EPS);
        const size_t base = (size_t)(m0 + r) * FDIM + (size_t)f * 64;
        #pragma unroll
        for (int b = 0; b < 4; ++b) {
            const int c = tc + 16*b;
            stacked[base + c] = __float2bfloat16((vals[b] - mean) * inv * vlng[c] + vlnb[c]);
        }
    }
}

// =====================================================================
// Pack w_w1 / w_skw into bf16 WcatT[160][FDIM]
// =====================================================================
__global__ void wprep_kernel(
    const float* __restrict__ w_w1, const float* __restrict__ w_skw,
    unsigned short* __restrict__ WcatT)
{
    const int c = blockIdx.y;
    const int k = blockIdx.x * 256 + threadIdx.x;
    if (k >= FDIM) return;
    float v = 0.f;
    if (c < 64)       v = w_w1[(size_t)k * 64 + c];
    else if (c < 145) v = w_skw[(size_t)k * 81 + (c - 64)];
    WcatT[(size_t)c * FDIM + k] = f2bf(v);
}

// =====================================================================
// Split-K fused weight-head GEMM (MFMA, LDS-free)  (unchanged)
// =====================================================================
__global__ __launch_bounds__(64) void wgemm_kernel(
    const __hip_bfloat16* __restrict__ stacked,
    const unsigned short* __restrict__ WcatT,
    float* __restrict__ partial)
{
    const int m0 = blockIdx.x * 16;
    const int ks = blockIdx.y;
    const int l  = threadIdx.x;
    const int lr = l & 15, lg = l >> 4;

    f32x4 acc[10];
    #pragma unroll
    for (int n = 0; n < 10; ++n) acc[n] = (f32x4){0.f, 0.f, 0.f, 0.f};

    const size_t arow = (size_t)(m0 + lr) * FDIM;
    const int k0base = ks * 576;
    for (int kk = 0; kk < 576; kk += 32) {
        const int k = k0base + kk + lg * 8;
        short8v af = *(const short8v*)(stacked + arow + k);
        #pragma unroll
        for (int n = 0; n < 10; ++n) {
            short8v bf = *(const short8v*)(WcatT + (size_t)(n*16 + lr) * FDIM + k);
            acc[n] = __builtin_amdgcn_mfma_f32_16x16x32_bf16(af, bf, acc[n], 0, 0, 0);
        }
    }
    #pragma unroll
    for (int n = 0; n < 10; ++n)
        #pragma unroll
        for (int j = 0; j < 4; ++j) {
            const int m = m0 + lg*4 + j;
            partial[((size_t)ks * MC + m) * NW + n*16 + lr] = acc[n][j];
        }
}

// =====================================================================
// Weight-GRN tail (unchanged)
// =====================================================================
__global__ __launch_bounds__(256) void wtail_kernel(
    const float* __restrict__ partial,
    const float* __restrict__ w_b1,  const float* __restrict__ w_skb,
    const float* __restrict__ w_w2,  const float* __restrict__ w_b2,
    const float* __restrict__ w_g1w, const float* __restrict__ w_g1b,
    const float* __restrict__ w_g2w, const float* __restrict__ w_g2b,
    const float* __restrict__ w_lng, const float* __restrict__ w_lnb,
    float* __restrict__ w81)
{
    __shared__ float sWh[4][64];
    __shared__ float sW2[4][96];
    const int wv = threadIdx.x >> 6, l = threadIdx.x & 63;
    const int m = blockIdx.x * 4 + wv;
    const bool v1 = (l < 17);

    float s0  = w_b1[l];
    float sk0 = w_skb[l];
    float sk1 = v1 ? w_skb[64 + l] : 0.f;
    for (int ks = 0; ks < KS; ++ks) {
        const float* pr = partial + ((size_t)ks * MC + m) * NW;
        s0  += pr[l];
        sk0 += pr[64 + l];
        if (v1) sk1 += pr[128 + l];
    }
    sWh[wv][l] = eluf_(s0);
    __syncthreads();

    float acc0 = w_b2[l], acc1 = v1 ? w_b2[64 + l] : 0.f;
    for (int i = 0; i < 64; ++i) {
        float h = sWh[wv][i];
        acc0 += h * w_w2[i*81 + l];
        if (v1) acc1 += h * w_w2[i*81 + 64 + l];
    }
    sW2[wv][l] = acc0; if (v1) sW2[wv][64 + l] = acc1;
    __syncthreads();

    float g10 = w_g1b[l], g20 = w_g2b[l];
    float g11 = v1 ? w_g1b[64 + l] : 0.f, g21 = v1 ? w_g2b[64 + l] : 0.f;
    for (int i = 0; i < 81; ++i) {
        float h = sW2[wv][i];
        g10 += h * w_g1w[i*81 + l];
        g20 += h * w_g2w[i*81 + l];
        if (v1) { g11 += h * w_g1w[i*81 + 64 + l]; g21 += h * w_g2w[i*81 + 64 + l]; }
    }
    float y0 = sigmoidf_(g10) * g20 + sk0;
    float y1 = v1 ? (sigmoidf_(g11) * g21 + sk1) : 0.f;

    float s = y0 + (v1 ? y1 : 0.f);
    #pragma unroll
    for (int off = 32; off; off >>= 1) s += __shfl_xor(s, off);
    const float mean = s / 81.f;
    float d0 = y0 - mean, d1 = v1 ? (y1 - mean) : 0.f;
    float vs = d0*d0 + (v1 ? d1*d1 : 0.f);
    #pragma unroll
    for (int off = 32; off; off >>= 1) vs += __shfl_xor(vs, off);
    const float inv = rsqrtf(vs / 81.f + LN_EPS);
    float wn0 = d0 * inv * w_lng[l] + w_lnb[l];
    float wn1 = v1 ? (d1 * inv * w_lng[64 + l] + w_lnb[64 + l]) : -1e30f;

    float mx = fmaxf(wn0, wn1);
    #pragma unroll
    for (int off = 32; off; off >>= 1) mx = fmaxf(mx, __shfl_xor(mx, off));
    float e0 = expf(wn0 - mx), e1 = v1 ? expf(wn1 - mx) : 0.f;
    float es = e0 + e1;
    #pragma unroll
    for (int off = 32; off; off >>= 1) es += __shfl_xor(es, off);
    const float r = 1.f / es;
    w81[(size_t)m * 81 + l] = e0 * r;
    if (v1) w81[(size_t)m * 81 + 64 + l] = e1 * r;
}

// =====================================================================
// selected: f32 + bf16 outputs
// =====================================================================
__global__ __launch_bounds__(256) void selected_kernel(
    const __hip_bfloat16* __restrict__ stacked, const float* __restrict__ w81,
    float* __restrict__ sel, __hip_bfloat16* __restrict__ selb)
{
    const int m = blockIdx.x;
    const int d = threadIdx.x & 63, fg = threadIdx.x >> 6;
    __shared__ float red[4][64];
    __shared__ float wsh[81];
    if (threadIdx.x < 81) wsh[threadIdx.x] = w81[(size_t)m * 81 + threadIdx.x];
    __syncthreads();
    float acc = 0.f;
    for (int f = fg; f < 81; f += 4)
        acc += __bfloat162float(stacked[(size_t)m * FDIM + f*64 + d]) * wsh[f];
    red[fg][d] = acc;
    __syncthreads();
    if (fg == 0) {
        float v = red[0][d] + red[1][d] + red[2][d] + red[3][d];
        sel[(size_t)m * 64 + d]  = v;
        selb[(size_t)m * 64 + d] = __float2bfloat16(v);
    }
}

// =====================================================================
// xW = selb @ wih^T + (bih+bhh)    MFMA, grid MTOT/64 blocks, 256 thr
// wih torch layout [256][64] = [outcol][k] -> LDS Wt[c][k] direct copy.
// =====================================================================
__global__ __launch_bounds__(256) void xw_kernel(
    const __hip_bfloat16* __restrict__ selb,
    const float* __restrict__ wih,
    const float* __restrict__ bih, const float* __restrict__ bhh,
    float* __restrict__ xW)
{
    const int m0 = blockIdx.x * 64;
    const int t = threadIdx.x;
    const int w = t >> 6, l = t & 63, lr = l & 15, lg = l >> 4;
    __shared__ __align__(16) unsigned short hA[64 * 72];
    __shared__ __align__(16) unsigned short Wt[256 * 72];
    __shared__ float vbs[256];

    vbs[t] = bih[t] + bhh[t];
    #pragma unroll
    for (int p = 0; p < 16; ++p) {
        int e = t + 256 * p; int r = e >> 6, d = e & 63;
        hA[r*72 + d] = *(const unsigned short*)&selb[(size_t)(m0 + r) * 64 + d];
    }
    #pragma unroll
    for (int p = 0; p < 64; ++p) {
        int e = t + 256 * p; int c = e >> 6, k = e & 63;
        Wt[c*72 + k] = f2bf(wih[c*64 + k]);
    }
    __syncthreads();

    f32x4 acc[4][4];
    #pragma unroll
    for (int rg = 0; rg < 4; ++rg)
        #pragma unroll
        for (int cf = 0; cf < 4; ++cf) acc[rg][cf] = (f32x4){0.f,0.f,0.f,0.f};
    #pragma unroll
    for (int ks = 0; ks < 2; ++ks) {
        short8v af[4];
        #pragma unroll
        for (int rg = 0; rg < 4; ++rg)
            af[rg] = *(const short8v*)&hA[(rg*16 + lr)*72 + ks*32 + lg*8];
        #pragma unroll
        for (int cf = 0; cf < 4; ++cf) {
            short8v bf = *(const short8v*)&Wt[(w*64 + cf*16 + lr)*72 + ks*32 + lg*8];
            #pragma unroll
            for (int rg = 0; rg < 4; ++rg)
                acc[rg][cf] = __builtin_amdgcn_mfma_f32_16x16x32_bf16(af[rg], bf, acc[rg][cf], 0, 0, 0);
        }
    }
    #pragma unroll
    for (int rg = 0; rg < 4; ++rg)
        #pragma unroll
        for (int cf = 0; cf < 4; ++cf)
            #pragma unroll
            for (int j = 0; j < 4; ++j) {
                int r = rg*16 + lg*4 + j, c = w*64 + cf*16 + lr;
                xW[(size_t)(m0 + r) * 256 + c] = acc[rg][cf][j] + vbs[c];
            }
}

// =====================================================================
// LSTM prep: transpose whh ([4H,64] -> [64,4H])
// =====================================================================
__global__ void lstm_prep_kernel(
    const float* __restrict__ whh, float* __restrict__ whhT)
{
    int id = blockIdx.x * 256 + threadIdx.x;
    if (id < 16384) {
        int i = id >> 8, j = id & 255;
        whhT[id] = whh[j*64 + i];
    }
}

// =====================================================================
// LSTM recurrence (unchanged)
// =====================================================================
__global__ __launch_bounds__(256) void lstm_kernel(
    const float* __restrict__ xW, const float* __restrict__ whhT,
    float* __restrict__ out)
{
    __shared__ float sh[4][64];
    __shared__ float sg[4][256];
    const int t = threadIdx.x;
    const int b0 = blockIdx.x * 4;
    const int rr = t >> 6, dd = t & 63;
    sh[rr][dd] = 0.f;
    float c_reg = 0.f;
    __syncthreads();
    for (int tt = 0; tt < TSEQ; ++tt) {
        float acc[4];
        #pragma unroll
        for (int r = 0; r < 4; ++r)
            acc[r] = xW[((size_t)(b0 + r) * TSEQ + tt) * 256 + t];
        for (int i = 0; i < 64; ++i) {
            float wvv = whhT[i*256 + t];
            #pragma unroll
            for (int r = 0; r < 4; ++r) acc[r] += sh[r][i] * wvv;
        }
        __syncthreads();
        #pragma unroll
        for (int r = 0; r < 4; ++r) sg[r][t] = acc[r];
        __syncthreads();
        {
            float gi = sg[rr][dd], gf = sg[rr][64 + dd], gg = sg[rr][128 + dd], go = sg[rr][192 + dd];
            c_reg = sigmoidf_(gf) * c_reg + sigmoidf_(gi) * tanhf(gg);
            float hn = sigmoidf_(go) * tanhf(c_reg);
            sh[rr][dd] = hn;
            out[((size_t)(b0 + rr) * TSEQ + tt) * 64 + dd] = hn;
        }
        __syncthreads();
    }
}

// =====================================================================
// fused GLU pair + residual + LN:  out = LN(sigmoid(in@G1+b1)*(in@G2+b2)+res)
// in: f32 [M,64]; out f32 + bf16.  grid MTOT/64, 256 thr. MFMA.
// =====================================================================
__global__ __launch_bounds__(256) void fused_pl_kernel(
    const float* __restrict__ in, const float* __restrict__ res,
    const float* __restrict__ g1w, const float* __restrict__ g1b,
    const float* __restrict__ g2w, const float* __restrict__ g2b,
    const float* __restrict__ lng, const float* __restrict__ lnb,
    float* __restrict__ outf, __hip_bfloat16* __restrict__ outb)
{
    const int m0 = blockIdx.x * 64;
    const int t = threadIdx.x;
    const int w = t >> 6, l = t & 63, lr = l & 15, lg = l >> 4;
    __shared__ __align__(16) unsigned short hA[64 * 72];
    __shared__ __align__(16) unsigned char uS[18432];
    unsigned short* Wt0 = (unsigned short*)uS;
    unsigned short* Wt1 = (unsigned short*)(uS + 9216);
    float* yA = (float*)uS;
    __shared__ float vg1b[64], vg2b[64], vlng[64], vlnb[64];

    if (t < 64) { vg1b[t] = g1b[t]; vg2b[t] = g2b[t]; vlng[t] = lng[t]; vlnb[t] = lnb[t]; }
    #pragma unroll
    for (int p = 0; p < 16; ++p) {
        int e = t + 256 * p; int r = e >> 6, d = e & 63;
        hA[r*72 + d] = f2bf(in[(size_t)(m0 + r) * 64 + d]);
    }
    #pragma unroll
    for (int p = 0; p < 16; ++p) {
        int e = t + 256 * p; int k = e >> 6, c = e & 63;
        Wt0[c*72 + k] = f2bf(g1w[k*64 + c]);
        Wt1[c*72 + k] = f2bf(g2w[k*64 + c]);
    }
    __syncthreads();

    f32x4 aA[4], aB[4];
    #pragma unroll
    for (int rg = 0; rg < 4; ++rg) { aA[rg] = (f32x4){0.f,0.f,0.f,0.f}; aB[rg] = (f32x4){0.f,0.f,0.f,0.f}; }
    #pragma unroll
    for (int ks = 0; ks < 2; ++ks) {
        short8v b0f = *(const short8v*)&Wt0[(w*16 + lr)*72 + ks*32 + lg*8];
        short8v b1f = *(const short8v*)&Wt1[(w*16 + lr)*72 + ks*32 + lg*8];
        #pragma unroll
        for (int rg = 0; rg < 4; ++rg) {
            short8v af = *(const short8v*)&hA[(rg*16 + lr)*72 + ks*32 + lg*8];
            aA[rg] = __builtin_amdgcn_mfma_f32_16x16x32_bf16(af, b0f, aA[rg], 0, 0, 0);
            aB[rg] = __builtin_amdgcn_mfma_f32_16x16x32_bf16(af, b1f, aB[rg], 0, 0, 0);
        }
    }
    __syncthreads();

    #pragma unroll
    for (int rg = 0; rg < 4; ++rg)
        #pragma unroll
        for (int j = 0; j < 4; ++j) {
            int r = rg*16 + lg*4 + j, c = w*16 + lr;
            float sg = sigmoidf_(aA[rg][j] + vg1b[c]);
            yA[r*68 + c] = sg * (aB[rg][j] + vg2b[c]) + res[(size_t)(m0 + r) * 64 + c];
        }
    __syncthreads();

    const int tr = t >> 4, tc = t & 15;
    #pragma unroll
    for (int a = 0; a < 4; ++a) {
        const int r = tr + 16*a;
        float vals[4]; float part = 0.f;
        #pragma unroll
        for (int b = 0; b < 4; ++b) { vals[b] = yA[r*68 + tc + 16*b]; part += vals[b]; }
        #pragma unroll
        for (int off = 1; off < 16; off <<= 1) part += __shfl_xor(part, off);
        const float mean = part * (1.f / 64.f);
        float vp = 0.f;
        #pragma unroll
        for (int b = 0; b < 4; ++b) { float d = vals[b] - mean; vp += d * d; }
        #pragma unroll
        for (int off = 1; off < 16; off <<= 1) vp += __shfl_xor(vp, off);
        const float inv = rsqrtf(vp * (1.f / 64.f) + LN_EPS);
        #pragma unroll
        for (int b = 0; b < 4; ++b) {
            const int c = tc + 16*b;
            float v = (vals[b] - mean) * inv * vlng[c] + vlnb[c];
            outf[(size_t)(m0 + r) * 64 + c] = v;
            outb[(size_t)(m0 + r) * 64 + c] = __float2bfloat16(v);
        }
    }
}

// =====================================================================
// qkv = temporal_bf16 @ attn_in_w[64,192] + b   MFMA, grid MTOT/64
// =====================================================================
__global__ __launch_bounds__(256) void qkv_kernel(
    const __hip_bfloat16* __restrict__ tb,
    const float* __restrict__ wqkv, const float* __restrict__ bqkv,
    float* __restrict__ qkv)
{
    const int m0 = blockIdx.x * 64;
    const int t = threadIdx.x;
    const int w = t >> 6, l = t & 63, lr = l & 15, lg = l >> 4;
    __shared__ __align__(16) unsigned short hA[64 * 72];
    __shared__ __align__(16) unsigned short Wt[192 * 72];
    __shared__ float vb[192];

    if (t < 192) vb[t] = bqkv[t];
    #pragma unroll
    for (int p = 0; p < 16; ++p) {
        int e = t + 256 * p; int r = e >> 6, d = e & 63;
        hA[r*72 + d] = *(const unsigned short*)&tb[(size_t)(m0 + r) * 64 + d];
    }
    #pragma unroll
    for (int p = 0; p < 48; ++p) {
        int e = t + 256 * p; int c = e >> 6, k = e & 63;
        Wt[c*72 + k] = f2bf(wqkv[(size_t)k * 192 + c]);
    }
    __syncthreads();

    f32x4 acc[4][3];
    #pragma unroll
    for (int rg = 0; rg < 4; ++rg)
        #pragma unroll
        for (int cf = 0; cf < 3; ++cf) acc[rg][cf] = (f32x4){0.f,0.f,0.f,0.f};
    #pragma unroll
    for (int ks = 0; ks < 2; ++ks) {
        short8v af[4];
        #pragma unroll
        for (int rg = 0; rg < 4; ++rg)
            af[rg] = *(const short8v*)&hA[(rg*16 + lr)*72 + ks*32 + lg*8];
        #pragma unroll
        for (int cf = 0; cf < 3; ++cf) {
            short8v bf = *(const short8v*)&Wt[(w*48 + cf*16 + lr)*72 + ks*32 + lg*8];
            #pragma unroll
            for (int rg = 0; rg < 4; ++rg)
                acc[rg][cf] = __builtin_amdgcn_mfma_f32_16x16x32_bf16(af[rg], bf, acc[rg][cf], 0, 0, 0);
        }
    }
    #pragma unroll
    for (int rg = 0; rg < 4; ++rg)
        #pragma unroll
        for (int cf = 0; cf < 3; ++cf)
            #pragma unroll
            for (int j = 0; j < 4; ++j) {
                int r = rg*16 + lg*4 + j, c = w*48 + cf*16 + lr;
                qkv[(size_t)(m0 + r) * 192 + c] = acc[rg][cf][j] + vb[c];
            }
}

// =====================================================================
// MHA core -> ao bf16
// =====================================================================
__global__ __launch_bounds__(256) void attn_kernel(
    const float* __restrict__ qkv, __hip_bfloat16* __restrict__ ao)
{
    const int b = blockIdx.x;
    const int h = threadIdx.x >> 6, l = threadIdx.x & 63;
    __shared__ float sq[4][24][16], sk[4][24][16], sv[4][24][16], sp[4][24][24];
    #pragma unroll
    for (int p = 0; p < 6; ++p) {
        int e = l + 64 * p; int ti = e >> 4, d = e & 15;
        size_t base = ((size_t)(b * TSEQ + ti)) * 192 + h * 16 + d;
        sq[h][ti][d] = qkv[base];
        sk[h][ti][d] = qkv[base + 64];
        sv[h][ti][d] = qkv[base + 128];
    }
    __syncthreads();
    #pragma unroll
    for (int p = 0; p < 9; ++p) {
        int e = l + 64 * p; int i = e / 24, j = e - i * 24;
        float s = 0.f;
        #pragma unroll
        for (int d = 0; d < 16; ++d) s += sq[h][i][d] * sk[h][j][d];
        sp[h][i][j] = s * 0.25f;
    }
    __syncthreads();
    if (l < 24) {
        float mx = -1e30f;
        for (int j = 0; j < 24; ++j) mx = fmaxf(mx, sp[h][l][j]);
        float s = 0.f;
        for (int j = 0; j < 24; ++j) { float e = expf(sp[h][l][j] - mx); sp[h][l][j] = e; s += e; }
        float inv = 1.f / s;
        for (int j = 0; j < 24; ++j) sp[h][l][j] *= inv;
    }
    __syncthreads();
    #pragma unroll
    for (int p = 0; p < 6; ++p) {
        int e = l + 64 * p; int ti = e >> 4, d = e & 15;
        float s = 0.f;
        #pragma unroll
        for (int j = 0; j < 24; ++j) s += sp[h][ti][j] * sv[h][j][d];
        ao[((size_t)(b * TSEQ + ti)) * 64 + h * 16 + d] = __float2bfloat16(s);
    }
}

// =====================================================================
// fused post-attn: ao@Wout+b -> GLU(pa) -> +temporal -> LN -> enriched
// =====================================================================
__global__ __launch_bounds__(256) void fused_pa_kernel(
    const __hip_bfloat16* __restrict__ ao, const float* __restrict__ res,
    const float* __restrict__ wout, const float* __restrict__ bout,
    const float* __restrict__ g1w, const float* __restrict__ g1b,
    const float* __restrict__ g2w, const float* __restrict__ g2b,
    const float* __restrict__ lng, const float* __restrict__ lnb,
    float* __restrict__ outf, __hip_bfloat16* __restrict__ outb)
{
    const int m0 = blockIdx.x * 64;
    const int t = threadIdx.x;
    const int w = t >> 6, l = t & 63, lr = l & 15, lg = l >> 4;
    __shared__ __align__(16) unsigned short hA[64 * 72];
    __shared__ __align__(16) unsigned char uS[18432];
    unsigned short* Wt0 = (unsigned short*)uS;
    unsigned short* Wt1 = (unsigned short*)(uS + 9216);
    float* yA = (float*)uS;
    __shared__ float vob[64], vg1b[64], vg2b[64], vlng[64], vlnb[64];

    if (t < 64) { vob[t] = bout[t]; vg1b[t] = g1b[t]; vg2b[t] = g2b[t]; vlng[t] = lng[t]; vlnb[t] = lnb[t]; }
    #pragma unroll
    for (int p = 0; p < 16; ++p) {
        int e = t + 256 * p; int r = e >> 6, d = e & 63;
        hA[r*72 + d] = *(const unsigned short*)&ao[(size_t)(m0 + r) * 64 + d];
    }
    #pragma unroll
    for (int p = 0; p < 16; ++p) {
        int e = t + 256 * p; int k = e >> 6, c = e & 63;
        Wt0[c*72 + k] = f2bf(wout[k*64 + c]);
    }
    __syncthreads();

    // mm1: attn_out
    f32x4 acc1[4];
    #pragma unroll
    for (int rg = 0; rg < 4; ++rg) acc1[rg] = (f32x4){0.f,0.f,0.f,0.f};
    #pragma unroll
    for (int ks = 0; ks < 2; ++ks) {
        short8v bf = *(const short8v*)&Wt0[(w*16 + lr)*72 + ks*32 + lg*8];
        #pragma unroll
        for (int rg = 0; rg < 4; ++rg) {
            short8v af = *(const short8v*)&hA[(rg*16 + lr)*72 + ks*32 + lg*8];
            acc1[rg] = __builtin_amdgcn_mfma_f32_16x16x32_bf16(af, bf, acc1[rg], 0, 0, 0);
        }
    }
    #pragma unroll
    for (int p = 0; p < 16; ++p) {
        int e = t + 256 * p; int k = e >> 6, c = e & 63;
        Wt1[c*72 + k] = f2bf(g1w[k*64 + c]);
    }
    __syncthreads();

    #pragma unroll
    for (int rg = 0; rg < 4; ++rg)
        #pragma unroll
        for (int j = 0; j < 4; ++j) {
            int r = rg*16 + lg*4 + j, c = w*16 + lr;
            hA[r*72 + c] = f2bf(acc1[rg][j] + vob[c]);
        }
    #pragma unroll
    for (int p = 0; p < 16; ++p) {
        int e = t + 256 * p; int k = e >> 6, c = e & 63;
        Wt0[c*72 + k] = f2bf(g2w[k*64 + c]);
    }
    __syncthreads();

    f32x4 aA[4], aB[4];
    #pragma unroll
    for (int rg = 0; rg < 4; ++rg) { aA[rg] = (f32x4){0.f,0.f,0.f,0.f}; aB[rg] = (f32x4){0.f,0.f,0.f,0.f}; }
    #pragma unroll
    for (int ks = 0; ks < 2; ++ks) {
        short8v b1f = *(const short8v*)&Wt1[(w*16 + lr)*72 + ks*32 + lg*8];
        short8v b2f = *(const short8v*)&Wt0[(w*16 + lr)*72 + ks*32 + lg*8];
        #pragma unroll
        for (int rg = 0; rg < 4; ++rg) {
            short8v af = *(const short8v*)&hA[(rg*16 + lr)*72 + ks*32 + lg*8];
            aA[rg] = __builtin_amdgcn_mfma_f32_16x16x32_bf16(af, b1f, aA[rg], 0, 0, 0);
            aB[rg] = __builtin_amdgcn_mfma_f32_16x16x32_bf16(af, b2f, aB[rg], 0, 0, 0);
        }
    }
    __syncthreads();

    #pragma unroll
    for (int rg = 0; rg < 4; ++rg)
        #pragma unroll
        for (int j = 0; j < 4; ++j) {
            int r = rg*16 + lg*4 + j, c = w*16 + lr;
            float sg = sigmoidf_(aA[rg][j] + vg1b[c]);
            yA[r*68 + c] = sg * (aB[rg][j] + vg2b[c]) + res[(size_t)(m0 + r) * 64 + c];
        }
    __syncthreads();

    const int tr = t >> 4, tc = t & 15;
    #pragma unroll
    for (int a = 0; a < 4; ++a) {
        const int r = tr + 16*a;
        float vals[4]; float part = 0.f;
        #pragma unroll
        for (int b = 0; b < 4; ++b) { vals[b] = yA[r*68 + tc + 16*b]; part += vals[b]; }
        #pragma unroll
        for (int off = 1; off < 16; off <<= 1) part += __shfl_xor(part, off);
        const float mean = part * (1.f / 64.f);
        float vp = 0.f;
        #pragma unroll
        for (int b = 0; b < 4; ++b) { float d = vals[b] - mean; vp += d * d; }
        #pragma unroll
        for (int off = 1; off < 16; off <<= 1) vp += __shfl_xor(vp, off);
        const float inv = rsqrtf(vp * (1.f / 64.f) + LN_EPS);
        #pragma unroll
        for (int b = 0; b < 4; ++b) {
            const int c = tc + 16*b;
            float v = (vals[b] - mean) * inv * vlng[c] + vlnb[c];
            outf[(size_t)(m0 + r) * 64 + c] = v;
            outb[(size_t)(m0 + r) * 64 + c] = __float2bfloat16(v);
        }
    }
}

// =====================================================================
// fused FF GRN: h=elu(e@W1+b1); h2=h@W2+b2; GLU(g1,g2); +enriched; LN
// =====================================================================
__global__ __launch_bounds__(256) void fused_ff_kernel(
    const __hip_bfloat16* __restrict__ eb, const float* __restrict__ res,
    const float* __restrict__ w1, const float* __restrict__ b1,
    const float* __restrict__ w2, const float* __restrict__ b2,
    const float* __restrict__ g1w, const float* __restrict__ g1b,
    const float* __restrict__ g2w, const float* __restrict__ g2b,
    const float* __restrict__ lng, const float* __restrict__ lnb,
    float* __restrict__ outf)
{
    const int m0 = blockIdx.x * 64;
    const int t = threadIdx.x;
    const int w = t >> 6, l = t & 63, lr = l & 15, lg = l >> 4;
    __shared__ __align__(16) unsigned short hA[64 * 72];    // 9216 B
    __shared__ __align__(16) unsigned short hB[64 * 136];   // 17408 B
    __shared__ __align__(16) unsigned char U1[18432];       // W1t then g1t+g2t
    __shared__ __align__(16) unsigned char U2[17408];       // W2t then yA
    __shared__ float vb1[128], vb2[64], vg1b[64], vg2b[64], vlng[64], vlnb[64];

    unsigned short* W1t = (unsigned short*)U1;              // [128][72]
    unsigned short* W2t = (unsigned short*)U2;              // [64][136]
    unsigned short* G1t = (unsigned short*)U1;              // [64][72]
    unsigned short* G2t = (unsigned short*)(U1 + 9216);     // [64][72]
    float* yA = (float*)U2;                                 // [64][68]

    if (t < 128) vb1[t] = b1[t];
    if (t < 64) { vb2[t] = b2[t]; vg1b[t] = g1b[t]; vg2b[t] = g2b[t]; vlng[t] = lng[t]; vlnb[t] = lnb[t]; }
    #pragma unroll
    for (int p = 0; p < 16; ++p) {
        int e = t + 256 * p; int r = e >> 6, d = e & 63;
        hA[r*72 + d] = *(const unsigned short*)&eb[(size_t)(m0 + r) * 64 + d];
    }
    #pragma unroll
    for (int p = 0; p < 32; ++p) {
        int e = t + 256 * p; int k = e >> 7, c = e & 127;
        W1t[c*72 + k] = f2bf(w1[(size_t)k * 128 + c]);
    }
    #pragma unroll
    for (int p = 0; p < 32; ++p) {
        int e = t + 256 * p; int k = e >> 6, c = e & 63;
        W2t[c*136 + k] = f2bf(w2[(size_t)k * 64 + c]);
    }
    __syncthreads();

    // mm1: e @ W1 (N=128): wave w owns cols w*32 + cf*16 + lr
    f32x4 acc1[4][2];
    #pragma unroll
    for (int rg = 0; rg < 4; ++rg)
        #pragma unroll
        for (int cf = 0; cf < 2; ++cf) acc1[rg][cf] = (f32x4){0.f,0.f,0.f,0.f};
    #pragma unroll
    for (int ks = 0; ks < 2; ++ks) {
        short8v af[4];
        #pragma unroll
        for (int rg = 0; rg < 4; ++rg)
            af[rg] = *(const short8v*)&hA[(rg*16 + lr)*72 + ks*32 + lg*8];
        #pragma unroll
        for (int cf = 0; cf < 2; ++cf) {
            short8v bf = *(const short8v*)&W1t[(w*32 + cf*16 + lr)*72 + ks*32 + lg*8];
            #pragma unroll
            for (int rg = 0; rg < 4; ++rg)
                acc1[rg][cf] = __builtin_amdgcn_mfma_f32_16x16x32_bf16(af[rg], bf, acc1[rg][cf], 0, 0, 0);
        }
    }
    // h -> hB (bf16, K-major for mm2)
    #pragma unroll
    for (int rg = 0; rg < 4; ++rg)
        #pragma unroll
        for (int cf = 0; cf < 2; ++cf)
            #pragma unroll
            for (int j = 0; j < 4; ++j) {
                int r = rg*16 + lg*4 + j, c = w*32 + cf*16 + lr;
                hB[r*136 + c] = f2bf(eluf_(acc1[rg][cf][j] + vb1[c]));
            }
    __syncthreads();   // hB visible; W1t dead everywhere

    // stage g1/g2 weights into U1
    #pragma unroll
    for (int p = 0; p < 16; ++p) {
        int e = t + 256 * p; int k = e >> 6, c = e & 63;
        G1t[c*72 + k] = f2bf(g1w[k*64 + c]);
        G2t[c*72 + k] = f2bf(g2w[k*64 + c]);
    }
    __syncthreads();

    // mm2: h @ W2 (K=128, N=64)
    f32x4 acc2[4];
    #pragma unroll
    for (int rg = 0; rg < 4; ++rg) acc2[rg] = (f32x4){0.f,0.f,0.f,0.f};
    #pragma unroll
    for (int ks = 0; ks < 4; ++ks) {
        short8v bf = *(const short8v*)&W2t[(w*16 + lr)*136 + ks*32 + lg*8];
        #pragma unroll
        for (int rg = 0; rg < 4; ++rg) {
            short8v af = *(const short8v*)&hB[(rg*16 + lr)*136 + ks*32 + lg*8];
            acc2[rg] = __builtin_amdgcn_mfma_f32_16x16x32_bf16(af, bf, acc2[rg], 0, 0, 0);
        }
    }
    // h2 -> hA (bf16)
    #pragma unroll
    for (int rg = 0; rg < 4; ++rg)
        #pragma unroll
        for (int j = 0; j < 4; ++j) {
            int r = rg*16 + lg*4 + j, c = w*16 + lr;
            hA[r*72 + c] = f2bf(acc2[rg][j] + vb2[c]);
        }
    __syncthreads();   // hA(h2) visible; W2t dead everywhere

    // mm3/4: GLU pair
    f32x4 aA[4], aB[4];
    #pragma unroll
    for (int rg = 0; rg < 4; ++rg) { aA[rg] = (f32x4){0.f,0.f,0.f,0.f}; aB[rg] = (f32x4){0.f,0.f,0.f,0.f}; }
    #pragma unroll
    for (int ks = 0; ks < 2; ++ks) {
        short8v b1f = *(const short8v*)&G1t[(w*16 + lr)*72 + ks*32 + lg*8];
        short8v b2f = *(const short8v*)&G2t[(w*16 + lr)*72 + ks*32 + lg*8];
        #pragma unroll
        for (int rg = 0; rg < 4; ++rg) {
            short8v af = *(const short8v*)&hA[(rg*16 + lr)*72 + ks*32 + lg*8];
            aA[rg] = __builtin_amdgcn_mfma_f32_16x16x32_bf16(af, b1f, aA[rg], 0, 0, 0);
            aB[rg] = __builtin_amdgcn_mfma_f32_16x16x32_bf16(af, b2f, aB[rg], 0, 0, 0);
        }
    }
    __syncthreads();   // W2t reads done -> yA may overlay

    #pragma unroll
    for (int rg = 0; rg < 4; ++rg)
        #pragma unroll
        for (int j = 0; j < 4; ++j) {
            int r = rg*16 + lg*4 + j, c = w*16 + lr;
            float sg = sigmoidf_(aA[rg][j] + vg1b[c]);
            yA[r*68 + c] = sg * (aB[rg][j] + vg2b[c]) + res[(size_t)(m0 + r) * 64 + c];
        }
    __syncthreads();

    const int tr = t >> 4, tc = t & 15;
    #pragma unroll
    for (int a = 0; a < 4; ++a) {
        const int r = tr + 16*a;
        float vals[4]; float part = 0.f;
        #pragma unroll
        for (int b = 0; b < 4; ++b) { vals[b] = yA[r*68 + tc + 16*b]; part += vals[b]; }
        #pragma unroll
        for (int off = 1; off < 16; off <<= 1) part += __shfl_xor(part, off);
        const float mean = part * (1.f / 64.f);
        float vp = 0.f;
        #pragma unroll
        for (int b = 0; b < 4; ++b) { float d = vals[b] - mean; vp += d * d; }
        #pragma unroll
        for (int off = 1; off < 16; off <<= 1) vp += __shfl_xor(vp, off);
        const float inv = rsqrtf(vp * (1.f / 64.f) + LN_EPS);
        #pragma unroll
        for (int b = 0; b < 4; ++b) {
            const int c = tc + 16*b;
            outf[(size_t)(m0 + r) * 64 + c] = (vals[b] - mean) * inv * vlng[c] + vlnb[c];
        }
    }
}

// =====================================================================
// head: mean over T -> fc1+relu -> fc2.  grid BB, 64 threads.
// =====================================================================
__global__ __launch_bounds__(64) void head_kernel(
    const float* __restrict__ outln,
    const float* __restrict__ fc1_w, const float* __restrict__ fc1_b,
    const float* __restrict__ fc2_w, const float* __restrict__ fc2_b,
    float* __restrict__ out)
{
    const int b = blockIdx.x, l = threadIdx.x;
    __shared__ float sp[64];
    float s = 0.f;
    #pragma unroll
    for (int tt = 0; tt < TSEQ; ++tt) s += outln[((size_t)(b * TSEQ + tt)) * 64 + l];
    sp[l] = s * (1.f / 24.f);
    __syncthreads();
    float a = fc1_b[l];
    for (int k = 0; k < 64; ++k) a += sp[k] * fc1_w[k*64 + l];
    float f1 = fmaxf(a, 0.f);
    #pragma unroll
    for (int j = 0; j < 6; ++j) {
        float p = f1 * fc2_w[l*6 + j];
        #pragma unroll
        for (int off = 32; off; off >>= 1) p += __shfl_xor(p, off);
        if (l == 0) out[b*6 + j] = p + fc2_b[j];
    }
}

// =====================================================================
extern "C" void kernel_launch(void* const* d_in, const int* in_sizes, int n_in,
                              void* d_out, int out_size, void* d_ws, size_t ws_size,
                              hipStream_t stream)
{
    const float* x        = (const float*)d_in[0];
    const float* f_w1     = (const float*)d_in[1];
    const float* f_b1     = (const float*)d_in[2];
    const float* f_w2     = (const float*)d_in[3];
    const float* f_b2     = (const float*)d_in[4];
    const float* f_g1w    = (const float*)d_in[5];
    const float* f_g1b    = (const float*)d_in[6];
    const float* f_g2w    = (const float*)d_in[7];
    const float* f_g2b    = (const float*)d_in[8];
    const float* f_skw    = (const float*)d_in[9];
    const float* f_skb    = (const float*)d_in[10];
    const float* f_lng    = (const float*)d_in[11];
    const float* f_lnb    = (const float*)d_in[12];
    const float* w_w1     = (const float*)d_in[13];
    const float* w_b1     = (const float*)d_in[14];
    const float* w_w2     = (const float*)d_in[15];
    const float* w_b2     = (const float*)d_in[16];
    const float* w_g1w    = (const float*)d_in[17];
    const float* w_g1b    = (const float*)d_in[18];
    const float* w_g2w    = (const float*)d_in[19];
    const float* w_g2b    = (const float*)d_in[20];
    const float* w_skw    = (const float*)d_in[21];
    const float* w_skb    = (const float*)d_in[22];
    const float* w_lng    = (const float*)d_in[23];
    const float* w_lnb    = (const float*)d_in[24];
    const float* lstm_wih = (const float*)d_in[25];
    const float* lstm_whh = (const float*)d_in[26];
    const float* lstm_bih = (const float*)d_in[27];
    const float* lstm_bhh = (const float*)d_in[28];
    const float* pl_g1w   = (const float*)d_in[29];
    const float* pl_g1b   = (const float*)d_in[30];
    const float* pl_g2w   = (const float*)d_in[31];
    const float* pl_g2b   = (const float*)d_in[32];
    const float* pl_lng   = (const float*)d_in[33];
    const float* pl_lnb   = (const float*)d_in[34];
    const float* attn_in_w  = (const float*)d_in[35];
    const float* attn_in_b  = (const float*)d_in[36];
    const float* attn_out_w = (const float*)d_in[37];
    const float* attn_out_b = (const float*)d_in[38];
    const float* pa_g1w   = (const float*)d_in[39];
    const float* pa_g1b   = (const float*)d_in[40];
    const float* pa_g2w   = (const float*)d_in[41];
    const float* pa_g2b   = (const float*)d_in[42];
    const float* pa_lng   = (const float*)d_in[43];
    const float* pa_lnb   = (const float*)d_in[44];
    const float* ff_w1    = (const float*)d_in[45];
    const float* ff_b1    = (const float*)d_in[46];
    const float* ff_w2    = (const float*)d_in[47];
    const float* ff_b2    = (const float*)d_in[48];
    const float* ff_g1w   = (const float*)d_in[49];
    const float* ff_g1b   = (const float*)d_in[50];
    const float* ff_g2w   = (const float*)d_in[51];
    const float* ff_g2b   = (const float*)d_in[52];
    const float* ff_lng   = (const float*)d_in[53];
    const float* ff_lnb   = (const float*)d_in[54];
    const float* fc1_w    = (const float*)d_in[55];
    const float* fc1_b    = (const float*)d_in[56];
    const float* fc2_w    = (const float*)d_in[57];
    const float* fc2_b    = (const float*)d_in[58];

    float* ws = (float*)d_ws;

    // ---------------- workspace layout -----------------------------------
    size_t o = 0;
    const size_t o_S0   = o; o += (size_t)MTOT * 256;   // xW / qkv
    const size_t o_A    = o; o += (size_t)MTOT * 64;    // lstm_out
    const size_t o_Bf   = o; o += (size_t)MTOT * 64;    // enriched f32
    const size_t o_Cf   = o; o += (size_t)MTOT * 64;    // outln f32
    const size_t o_Df   = o; o += (size_t)MTOT * 64;    // temporal f32
    const size_t o_F    = o; o += (size_t)MTOT * 128;   // bf16 trio: tb/ab/eb
    const size_t o_whhT = o; o += 16384;
    const size_t union_end = o;                          // 7,880,704 floats

    const size_t o_tb = o_F;                              // temporal bf16 (MTOT*64 elems)
    const size_t o_ab = o_F + (size_t)MTOT * 32;          // ao bf16
    const size_t o_eb = o_F + (size_t)MTOT * 64;          // enriched bf16

    // chunk-phase overlay (inside the union)
    const size_t o_partial = ((size_t)MC * FDIM) / 2;             // 3,981,312
    const size_t o_w81c    = o_partial + (size_t)KS * MC * NW;    // 6,193,152
    const size_t o_wcat    = o_w81c + (size_t)MC * 81;            // 6,317,568
    static_assert(6317568 + ((size_t)NW * FDIM) / 2 <= 7880704, "chunk phase must fit union");

    // persistent region
    o = union_end;
    const size_t o_sel  = o; o += (size_t)MTOT * 64;     // selected f32
    const size_t o_selb = o; o += (size_t)MTOT * 32;     // selected bf16
    const size_t need   = o;                             // 9,060,352 floats = 36.2 MB
    if (ws_size < need * sizeof(float)) return;

    const dim3 blk(256);

    // 0) pack weight-head matrices to bf16 (transposed)
    wprep_kernel<<<dim3((FDIM + 255) / 256, NW), blk, 0, stream>>>(
        w_w1, w_skw, (unsigned short*)(ws + o_wcat));

    // ---------------- phase 1: VSN + weight-GRN, chunked over M ----------
    for (int mb = 0; mb < MTOT; mb += MC) {
        __hip_bfloat16* chunk = (__hip_bfloat16*)ws;
        vsn_kernel<<<dim3(NF, MC / 64), blk, 0, stream>>>(
            x + (size_t)mb * NF, f_w1, f_b1, f_w2, f_b2, f_g1w, f_g1b,
            f_g2w, f_g2b, f_skw, f_skb, f_lng, f_lnb, chunk);
        wgemm_kernel<<<dim3(MC / 16, KS), dim3(64), 0, stream>>>(
            chunk, (const unsigned short*)(ws + o_wcat), ws + o_partial);
        wtail_kernel<<<dim3(MC / 4), blk, 0, stream>>>(
            ws + o_partial, w_b1, w_skb, w_w2, w_b2, w_g1w, w_g1b,
            w_g2w, w_g2b, w_lng, w_lnb, ws + o_w81c);
        selected_kernel<<<dim3(MC), blk, 0, stream>>>(
            chunk, ws + o_w81c, ws + o_sel + (size_t)mb * 64,
            (__hip_bfloat16*)(ws + o_selb) + (size_t)mb * 64);
    }

    // ---------------- phase 2: LSTM -> attention -> head -----------------
    lstm_prep_kernel<<<dim3(64), blk, 0, stream>>>(lstm_whh, ws + o_whhT);
    xw_kernel<<<dim3(MTOT / 64), blk, 0, stream>>>(
        (const __hip_bfloat16*)(ws + o_selb), lstm_wih, lstm_bih, lstm_bhh, ws + o_S0);
    lstm_kernel<<<dim3(BB / 4), blk, 0, stream>>>(ws + o_S0, ws + o_whhT, ws + o_A);
    fused_pl_kernel<<<dim3(MTOT / 64), blk, 0, stream>>>(
        ws + o_A, ws + o_sel, pl_g1w, pl_g1b, pl_g2w, pl_g2b, pl_lng, pl_lnb,
        ws + o_Df, (__hip_bfloat16*)(ws + o_tb));
    qkv_kernel<<<dim3(MTOT / 64), blk, 0, stream>>>(
        (const __hip_bfloat16*)(ws + o_tb), attn_in_w, attn_in_b, ws + o_S0);
    attn_kernel<<<dim3(BB), blk, 0, stream>>>(
        ws + o_S0, (__hip_bfloat16*)(ws + o_ab));
    fused_pa_kernel<<<dim3(MTOT / 64), blk, 0, stream>>>(
        (const __hip_bfloat16*)(ws + o_ab), ws + o_Df,
        attn_out_w, attn_out_b, pa_g1w, pa_g1b, pa_g2w, pa_g2b, pa_lng, pa_lnb,
        ws + o_Bf, (__hip_bfloat16*)(ws + o_eb));
    fused_ff_kernel<<<dim3(MTOT / 64), blk, 0, stream>>>(
        (const __hip_bfloat16*)(ws + o_eb), ws + o_Bf,
        ff_w1, ff_b1, ff_w2, ff_b2, ff_g1w, ff_g1b, ff_g2w, ff_g2b,
        ff_lng, ff_lnb, ws + o_Cf);
    head_kernel<<<dim3(BB), dim3(64), 0, stream>>>(
        ws + o_Cf, fc1_w, fc1_b, fc2_w, fc2_b, (float*)d_out);
}

// Round 6
// 1120.275 us; speedup vs baseline: 10.1478x; 1.0389x over previous
//
#include <hip/hip_runtime.h>
#include <hip/hip_bf16.h>
#include <math.h>

// ---------------- problem constants ----------------
constexpr int BB   = 512;
constexpr int TSEQ = 24;
constexpr int NF   = 81;
constexpr int DD   = 64;
constexpr int MTOT = BB * TSEQ;      // 12288
constexpr int FDIM = NF * DD;        // 5184
constexpr int MC   = 1536;           // M-chunk for VSN phase (8 chunks)
constexpr int KS   = 9;              // split-K groups for weight-head GEMM
constexpr int NW   = 160;            // padded combined N: 64 (wh1) + 81 (sk) + 15 pad
constexpr float LN_EPS = 1e-5f;

typedef __attribute__((ext_vector_type(8))) short short8v;   // 8 bf16 (4 VGPRs)
typedef __attribute__((ext_vector_type(4))) float f32x4;     // MFMA C/D

static __device__ __forceinline__ float sigmoidf_(float x) { return 1.f / (1.f + expf(-x)); }
static __device__ __forceinline__ float eluf_(float x)     { return x > 0.f ? x : (expf(x) - 1.f); }
static __device__ __forceinline__ unsigned short f2bf(float x) {
    __hip_bfloat16 h = __float2bfloat16(x);
    return *reinterpret_cast<unsigned short*>(&h);
}

// =====================================================================
// Kernel 1: VSN — 81 per-feature GRNs -> stacked chunk [MC, NF*64] (bf16)
// =====================================================================
__global__ __launch_bounds__(256) void vsn_kernel(
    const float* __restrict__ x,
    const float* __restrict__ f_w1,  const float* __restrict__ f_b1,
    const float* __restrict__ f_w2,  const float* __restrict__ f_b2,
    const float* __restrict__ f_g1w, const float* __restrict__ f_g1b,
    const float* __restrict__ f_g2w, const float* __restrict__ f_g2b,
    const float* __restrict__ f_skw, const float* __restrict__ f_skb,
    const float* __restrict__ f_lng, const float* __restrict__ f_lnb,
    __hip_bfloat16* __restrict__ stacked)
{
    const int f  = blockIdx.x;
    const int m0 = blockIdx.y * 64;
    const int t  = threadIdx.x;
    const int w  = t >> 6;
    const int l  = t & 63;
    const int lr = l & 15;
    const int lg = l >> 4;

    __shared__ __align__(16) unsigned short hA[64 * 72];
    __shared__ __align__(16) unsigned char  uS[18432];
    __shared__ float vw1[64], vb1[64], vb2[64], vg1b[64], vg2b[64];
    __shared__ float vskw[64], vskb[64], vlng[64], vlnb[64], xv[64];

    unsigned short* Wt0 = (unsigned short*)uS;
    unsigned short* Wt1 = (unsigned short*)(uS + 9216);
    float*          yA  = (float*)uS;

    if (t < 64) {
        vw1[t]  = f_w1 [f*64 + t];  vb1[t]  = f_b1 [f*64 + t];
        vb2[t]  = f_b2 [f*64 + t];
        vg1b[t] = f_g1b[f*64 + t];  vg2b[t] = f_g2b[f*64 + t];
        vskw[t] = f_skw[f*64 + t];  vskb[t] = f_skb[f*64 + t];
        vlng[t] = f_lng[f*64 + t];  vlnb[t] = f_lnb[f*64 + t];
        xv[t]   = x[(size_t)(m0 + t) * NF + f];
    }
    __syncthreads();

    {
        const float* w2p = f_w2 + (size_t)f * 4096;
        #pragma unroll
        for (int p = 0; p < 16; ++p) {
            int e = t + 256 * p; int k = e >> 6, c = e & 63;
            Wt0[c*72 + k] = f2bf(w2p[k*64 + c]);
        }
        #pragma unroll
        for (int p = 0; p < 16; ++p) {
            int e = t + 256 * p; int r = e >> 6, d = e & 63;
            hA[r*72 + d] = f2bf(eluf_(xv[r] * vw1[d] + vb1[d]));
        }
    }
    __syncthreads();

    f32x4 acc1[4];
    #pragma unroll
    for (int rg = 0; rg < 4; ++rg) acc1[rg] = (f32x4){0.f, 0.f, 0.f, 0.f};
    #pragma unroll
    for (int ks = 0; ks < 2; ++ks) {
        short8v bf = *(const short8v*)&Wt0[(w*16 + lr)*72 + ks*32 + lg*8];
        #pragma unroll
        for (int rg = 0; rg < 4; ++rg) {
            short8v af = *(const short8v*)&hA[(rg*16 + lr)*72 + ks*32 + lg*8];
            acc1[rg] = __builtin_amdgcn_mfma_f32_16x16x32_bf16(af, bf, acc1[rg], 0, 0, 0);
        }
    }
    {
        const float* g1p = f_g1w + (size_t)f * 4096;
        #pragma unroll
        for (int p = 0; p < 16; ++p) {
            int e = t + 256 * p; int k = e >> 6, c = e & 63;
            Wt1[c*72 + k] = f2bf(g1p[k*64 + c]);
        }
    }
    __syncthreads();

    #pragma unroll
    for (int rg = 0; rg < 4; ++rg)
        #pragma unroll
        for (int j = 0; j < 4; ++j) {
            int r = rg*16 + lg*4 + j, c = w*16 + lr;
            hA[r*72 + c] = f2bf(acc1[rg][j] + vb2[c]);
        }
    {
        const float* g2p = f_g2w + (size_t)f * 4096;
        #pragma unroll
        for (int p = 0; p < 16; ++p) {
            int e = t + 256 * p; int k = e >> 6, c = e & 63;
            Wt0[c*72 + k] = f2bf(g2p[k*64 + c]);
        }
    }
    __syncthreads();

    f32x4 aA[4], aB[4];
    #pragma unroll
    for (int rg = 0; rg < 4; ++rg) { aA[rg] = (f32x4){0.f,0.f,0.f,0.f}; aB[rg] = (f32x4){0.f,0.f,0.f,0.f}; }
    #pragma unroll
    for (int ks = 0; ks < 2; ++ks) {
        short8v b1f = *(const short8v*)&Wt1[(w*16 + lr)*72 + ks*32 + lg*8];
        short8v b2f = *(const short8v*)&Wt0[(w*16 + lr)*72 + ks*32 + lg*8];
        #pragma unroll
        for (int rg = 0; rg < 4; ++rg) {
            short8v af = *(const short8v*)&hA[(rg*16 + lr)*72 + ks*32 + lg*8];
            aA[rg] = __builtin_amdgcn_mfma_f32_16x16x32_bf16(af, b1f, aA[rg], 0, 0, 0);
            aB[rg] = __builtin_amdgcn_mfma_f32_16x16x32_bf16(af, b2f, aB[rg], 0, 0, 0);
        }
    }
    __syncthreads();

    #pragma unroll
    for (int rg = 0; rg < 4; ++rg)
        #pragma unroll
        for (int j = 0; j < 4; ++j) {
            int r = rg*16 + lg*4 + j, c = w*16 + lr;
            float sg = sigmoidf_(aA[rg][j] + vg1b[c]);
            float y  = sg * (aB[rg][j] + vg2b[c]) + xv[r] * vskw[c] + vskb[c];
            yA[r*68 + c] = y;
        }
    __syncthreads();

    const int tr = t >> 4, tc = t & 15;
    #pragma unroll
    for (int a = 0; a < 4; ++a) {
        const int r = tr + 16*a;
        float vals[4];
        float part = 0.f;
        #pragma unroll
        for (int b = 0; b < 4; ++b) { vals[b] = yA[r*68 + tc + 16*b]; part += vals[b]; }
        #pragma unroll
        for (int off = 1; off < 16; off <<= 1) part += __shfl_xor(part, off);
        const float mean = part * (1.f / 64.f);
        float vp = 0.f;
        #pragma unroll
        for (int b = 0; b < 4; ++b) { float d = vals[b] - mean; vp += d * d; }
        #pragma unroll
        for (int off = 1; off < 16; off <<= 1) vp += __shfl_xor(vp, off);
        const float inv = rsqrtf(vp * (1.f / 64.f) + LN_EPS);
        const size_t base = (size_t)(m0 + r) * FDIM + (size_t)f * 64;
        #pragma unroll
        for (int b = 0; b < 4; ++b) {
            const int c = tc + 16*b;
            stacked[base + c] = __float2bfloat16((vals[b] - mean) * inv * vlng[c] + vlnb[c]);
        }
    }
}

// =====================================================================
// Pack w_w1 / w_skw into bf16 WcatT[160][FDIM]
// =====================================================================
__global__ void wprep_kernel(
    const float* __restrict__ w_w1, const float* __restrict__ w_skw,
    unsigned short* __restrict__ WcatT)
{
    const int c = blockIdx.y;
    const int k = blockIdx.x * 256 + threadIdx.x;
    if (k >= FDIM) return;
    float v = 0.f;
    if (c < 64)       v = w_w1[(size_t)k * 64 + c];
    else if (c < 145) v = w_skw[(size_t)k * 81 + (c - 64)];
    WcatT[(size_t)c * FDIM + k] = f2bf(v);
}

// =====================================================================
// Split-K fused weight-head GEMM (MFMA, LDS-free)
// =====================================================================
__global__ __launch_bounds__(64) void wgemm_kernel(
    const __hip_bfloat16* __restrict__ stacked,
    const unsigned short* __restrict__ WcatT,
    float* __restrict__ partial)
{
    const int m0 = blockIdx.x * 16;
    const int ks = blockIdx.y;
    const int l  = threadIdx.x;
    const int lr = l & 15, lg = l >> 4;

    f32x4 acc[10];
    #pragma unroll
    for (int n = 0; n < 10; ++n) acc[n] = (f32x4){0.f, 0.f, 0.f, 0.f};

    const size_t arow = (size_t)(m0 + lr) * FDIM;
    const int k0base = ks * 576;
    for (int kk = 0; kk < 576; kk += 32) {
        const int k = k0base + kk + lg * 8;
        short8v af = *(const short8v*)(stacked + arow + k);
        #pragma unroll
        for (int n = 0; n < 10; ++n) {
            short8v bf = *(const short8v*)(WcatT + (size_t)(n*16 + lr) * FDIM + k);
            acc[n] = __builtin_amdgcn_mfma_f32_16x16x32_bf16(af, bf, acc[n], 0, 0, 0);
        }
    }
    #pragma unroll
    for (int n = 0; n < 10; ++n)
        #pragma unroll
        for (int j = 0; j < 4; ++j) {
            const int m = m0 + lg*4 + j;
            partial[((size_t)ks * MC + m) * NW + n*16 + lr] = acc[n][j];
        }
}

// =====================================================================
// Weight-GRN tail v2: LDS-staged weights, 16 rows/block (4 waves x 4 rows)
// grid MC/16 = 96 blocks, 256 threads. ~83 KB LDS -> 1 block/CU.
// =====================================================================
__global__ __launch_bounds__(256) void wtail_kernel(
    const float* __restrict__ partial,
    const float* __restrict__ w_b1,  const float* __restrict__ w_skb,
    const float* __restrict__ w_w2,  const float* __restrict__ w_b2,
    const float* __restrict__ w_g1w, const float* __restrict__ w_g1b,
    const float* __restrict__ w_g2w, const float* __restrict__ w_g2b,
    const float* __restrict__ w_lng, const float* __restrict__ w_lnb,
    float* __restrict__ w81)
{
    __shared__ float w2s[5184];      // w_w2  [64][81]
    __shared__ float g1s[6561];      // w_g1w [81][81]
    __shared__ float g2s[6561];      // w_g2w [81][81]
    __shared__ float sWh[16][64];
    __shared__ float sW2[16][96];

    const int t  = threadIdx.x;
    const int wv = t >> 6, l = t & 63;
    const int m0 = blockIdx.x * 16;
    const bool v1 = (l < 17);

    for (int e = t; e < 5184; e += 256) w2s[e] = w_w2[e];
    for (int e = t; e < 6561; e += 256) { g1s[e] = w_g1w[e]; g2s[e] = w_g2w[e]; }

    // ---- reduce split-K partials (4 rows per wave) ----
    float s0[4], sk0[4], sk1[4];
    {
        const float b1v = w_b1[l], skb0 = w_skb[l], skb1 = v1 ? w_skb[64 + l] : 0.f;
        #pragma unroll
        for (int rr = 0; rr < 4; ++rr) { s0[rr] = b1v; sk0[rr] = skb0; sk1[rr] = skb1; }
    }
    #pragma unroll
    for (int ks = 0; ks < KS; ++ks) {
        #pragma unroll
        for (int rr = 0; rr < 4; ++rr) {
            const float* pr = partial + ((size_t)ks * MC + (m0 + wv*4 + rr)) * NW;
            s0[rr]  += pr[l];
            sk0[rr] += pr[64 + l];
            if (v1) sk1[rr] += pr[128 + l];
        }
    }
    #pragma unroll
    for (int rr = 0; rr < 4; ++rr) sWh[wv*4 + rr][l] = eluf_(s0[rr]);
    __syncthreads();   // sWh + staged weights ready

    // ---- wh2 = wh1 @ w_w2 + b2  (64 -> 81) ----
    float a0[4], a1[4];
    {
        const float b0 = w_b2[l], b1v = v1 ? w_b2[64 + l] : 0.f;
        #pragma unroll
        for (int rr = 0; rr < 4; ++rr) { a0[rr] = b0; a1[rr] = b1v; }
    }
    #pragma unroll 4
    for (int i = 0; i < 64; ++i) {
        const float wl = w2s[i*81 + l];
        const float wh = v1 ? w2s[i*81 + 64 + l] : 0.f;
        #pragma unroll
        for (int rr = 0; rr < 4; ++rr) {
            const float h = sWh[wv*4 + rr][i];
            a0[rr] += h * wl;
            a1[rr] += h * wh;
        }
    }
    #pragma unroll
    for (int rr = 0; rr < 4; ++rr) {
        sW2[wv*4 + rr][l] = a0[rr];
        if (v1) sW2[wv*4 + rr][64 + l] = a1[rr];
    }
    __syncthreads();

    // ---- GLU (81 -> 81, two mats) ----
    float g10[4], g20[4], g11[4], g21[4];
    {
        const float c10 = w_g1b[l], c20 = w_g2b[l];
        const float c11 = v1 ? w_g1b[64 + l] : 0.f, c21 = v1 ? w_g2b[64 + l] : 0.f;
        #pragma unroll
        for (int rr = 0; rr < 4; ++rr) { g10[rr] = c10; g20[rr] = c20; g11[rr] = c11; g21[rr] = c21; }
    }
    #pragma unroll 3
    for (int i = 0; i < 81; ++i) {
        const float w1l = g1s[i*81 + l],            w2l = g2s[i*81 + l];
        const float w1h = v1 ? g1s[i*81 + 64 + l] : 0.f;
        const float w2h = v1 ? g2s[i*81 + 64 + l] : 0.f;
        #pragma unroll
        for (int rr = 0; rr < 4; ++rr) {
            const float h = sW2[wv*4 + rr][i];
            g10[rr] += h * w1l; g20[rr] += h * w2l;
            g11[rr] += h * w1h; g21[rr] += h * w2h;
        }
    }

    // ---- per-row LN(81) + softmax(81) ----
    #pragma unroll
    for (int rr = 0; rr < 4; ++rr) {
        const int m = m0 + wv*4 + rr;
        float y0 = sigmoidf_(g10[rr]) * g20[rr] + sk0[rr];
        float y1 = v1 ? (sigmoidf_(g11[rr]) * g21[rr] + sk1[rr]) : 0.f;

        float s = y0 + (v1 ? y1 : 0.f);
        #pragma unroll
        for (int off = 32; off; off >>= 1) s += __shfl_xor(s, off);
        const float mean = s / 81.f;
        float d0 = y0 - mean, d1 = v1 ? (y1 - mean) : 0.f;
        float vs = d0*d0 + (v1 ? d1*d1 : 0.f);
        #pragma unroll
        for (int off = 32; off; off >>= 1) vs += __shfl_xor(vs, off);
        const float inv = rsqrtf(vs / 81.f + LN_EPS);
        float wn0 = d0 * inv * w_lng[l] + w_lnb[l];
        float wn1 = v1 ? (d1 * inv * w_lng[64 + l] + w_lnb[64 + l]) : -1e30f;

        float mx = fmaxf(wn0, wn1);
        #pragma unroll
        for (int off = 32; off; off >>= 1) mx = fmaxf(mx, __shfl_xor(mx, off));
        float e0 = expf(wn0 - mx), e1 = v1 ? expf(wn1 - mx) : 0.f;
        float es = e0 + e1;
        #pragma unroll
        for (int off = 32; off; off >>= 1) es += __shfl_xor(es, off);
        const float r = 1.f / es;
        w81[(size_t)m * 81 + l] = e0 * r;
        if (v1) w81[(size_t)m * 81 + 64 + l] = e1 * r;
    }
}

// =====================================================================
// selected: f32 + bf16 outputs
// =====================================================================
__global__ __launch_bounds__(256) void selected_kernel(
    const __hip_bfloat16* __restrict__ stacked, const float* __restrict__ w81,
    float* __restrict__ sel, __hip_bfloat16* __restrict__ selb)
{
    const int m = blockIdx.x;
    const int d = threadIdx.x & 63, fg = threadIdx.x >> 6;
    __shared__ float red[4][64];
    __shared__ float wsh[81];
    if (threadIdx.x < 81) wsh[threadIdx.x] = w81[(size_t)m * 81 + threadIdx.x];
    __syncthreads();
    float acc = 0.f;
    for (int f = fg; f < 81; f += 4)
        acc += __bfloat162float(stacked[(size_t)m * FDIM + f*64 + d]) * wsh[f];
    red[fg][d] = acc;
    __syncthreads();
    if (fg == 0) {
        float v = red[0][d] + red[1][d] + red[2][d] + red[3][d];
        sel[(size_t)m * 64 + d]  = v;
        selb[(size_t)m * 64 + d] = __float2bfloat16(v);
    }
}

// =====================================================================
// xW = selb @ wih^T + (bih+bhh)    MFMA, grid MTOT/64 blocks, 256 thr
// =====================================================================
__global__ __launch_bounds__(256) void xw_kernel(
    const __hip_bfloat16* __restrict__ selb,
    const float* __restrict__ wih,
    const float* __restrict__ bih, const float* __restrict__ bhh,
    float* __restrict__ xW)
{
    const int m0 = blockIdx.x * 64;
    const int t = threadIdx.x;
    const int w = t >> 6, l = t & 63, lr = l & 15, lg = l >> 4;
    __shared__ __align__(16) unsigned short hA[64 * 72];
    __shared__ __align__(16) unsigned short Wt[256 * 72];
    __shared__ float vbs[256];

    vbs[t] = bih[t] + bhh[t];
    #pragma unroll
    for (int p = 0; p < 16; ++p) {
        int e = t + 256 * p; int r = e >> 6, d = e & 63;
        hA[r*72 + d] = *(const unsigned short*)&selb[(size_t)(m0 + r) * 64 + d];
    }
    #pragma unroll
    for (int p = 0; p < 64; ++p) {
        int e = t + 256 * p; int c = e >> 6, k = e & 63;
        Wt[c*72 + k] = f2bf(wih[c*64 + k]);
    }
    __syncthreads();

    f32x4 acc[4][4];
    #pragma unroll
    for (int rg = 0; rg < 4; ++rg)
        #pragma unroll
        for (int cf = 0; cf < 4; ++cf) acc[rg][cf] = (f32x4){0.f,0.f,0.f,0.f};
    #pragma unroll
    for (int ks = 0; ks < 2; ++ks) {
        short8v af[4];
        #pragma unroll
        for (int rg = 0; rg < 4; ++rg)
            af[rg] = *(const short8v*)&hA[(rg*16 + lr)*72 + ks*32 + lg*8];
        #pragma unroll
        for (int cf = 0; cf < 4; ++cf) {
            short8v bf = *(const short8v*)&Wt[(w*64 + cf*16 + lr)*72 + ks*32 + lg*8];
            #pragma unroll
            for (int rg = 0; rg < 4; ++rg)
                acc[rg][cf] = __builtin_amdgcn_mfma_f32_16x16x32_bf16(af[rg], bf, acc[rg][cf], 0, 0, 0);
        }
    }
    #pragma unroll
    for (int rg = 0; rg < 4; ++rg)
        #pragma unroll
        for (int cf = 0; cf < 4; ++cf)
            #pragma unroll
            for (int j = 0; j < 4; ++j) {
                int r = rg*16 + lg*4 + j, c = w*64 + cf*16 + lr;
                xW[(size_t)(m0 + r) * 256 + c] = acc[rg][cf][j] + vbs[c];
            }
}

// =====================================================================
// LSTM prep: transpose whh ([4H,64] -> [64,4H])
// =====================================================================
__global__ void lstm_prep_kernel(
    const float* __restrict__ whh, float* __restrict__ whhT)
{
    int id = blockIdx.x * 256 + threadIdx.x;
    if (id < 16384) {
        int i = id >> 8, j = id & 255;
        whhT[id] = whh[j*64 + i];
    }
}

// =====================================================================
// LSTM recurrence v2: whhT column in registers (64 VGPR),
// xW loads double-buffered across timesteps. grid 128, 256 thr.
// =====================================================================
__global__ __launch_bounds__(256) void lstm_kernel(
    const float* __restrict__ xW, const float* __restrict__ whhT,
    float* __restrict__ out)
{
    __shared__ float sh[4][64];
    __shared__ float sg[4][256];
    const int t = threadIdx.x;
    const int b0 = blockIdx.x * 4;
    const int rr = t >> 6, dd = t & 63;

    float wreg[64];
    #pragma unroll
    for (int i = 0; i < 64; ++i) wreg[i] = whhT[i*256 + t];

    sh[rr][dd] = 0.f;
    float c_reg = 0.f;

    float xnext[4];
    #pragma unroll
    for (int r = 0; r < 4; ++r)
        xnext[r] = xW[((size_t)(b0 + r) * TSEQ + 0) * 256 + t];
    __syncthreads();

    for (int tt = 0; tt < TSEQ; ++tt) {
        float acc[4];
        #pragma unroll
        for (int r = 0; r < 4; ++r) acc[r] = xnext[r];
        // prefetch next timestep's xW early (hides under the FMA block)
        if (tt + 1 < TSEQ) {
            #pragma unroll
            for (int r = 0; r < 4; ++r)
                xnext[r] = xW[((size_t)(b0 + r) * TSEQ + tt + 1) * 256 + t];
        }
        #pragma unroll
        for (int i = 0; i < 64; ++i) {
            #pragma unroll
            for (int r = 0; r < 4; ++r) acc[r] += sh[r][i] * wreg[i];
        }
        __syncthreads();   // all sh reads done
        #pragma unroll
        for (int r = 0; r < 4; ++r) sg[r][t] = acc[r];
        __syncthreads();
        {
            float gi = sg[rr][dd], gf = sg[rr][64 + dd], gg = sg[rr][128 + dd], go = sg[rr][192 + dd];
            c_reg = sigmoidf_(gf) * c_reg + sigmoidf_(gi) * tanhf(gg);
            float hn = sigmoidf_(go) * tanhf(c_reg);
            sh[rr][dd] = hn;
            out[((size_t)(b0 + rr) * TSEQ + tt) * 64 + dd] = hn;
        }
        __syncthreads();
    }
}

// =====================================================================
// fused GLU pair + residual + LN (post-LSTM)
// =====================================================================
__global__ __launch_bounds__(256) void fused_pl_kernel(
    const float* __restrict__ in, const float* __restrict__ res,
    const float* __restrict__ g1w, const float* __restrict__ g1b,
    const float* __restrict__ g2w, const float* __restrict__ g2b,
    const float* __restrict__ lng, const float* __restrict__ lnb,
    float* __restrict__ outf, __hip_bfloat16* __restrict__ outb)
{
    const int m0 = blockIdx.x * 64;
    const int t = threadIdx.x;
    const int w = t >> 6, l = t & 63, lr = l & 15, lg = l >> 4;
    __shared__ __align__(16) unsigned short hA[64 * 72];
    __shared__ __align__(16) unsigned char uS[18432];
    unsigned short* Wt0 = (unsigned short*)uS;
    unsigned short* Wt1 = (unsigned short*)(uS + 9216);
    float* yA = (float*)uS;
    __shared__ float vg1b[64], vg2b[64], vlng[64], vlnb[64];

    if (t < 64) { vg1b[t] = g1b[t]; vg2b[t] = g2b[t]; vlng[t] = lng[t]; vlnb[t] = lnb[t]; }
    #pragma unroll
    for (int p = 0; p < 16; ++p) {
        int e = t + 256 * p; int r = e >> 6, d = e & 63;
        hA[r*72 + d] = f2bf(in[(size_t)(m0 + r) * 64 + d]);
    }
    #pragma unroll
    for (int p = 0; p < 16; ++p) {
        int e = t + 256 * p; int k = e >> 6, c = e & 63;
        Wt0[c*72 + k] = f2bf(g1w[k*64 + c]);
        Wt1[c*72 + k] = f2bf(g2w[k*64 + c]);
    }
    __syncthreads();

    f32x4 aA[4], aB[4];
    #pragma unroll
    for (int rg = 0; rg < 4; ++rg) { aA[rg] = (f32x4){0.f,0.f,0.f,0.f}; aB[rg] = (f32x4){0.f,0.f,0.f,0.f}; }
    #pragma unroll
    for (int ks = 0; ks < 2; ++ks) {
        short8v b0f = *(const short8v*)&Wt0[(w*16 + lr)*72 + ks*32 + lg*8];
        short8v b1f = *(const short8v*)&Wt1[(w*16 + lr)*72 + ks*32 + lg*8];
        #pragma unroll
        for (int rg = 0; rg < 4; ++rg) {
            short8v af = *(const short8v*)&hA[(rg*16 + lr)*72 + ks*32 + lg*8];
            aA[rg] = __builtin_amdgcn_mfma_f32_16x16x32_bf16(af, b0f, aA[rg], 0, 0, 0);
            aB[rg] = __builtin_amdgcn_mfma_f32_16x16x32_bf16(af, b1f, aB[rg], 0, 0, 0);
        }
    }
    __syncthreads();

    #pragma unroll
    for (int rg = 0; rg < 4; ++rg)
        #pragma unroll
        for (int j = 0; j < 4; ++j) {
            int r = rg*16 + lg*4 + j, c = w*16 + lr;
            float sg = sigmoidf_(aA[rg][j] + vg1b[c]);
            yA[r*68 + c] = sg * (aB[rg][j] + vg2b[c]) + res[(size_t)(m0 + r) * 64 + c];
        }
    __syncthreads();

    const int tr = t >> 4, tc = t & 15;
    #pragma unroll
    for (int a = 0; a < 4; ++a) {
        const int r = tr + 16*a;
        float vals[4]; float part = 0.f;
        #pragma unroll
        for (int b = 0; b < 4; ++b) { vals[b] = yA[r*68 + tc + 16*b]; part += vals[b]; }
        #pragma unroll
        for (int off = 1; off < 16; off <<= 1) part += __shfl_xor(part, off);
        const float mean = part * (1.f / 64.f);
        float vp = 0.f;
        #pragma unroll
        for (int b = 0; b < 4; ++b) { float d = vals[b] - mean; vp += d * d; }
        #pragma unroll
        for (int off = 1; off < 16; off <<= 1) vp += __shfl_xor(vp, off);
        const float inv = rsqrtf(vp * (1.f / 64.f) + LN_EPS);
        #pragma unroll
        for (int b = 0; b < 4; ++b) {
            const int c = tc + 16*b;
            float v = (vals[b] - mean) * inv * vlng[c] + vlnb[c];
            outf[(size_t)(m0 + r) * 64 + c] = v;
            outb[(size_t)(m0 + r) * 64 + c] = __float2bfloat16(v);
        }
    }
}

// =====================================================================
// qkv = temporal_bf16 @ attn_in_w[64,192] + b
// =====================================================================
__global__ __launch_bounds__(256) void qkv_kernel(
    const __hip_bfloat16* __restrict__ tb,
    const float* __restrict__ wqkv, const float* __restrict__ bqkv,
    float* __restrict__ qkv)
{
    const int m0 = blockIdx.x * 64;
    const int t = threadIdx.x;
    const int w = t >> 6, l = t & 63, lr = l & 15, lg = l >> 4;
    __shared__ __align__(16) unsigned short hA[64 * 72];
    __shared__ __align__(16) unsigned short Wt[192 * 72];
    __shared__ float vb[192];

    if (t < 192) vb[t] = bqkv[t];
    #pragma unroll
    for (int p = 0; p < 16; ++p) {
        int e = t + 256 * p; int r = e >> 6, d = e & 63;
        hA[r*72 + d] = *(const unsigned short*)&tb[(size_t)(m0 + r) * 64 + d];
    }
    #pragma unroll
    for (int p = 0; p < 48; ++p) {
        int e = t + 256 * p; int c = e >> 6, k = e & 63;
        Wt[c*72 + k] = f2bf(wqkv[(size_t)k * 192 + c]);
    }
    __syncthreads();

    f32x4 acc[4][3];
    #pragma unroll
    for (int rg = 0; rg < 4; ++rg)
        #pragma unroll
        for (int cf = 0; cf < 3; ++cf) acc[rg][cf] = (f32x4){0.f,0.f,0.f,0.f};
    #pragma unroll
    for (int ks = 0; ks < 2; ++ks) {
        short8v af[4];
        #pragma unroll
        for (int rg = 0; rg < 4; ++rg)
            af[rg] = *(const short8v*)&hA[(rg*16 + lr)*72 + ks*32 + lg*8];
        #pragma unroll
        for (int cf = 0; cf < 3; ++cf) {
            short8v bf = *(const short8v*)&Wt[(w*48 + cf*16 + lr)*72 + ks*32 + lg*8];
            #pragma unroll
            for (int rg = 0; rg < 4; ++rg)
                acc[rg][cf] = __builtin_amdgcn_mfma_f32_16x16x32_bf16(af[rg], bf, acc[rg][cf], 0, 0, 0);
        }
    }
    #pragma unroll
    for (int rg = 0; rg < 4; ++rg)
        #pragma unroll
        for (int cf = 0; cf < 3; ++cf)
            #pragma unroll
            for (int j = 0; j < 4; ++j) {
                int r = rg*16 + lg*4 + j, c = w*48 + cf*16 + lr;
                qkv[(size_t)(m0 + r) * 192 + c] = acc[rg][cf][j] + vb[c];
            }
}

// =====================================================================
// MHA core -> ao bf16
// =====================================================================
__global__ __launch_bounds__(256) void attn_kernel(
    const float* __restrict__ qkv, __hip_bfloat16* __restrict__ ao)
{
    const int b = blockIdx.x;
    const int h = threadIdx.x >> 6, l = threadIdx.x & 63;
    __shared__ float sq[4][24][16], sk[4][24][16], sv[4][24][16], sp[4][24][24];
    #pragma unroll
    for (int p = 0; p < 6; ++p) {
        int e = l + 64 * p; int ti = e >> 4, d = e & 15;
        size_t base = ((size_t)(b * TSEQ + ti)) * 192 + h * 16 + d;
        sq[h][ti][d] = qkv[base];
        sk[h][ti][d] = qkv[base + 64];
        sv[h][ti][d] = qkv[base + 128];
    }
    __syncthreads();
    #pragma unroll
    for (int p = 0; p < 9; ++p) {
        int e = l + 64 * p; int i = e / 24, j = e - i * 24;
        float s = 0.f;
        #pragma unroll
        for (int d = 0; d < 16; ++d) s += sq[h][i][d] * sk[h][j][d];
        sp[h][i][j] = s * 0.25f;
    }
    __syncthreads();
    if (l < 24) {
        float mx = -1e30f;
        for (int j = 0; j < 24; ++j) mx = fmaxf(mx, sp[h][l][j]);
        float s = 0.f;
        for (int j = 0; j < 24; ++j) { float e = expf(sp[h][l][j] - mx); sp[h][l][j] = e; s += e; }
        float inv = 1.f / s;
        for (int j = 0; j < 24; ++j) sp[h][l][j] *= inv;
    }
    __syncthreads();
    #pragma unroll
    for (int p = 0; p < 6; ++p) {
        int e = l + 64 * p; int ti = e >> 4, d = e & 15;
        float s = 0.f;
        #pragma unroll
        for (int j = 0; j < 24; ++j) s += sp[h][ti][j] * sv[h][j][d];
        ao[((size_t)(b * TSEQ + ti)) * 64 + h * 16 + d] = __float2bfloat16(s);
    }
}

// =====================================================================
// fused post-attn: ao@Wout+b -> GLU(pa) -> +temporal -> LN -> enriched
// =====================================================================
__global__ __launch_bounds__(256) void fused_pa_kernel(
    const __hip_bfloat16* __restrict__ ao, const float* __restrict__ res,
    const float* __restrict__ wout, const float* __restrict__ bout,
    const float* __restrict__ g1w, const float* __restrict__ g1b,
    const float* __restrict__ g2w, const float* __restrict__ g2b,
    const float* __restrict__ lng, const float* __restrict__ lnb,
    float* __restrict__ outf, __hip_bfloat16* __restrict__ outb)
{
    const int m0 = blockIdx.x * 64;
    const int t = threadIdx.x;
    const int w = t >> 6, l = t & 63, lr = l & 15, lg = l >> 4;
    __shared__ __align__(16) unsigned short hA[64 * 72];
    __shared__ __align__(16) unsigned char uS[18432];
    unsigned short* Wt0 = (unsigned short*)uS;
    unsigned short* Wt1 = (unsigned short*)(uS + 9216);
    float* yA = (float*)uS;
    __shared__ float vob[64], vg1b[64], vg2b[64], vlng[64], vlnb[64];

    if (t < 64) { vob[t] = bout[t]; vg1b[t] = g1b[t]; vg2b[t] = g2b[t]; vlng[t] = lng[t]; vlnb[t] = lnb[t]; }
    #pragma unroll
    for (int p = 0; p < 16; ++p) {
        int e = t + 256 * p; int r = e >> 6, d = e & 63;
        hA[r*72 + d] = *(const unsigned short*)&ao[(size_t)(m0 + r) * 64 + d];
    }
    #pragma unroll
    for (int p = 0; p < 16; ++p) {
        int e = t + 256 * p; int k = e >> 6, c = e & 63;
        Wt0[c*72 + k] = f2bf(wout[k*64 + c]);
    }
    __syncthreads();

    f32x4 acc1[4];
    #pragma unroll
    for (int rg = 0; rg < 4; ++rg) acc1[rg] = (f32x4){0.f,0.f,0.f,0.f};
    #pragma unroll
    for (int ks = 0; ks < 2; ++ks) {
        short8v bf = *(const short8v*)&Wt0[(w*16 + lr)*72 + ks*32 + lg*8];
        #pragma unroll
        for (int rg = 0; rg < 4; ++rg) {
            short8v af = *(const short8v*)&hA[(rg*16 + lr)*72 + ks*32 + lg*8];
            acc1[rg] = __builtin_amdgcn_mfma_f32_16x16x32_bf16(af, bf, acc1[rg], 0, 0, 0);
        }
    }
    #pragma unroll
    for (int p = 0; p < 16; ++p) {
        int e = t + 256 * p; int k = e >> 6, c = e & 63;
        Wt1[c*72 + k] = f2bf(g1w[k*64 + c]);
    }
    __syncthreads();

    #pragma unroll
    for (int rg = 0; rg < 4; ++rg)
        #pragma unroll
        for (int j = 0; j < 4; ++j) {
            int r = rg*16 + lg*4 + j, c = w*16 + lr;
            hA[r*72 + c] = f2bf(acc1[rg][j] + vob[c]);
        }
    #pragma unroll
    for (int p = 0; p < 16; ++p) {
        int e = t + 256 * p; int k = e >> 6, c = e & 63;
        Wt0[c*72 + k] = f2bf(g2w[k*64 + c]);
    }
    __syncthreads();

    f32x4 aA[4], aB[4];
    #pragma unroll
    for (int rg = 0; rg < 4; ++rg) { aA[rg] = (f32x4){0.f,0.f,0.f,0.f}; aB[rg] = (f32x4){0.f,0.f,0.f,0.f}; }
    #pragma unroll
    for (int ks = 0; ks < 2; ++ks) {
        short8v b1f = *(const short8v*)&Wt1[(w*16 + lr)*72 + ks*32 + lg*8];
        short8v b2f = *(const short8v*)&Wt0[(w*16 + lr)*72 + ks*32 + lg*8];
        #pragma unroll
        for (int rg = 0; rg < 4; ++rg) {
            short8v af = *(const short8v*)&hA[(rg*16 + lr)*72 + ks*32 + lg*8];
            aA[rg] = __builtin_amdgcn_mfma_f32_16x16x32_bf16(af, b1f, aA[rg], 0, 0, 0);
            aB[rg] = __builtin_amdgcn_mfma_f32_16x16x32_bf16(af, b2f, aB[rg], 0, 0, 0);
        }
    }
    __syncthreads();

    #pragma unroll
    for (int rg = 0; rg < 4; ++rg)
        #pragma unroll
        for (int j = 0; j < 4; ++j) {
            int r = rg*16 + lg*4 + j, c = w*16 + lr;
            float sg = sigmoidf_(aA[rg][j] + vg1b[c]);
            yA[r*68 + c] = sg * (aB[rg][j] + vg2b[c]) + res[(size_t)(m0 + r) * 64 + c];
        }
    __syncthreads();

    const int tr = t >> 4, tc = t & 15;
    #pragma unroll
    for (int a = 0; a < 4; ++a) {
        const int r = tr + 16*a;
        float vals[4]; float part = 0.f;
        #pragma unroll
        for (int b = 0; b < 4; ++b) { vals[b] = yA[r*68 + tc + 16*b]; part += vals[b]; }
        #pragma unroll
        for (int off = 1; off < 16; off <<= 1) part += __shfl_xor(part, off);
        const float mean = part * (1.f / 64.f);
        float vp = 0.f;
        #pragma unroll
        for (int b = 0; b < 4; ++b) { float d = vals[b] - mean; vp += d * d; }
        #pragma unroll
        for (int off = 1; off < 16; off <<= 1) vp += __shfl_xor(vp, off);
        const float inv = rsqrtf(vp * (1.f / 64.f) + LN_EPS);
        #pragma unroll
        for (int b = 0; b < 4; ++b) {
            const int c = tc + 16*b;
            float v = (vals[b] - mean) * inv * vlng[c] + vlnb[c];
            outf[(size_t)(m0 + r) * 64 + c] = v;
            outb[(size_t)(m0 + r) * 64 + c] = __float2bfloat16(v);
        }
    }
}

// =====================================================================
// fused FF GRN
// =====================================================================
__global__ __launch_bounds__(256) void fused_ff_kernel(
    const __hip_bfloat16* __restrict__ eb, const float* __restrict__ res,
    const float* __restrict__ w1, const float* __restrict__ b1,
    const float* __restrict__ w2, const float* __restrict__ b2,
    const float* __restrict__ g1w, const float* __restrict__ g1b,
    const float* __restrict__ g2w, const float* __restrict__ g2b,
    const float* __restrict__ lng, const float* __restrict__ lnb,
    float* __restrict__ outf)
{
    const int m0 = blockIdx.x * 64;
    const int t = threadIdx.x;
    const int w = t >> 6, l = t & 63, lr = l & 15, lg = l >> 4;
    __shared__ __align__(16) unsigned short hA[64 * 72];
    __shared__ __align__(16) unsigned short hB[64 * 136];
    __shared__ __align__(16) unsigned char U1[18432];
    __shared__ __align__(16) unsigned char U2[17408];
    __shared__ float vb1[128], vb2[64], vg1b[64], vg2b[64], vlng[64], vlnb[64];

    unsigned short* W1t = (unsigned short*)U1;
    unsigned short* W2t = (unsigned short*)U2;
    unsigned short* G1t = (unsigned short*)U1;
    unsigned short* G2t = (unsigned short*)(U1 + 9216);
    float* yA = (float*)U2;

    if (t < 128) vb1[t] = b1[t];
    if (t < 64) { vb2[t] = b2[t]; vg1b[t] = g1b[t]; vg2b[t] = g2b[t]; vlng[t] = lng[t]; vlnb[t] = lnb[t]; }
    #pragma unroll
    for (int p = 0; p < 16; ++p) {
        int e = t + 256 * p; int r = e >> 6, d = e & 63;
        hA[r*72 + d] = *(const unsigned short*)&eb[(size_t)(m0 + r) * 64 + d];
    }
    #pragma unroll
    for (int p = 0; p < 32; ++p) {
        int e = t + 256 * p; int k = e >> 7, c = e & 127;
        W1t[c*72 + k] = f2bf(w1[(size_t)k * 128 + c]);
    }
    #pragma unroll
    for (int p = 0; p < 32; ++p) {
        int e = t + 256 * p; int k = e >> 6, c = e & 63;
        W2t[c*136 + k] = f2bf(w2[(size_t)k * 64 + c]);
    }
    __syncthreads();

    f32x4 acc1[4][2];
    #pragma unroll
    for (int rg = 0; rg < 4; ++rg)
        #pragma unroll
        for (int cf = 0; cf < 2; ++cf) acc1[rg][cf] = (f32x4){0.f,0.f,0.f,0.f};
    #pragma unroll
    for (int ks = 0; ks < 2; ++ks) {
        short8v af[4];
        #pragma unroll
        for (int rg = 0; rg < 4; ++rg)
            af[rg] = *(const short8v*)&hA[(rg*16 + lr)*72 + ks*32 + lg*8];
        #pragma unroll
        for (int cf = 0; cf < 2; ++cf) {
            short8v bf = *(const short8v*)&W1t[(w*32 + cf*16 + lr)*72 + ks*32 + lg*8];
            #pragma unroll
            for (int rg = 0; rg < 4; ++rg)
                acc1[rg][cf] = __builtin_amdgcn_mfma_f32_16x16x32_bf16(af[rg], bf, acc1[rg][cf], 0, 0, 0);
        }
    }
    #pragma unroll
    for (int rg = 0; rg < 4; ++rg)
        #pragma unroll
        for (int cf = 0; cf < 2; ++cf)
            #pragma unroll
            for (int j = 0; j < 4; ++j) {
                int r = rg*16 + lg*4 + j, c = w*32 + cf*16 + lr;
                hB[r*136 + c] = f2bf(eluf_(acc1[rg][cf][j] + vb1[c]));
            }
    __syncthreads();

    #pragma unroll
    for (int p = 0; p < 16; ++p) {
        int e = t + 256 * p; int k = e >> 6, c = e & 63;
        G1t[c*72 + k] = f2bf(g1w[k*64 + c]);
        G2t[c*72 + k] = f2bf(g2w[k*64 + c]);
    }
    __syncthreads();

    f32x4 acc2[4];
    #pragma unroll
    for (int rg = 0; rg < 4; ++rg) acc2[rg] = (f32x4){0.f,0.f,0.f,0.f};
    #pragma unroll
    for (int ks = 0; ks < 4; ++ks) {
        short8v bf = *(const short8v*)&W2t[(w*16 + lr)*136 + ks*32 + lg*8];
        #pragma unroll
        for (int rg = 0; rg < 4; ++rg) {
            short8v af = *(const short8v*)&hB[(rg*16 + lr)*136 + ks*32 + lg*8];
            acc2[rg] = __builtin_amdgcn_mfma_f32_16x16x32_bf16(af, bf, acc2[rg], 0, 0, 0);
        }
    }
    #pragma unroll
    for (int rg = 0; rg < 4; ++rg)
        #pragma unroll
        for (int j = 0; j < 4; ++j) {
            int r = rg*16 + lg*4 + j, c = w*16 + lr;
            hA[r*72 + c] = f2bf(acc2[rg][j] + vb2[c]);
        }
    __syncthreads();

    f32x4 aA[4], aB[4];
    #pragma unroll
    for (int rg = 0; rg < 4; ++rg) { aA[rg] = (f32x4){0.f,0.f,0.f,0.f}; aB[rg] = (f32x4){0.f,0.f,0.f,0.f}; }
    #pragma unroll
    for (int ks = 0; ks < 2; ++ks) {
        short8v b1f = *(const short8v*)&G1t[(w*16 + lr)*72 + ks*32 + lg*8];
        short8v b2f = *(const short8v*)&G2t[(w*16 + lr)*72 + ks*32 + lg*8];
        #pragma unroll
        for (int rg = 0; rg < 4; ++rg) {
            short8v af = *(const short8v*)&hA[(rg*16 + lr)*72 + ks*32 + lg*8];
            aA[rg] = __builtin_amdgcn_mfma_f32_16x16x32_bf16(af, b1f, aA[rg], 0, 0, 0);
            aB[rg] = __builtin_amdgcn_mfma_f32_16x16x32_bf16(af, b2f, aB[rg], 0, 0, 0);
        }
    }
    __syncthreads();

    #pragma unroll
    for (int rg = 0; rg < 4; ++rg)
        #pragma unroll
        for (int j = 0; j < 4; ++j) {
            int r = rg*16 + lg*4 + j, c = w*16 + lr;
            float sg = sigmoidf_(aA[rg][j] + vg1b[c]);
            yA[r*68 + c] = sg * (aB[rg][j] + vg2b[c]) + res[(size_t)(m0 + r) * 64 + c];
        }
    __syncthreads();

    const int tr = t >> 4, tc = t & 15;
    #pragma unroll
    for (int a = 0; a < 4; ++a) {
        const int r = tr + 16*a;
        float vals[4]; float part = 0.f;
        #pragma unroll
        for (int b = 0; b < 4; ++b) { vals[b] = yA[r*68 + tc + 16*b]; part += vals[b]; }
        #pragma unroll
        for (int off = 1; off < 16; off <<= 1) part += __shfl_xor(part, off);
        const float mean = part * (1.f / 64.f);
        float vp = 0.f;
        #pragma unroll
        for (int b = 0; b < 4; ++b) { float d = vals[b] - mean; vp += d * d; }
        #pragma unroll
        for (int off = 1; off < 16; off <<= 1) vp += __shfl_xor(vp, off);
        const float inv = rsqrtf(vp * (1.f / 64.f) + LN_EPS);
        #pragma unroll
        for (int b = 0; b < 4; ++b) {
            const int c = tc + 16*b;
            outf[(size_t)(m0 + r) * 64 + c] = (vals[b] - mean) * inv * vlng[c] + vlnb[c];
        }
    }
}

// =====================================================================
// head: mean over T -> fc1+relu -> fc2
// =====================================================================
__global__ __launch_bounds__(64) void head_kernel(
    const float* __restrict__ outln,
    const float* __restrict__ fc1_w, const float* __restrict__ fc1_b,
    const float* __restrict__ fc2_w, const float* __restrict__ fc2_b,
    float* __restrict__ out)
{
    const int b = blockIdx.x, l = threadIdx.x;
    __shared__ float sp[64];
    float s = 0.f;
    #pragma unroll
    for (int tt = 0; tt < TSEQ; ++tt) s += outln[((size_t)(b * TSEQ + tt)) * 64 + l];
    sp[l] = s * (1.f / 24.f);
    __syncthreads();
    float a = fc1_b[l];
    for (int k = 0; k < 64; ++k) a += sp[k] * fc1_w[k*64 + l];
    float f1 = fmaxf(a, 0.f);
    #pragma unroll
    for (int j = 0; j < 6; ++j) {
        float p = f1 * fc2_w[l*6 + j];
        #pragma unroll
        for (int off = 32; off; off >>= 1) p += __shfl_xor(p, off);
        if (l == 0) out[b*6 + j] = p + fc2_b[j];
    }
}

// =====================================================================
extern "C" void kernel_launch(void* const* d_in, const int* in_sizes, int n_in,
                              void* d_out, int out_size, void* d_ws, size_t ws_size,
                              hipStream_t stream)
{
    const float* x        = (const float*)d_in[0];
    const float* f_w1     = (const float*)d_in[1];
    const float* f_b1     = (const float*)d_in[2];
    const float* f_w2     = (const float*)d_in[3];
    const float* f_b2     = (const float*)d_in[4];
    const float* f_g1w    = (const float*)d_in[5];
    const float* f_g1b    = (const float*)d_in[6];
    const float* f_g2w    = (const float*)d_in[7];
    const float* f_g2b    = (const float*)d_in[8];
    const float* f_skw    = (const float*)d_in[9];
    const float* f_skb    = (const float*)d_in[10];
    const float* f_lng    = (const float*)d_in[11];
    const float* f_lnb    = (const float*)d_in[12];
    const float* w_w1     = (const float*)d_in[13];
    const float* w_b1     = (const float*)d_in[14];
    const float* w_w2     = (const float*)d_in[15];
    const float* w_b2     = (const float*)d_in[16];
    const float* w_g1w    = (const float*)d_in[17];
    const float* w_g1b    = (const float*)d_in[18];
    const float* w_g2w    = (const float*)d_in[19];
    const float* w_g2b    = (const float*)d_in[20];
    const float* w_skw    = (const float*)d_in[21];
    const float* w_skb    = (const float*)d_in[22];
    const float* w_lng    = (const float*)d_in[23];
    const float* w_lnb    = (const float*)d_in[24];
    const float* lstm_wih = (const float*)d_in[25];
    const float* lstm_whh = (const float*)d_in[26];
    const float* lstm_bih = (const float*)d_in[27];
    const float* lstm_bhh = (const float*)d_in[28];
    const float* pl_g1w   = (const float*)d_in[29];
    const float* pl_g1b   = (const float*)d_in[30];
    const float* pl_g2w   = (const float*)d_in[31];
    const float* pl_g2b   = (const float*)d_in[32];
    const float* pl_lng   = (const float*)d_in[33];
    const float* pl_lnb   = (const float*)d_in[34];
    const float* attn_in_w  = (const float*)d_in[35];
    const float* attn_in_b  = (const float*)d_in[36];
    const float* attn_out_w = (const float*)d_in[37];
    const float* attn_out_b = (const float*)d_in[38];
    const float* pa_g1w   = (const float*)d_in[39];
    const float* pa_g1b   = (const float*)d_in[40];
    const float* pa_g2w   = (const float*)d_in[41];
    const float* pa_g2b   = (const float*)d_in[42];
    const float* pa_lng   = (const float*)d_in[43];
    const float* pa_lnb   = (const float*)d_in[44];
    const float* ff_w1    = (const float*)d_in[45];
    const float* ff_b1    = (const float*)d_in[46];
    const float* ff_w2    = (const float*)d_in[47];
    const float* ff_b2    = (const float*)d_in[48];
    const float* ff_g1w   = (const float*)d_in[49];
    const float* ff_g1b   = (const float*)d_in[50];
    const float* ff_g2w   = (const float*)d_in[51];
    const float* ff_g2b   = (const float*)d_in[52];
    const float* ff_lng   = (const float*)d_in[53];
    const float* ff_lnb   = (const float*)d_in[54];
    const float* fc1_w    = (const float*)d_in[55];
    const float* fc1_b    = (const float*)d_in[56];
    const float* fc2_w    = (const float*)d_in[57];
    const float* fc2_b    = (const float*)d_in[58];

    float* ws = (float*)d_ws;

    // ---------------- workspace layout -----------------------------------
    size_t o = 0;
    const size_t o_S0   = o; o += (size_t)MTOT * 256;   // xW / qkv
    const size_t o_A    = o; o += (size_t)MTOT * 64;    // lstm_out
    const size_t o_Bf   = o; o += (size_t)MTOT * 64;    // enriched f32
    const size_t o_Cf   = o; o += (size_t)MTOT * 64;    // outln f32
    const size_t o_Df   = o; o += (size_t)MTOT * 64;    // temporal f32
    const size_t o_F    = o; o += (size_t)MTOT * 128;   // bf16 trio: tb/ab/eb
    const size_t o_whhT = o; o += 16384;
    const size_t union_end = o;                          // 7,880,704 floats

    const size_t o_tb = o_F;
    const size_t o_ab = o_F + (size_t)MTOT * 32;
    const size_t o_eb = o_F + (size_t)MTOT * 64;

    // chunk-phase overlay (inside the union)
    const size_t o_partial = ((size_t)MC * FDIM) / 2;             // 3,981,312
    const size_t o_w81c    = o_partial + (size_t)KS * MC * NW;    // 6,193,152
    const size_t o_wcat    = o_w81c + (size_t)MC * 81;            // 6,317,568
    static_assert(6317568 + ((size_t)NW * FDIM) / 2 <= 7880704, "chunk phase must fit union");

    // persistent region
    o = union_end;
    const size_t o_sel  = o; o += (size_t)MTOT * 64;
    const size_t o_selb = o; o += (size_t)MTOT * 32;
    const size_t need   = o;                             // 9,060,352 floats = 36.2 MB
    if (ws_size < need * sizeof(float)) return;

    const dim3 blk(256);

    // 0) pack weight-head matrices to bf16 (transposed)
    wprep_kernel<<<dim3((FDIM + 255) / 256, NW), blk, 0, stream>>>(
        w_w1, w_skw, (unsigned short*)(ws + o_wcat));

    // ---------------- phase 1: VSN + weight-GRN, chunked over M ----------
    for (int mb = 0; mb < MTOT; mb += MC) {
        __hip_bfloat16* chunk = (__hip_bfloat16*)ws;
        vsn_kernel<<<dim3(NF, MC / 64), blk, 0, stream>>>(
            x + (size_t)mb * NF, f_w1, f_b1, f_w2, f_b2, f_g1w, f_g1b,
            f_g2w, f_g2b, f_skw, f_skb, f_lng, f_lnb, chunk);
        wgemm_kernel<<<dim3(MC / 16, KS), dim3(64), 0, stream>>>(
            chunk, (const unsigned short*)(ws + o_wcat), ws + o_partial);
        wtail_kernel<<<dim3(MC / 16), blk, 0, stream>>>(
            ws + o_partial, w_b1, w_skb, w_w2, w_b2, w_g1w, w_g1b,
            w_g2w, w_g2b, w_lng, w_lnb, ws + o_w81c);
        selected_kernel<<<dim3(MC), blk, 0, stream>>>(
            chunk, ws + o_w81c, ws + o_sel + (size_t)mb * 64,
            (__hip_bfloat16*)(ws + o_selb) + (size_t)mb * 64);
    }

    // ---------------- phase 2: LSTM -> attention -> head -----------------
    lstm_prep_kernel<<<dim3(64), blk, 0, stream>>>(lstm_whh, ws + o_whhT);
    xw_kernel<<<dim3(MTOT / 64), blk, 0, stream>>>(
        (const __hip_bfloat16*)(ws + o_selb), lstm_wih, lstm_bih, lstm_bhh, ws + o_S0);
    lstm_kernel<<<dim3(BB / 4), blk, 0, stream>>>(ws + o_S0, ws + o_whhT, ws + o_A);
    fused_pl_kernel<<<dim3(MTOT / 64), blk, 0, stream>>>(
        ws + o_A, ws + o_sel, pl_g1w, pl_g1b, pl_g2w, pl_g2b, pl_lng, pl_lnb,
        ws + o_Df, (__hip_bfloat16*)(ws + o_tb));
    qkv_kernel<<<dim3(MTOT / 64), blk, 0, stream>>>(
        (const __hip_bfloat16*)(ws + o_tb), attn_in_w, attn_in_b, ws + o_S0);
    attn_kernel<<<dim3(BB), blk, 0, stream>>>(
        ws + o_S0, (__hip_bfloat16*)(ws + o_ab));
    fused_pa_kernel<<<dim3(MTOT / 64), blk, 0, stream>>>(
        (const __hip_bfloat16*)(ws + o_ab), ws + o_Df,
        attn_out_w, attn_out_b, pa_g1w, pa_g1b, pa_g2w, pa_g2b, pa_lng, pa_lnb,
        ws + o_Bf, (__hip_bfloat16*)(ws + o_eb));
    fused_ff_kernel<<<dim3(MTOT / 64), blk, 0, stream>>>(
        (const __hip_bfloat16*)(ws + o_eb), ws + o_Bf,
        ff_w1, ff_b1, ff_w2, ff_b2, ff_g1w, ff_g1b, ff_g2w, ff_g2b,
        ff_lng, ff_lnb, ws + o_Cf);
    head_kernel<<<dim3(BB), dim3(64), 0, stream>>>(
        ws + o_Cf, fc1_w, fc1_b, fc2_w, fc2_b, (float*)d_out);
}

// Round 7
// 655.516 us; speedup vs baseline: 17.3426x; 1.7090x over previous
//
#include <hip/hip_runtime.h>
#include <hip/hip_bf16.h>
#include <math.h>

// ---------------- problem constants ----------------
constexpr int BB   = 512;
constexpr int TSEQ = 24;
constexpr int NF   = 81;
constexpr int DD   = 64;
constexpr int MTOT = BB * TSEQ;      // 12288
constexpr int FDIM = NF * DD;        // 5184
constexpr int KS   = 9;              // split-K groups for weight-head GEMM
constexpr int NW   = 160;            // padded combined N: 64 (wh1) + 81 (sk) + 15 pad
constexpr int NT   = 6;              // m-tiles per VSN block
constexpr float LN_EPS = 1e-5f;

typedef __attribute__((ext_vector_type(8))) short short8v;   // 8 bf16 (4 VGPRs)
typedef __attribute__((ext_vector_type(4))) float f32x4;     // MFMA C/D

static __device__ __forceinline__ float sigmoidf_(float x) { return 1.f / (1.f + expf(-x)); }
static __device__ __forceinline__ float eluf_(float x)     { return x > 0.f ? x : (expf(x) - 1.f); }
static __device__ __forceinline__ unsigned short f2bf(float x) {
    __hip_bfloat16 h = __float2bfloat16(x);
    return *reinterpret_cast<unsigned short*>(&h);
}

// =====================================================================
// Kernel 1: VSN v3 — persistent weight LDS, NT m-tiles per block.
// grid (NF, (mc/64)/NT), 256 threads = 4 waves.
// =====================================================================
__global__ __launch_bounds__(256) void vsn_kernel(
    const float* __restrict__ x,
    const float* __restrict__ f_w1,  const float* __restrict__ f_b1,
    const float* __restrict__ f_w2,  const float* __restrict__ f_b2,
    const float* __restrict__ f_g1w, const float* __restrict__ f_g1b,
    const float* __restrict__ f_g2w, const float* __restrict__ f_g2b,
    const float* __restrict__ f_skw, const float* __restrict__ f_skb,
    const float* __restrict__ f_lng, const float* __restrict__ f_lnb,
    __hip_bfloat16* __restrict__ stacked)
{
    const int f  = blockIdx.x;
    const int t  = threadIdx.x;
    const int w  = t >> 6;
    const int l  = t & 63;
    const int lr = l & 15;
    const int lg = l >> 4;

    __shared__ __align__(16) unsigned short hA[64 * 72];    // 9216 B
    __shared__ __align__(16) unsigned short W2t[64 * 72];
    __shared__ __align__(16) unsigned short G1t[64 * 72];
    __shared__ __align__(16) unsigned short G2t[64 * 72];
    __shared__ __align__(16) float yA[64 * 68];             // 17408 B
    __shared__ float vw1[64], vb1[64], vb2[64], vg1b[64], vg2b[64];
    __shared__ float vskw[64], vskb[64], vlng[64], vlnb[64];

    if (t < 64) {
        vw1[t]  = f_w1 [f*64 + t];  vb1[t]  = f_b1 [f*64 + t];
        vb2[t]  = f_b2 [f*64 + t];
        vg1b[t] = f_g1b[f*64 + t];  vg2b[t] = f_g2b[f*64 + t];
        vskw[t] = f_skw[f*64 + t];  vskb[t] = f_skb[f*64 + t];
        vlng[t] = f_lng[f*64 + t];  vlnb[t] = f_lnb[f*64 + t];
    }
    {
        const float* w2p = f_w2  + (size_t)f * 4096;
        const float* g1p = f_g1w + (size_t)f * 4096;
        const float* g2p = f_g2w + (size_t)f * 4096;
        #pragma unroll
        for (int p = 0; p < 16; ++p) {
            int e = t + 256 * p; int k = e >> 6, c = e & 63;
            W2t[c*72 + k] = f2bf(w2p[k*64 + c]);
            G1t[c*72 + k] = f2bf(g1p[k*64 + c]);
            G2t[c*72 + k] = f2bf(g2p[k*64 + c]);
        }
    }

    for (int it = 0; it < NT; ++it) {
        const int m0 = (blockIdx.y * NT + it) * 64;

        // h0 = elu(x*w1 + b1) -> hA (direct x loads, L1-broadcast)
        #pragma unroll
        for (int p = 0; p < 16; ++p) {
            int e = t + 256 * p; int r = e >> 6, d = e & 63;
            float xvv = x[(size_t)(m0 + r) * NF + f];
            hA[r*72 + d] = f2bf(eluf_(xvv * vw1[d] + vb1[d]));
        }
        __syncthreads();   // bar1: hA(h0) + (iter0) weights/params ready

        // mm1: h1 = h0 @ w2
        f32x4 acc1[4];
        #pragma unroll
        for (int rg = 0; rg < 4; ++rg) acc1[rg] = (f32x4){0.f, 0.f, 0.f, 0.f};
        #pragma unroll
        for (int ks = 0; ks < 2; ++ks) {
            short8v bf = *(const short8v*)&W2t[(w*16 + lr)*72 + ks*32 + lg*8];
            #pragma unroll
            for (int rg = 0; rg < 4; ++rg) {
                short8v af = *(const short8v*)&hA[(rg*16 + lr)*72 + ks*32 + lg*8];
                acc1[rg] = __builtin_amdgcn_mfma_f32_16x16x32_bf16(af, bf, acc1[rg], 0, 0, 0);
            }
        }
        __syncthreads();   // bar2: all mm1 reads of hA done

        #pragma unroll
        for (int rg = 0; rg < 4; ++rg)
            #pragma unroll
            for (int j = 0; j < 4; ++j) {
                int r = rg*16 + lg*4 + j, c = w*16 + lr;
                hA[r*72 + c] = f2bf(acc1[rg][j] + vb2[c]);
            }
        __syncthreads();   // bar3: hA(h1) ready

        // mm2: g1 = h1 @ g1w ; mm3: g2 = h1 @ g2w
        f32x4 aA[4], aB[4];
        #pragma unroll
        for (int rg = 0; rg < 4; ++rg) { aA[rg] = (f32x4){0.f,0.f,0.f,0.f}; aB[rg] = (f32x4){0.f,0.f,0.f,0.f}; }
        #pragma unroll
        for (int ks = 0; ks < 2; ++ks) {
            short8v b1f = *(const short8v*)&G1t[(w*16 + lr)*72 + ks*32 + lg*8];
            short8v b2f = *(const short8v*)&G2t[(w*16 + lr)*72 + ks*32 + lg*8];
            #pragma unroll
            for (int rg = 0; rg < 4; ++rg) {
                short8v af = *(const short8v*)&hA[(rg*16 + lr)*72 + ks*32 + lg*8];
                aA[rg] = __builtin_amdgcn_mfma_f32_16x16x32_bf16(af, b1f, aA[rg], 0, 0, 0);
                aB[rg] = __builtin_amdgcn_mfma_f32_16x16x32_bf16(af, b2f, aB[rg], 0, 0, 0);
            }
        }
        // GLU + skip -> yA
        #pragma unroll
        for (int rg = 0; rg < 4; ++rg)
            #pragma unroll
            for (int j = 0; j < 4; ++j) {
                int r = rg*16 + lg*4 + j, c = w*16 + lr;
                float xvv = x[(size_t)(m0 + r) * NF + f];
                float sg = sigmoidf_(aA[rg][j] + vg1b[c]);
                yA[r*68 + c] = sg * (aB[rg][j] + vg2b[c]) + xvv * vskw[c] + vskb[c];
            }
        __syncthreads();   // bar4: yA ready

        // LayerNorm(64) + bf16 store
        const int tr = t >> 4, tc = t & 15;
        #pragma unroll
        for (int a = 0; a < 4; ++a) {
            const int r = tr + 16*a;
            float vals[4];
            float part = 0.f;
            #pragma unroll
            for (int b = 0; b < 4; ++b) { vals[b] = yA[r*68 + tc + 16*b]; part += vals[b]; }
            #pragma unroll
            for (int off = 1; off < 16; off <<= 1) part += __shfl_xor(part, off);
            const float mean = part * (1.f / 64.f);
            float vp = 0.f;
            #pragma unroll
            for (int b = 0; b < 4; ++b) { float d = vals[b] - mean; vp += d * d; }
            #pragma unroll
            for (int off = 1; off < 16; off <<= 1) vp += __shfl_xor(vp, off);
            const float inv = rsqrtf(vp * (1.f / 64.f) + LN_EPS);
            const size_t base = (size_t)(m0 + r) * FDIM + (size_t)f * 64;
            #pragma unroll
            for (int b = 0; b < 4; ++b) {
                const int c = tc + 16*b;
                stacked[base + c] = __float2bfloat16((vals[b] - mean) * inv * vlng[c] + vlnb[c]);
            }
        }
        __syncthreads();   // bar5: LN reads of yA done before next iter's writes
    }
}

// =====================================================================
// Pack w_w1 / w_skw into bf16 WcatT[160][FDIM]
// =====================================================================
__global__ void wprep_kernel(
    const float* __restrict__ w_w1, const float* __restrict__ w_skw,
    unsigned short* __restrict__ WcatT)
{
    const int c = blockIdx.y;
    const int k = blockIdx.x * 256 + threadIdx.x;
    if (k >= FDIM) return;
    float v = 0.f;
    if (c < 64)       v = w_w1[(size_t)k * 64 + c];
    else if (c < 145) v = w_skw[(size_t)k * 81 + (c - 64)];
    WcatT[(size_t)c * FDIM + k] = f2bf(v);
}

// =====================================================================
// Split-K fused weight-head GEMM (MFMA, LDS-free), mc-parameterized
// =====================================================================
__global__ __launch_bounds__(64) void wgemm_kernel(
    const __hip_bfloat16* __restrict__ stacked,
    const unsigned short* __restrict__ WcatT,
    float* __restrict__ partial, int mc)
{
    const int m0 = blockIdx.x * 16;
    const int ks = blockIdx.y;
    const int l  = threadIdx.x;
    const int lr = l & 15, lg = l >> 4;

    f32x4 acc[10];
    #pragma unroll
    for (int n = 0; n < 10; ++n) acc[n] = (f32x4){0.f, 0.f, 0.f, 0.f};

    const size_t arow = (size_t)(m0 + lr) * FDIM;
    const int k0base = ks * 576;
    for (int kk = 0; kk < 576; kk += 32) {
        const int k = k0base + kk + lg * 8;
        short8v af = *(const short8v*)(stacked + arow + k);
        #pragma unroll
        for (int n = 0; n < 10; ++n) {
            short8v bf = *(const short8v*)(WcatT + (size_t)(n*16 + lr) * FDIM + k);
            acc[n] = __builtin_amdgcn_mfma_f32_16x16x32_bf16(af, bf, acc[n], 0, 0, 0);
        }
    }
    #pragma unroll
    for (int n = 0; n < 10; ++n)
        #pragma unroll
        for (int j = 0; j < 4; ++j) {
            const int m = m0 + lg*4 + j;
            partial[((size_t)ks * mc + m) * NW + n*16 + lr] = acc[n][j];
        }
}

// =====================================================================
// Weight-GRN tail: LDS-staged weights, 16 rows/block, mc-parameterized
// =====================================================================
__global__ __launch_bounds__(256) void wtail_kernel(
    const float* __restrict__ partial,
    const float* __restrict__ w_b1,  const float* __restrict__ w_skb,
    const float* __restrict__ w_w2,  const float* __restrict__ w_b2,
    const float* __restrict__ w_g1w, const float* __restrict__ w_g1b,
    const float* __restrict__ w_g2w, const float* __restrict__ w_g2b,
    const float* __restrict__ w_lng, const float* __restrict__ w_lnb,
    float* __restrict__ w81, int mc)
{
    __shared__ float w2s[5184];
    __shared__ float g1s[6561];
    __shared__ float g2s[6561];
    __shared__ float sWh[16][64];
    __shared__ float sW2[16][96];

    const int t  = threadIdx.x;
    const int wv = t >> 6, l = t & 63;
    const int m0 = blockIdx.x * 16;
    const bool v1 = (l < 17);

    for (int e = t; e < 5184; e += 256) w2s[e] = w_w2[e];
    for (int e = t; e < 6561; e += 256) { g1s[e] = w_g1w[e]; g2s[e] = w_g2w[e]; }

    float s0[4], sk0[4], sk1[4];
    {
        const float b1v = w_b1[l], skb0 = w_skb[l], skb1 = v1 ? w_skb[64 + l] : 0.f;
        #pragma unroll
        for (int rr = 0; rr < 4; ++rr) { s0[rr] = b1v; sk0[rr] = skb0; sk1[rr] = skb1; }
    }
    #pragma unroll
    for (int ks = 0; ks < KS; ++ks) {
        #pragma unroll
        for (int rr = 0; rr < 4; ++rr) {
            const float* pr = partial + ((size_t)ks * mc + (m0 + wv*4 + rr)) * NW;
            s0[rr]  += pr[l];
            sk0[rr] += pr[64 + l];
            if (v1) sk1[rr] += pr[128 + l];
        }
    }
    #pragma unroll
    for (int rr = 0; rr < 4; ++rr) sWh[wv*4 + rr][l] = eluf_(s0[rr]);
    __syncthreads();

    float a0[4], a1[4];
    {
        const float b0 = w_b2[l], b1v = v1 ? w_b2[64 + l] : 0.f;
        #pragma unroll
        for (int rr = 0; rr < 4; ++rr) { a0[rr] = b0; a1[rr] = b1v; }
    }
    #pragma unroll 4
    for (int i = 0; i < 64; ++i) {
        const float wl = w2s[i*81 + l];
        const float wh = v1 ? w2s[i*81 + 64 + l] : 0.f;
        #pragma unroll
        for (int rr = 0; rr < 4; ++rr) {
            const float h = sWh[wv*4 + rr][i];
            a0[rr] += h * wl;
            a1[rr] += h * wh;
        }
    }
    #pragma unroll
    for (int rr = 0; rr < 4; ++rr) {
        sW2[wv*4 + rr][l] = a0[rr];
        if (v1) sW2[wv*4 + rr][64 + l] = a1[rr];
    }
    __syncthreads();

    float g10[4], g20[4], g11[4], g21[4];
    {
        const float c10 = w_g1b[l], c20 = w_g2b[l];
        const float c11 = v1 ? w_g1b[64 + l] : 0.f, c21 = v1 ? w_g2b[64 + l] : 0.f;
        #pragma unroll
        for (int rr = 0; rr < 4; ++rr) { g10[rr] = c10; g20[rr] = c20; g11[rr] = c11; g21[rr] = c21; }
    }
    #pragma unroll 3
    for (int i = 0; i < 81; ++i) {
        const float w1l = g1s[i*81 + l],            w2l = g2s[i*81 + l];
        const float w1h = v1 ? g1s[i*81 + 64 + l] : 0.f;
        const float w2h = v1 ? g2s[i*81 + 64 + l] : 0.f;
        #pragma unroll
        for (int rr = 0; rr < 4; ++rr) {
            const float h = sW2[wv*4 + rr][i];
            g10[rr] += h * w1l; g20[rr] += h * w2l;
            g11[rr] += h * w1h; g21[rr] += h * w2h;
        }
    }

    #pragma unroll
    for (int rr = 0; rr < 4; ++rr) {
        const int m = m0 + wv*4 + rr;
        float y0 = sigmoidf_(g10[rr]) * g20[rr] + sk0[rr];
        float y1 = v1 ? (sigmoidf_(g11[rr]) * g21[rr] + sk1[rr]) : 0.f;

        float s = y0 + (v1 ? y1 : 0.f);
        #pragma unroll
        for (int off = 32; off; off >>= 1) s += __shfl_xor(s, off);
        const float mean = s / 81.f;
        float d0 = y0 - mean, d1 = v1 ? (y1 - mean) : 0.f;
        float vs = d0*d0 + (v1 ? d1*d1 : 0.f);
        #pragma unroll
        for (int off = 32; off; off >>= 1) vs += __shfl_xor(vs, off);
        const float inv = rsqrtf(vs / 81.f + LN_EPS);
        float wn0 = d0 * inv * w_lng[l] + w_lnb[l];
        float wn1 = v1 ? (d1 * inv * w_lng[64 + l] + w_lnb[64 + l]) : -1e30f;

        float mx = fmaxf(wn0, wn1);
        #pragma unroll
        for (int off = 32; off; off >>= 1) mx = fmaxf(mx, __shfl_xor(mx, off));
        float e0 = expf(wn0 - mx), e1 = v1 ? expf(wn1 - mx) : 0.f;
        float es = e0 + e1;
        #pragma unroll
        for (int off = 32; off; off >>= 1) es += __shfl_xor(es, off);
        const float r = 1.f / es;
        w81[(size_t)m * 81 + l] = e0 * r;
        if (v1) w81[(size_t)m * 81 + 64 + l] = e1 * r;
    }
}

// =====================================================================
// selected: f32 + bf16 outputs
// =====================================================================
__global__ __launch_bounds__(256) void selected_kernel(
    const __hip_bfloat16* __restrict__ stacked, const float* __restrict__ w81,
    float* __restrict__ sel, __hip_bfloat16* __restrict__ selb)
{
    const int m = blockIdx.x;
    const int d = threadIdx.x & 63, fg = threadIdx.x >> 6;
    __shared__ float red[4][64];
    __shared__ float wsh[81];
    if (threadIdx.x < 81) wsh[threadIdx.x] = w81[(size_t)m * 81 + threadIdx.x];
    __syncthreads();
    float acc = 0.f;
    for (int f = fg; f < 81; f += 4)
        acc += __bfloat162float(stacked[(size_t)m * FDIM + f*64 + d]) * wsh[f];
    red[fg][d] = acc;
    __syncthreads();
    if (fg == 0) {
        float v = red[0][d] + red[1][d] + red[2][d] + red[3][d];
        sel[(size_t)m * 64 + d]  = v;
        selb[(size_t)m * 64 + d] = __float2bfloat16(v);
    }
}

// =====================================================================
// xW = selb @ wih^T + (bih+bhh)    MFMA, grid MTOT/64 blocks, 256 thr
// =====================================================================
__global__ __launch_bounds__(256) void xw_kernel(
    const __hip_bfloat16* __restrict__ selb,
    const float* __restrict__ wih,
    const float* __restrict__ bih, const float* __restrict__ bhh,
    float* __restrict__ xW)
{
    const int m0 = blockIdx.x * 64;
    const int t = threadIdx.x;
    const int w = t >> 6, l = t & 63, lr = l & 15, lg = l >> 4;
    __shared__ __align__(16) unsigned short hA[64 * 72];
    __shared__ __align__(16) unsigned short Wt[256 * 72];
    __shared__ float vbs[256];

    vbs[t] = bih[t] + bhh[t];
    #pragma unroll
    for (int p = 0; p < 16; ++p) {
        int e = t + 256 * p; int r = e >> 6, d = e & 63;
        hA[r*72 + d] = *(const unsigned short*)&selb[(size_t)(m0 + r) * 64 + d];
    }
    #pragma unroll
    for (int p = 0; p < 64; ++p) {
        int e = t + 256 * p; int c = e >> 6, k = e & 63;
        Wt[c*72 + k] = f2bf(wih[c*64 + k]);
    }
    __syncthreads();

    f32x4 acc[4][4];
    #pragma unroll
    for (int rg = 0; rg < 4; ++rg)
        #pragma unroll
        for (int cf = 0; cf < 4; ++cf) acc[rg][cf] = (f32x4){0.f,0.f,0.f,0.f};
    #pragma unroll
    for (int ks = 0; ks < 2; ++ks) {
        short8v af[4];
        #pragma unroll
        for (int rg = 0; rg < 4; ++rg)
            af[rg] = *(const short8v*)&hA[(rg*16 + lr)*72 + ks*32 + lg*8];
        #pragma unroll
        for (int cf = 0; cf < 4; ++cf) {
            short8v bf = *(const short8v*)&Wt[(w*64 + cf*16 + lr)*72 + ks*32 + lg*8];
            #pragma unroll
            for (int rg = 0; rg < 4; ++rg)
                acc[rg][cf] = __builtin_amdgcn_mfma_f32_16x16x32_bf16(af[rg], bf, acc[rg][cf], 0, 0, 0);
        }
    }
    #pragma unroll
    for (int rg = 0; rg < 4; ++rg)
        #pragma unroll
        for (int cf = 0; cf < 4; ++cf)
            #pragma unroll
            for (int j = 0; j < 4; ++j) {
                int r = rg*16 + lg*4 + j, c = w*64 + cf*16 + lr;
                xW[(size_t)(m0 + r) * 256 + c] = acc[rg][cf][j] + vbs[c];
            }
}

// =====================================================================
// LSTM prep: transpose whh ([4H,64] -> [64,4H])
// =====================================================================
__global__ void lstm_prep_kernel(
    const float* __restrict__ whh, float* __restrict__ whhT)
{
    int id = blockIdx.x * 256 + threadIdx.x;
    if (id < 16384) {
        int i = id >> 8, j = id & 255;
        whhT[id] = whh[j*64 + i];
    }
}

// =====================================================================
// LSTM recurrence v3: 1 batch row per block (grid BB=512), 256 threads.
// Thread t owns gate column t; whhT column in 64 VGPRs; 2 barriers/step.
// =====================================================================
__global__ __launch_bounds__(256) void lstm_kernel(
    const float* __restrict__ xW, const float* __restrict__ whhT,
    float* __restrict__ out)
{
    __shared__ float sh[64];
    __shared__ float sg[256];
    const int t = threadIdx.x;
    const int b = blockIdx.x;

    float wreg[64];
    #pragma unroll
    for (int i = 0; i < 64; ++i) wreg[i] = whhT[i*256 + t];

    if (t < 64) sh[t] = 0.f;
    float c_reg = 0.f;

    float xnext = xW[((size_t)b * TSEQ + 0) * 256 + t];
    __syncthreads();

    for (int tt = 0; tt < TSEQ; ++tt) {
        float acc = xnext;
        if (tt + 1 < TSEQ)
            xnext = xW[((size_t)b * TSEQ + tt + 1) * 256 + t];
        #pragma unroll
        for (int i = 0; i < 64; ++i) acc += sh[i] * wreg[i];
        sg[t] = acc;
        __syncthreads();           // gates visible; all sh reads complete
        if (t < 64) {
            float gi = sg[t], gf = sg[64 + t], gg = sg[128 + t], go = sg[192 + t];
            c_reg = sigmoidf_(gf) * c_reg + sigmoidf_(gi) * tanhf(gg);
            float hn = sigmoidf_(go) * tanhf(c_reg);
            sh[t] = hn;
            out[((size_t)b * TSEQ + tt) * 64 + t] = hn;
        }
        __syncthreads();           // new h visible
    }
}

// =====================================================================
// fused GLU pair + residual + LN (post-LSTM)
// =====================================================================
__global__ __launch_bounds__(256) void fused_pl_kernel(
    const float* __restrict__ in, const float* __restrict__ res,
    const float* __restrict__ g1w, const float* __restrict__ g1b,
    const float* __restrict__ g2w, const float* __restrict__ g2b,
    const float* __restrict__ lng, const float* __restrict__ lnb,
    float* __restrict__ outf, __hip_bfloat16* __restrict__ outb)
{
    const int m0 = blockIdx.x * 64;
    const int t = threadIdx.x;
    const int w = t >> 6, l = t & 63, lr = l & 15, lg = l >> 4;
    __shared__ __align__(16) unsigned short hA[64 * 72];
    __shared__ __align__(16) unsigned char uS[18432];
    unsigned short* Wt0 = (unsigned short*)uS;
    unsigned short* Wt1 = (unsigned short*)(uS + 9216);
    float* yA = (float*)uS;
    __shared__ float vg1b[64], vg2b[64], vlng[64], vlnb[64];

    if (t < 64) { vg1b[t] = g1b[t]; vg2b[t] = g2b[t]; vlng[t] = lng[t]; vlnb[t] = lnb[t]; }
    #pragma unroll
    for (int p = 0; p < 16; ++p) {
        int e = t + 256 * p; int r = e >> 6, d = e & 63;
        hA[r*72 + d] = f2bf(in[(size_t)(m0 + r) * 64 + d]);
    }
    #pragma unroll
    for (int p = 0; p < 16; ++p) {
        int e = t + 256 * p; int k = e >> 6, c = e & 63;
        Wt0[c*72 + k] = f2bf(g1w[k*64 + c]);
        Wt1[c*72 + k] = f2bf(g2w[k*64 + c]);
    }
    __syncthreads();

    f32x4 aA[4], aB[4];
    #pragma unroll
    for (int rg = 0; rg < 4; ++rg) { aA[rg] = (f32x4){0.f,0.f,0.f,0.f}; aB[rg] = (f32x4){0.f,0.f,0.f,0.f}; }
    #pragma unroll
    for (int ks = 0; ks < 2; ++ks) {
        short8v b0f = *(const short8v*)&Wt0[(w*16 + lr)*72 + ks*32 + lg*8];
        short8v b1f = *(const short8v*)&Wt1[(w*16 + lr)*72 + ks*32 + lg*8];
        #pragma unroll
        for (int rg = 0; rg < 4; ++rg) {
            short8v af = *(const short8v*)&hA[(rg*16 + lr)*72 + ks*32 + lg*8];
            aA[rg] = __builtin_amdgcn_mfma_f32_16x16x32_bf16(af, b0f, aA[rg], 0, 0, 0);
            aB[rg] = __builtin_amdgcn_mfma_f32_16x16x32_bf16(af, b1f, aB[rg], 0, 0, 0);
        }
    }
    __syncthreads();

    #pragma unroll
    for (int rg = 0; rg < 4; ++rg)
        #pragma unroll
        for (int j = 0; j < 4; ++j) {
            int r = rg*16 + lg*4 + j, c = w*16 + lr;
            float sg = sigmoidf_(aA[rg][j] + vg1b[c]);
            yA[r*68 + c] = sg * (aB[rg][j] + vg2b[c]) + res[(size_t)(m0 + r) * 64 + c];
        }
    __syncthreads();

    const int tr = t >> 4, tc = t & 15;
    #pragma unroll
    for (int a = 0; a < 4; ++a) {
        const int r = tr + 16*a;
        float vals[4]; float part = 0.f;
        #pragma unroll
        for (int b = 0; b < 4; ++b) { vals[b] = yA[r*68 + tc + 16*b]; part += vals[b]; }
        #pragma unroll
        for (int off = 1; off < 16; off <<= 1) part += __shfl_xor(part, off);
        const float mean = part * (1.f / 64.f);
        float vp = 0.f;
        #pragma unroll
        for (int b = 0; b < 4; ++b) { float d = vals[b] - mean; vp += d * d; }
        #pragma unroll
        for (int off = 1; off < 16; off <<= 1) vp += __shfl_xor(vp, off);
        const float inv = rsqrtf(vp * (1.f / 64.f) + LN_EPS);
        #pragma unroll
        for (int b = 0; b < 4; ++b) {
            const int c = tc + 16*b;
            float v = (vals[b] - mean) * inv * vlng[c] + vlnb[c];
            outf[(size_t)(m0 + r) * 64 + c] = v;
            outb[(size_t)(m0 + r) * 64 + c] = __float2bfloat16(v);
        }
    }
}

// =====================================================================
// qkv = temporal_bf16 @ attn_in_w[64,192] + b
// =====================================================================
__global__ __launch_bounds__(256) void qkv_kernel(
    const __hip_bfloat16* __restrict__ tb,
    const float* __restrict__ wqkv, const float* __restrict__ bqkv,
    float* __restrict__ qkv)
{
    const int m0 = blockIdx.x * 64;
    const int t = threadIdx.x;
    const int w = t >> 6, l = t & 63, lr = l & 15, lg = l >> 4;
    __shared__ __align__(16) unsigned short hA[64 * 72];
    __shared__ __align__(16) unsigned short Wt[192 * 72];
    __shared__ float vb[192];

    if (t < 192) vb[t] = bqkv[t];
    #pragma unroll
    for (int p = 0; p < 16; ++p) {
        int e = t + 256 * p; int r = e >> 6, d = e & 63;
        hA[r*72 + d] = *(const unsigned short*)&tb[(size_t)(m0 + r) * 64 + d];
    }
    #pragma unroll
    for (int p = 0; p < 48; ++p) {
        int e = t + 256 * p; int c = e >> 6, k = e & 63;
        Wt[c*72 + k] = f2bf(wqkv[(size_t)k * 192 + c]);
    }
    __syncthreads();

    f32x4 acc[4][3];
    #pragma unroll
    for (int rg = 0; rg < 4; ++rg)
        #pragma unroll
        for (int cf = 0; cf < 3; ++cf) acc[rg][cf] = (f32x4){0.f,0.f,0.f,0.f};
    #pragma unroll
    for (int ks = 0; ks < 2; ++ks) {
        short8v af[4];
        #pragma unroll
        for (int rg = 0; rg < 4; ++rg)
            af[rg] = *(const short8v*)&hA[(rg*16 + lr)*72 + ks*32 + lg*8];
        #pragma unroll
        for (int cf = 0; cf < 3; ++cf) {
            short8v bf = *(const short8v*)&Wt[(w*48 + cf*16 + lr)*72 + ks*32 + lg*8];
            #pragma unroll
            for (int rg = 0; rg < 4; ++rg)
                acc[rg][cf] = __builtin_amdgcn_mfma_f32_16x16x32_bf16(af[rg], bf, acc[rg][cf], 0, 0, 0);
        }
    }
    #pragma unroll
    for (int rg = 0; rg < 4; ++rg)
        #pragma unroll
        for (int cf = 0; cf < 3; ++cf)
            #pragma unroll
            for (int j = 0; j < 4; ++j) {
                int r = rg*16 + lg*4 + j, c = w*48 + cf*16 + lr;
                qkv[(size_t)(m0 + r) * 192 + c] = acc[rg][cf][j] + vb[c];
            }
}

// =====================================================================
// MHA core -> ao bf16
// =====================================================================
__global__ __launch_bounds__(256) void attn_kernel(
    const float* __restrict__ qkv, __hip_bfloat16* __restrict__ ao)
{
    const int b = blockIdx.x;
    const int h = threadIdx.x >> 6, l = threadIdx.x & 63;
    __shared__ float sq[4][24][16], sk[4][24][16], sv[4][24][16], sp[4][24][24];
    #pragma unroll
    for (int p = 0; p < 6; ++p) {
        int e = l + 64 * p; int ti = e >> 4, d = e & 15;
        size_t base = ((size_t)(b * TSEQ + ti)) * 192 + h * 16 + d;
        sq[h][ti][d] = qkv[base];
        sk[h][ti][d] = qkv[base + 64];
        sv[h][ti][d] = qkv[base + 128];
    }
    __syncthreads();
    #pragma unroll
    for (int p = 0; p < 9; ++p) {
        int e = l + 64 * p; int i = e / 24, j = e - i * 24;
        float s = 0.f;
        #pragma unroll
        for (int d = 0; d < 16; ++d) s += sq[h][i][d] * sk[h][j][d];
        sp[h][i][j] = s * 0.25f;
    }
    __syncthreads();
    if (l < 24) {
        float mx = -1e30f;
        for (int j = 0; j < 24; ++j) mx = fmaxf(mx, sp[h][l][j]);
        float s = 0.f;
        for (int j = 0; j < 24; ++j) { float e = expf(sp[h][l][j] - mx); sp[h][l][j] = e; s += e; }
        float inv = 1.f / s;
        for (int j = 0; j < 24; ++j) sp[h][l][j] *= inv;
    }
    __syncthreads();
    #pragma unroll
    for (int p = 0; p < 6; ++p) {
        int e = l + 64 * p; int ti = e >> 4, d = e & 15;
        float s = 0.f;
        #pragma unroll
        for (int j = 0; j < 24; ++j) s += sp[h][ti][j] * sv[h][j][d];
        ao[((size_t)(b * TSEQ + ti)) * 64 + h * 16 + d] = __float2bfloat16(s);
    }
}

// =====================================================================
// fused post-attn: ao@Wout+b -> GLU(pa) -> +temporal -> LN -> enriched
// =====================================================================
__global__ __launch_bounds__(256) void fused_pa_kernel(
    const __hip_bfloat16* __restrict__ ao, const float* __restrict__ res,
    const float* __restrict__ wout, const float* __restrict__ bout,
    const float* __restrict__ g1w, const float* __restrict__ g1b,
    const float* __restrict__ g2w, const float* __restrict__ g2b,
    const float* __restrict__ lng, const float* __restrict__ lnb,
    float* __restrict__ outf, __hip_bfloat16* __restrict__ outb)
{
    const int m0 = blockIdx.x * 64;
    const int t = threadIdx.x;
    const int w = t >> 6, l = t & 63, lr = l & 15, lg = l >> 4;
    __shared__ __align__(16) unsigned short hA[64 * 72];
    __shared__ __align__(16) unsigned char uS[18432];
    unsigned short* Wt0 = (unsigned short*)uS;
    unsigned short* Wt1 = (unsigned short*)(uS + 9216);
    float* yA = (float*)uS;
    __shared__ float vob[64], vg1b[64], vg2b[64], vlng[64], vlnb[64];

    if (t < 64) { vob[t] = bout[t]; vg1b[t] = g1b[t]; vg2b[t] = g2b[t]; vlng[t] = lng[t]; vlnb[t] = lnb[t]; }
    #pragma unroll
    for (int p = 0; p < 16; ++p) {
        int e = t + 256 * p; int r = e >> 6, d = e & 63;
        hA[r*72 + d] = *(const unsigned short*)&ao[(size_t)(m0 + r) * 64 + d];
    }
    #pragma unroll
    for (int p = 0; p < 16; ++p) {
        int e = t + 256 * p; int k = e >> 6, c = e & 63;
        Wt0[c*72 + k] = f2bf(wout[k*64 + c]);
    }
    __syncthreads();

    f32x4 acc1[4];
    #pragma unroll
    for (int rg = 0; rg < 4; ++rg) acc1[rg] = (f32x4){0.f,0.f,0.f,0.f};
    #pragma unroll
    for (int ks = 0; ks < 2; ++ks) {
        short8v bf = *(const short8v*)&Wt0[(w*16 + lr)*72 + ks*32 + lg*8];
        #pragma unroll
        for (int rg = 0; rg < 4; ++rg) {
            short8v af = *(const short8v*)&hA[(rg*16 + lr)*72 + ks*32 + lg*8];
            acc1[rg] = __builtin_amdgcn_mfma_f32_16x16x32_bf16(af, bf, acc1[rg], 0, 0, 0);
        }
    }
    #pragma unroll
    for (int p = 0; p < 16; ++p) {
        int e = t + 256 * p; int k = e >> 6, c = e & 63;
        Wt1[c*72 + k] = f2bf(g1w[k*64 + c]);
    }
    __syncthreads();

    #pragma unroll
    for (int rg = 0; rg < 4; ++rg)
        #pragma unroll
        for (int j = 0; j < 4; ++j) {
            int r = rg*16 + lg*4 + j, c = w*16 + lr;
            hA[r*72 + c] = f2bf(acc1[rg][j] + vob[c]);
        }
    #pragma unroll
    for (int p = 0; p < 16; ++p) {
        int e = t + 256 * p; int k = e >> 6, c = e & 63;
        Wt0[c*72 + k] = f2bf(g2w[k*64 + c]);
    }
    __syncthreads();

    f32x4 aA[4], aB[4];
    #pragma unroll
    for (int rg = 0; rg < 4; ++rg) { aA[rg] = (f32x4){0.f,0.f,0.f,0.f}; aB[rg] = (f32x4){0.f,0.f,0.f,0.f}; }
    #pragma unroll
    for (int ks = 0; ks < 2; ++ks) {
        short8v b1f = *(const short8v*)&Wt1[(w*16 + lr)*72 + ks*32 + lg*8];
        short8v b2f = *(const short8v*)&Wt0[(w*16 + lr)*72 + ks*32 + lg*8];
        #pragma unroll
        for (int rg = 0; rg < 4; ++rg) {
            short8v af = *(const short8v*)&hA[(rg*16 + lr)*72 + ks*32 + lg*8];
            aA[rg] = __builtin_amdgcn_mfma_f32_16x16x32_bf16(af, b1f, aA[rg], 0, 0, 0);
            aB[rg] = __builtin_amdgcn_mfma_f32_16x16x32_bf16(af, b2f, aB[rg], 0, 0, 0);
        }
    }
    __syncthreads();

    #pragma unroll
    for (int rg = 0; rg < 4; ++rg)
        #pragma unroll
        for (int j = 0; j < 4; ++j) {
            int r = rg*16 + lg*4 + j, c = w*16 + lr;
            float sg = sigmoidf_(aA[rg][j] + vg1b[c]);
            yA[r*68 + c] = sg * (aB[rg][j] + vg2b[c]) + res[(size_t)(m0 + r) * 64 + c];
        }
    __syncthreads();

    const int tr = t >> 4, tc = t & 15;
    #pragma unroll
    for (int a = 0; a < 4; ++a) {
        const int r = tr + 16*a;
        float vals[4]; float part = 0.f;
        #pragma unroll
        for (int b = 0; b < 4; ++b) { vals[b] = yA[r*68 + tc + 16*b]; part += vals[b]; }
        #pragma unroll
        for (int off = 1; off < 16; off <<= 1) part += __shfl_xor(part, off);
        const float mean = part * (1.f / 64.f);
        float vp = 0.f;
        #pragma unroll
        for (int b = 0; b < 4; ++b) { float d = vals[b] - mean; vp += d * d; }
        #pragma unroll
        for (int off = 1; off < 16; off <<= 1) vp += __shfl_xor(vp, off);
        const float inv = rsqrtf(vp * (1.f / 64.f) + LN_EPS);
        #pragma unroll
        for (int b = 0; b < 4; ++b) {
            const int c = tc + 16*b;
            float v = (vals[b] - mean) * inv * vlng[c] + vlnb[c];
            outf[(size_t)(m0 + r) * 64 + c] = v;
            outb[(size_t)(m0 + r) * 64 + c] = __float2bfloat16(v);
        }
    }
}

// =====================================================================
// fused FF GRN
// =====================================================================
__global__ __launch_bounds__(256) void fused_ff_kernel(
    const __hip_bfloat16* __restrict__ eb, const float* __restrict__ res,
    const float* __restrict__ w1, const float* __restrict__ b1,
    const float* __restrict__ w2, const float* __restrict__ b2,
    const float* __restrict__ g1w, const float* __restrict__ g1b,
    const float* __restrict__ g2w, const float* __restrict__ g2b,
    const float* __restrict__ lng, const float* __restrict__ lnb,
    float* __restrict__ outf)
{
    const int m0 = blockIdx.x * 64;
    const int t = threadIdx.x;
    const int w = t >> 6, l = t & 63, lr = l & 15, lg = l >> 4;
    __shared__ __align__(16) unsigned short hA[64 * 72];
    __shared__ __align__(16) unsigned short hB[64 * 136];
    __shared__ __align__(16) unsigned char U1[18432];
    __shared__ __align__(16) unsigned char U2[17408];
    __shared__ float vb1[128], vb2[64], vg1b[64], vg2b[64], vlng[64], vlnb[64];

    unsigned short* W1t = (unsigned short*)U1;
    unsigned short* W2t = (unsigned short*)U2;
    unsigned short* G1t = (unsigned short*)U1;
    unsigned short* G2t = (unsigned short*)(U1 + 9216);
    float* yA = (float*)U2;

    if (t < 128) vb1[t] = b1[t];
    if (t < 64) { vb2[t] = b2[t]; vg1b[t] = g1b[t]; vg2b[t] = g2b[t]; vlng[t] = lng[t]; vlnb[t] = lnb[t]; }
    #pragma unroll
    for (int p = 0; p < 16; ++p) {
        int e = t + 256 * p; int r = e >> 6, d = e & 63;
        hA[r*72 + d] = *(const unsigned short*)&eb[(size_t)(m0 + r) * 64 + d];
    }
    #pragma unroll
    for (int p = 0; p < 32; ++p) {
        int e = t + 256 * p; int k = e >> 7, c = e & 127;
        W1t[c*72 + k] = f2bf(w1[(size_t)k * 128 + c]);
    }
    #pragma unroll
    for (int p = 0; p < 32; ++p) {
        int e = t + 256 * p; int k = e >> 6, c = e & 63;
        W2t[c*136 + k] = f2bf(w2[(size_t)k * 64 + c]);
    }
    __syncthreads();

    f32x4 acc1[4][2];
    #pragma unroll
    for (int rg = 0; rg < 4; ++rg)
        #pragma unroll
        for (int cf = 0; cf < 2; ++cf) acc1[rg][cf] = (f32x4){0.f,0.f,0.f,0.f};
    #pragma unroll
    for (int ks = 0; ks < 2; ++ks) {
        short8v af[4];
        #pragma unroll
        for (int rg = 0; rg < 4; ++rg)
            af[rg] = *(const short8v*)&hA[(rg*16 + lr)*72 + ks*32 + lg*8];
        #pragma unroll
        for (int cf = 0; cf < 2; ++cf) {
            short8v bf = *(const short8v*)&W1t[(w*32 + cf*16 + lr)*72 + ks*32 + lg*8];
            #pragma unroll
            for (int rg = 0; rg < 4; ++rg)
                acc1[rg][cf] = __builtin_amdgcn_mfma_f32_16x16x32_bf16(af[rg], bf, acc1[rg][cf], 0, 0, 0);
        }
    }
    #pragma unroll
    for (int rg = 0; rg < 4; ++rg)
        #pragma unroll
        for (int cf = 0; cf < 2; ++cf)
            #pragma unroll
            for (int j = 0; j < 4; ++j) {
                int r = rg*16 + lg*4 + j, c = w*32 + cf*16 + lr;
                hB[r*136 + c] = f2bf(eluf_(acc1[rg][cf][j] + vb1[c]));
            }
    __syncthreads();

    #pragma unroll
    for (int p = 0; p < 16; ++p) {
        int e = t + 256 * p; int k = e >> 6, c = e & 63;
        G1t[c*72 + k] = f2bf(g1w[k*64 + c]);
        G2t[c*72 + k] = f2bf(g2w[k*64 + c]);
    }
    __syncthreads();

    f32x4 acc2[4];
    #pragma unroll
    for (int rg = 0; rg < 4; ++rg) acc2[rg] = (f32x4){0.f,0.f,0.f,0.f};
    #pragma unroll
    for (int ks = 0; ks < 4; ++ks) {
        short8v bf = *(const short8v*)&W2t[(w*16 + lr)*136 + ks*32 + lg*8];
        #pragma unroll
        for (int rg = 0; rg < 4; ++rg) {
            short8v af = *(const short8v*)&hB[(rg*16 + lr)*136 + ks*32 + lg*8];
            acc2[rg] = __builtin_amdgcn_mfma_f32_16x16x32_bf16(af, bf, acc2[rg], 0, 0, 0);
        }
    }
    #pragma unroll
    for (int rg = 0; rg < 4; ++rg)
        #pragma unroll
        for (int j = 0; j < 4; ++j) {
            int r = rg*16 + lg*4 + j, c = w*16 + lr;
            hA[r*72 + c] = f2bf(acc2[rg][j] + vb2[c]);
        }
    __syncthreads();

    f32x4 aA[4], aB[4];
    #pragma unroll
    for (int rg = 0; rg < 4; ++rg) { aA[rg] = (f32x4){0.f,0.f,0.f,0.f}; aB[rg] = (f32x4){0.f,0.f,0.f,0.f}; }
    #pragma unroll
    for (int ks = 0; ks < 2; ++ks) {
        short8v b1f = *(const short8v*)&G1t[(w*16 + lr)*72 + ks*32 + lg*8];
        short8v b2f = *(const short8v*)&G2t[(w*16 + lr)*72 + ks*32 + lg*8];
        #pragma unroll
        for (int rg = 0; rg < 4; ++rg) {
            short8v af = *(const short8v*)&hA[(rg*16 + lr)*72 + ks*32 + lg*8];
            aA[rg] = __builtin_amdgcn_mfma_f32_16x16x32_bf16(af, b1f, aA[rg], 0, 0, 0);
            aB[rg] = __builtin_amdgcn_mfma_f32_16x16x32_bf16(af, b2f, aB[rg], 0, 0, 0);
        }
    }
    __syncthreads();

    #pragma unroll
    for (int rg = 0; rg < 4; ++rg)
        #pragma unroll
        for (int j = 0; j < 4; ++j) {
            int r = rg*16 + lg*4 + j, c = w*16 + lr;
            float sg = sigmoidf_(aA[rg][j] + vg1b[c]);
            yA[r*68 + c] = sg * (aB[rg][j] + vg2b[c]) + res[(size_t)(m0 + r) * 64 + c];
        }
    __syncthreads();

    const int tr = t >> 4, tc = t & 15;
    #pragma unroll
    for (int a = 0; a < 4; ++a) {
        const int r = tr + 16*a;
        float vals[4]; float part = 0.f;
        #pragma unroll
        for (int b = 0; b < 4; ++b) { vals[b] = yA[r*68 + tc + 16*b]; part += vals[b]; }
        #pragma unroll
        for (int off = 1; off < 16; off <<= 1) part += __shfl_xor(part, off);
        const float mean = part * (1.f / 64.f);
        float vp = 0.f;
        #pragma unroll
        for (int b = 0; b < 4; ++b) { float d = vals[b] - mean; vp += d * d; }
        #pragma unroll
        for (int off = 1; off < 16; off <<= 1) vp += __shfl_xor(vp, off);
        const float inv = rsqrtf(vp * (1.f / 64.f) + LN_EPS);
        #pragma unroll
        for (int b = 0; b < 4; ++b) {
            const int c = tc + 16*b;
            outf[(size_t)(m0 + r) * 64 + c] = (vals[b] - mean) * inv * vlng[c] + vlnb[c];
        }
    }
}

// =====================================================================
// head: mean over T -> fc1+relu -> fc2
// =====================================================================
__global__ __launch_bounds__(64) void head_kernel(
    const float* __restrict__ outln,
    const float* __restrict__ fc1_w, const float* __restrict__ fc1_b,
    const float* __restrict__ fc2_w, const float* __restrict__ fc2_b,
    float* __restrict__ out)
{
    const int b = blockIdx.x, l = threadIdx.x;
    __shared__ float sp[64];
    float s = 0.f;
    #pragma unroll
    for (int tt = 0; tt < TSEQ; ++tt) s += outln[((size_t)(b * TSEQ + tt)) * 64 + l];
    sp[l] = s * (1.f / 24.f);
    __syncthreads();
    float a = fc1_b[l];
    for (int k = 0; k < 64; ++k) a += sp[k] * fc1_w[k*64 + l];
    float f1 = fmaxf(a, 0.f);
    #pragma unroll
    for (int j = 0; j < 6; ++j) {
        float p = f1 * fc2_w[l*6 + j];
        #pragma unroll
        for (int off = 32; off; off >>= 1) p += __shfl_xor(p, off);
        if (l == 0) out[b*6 + j] = p + fc2_b[j];
    }
}

// =====================================================================
extern "C" void kernel_launch(void* const* d_in, const int* in_sizes, int n_in,
                              void* d_out, int out_size, void* d_ws, size_t ws_size,
                              hipStream_t stream)
{
    const float* x        = (const float*)d_in[0];
    const float* f_w1     = (const float*)d_in[1];
    const float* f_b1     = (const float*)d_in[2];
    const float* f_w2     = (const float*)d_in[3];
    const float* f_b2     = (const float*)d_in[4];
    const float* f_g1w    = (const float*)d_in[5];
    const float* f_g1b    = (const float*)d_in[6];
    const float* f_g2w    = (const float*)d_in[7];
    const float* f_g2b    = (const float*)d_in[8];
    const float* f_skw    = (const float*)d_in[9];
    const float* f_skb    = (const float*)d_in[10];
    const float* f_lng    = (const float*)d_in[11];
    const float* f_lnb    = (const float*)d_in[12];
    const float* w_w1     = (const float*)d_in[13];
    const float* w_b1     = (const float*)d_in[14];
    const float* w_w2     = (const float*)d_in[15];
    const float* w_b2     = (const float*)d_in[16];
    const float* w_g1w    = (const float*)d_in[17];
    const float* w_g1b    = (const float*)d_in[18];
    const float* w_g2w    = (const float*)d_in[19];
    const float* w_g2b    = (const float*)d_in[20];
    const float* w_skw    = (const float*)d_in[21];
    const float* w_skb    = (const float*)d_in[22];
    const float* w_lng    = (const float*)d_in[23];
    const float* w_lnb    = (const float*)d_in[24];
    const float* lstm_wih = (const float*)d_in[25];
    const float* lstm_whh = (const float*)d_in[26];
    const float* lstm_bih = (const float*)d_in[27];
    const float* lstm_bhh = (const float*)d_in[28];
    const float* pl_g1w   = (const float*)d_in[29];
    const float* pl_g1b   = (const float*)d_in[30];
    const float* pl_g2w   = (const float*)d_in[31];
    const float* pl_g2b   = (const float*)d_in[32];
    const float* pl_lng   = (const float*)d_in[33];
    const float* pl_lnb   = (const float*)d_in[34];
    const float* attn_in_w  = (const float*)d_in[35];
    const float* attn_in_b  = (const float*)d_in[36];
    const float* attn_out_w = (const float*)d_in[37];
    const float* attn_out_b = (const float*)d_in[38];
    const float* pa_g1w   = (const float*)d_in[39];
    const float* pa_g1b   = (const float*)d_in[40];
    const float* pa_g2w   = (const float*)d_in[41];
    const float* pa_g2b   = (const float*)d_in[42];
    const float* pa_lng   = (const float*)d_in[43];
    const float* pa_lnb   = (const float*)d_in[44];
    const float* ff_w1    = (const float*)d_in[45];
    const float* ff_b1    = (const float*)d_in[46];
    const float* ff_w2    = (const float*)d_in[47];
    const float* ff_b2    = (const float*)d_in[48];
    const float* ff_g1w   = (const float*)d_in[49];
    const float* ff_g1b   = (const float*)d_in[50];
    const float* ff_g2w   = (const float*)d_in[51];
    const float* ff_g2b   = (const float*)d_in[52];
    const float* ff_lng   = (const float*)d_in[53];
    const float* ff_lnb   = (const float*)d_in[54];
    const float* fc1_w    = (const float*)d_in[55];
    const float* fc1_b    = (const float*)d_in[56];
    const float* fc2_w    = (const float*)d_in[57];
    const float* fc2_b    = (const float*)d_in[58];

    float* ws = (float*)d_ws;

    // ---------------- phase-2 union (fixed offsets) ----------------------
    size_t o = 0;
    const size_t o_S0   = o; o += (size_t)MTOT * 256;   // xW / qkv
    const size_t o_A    = o; o += (size_t)MTOT * 64;    // lstm_out
    const size_t o_Bf   = o; o += (size_t)MTOT * 64;    // enriched f32
    const size_t o_Cf   = o; o += (size_t)MTOT * 64;    // outln f32
    const size_t o_Df   = o; o += (size_t)MTOT * 64;    // temporal f32
    const size_t o_F    = o; o += (size_t)MTOT * 128;   // bf16 trio: tb/ab/eb
    const size_t o_whhT = o; o += 16384;
    const size_t unionP2 = o;                            // 7,880,704 floats

    const size_t o_tb = o_F;
    const size_t o_ab = o_F + (size_t)MTOT * 32;
    const size_t o_eb = o_F + (size_t)MTOT * 64;

    // ---------------- adaptive M-chunk selection --------------------------
    // overlay(mc) = stacked bf16 + partials + w81 + wcat  (in floats)
    const size_t persist = (size_t)MTOT * 96;            // sel f32 + selb bf16
    int mc = 0;
    {
        const int cands[4] = {12288, 6144, 3072, 1536};
        for (int ci = 0; ci < 4; ++ci) {
            const size_t c = (size_t)cands[ci];
            size_t overlay = c * FDIM / 2 + (size_t)KS * c * NW + c * 81
                           + (size_t)NW * FDIM / 2;
            size_t A = overlay > unionP2 ? overlay : unionP2;
            if ((A + persist) * sizeof(float) <= ws_size) { mc = cands[ci]; break; }
        }
        if (mc == 0) return;                             // workspace too small
    }
    const size_t ovl_partial = (size_t)mc * FDIM / 2;
    const size_t ovl_w81     = ovl_partial + (size_t)KS * mc * NW;
    const size_t ovl_wcat    = ovl_w81 + (size_t)mc * 81;
    const size_t ovl_end     = ovl_wcat + (size_t)NW * FDIM / 2;
    const size_t regA        = ovl_end > unionP2 ? ovl_end : unionP2;
    const size_t o_sel  = regA;
    const size_t o_selb = o_sel + (size_t)MTOT * 64;

    const dim3 blk(256);

    // 0) pack weight-head matrices to bf16 (transposed)
    wprep_kernel<<<dim3((FDIM + 255) / 256, NW), blk, 0, stream>>>(
        w_w1, w_skw, (unsigned short*)(ws + ovl_wcat));

    // ---------------- phase 1: VSN + weight-GRN, chunked over M ----------
    for (int mb = 0; mb < MTOT; mb += mc) {
        __hip_bfloat16* chunk = (__hip_bfloat16*)ws;
        vsn_kernel<<<dim3(NF, (mc / 64) / NT), blk, 0, stream>>>(
            x + (size_t)mb * NF, f_w1, f_b1, f_w2, f_b2, f_g1w, f_g1b,
            f_g2w, f_g2b, f_skw, f_skb, f_lng, f_lnb, chunk);
        wgemm_kernel<<<dim3(mc / 16, KS), dim3(64), 0, stream>>>(
            chunk, (const unsigned short*)(ws + ovl_wcat), ws + ovl_partial, mc);
        wtail_kernel<<<dim3(mc / 16), blk, 0, stream>>>(
            ws + ovl_partial, w_b1, w_skb, w_w2, w_b2, w_g1w, w_g1b,
            w_g2w, w_g2b, w_lng, w_lnb, ws + ovl_w81, mc);
        selected_kernel<<<dim3(mc), blk, 0, stream>>>(
            chunk, ws + ovl_w81, ws + o_sel + (size_t)mb * 64,
            (__hip_bfloat16*)(ws + o_selb) + (size_t)mb * 64);
    }

    // ---------------- phase 2: LSTM -> attention -> head -----------------
    lstm_prep_kernel<<<dim3(64), blk, 0, stream>>>(lstm_whh, ws + o_whhT);
    xw_kernel<<<dim3(MTOT / 64), blk, 0, stream>>>(
        (const __hip_bfloat16*)(ws + o_selb), lstm_wih, lstm_bih, lstm_bhh, ws + o_S0);
    lstm_kernel<<<dim3(BB), blk, 0, stream>>>(ws + o_S0, ws + o_whhT, ws + o_A);
    fused_pl_kernel<<<dim3(MTOT / 64), blk, 0, stream>>>(
        ws + o_A, ws + o_sel, pl_g1w, pl_g1b, pl_g2w, pl_g2b, pl_lng, pl_lnb,
        ws + o_Df, (__hip_bfloat16*)(ws + o_tb));
    qkv_kernel<<<dim3(MTOT / 64), blk, 0, stream>>>(
        (const __hip_bfloat16*)(ws + o_tb), attn_in_w, attn_in_b, ws + o_S0);
    attn_kernel<<<dim3(BB), blk, 0, stream>>>(
        ws + o_S0, (__hip_bfloat16*)(ws + o_ab));
    fused_pa_kernel<<<dim3(MTOT / 64), blk, 0, stream>>>(
        (const __hip_bfloat16*)(ws + o_ab), ws + o_Df,
        attn_out_w, attn_out_b, pa_g1w, pa_g1b, pa_g2w, pa_g2b, pa_lng, pa_lnb,
        ws + o_Bf, (__hip_bfloat16*)(ws + o_eb));
    fused_ff_kernel<<<dim3(MTOT / 64), blk, 0, stream>>>(
        (const __hip_bfloat16*)(ws + o_eb), ws + o_Bf,
        ff_w1, ff_b1, ff_w2, ff_b2, ff_g1w, ff_g1b, ff_g2w, ff_g2b,
        ff_lng, ff_lnb, ws + o_Cf);
    head_kernel<<<dim3(BB), dim3(64), 0, stream>>>(
        ws + o_Cf, fc1_w, fc1_b, fc2_w, fc2_b, (float*)d_out);
}

// Round 8
// 576.784 us; speedup vs baseline: 19.7099x; 1.1365x over previous
//
#include <hip/hip_runtime.h>
#include <hip/hip_bf16.h>
#include <math.h>

// ---------------- problem constants ----------------
constexpr int BB   = 512;
constexpr int TSEQ = 24;
constexpr int NF   = 81;
constexpr int DD   = 64;
constexpr int MTOT = BB * TSEQ;      // 12288
constexpr int FDIM = NF * DD;        // 5184
constexpr int KS   = 9;              // split-K groups for weight-head GEMM
constexpr int NW   = 160;            // padded combined N: 64 (wh1) + 81 (sk) + 15 pad
constexpr int NT   = 6;              // m-tiles per VSN block
constexpr float LN_EPS = 1e-5f;

typedef __attribute__((ext_vector_type(8))) short short8v;   // 8 bf16 (4 VGPRs)
typedef __attribute__((ext_vector_type(4))) float f32x4;     // MFMA C/D

static __device__ __forceinline__ float sigmoidf_(float x) { return 1.f / (1.f + expf(-x)); }
static __device__ __forceinline__ float eluf_(float x)     { return x > 0.f ? x : (expf(x) - 1.f); }
static __device__ __forceinline__ unsigned short f2bf(float x) {
    __hip_bfloat16 h = __float2bfloat16(x);
    return *reinterpret_cast<unsigned short*>(&h);
}

// =====================================================================
// x transpose: xT[f][m] = x[m][f]
// =====================================================================
__global__ void xt_kernel(const float* __restrict__ x, float* __restrict__ xT)
{
    int id = blockIdx.x * 256 + threadIdx.x;
    if (id >= NF * MTOT) return;
    int f = id / MTOT, m = id - f * MTOT;
    xT[id] = x[(size_t)m * NF + f];
}

// =====================================================================
// Kernel 1: VSN v4 — persistent weight LDS, xv staging, hA∪yA union,
// vectorized LN stores. grid (NF, (mc/64)/NT), 256 threads.
// =====================================================================
__global__ __launch_bounds__(256) void vsn_kernel(
    const float* __restrict__ xT,   // xT + mb ; feature stride MTOT
    const float* __restrict__ f_w1,  const float* __restrict__ f_b1,
    const float* __restrict__ f_w2,  const float* __restrict__ f_b2,
    const float* __restrict__ f_g1w, const float* __restrict__ f_g1b,
    const float* __restrict__ f_g2w, const float* __restrict__ f_g2b,
    const float* __restrict__ f_skw, const float* __restrict__ f_skb,
    const float* __restrict__ f_lng, const float* __restrict__ f_lnb,
    __hip_bfloat16* __restrict__ stacked)
{
    const int f  = blockIdx.x;
    const int t  = threadIdx.x;
    const int w  = t >> 6;
    const int l  = t & 63;
    const int lr = l & 15;
    const int lg = l >> 4;

    __shared__ __align__(16) unsigned short W2t[64 * 72];
    __shared__ __align__(16) unsigned short G1t[64 * 72];
    __shared__ __align__(16) unsigned short G2t[64 * 72];
    __shared__ __align__(16) unsigned char  U[17408];      // hA (9216) ∪ yA (17408)
    unsigned short* hA = (unsigned short*)U;               // [64][72] bf16
    float*          yA = (float*)U;                        // [64][68] f32
    __shared__ float vw1[64], vb1[64], vb2[64], vg1b[64], vg2b[64];
    __shared__ float vskw[64], vskb[64], vlng[64], vlnb[64], xv[64];

    if (t < 64) {
        vw1[t]  = f_w1 [f*64 + t];  vb1[t]  = f_b1 [f*64 + t];
        vb2[t]  = f_b2 [f*64 + t];
        vg1b[t] = f_g1b[f*64 + t];  vg2b[t] = f_g2b[f*64 + t];
        vskw[t] = f_skw[f*64 + t];  vskb[t] = f_skb[f*64 + t];
        vlng[t] = f_lng[f*64 + t];  vlnb[t] = f_lnb[f*64 + t];
        xv[t]   = xT[(size_t)f * MTOT + blockIdx.y * (NT * 64) + t];
    }
    {
        const float* w2p = f_w2  + (size_t)f * 4096;
        const float* g1p = f_g1w + (size_t)f * 4096;
        const float* g2p = f_g2w + (size_t)f * 4096;
        #pragma unroll
        for (int p = 0; p < 16; ++p) {
            int e = t + 256 * p; int k = e >> 6, c = e & 63;
            W2t[c*72 + k] = f2bf(w2p[k*64 + c]);
            G1t[c*72 + k] = f2bf(g1p[k*64 + c]);
            G2t[c*72 + k] = f2bf(g2p[k*64 + c]);
        }
    }
    __syncthreads();   // bar0: weights + params + xv(tile0)

    for (int it = 0; it < NT; ++it) {
        const int m0 = (blockIdx.y * NT + it) * 64;

        // A: h0 = elu(x*w1 + b1) -> hA
        #pragma unroll
        for (int p = 0; p < 16; ++p) {
            int e = t + 256 * p; int r = e >> 6, d = e & 63;
            hA[r*72 + d] = f2bf(eluf_(xv[r] * vw1[d] + vb1[d]));
        }
        __syncthreads();   // bar1

        // B: mm1 h1 = h0 @ w2
        f32x4 acc1[4];
        #pragma unroll
        for (int rg = 0; rg < 4; ++rg) acc1[rg] = (f32x4){0.f, 0.f, 0.f, 0.f};
        #pragma unroll
        for (int ks = 0; ks < 2; ++ks) {
            short8v bf = *(const short8v*)&W2t[(w*16 + lr)*72 + ks*32 + lg*8];
            #pragma unroll
            for (int rg = 0; rg < 4; ++rg) {
                short8v af = *(const short8v*)&hA[(rg*16 + lr)*72 + ks*32 + lg*8];
                acc1[rg] = __builtin_amdgcn_mfma_f32_16x16x32_bf16(af, bf, acc1[rg], 0, 0, 0);
            }
        }
        __syncthreads();   // bar2: mm1 reads of hA done

        // C: write h1 (+b2) -> hA
        #pragma unroll
        for (int rg = 0; rg < 4; ++rg)
            #pragma unroll
            for (int j = 0; j < 4; ++j) {
                int r = rg*16 + lg*4 + j, c = w*16 + lr;
                hA[r*72 + c] = f2bf(acc1[rg][j] + vb2[c]);
            }
        __syncthreads();   // bar3: hA(h1) ready

        // D: mm2/mm3 + GLU+skip into registers
        f32x4 aA[4], aB[4];
        #pragma unroll
        for (int rg = 0; rg < 4; ++rg) { aA[rg] = (f32x4){0.f,0.f,0.f,0.f}; aB[rg] = (f32x4){0.f,0.f,0.f,0.f}; }
        #pragma unroll
        for (int ks = 0; ks < 2; ++ks) {
            short8v b1f = *(const short8v*)&G1t[(w*16 + lr)*72 + ks*32 + lg*8];
            short8v b2f = *(const short8v*)&G2t[(w*16 + lr)*72 + ks*32 + lg*8];
            #pragma unroll
            for (int rg = 0; rg < 4; ++rg) {
                short8v af = *(const short8v*)&hA[(rg*16 + lr)*72 + ks*32 + lg*8];
                aA[rg] = __builtin_amdgcn_mfma_f32_16x16x32_bf16(af, b1f, aA[rg], 0, 0, 0);
                aB[rg] = __builtin_amdgcn_mfma_f32_16x16x32_bf16(af, b2f, aB[rg], 0, 0, 0);
            }
        }
        float yv[4][4];
        #pragma unroll
        for (int rg = 0; rg < 4; ++rg)
            #pragma unroll
            for (int j = 0; j < 4; ++j) {
                int r = rg*16 + lg*4 + j, c = w*16 + lr;
                float sg = sigmoidf_(aA[rg][j] + vg1b[c]);
                yv[rg][j] = sg * (aB[rg][j] + vg2b[c]) + xv[r] * vskw[c] + vskb[c];
            }
        __syncthreads();   // bar4: all hA + xv reads done

        // E: write yA (overlays hA) ; stage next tile's xv
        #pragma unroll
        for (int rg = 0; rg < 4; ++rg)
            #pragma unroll
            for (int j = 0; j < 4; ++j) {
                int r = rg*16 + lg*4 + j, c = w*16 + lr;
                yA[r*68 + c] = yv[rg][j];
            }
        if (t < 64 && it + 1 < NT)
            xv[t] = xT[(size_t)f * MTOT + m0 + 64 + t];
        __syncthreads();   // bar5: yA ready

        // F: LayerNorm(64) + vectorized bf16 store (lane owns 4 consecutive c)
        const int tr = t >> 4, tc = t & 15;
        #pragma unroll
        for (int a = 0; a < 4; ++a) {
            const int r = tr + 16*a;
            float4 v4 = *(const float4*)&yA[r*68 + tc*4];
            float part = v4.x + v4.y + v4.z + v4.w;
            #pragma unroll
            for (int off = 1; off < 16; off <<= 1) part += __shfl_xor(part, off);
            const float mean = part * (1.f / 64.f);
            float d0 = v4.x - mean, d1 = v4.y - mean, d2 = v4.z - mean, d3 = v4.w - mean;
            float vp = d0*d0 + d1*d1 + d2*d2 + d3*d3;
            #pragma unroll
            for (int off = 1; off < 16; off <<= 1) vp += __shfl_xor(vp, off);
            const float inv = rsqrtf(vp * (1.f / 64.f) + LN_EPS);
            const int c0 = tc * 4;
            ushort4 o;
            o.x = f2bf(d0 * inv * vlng[c0+0] + vlnb[c0+0]);
            o.y = f2bf(d1 * inv * vlng[c0+1] + vlnb[c0+1]);
            o.z = f2bf(d2 * inv * vlng[c0+2] + vlnb[c0+2]);
            o.w = f2bf(d3 * inv * vlng[c0+3] + vlnb[c0+3]);
            *(ushort4*)&stacked[(size_t)(m0 + r) * FDIM + f*64 + c0] = o;
        }
        __syncthreads();   // bar6: yA reads done before next tile's hA writes
    }
}

// =====================================================================
// Pack w_w1 / w_skw into bf16 WcatT[160][FDIM]
// =====================================================================
__global__ void wprep_kernel(
    const float* __restrict__ w_w1, const float* __restrict__ w_skw,
    unsigned short* __restrict__ WcatT)
{
    const int c = blockIdx.y;
    const int k = blockIdx.x * 256 + threadIdx.x;
    if (k >= FDIM) return;
    float v = 0.f;
    if (c < 64)       v = w_w1[(size_t)k * 64 + c];
    else if (c < 145) v = w_skw[(size_t)k * 81 + (c - 64)];
    WcatT[(size_t)c * FDIM + k] = f2bf(v);
}

// =====================================================================
// Split-K fused weight-head GEMM (MFMA, LDS-free), MR=2 (32 rows/block)
// grid (mc/32, KS), 64 threads.
// =====================================================================
__global__ __launch_bounds__(64) void wgemm_kernel(
    const __hip_bfloat16* __restrict__ stacked,
    const unsigned short* __restrict__ WcatT,
    float* __restrict__ partial, int mc)
{
    const int m0 = blockIdx.x * 32;
    const int ks = blockIdx.y;
    const int l  = threadIdx.x;
    const int lr = l & 15, lg = l >> 4;

    f32x4 acc[2][10];
    #pragma unroll
    for (int h = 0; h < 2; ++h)
        #pragma unroll
        for (int n = 0; n < 10; ++n) acc[h][n] = (f32x4){0.f, 0.f, 0.f, 0.f};

    const size_t a0r = (size_t)(m0 + lr) * FDIM;
    const size_t a1r = (size_t)(m0 + 16 + lr) * FDIM;
    const int k0base = ks * 576;
    for (int kk = 0; kk < 576; kk += 32) {
        const int k = k0base + kk + lg * 8;
        short8v a0 = *(const short8v*)(stacked + a0r + k);
        short8v a1 = *(const short8v*)(stacked + a1r + k);
        #pragma unroll
        for (int n = 0; n < 10; ++n) {
            short8v bf = *(const short8v*)(WcatT + (size_t)(n*16 + lr) * FDIM + k);
            acc[0][n] = __builtin_amdgcn_mfma_f32_16x16x32_bf16(a0, bf, acc[0][n], 0, 0, 0);
            acc[1][n] = __builtin_amdgcn_mfma_f32_16x16x32_bf16(a1, bf, acc[1][n], 0, 0, 0);
        }
    }
    #pragma unroll
    for (int h = 0; h < 2; ++h)
        #pragma unroll
        for (int n = 0; n < 10; ++n)
            #pragma unroll
            for (int j = 0; j < 4; ++j) {
                const int m = m0 + h*16 + lg*4 + j;
                partial[((size_t)ks * mc + m) * NW + n*16 + lr] = acc[h][n][j];
            }
}

// =====================================================================
// Weight-GRN tail: LDS-staged weights, 16 rows/block, mc-parameterized
// =====================================================================
__global__ __launch_bounds__(256) void wtail_kernel(
    const float* __restrict__ partial,
    const float* __restrict__ w_b1,  const float* __restrict__ w_skb,
    const float* __restrict__ w_w2,  const float* __restrict__ w_b2,
    const float* __restrict__ w_g1w, const float* __restrict__ w_g1b,
    const float* __restrict__ w_g2w, const float* __restrict__ w_g2b,
    const float* __restrict__ w_lng, const float* __restrict__ w_lnb,
    float* __restrict__ w81, int mc)
{
    __shared__ float w2s[5184];
    __shared__ float g1s[6561];
    __shared__ float g2s[6561];
    __shared__ float sWh[16][64];
    __shared__ float sW2[16][96];

    const int t  = threadIdx.x;
    const int wv = t >> 6, l = t & 63;
    const int m0 = blockIdx.x * 16;
    const bool v1 = (l < 17);

    for (int e = t; e < 5184; e += 256) w2s[e] = w_w2[e];
    for (int e = t; e < 6561; e += 256) { g1s[e] = w_g1w[e]; g2s[e] = w_g2w[e]; }

    float s0[4], sk0[4], sk1[4];
    {
        const float b1v = w_b1[l], skb0 = w_skb[l], skb1 = v1 ? w_skb[64 + l] : 0.f;
        #pragma unroll
        for (int rr = 0; rr < 4; ++rr) { s0[rr] = b1v; sk0[rr] = skb0; sk1[rr] = skb1; }
    }
    #pragma unroll
    for (int ks = 0; ks < KS; ++ks) {
        #pragma unroll
        for (int rr = 0; rr < 4; ++rr) {
            const float* pr = partial + ((size_t)ks * mc + (m0 + wv*4 + rr)) * NW;
            s0[rr]  += pr[l];
            sk0[rr] += pr[64 + l];
            if (v1) sk1[rr] += pr[128 + l];
        }
    }
    #pragma unroll
    for (int rr = 0; rr < 4; ++rr) sWh[wv*4 + rr][l] = eluf_(s0[rr]);
    __syncthreads();

    float a0[4], a1[4];
    {
        const float b0 = w_b2[l], b1v = v1 ? w_b2[64 + l] : 0.f;
        #pragma unroll
        for (int rr = 0; rr < 4; ++rr) { a0[rr] = b0; a1[rr] = b1v; }
    }
    #pragma unroll 4
    for (int i = 0; i < 64; ++i) {
        const float wl = w2s[i*81 + l];
        const float wh = v1 ? w2s[i*81 + 64 + l] : 0.f;
        #pragma unroll
        for (int rr = 0; rr < 4; ++rr) {
            const float h = sWh[wv*4 + rr][i];
            a0[rr] += h * wl;
            a1[rr] += h * wh;
        }
    }
    #pragma unroll
    for (int rr = 0; rr < 4; ++rr) {
        sW2[wv*4 + rr][l] = a0[rr];
        if (v1) sW2[wv*4 + rr][64 + l] = a1[rr];
    }
    __syncthreads();

    float g10[4], g20[4], g11[4], g21[4];
    {
        const float c10 = w_g1b[l], c20 = w_g2b[l];
        const float c11 = v1 ? w_g1b[64 + l] : 0.f, c21 = v1 ? w_g2b[64 + l] : 0.f;
        #pragma unroll
        for (int rr = 0; rr < 4; ++rr) { g10[rr] = c10; g20[rr] = c20; g11[rr] = c11; g21[rr] = c21; }
    }
    #pragma unroll 3
    for (int i = 0; i < 81; ++i) {
        const float w1l = g1s[i*81 + l],            w2l = g2s[i*81 + l];
        const float w1h = v1 ? g1s[i*81 + 64 + l] : 0.f;
        const float w2h = v1 ? g2s[i*81 + 64 + l] : 0.f;
        #pragma unroll
        for (int rr = 0; rr < 4; ++rr) {
            const float h = sW2[wv*4 + rr][i];
            g10[rr] += h * w1l; g20[rr] += h * w2l;
            g11[rr] += h * w1h; g21[rr] += h * w2h;
        }
    }

    #pragma unroll
    for (int rr = 0; rr < 4; ++rr) {
        const int m = m0 + wv*4 + rr;
        float y0 = sigmoidf_(g10[rr]) * g20[rr] + sk0[rr];
        float y1 = v1 ? (sigmoidf_(g11[rr]) * g21[rr] + sk1[rr]) : 0.f;

        float s = y0 + (v1 ? y1 : 0.f);
        #pragma unroll
        for (int off = 32; off; off >>= 1) s += __shfl_xor(s, off);
        const float mean = s / 81.f;
        float d0 = y0 - mean, d1 = v1 ? (y1 - mean) : 0.f;
        float vs = d0*d0 + (v1 ? d1*d1 : 0.f);
        #pragma unroll
        for (int off = 32; off; off >>= 1) vs += __shfl_xor(vs, off);
        const float inv = rsqrtf(vs / 81.f + LN_EPS);
        float wn0 = d0 * inv * w_lng[l] + w_lnb[l];
        float wn1 = v1 ? (d1 * inv * w_lng[64 + l] + w_lnb[64 + l]) : -1e30f;

        float mx = fmaxf(wn0, wn1);
        #pragma unroll
        for (int off = 32; off; off >>= 1) mx = fmaxf(mx, __shfl_xor(mx, off));
        float e0 = expf(wn0 - mx), e1 = v1 ? expf(wn1 - mx) : 0.f;
        float es = e0 + e1;
        #pragma unroll
        for (int off = 32; off; off >>= 1) es += __shfl_xor(es, off);
        const float r = 1.f / es;
        w81[(size_t)m * 81 + l] = e0 * r;
        if (v1) w81[(size_t)m * 81 + 64 + l] = e1 * r;
    }
}

// =====================================================================
// selected: f32 + bf16 outputs
// =====================================================================
__global__ __launch_bounds__(256) void selected_kernel(
    const __hip_bfloat16* __restrict__ stacked, const float* __restrict__ w81,
    float* __restrict__ sel, __hip_bfloat16* __restrict__ selb)
{
    const int m = blockIdx.x;
    const int d = threadIdx.x & 63, fg = threadIdx.x >> 6;
    __shared__ float red[4][64];
    __shared__ float wsh[81];
    if (threadIdx.x < 81) wsh[threadIdx.x] = w81[(size_t)m * 81 + threadIdx.x];
    __syncthreads();
    float acc = 0.f;
    for (int f = fg; f < 81; f += 4)
        acc += __bfloat162float(stacked[(size_t)m * FDIM + f*64 + d]) * wsh[f];
    red[fg][d] = acc;
    __syncthreads();
    if (fg == 0) {
        float v = red[0][d] + red[1][d] + red[2][d] + red[3][d];
        sel[(size_t)m * 64 + d]  = v;
        selb[(size_t)m * 64 + d] = __float2bfloat16(v);
    }
}

// =====================================================================
// xW = selb @ wih^T + (bih+bhh)    MFMA, grid MTOT/64 blocks, 256 thr
// =====================================================================
__global__ __launch_bounds__(256) void xw_kernel(
    const __hip_bfloat16* __restrict__ selb,
    const float* __restrict__ wih,
    const float* __restrict__ bih, const float* __restrict__ bhh,
    float* __restrict__ xW)
{
    const int m0 = blockIdx.x * 64;
    const int t = threadIdx.x;
    const int w = t >> 6, l = t & 63, lr = l & 15, lg = l >> 4;
    __shared__ __align__(16) unsigned short hA[64 * 72];
    __shared__ __align__(16) unsigned short Wt[256 * 72];
    __shared__ float vbs[256];

    vbs[t] = bih[t] + bhh[t];
    #pragma unroll
    for (int p = 0; p < 16; ++p) {
        int e = t + 256 * p; int r = e >> 6, d = e & 63;
        hA[r*72 + d] = *(const unsigned short*)&selb[(size_t)(m0 + r) * 64 + d];
    }
    #pragma unroll
    for (int p = 0; p < 64; ++p) {
        int e = t + 256 * p; int c = e >> 6, k = e & 63;
        Wt[c*72 + k] = f2bf(wih[c*64 + k]);
    }
    __syncthreads();

    f32x4 acc[4][4];
    #pragma unroll
    for (int rg = 0; rg < 4; ++rg)
        #pragma unroll
        for (int cf = 0; cf < 4; ++cf) acc[rg][cf] = (f32x4){0.f,0.f,0.f,0.f};
    #pragma unroll
    for (int ks = 0; ks < 2; ++ks) {
        short8v af[4];
        #pragma unroll
        for (int rg = 0; rg < 4; ++rg)
            af[rg] = *(const short8v*)&hA[(rg*16 + lr)*72 + ks*32 + lg*8];
        #pragma unroll
        for (int cf = 0; cf < 4; ++cf) {
            short8v bf = *(const short8v*)&Wt[(w*64 + cf*16 + lr)*72 + ks*32 + lg*8];
            #pragma unroll
            for (int rg = 0; rg < 4; ++rg)
                acc[rg][cf] = __builtin_amdgcn_mfma_f32_16x16x32_bf16(af[rg], bf, acc[rg][cf], 0, 0, 0);
        }
    }
    #pragma unroll
    for (int rg = 0; rg < 4; ++rg)
        #pragma unroll
        for (int cf = 0; cf < 4; ++cf)
            #pragma unroll
            for (int j = 0; j < 4; ++j) {
                int r = rg*16 + lg*4 + j, c = w*64 + cf*16 + lr;
                xW[(size_t)(m0 + r) * 256 + c] = acc[rg][cf][j] + vbs[c];
            }
}

// =====================================================================
// LSTM prep: transpose whh ([4H,64] -> [64,4H])
// =====================================================================
__global__ void lstm_prep_kernel(
    const float* __restrict__ whh, float* __restrict__ whhT)
{
    int id = blockIdx.x * 256 + threadIdx.x;
    if (id < 16384) {
        int i = id >> 8, j = id & 255;
        whhT[id] = whh[j*64 + i];
    }
}

// =====================================================================
// LSTM recurrence v3: 1 batch row per block (grid BB=512), 256 threads.
// =====================================================================
__global__ __launch_bounds__(256) void lstm_kernel(
    const float* __restrict__ xW, const float* __restrict__ whhT,
    float* __restrict__ out)
{
    __shared__ float sh[64];
    __shared__ float sg[256];
    const int t = threadIdx.x;
    const int b = blockIdx.x;

    float wreg[64];
    #pragma unroll
    for (int i = 0; i < 64; ++i) wreg[i] = whhT[i*256 + t];

    if (t < 64) sh[t] = 0.f;
    float c_reg = 0.f;

    float xnext = xW[((size_t)b * TSEQ + 0) * 256 + t];
    __syncthreads();

    for (int tt = 0; tt < TSEQ; ++tt) {
        float acc = xnext;
        if (tt + 1 < TSEQ)
            xnext = xW[((size_t)b * TSEQ + tt + 1) * 256 + t];
        #pragma unroll
        for (int i = 0; i < 64; ++i) acc += sh[i] * wreg[i];
        sg[t] = acc;
        __syncthreads();
        if (t < 64) {
            float gi = sg[t], gf = sg[64 + t], gg = sg[128 + t], go = sg[192 + t];
            c_reg = sigmoidf_(gf) * c_reg + sigmoidf_(gi) * tanhf(gg);
            float hn = sigmoidf_(go) * tanhf(c_reg);
            sh[t] = hn;
            out[((size_t)b * TSEQ + tt) * 64 + t] = hn;
        }
        __syncthreads();
    }
}

// =====================================================================
// fused GLU pair + residual + LN (post-LSTM)
// =====================================================================
__global__ __launch_bounds__(256) void fused_pl_kernel(
    const float* __restrict__ in, const float* __restrict__ res,
    const float* __restrict__ g1w, const float* __restrict__ g1b,
    const float* __restrict__ g2w, const float* __restrict__ g2b,
    const float* __restrict__ lng, const float* __restrict__ lnb,
    float* __restrict__ outf, __hip_bfloat16* __restrict__ outb)
{
    const int m0 = blockIdx.x * 64;
    const int t = threadIdx.x;
    const int w = t >> 6, l = t & 63, lr = l & 15, lg = l >> 4;
    __shared__ __align__(16) unsigned short hA[64 * 72];
    __shared__ __align__(16) unsigned char uS[18432];
    unsigned short* Wt0 = (unsigned short*)uS;
    unsigned short* Wt1 = (unsigned short*)(uS + 9216);
    float* yA = (float*)uS;
    __shared__ float vg1b[64], vg2b[64], vlng[64], vlnb[64];

    if (t < 64) { vg1b[t] = g1b[t]; vg2b[t] = g2b[t]; vlng[t] = lng[t]; vlnb[t] = lnb[t]; }
    #pragma unroll
    for (int p = 0; p < 16; ++p) {
        int e = t + 256 * p; int r = e >> 6, d = e & 63;
        hA[r*72 + d] = f2bf(in[(size_t)(m0 + r) * 64 + d]);
    }
    #pragma unroll
    for (int p = 0; p < 16; ++p) {
        int e = t + 256 * p; int k = e >> 6, c = e & 63;
        Wt0[c*72 + k] = f2bf(g1w[k*64 + c]);
        Wt1[c*72 + k] = f2bf(g2w[k*64 + c]);
    }
    __syncthreads();

    f32x4 aA[4], aB[4];
    #pragma unroll
    for (int rg = 0; rg < 4; ++rg) { aA[rg] = (f32x4){0.f,0.f,0.f,0.f}; aB[rg] = (f32x4){0.f,0.f,0.f,0.f}; }
    #pragma unroll
    for (int ks = 0; ks < 2; ++ks) {
        short8v b0f = *(const short8v*)&Wt0[(w*16 + lr)*72 + ks*32 + lg*8];
        short8v b1f = *(const short8v*)&Wt1[(w*16 + lr)*72 + ks*32 + lg*8];
        #pragma unroll
        for (int rg = 0; rg < 4; ++rg) {
            short8v af = *(const short8v*)&hA[(rg*16 + lr)*72 + ks*32 + lg*8];
            aA[rg] = __builtin_amdgcn_mfma_f32_16x16x32_bf16(af, b0f, aA[rg], 0, 0, 0);
            aB[rg] = __builtin_amdgcn_mfma_f32_16x16x32_bf16(af, b1f, aB[rg], 0, 0, 0);
        }
    }
    __syncthreads();

    #pragma unroll
    for (int rg = 0; rg < 4; ++rg)
        #pragma unroll
        for (int j = 0; j < 4; ++j) {
            int r = rg*16 + lg*4 + j, c = w*16 + lr;
            float sg = sigmoidf_(aA[rg][j] + vg1b[c]);
            yA[r*68 + c] = sg * (aB[rg][j] + vg2b[c]) + res[(size_t)(m0 + r) * 64 + c];
        }
    __syncthreads();

    const int tr = t >> 4, tc = t & 15;
    #pragma unroll
    for (int a = 0; a < 4; ++a) {
        const int r = tr + 16*a;
        float vals[4]; float part = 0.f;
        #pragma unroll
        for (int b = 0; b < 4; ++b) { vals[b] = yA[r*68 + tc + 16*b]; part += vals[b]; }
        #pragma unroll
        for (int off = 1; off < 16; off <<= 1) part += __shfl_xor(part, off);
        const float mean = part * (1.f / 64.f);
        float vp = 0.f;
        #pragma unroll
        for (int b = 0; b < 4; ++b) { float d = vals[b] - mean; vp += d * d; }
        #pragma unroll
        for (int off = 1; off < 16; off <<= 1) vp += __shfl_xor(vp, off);
        const float inv = rsqrtf(vp * (1.f / 64.f) + LN_EPS);
        #pragma unroll
        for (int b = 0; b < 4; ++b) {
            const int c = tc + 16*b;
            float v = (vals[b] - mean) * inv * vlng[c] + vlnb[c];
            outf[(size_t)(m0 + r) * 64 + c] = v;
            outb[(size_t)(m0 + r) * 64 + c] = __float2bfloat16(v);
        }
    }
}

// =====================================================================
// qkv = temporal_bf16 @ attn_in_w[64,192] + b
// =====================================================================
__global__ __launch_bounds__(256) void qkv_kernel(
    const __hip_bfloat16* __restrict__ tb,
    const float* __restrict__ wqkv, const float* __restrict__ bqkv,
    float* __restrict__ qkv)
{
    const int m0 = blockIdx.x * 64;
    const int t = threadIdx.x;
    const int w = t >> 6, l = t & 63, lr = l & 15, lg = l >> 4;
    __shared__ __align__(16) unsigned short hA[64 * 72];
    __shared__ __align__(16) unsigned short Wt[192 * 72];
    __shared__ float vb[192];

    if (t < 192) vb[t] = bqkv[t];
    #pragma unroll
    for (int p = 0; p < 16; ++p) {
        int e = t + 256 * p; int r = e >> 6, d = e & 63;
        hA[r*72 + d] = *(const unsigned short*)&tb[(size_t)(m0 + r) * 64 + d];
    }
    #pragma unroll
    for (int p = 0; p < 48; ++p) {
        int e = t + 256 * p; int c = e >> 6, k = e & 63;
        Wt[c*72 + k] = f2bf(wqkv[(size_t)k * 192 + c]);
    }
    __syncthreads();

    f32x4 acc[4][3];
    #pragma unroll
    for (int rg = 0; rg < 4; ++rg)
        #pragma unroll
        for (int cf = 0; cf < 3; ++cf) acc[rg][cf] = (f32x4){0.f,0.f,0.f,0.f};
    #pragma unroll
    for (int ks = 0; ks < 2; ++ks) {
        short8v af[4];
        #pragma unroll
        for (int rg = 0; rg < 4; ++rg)
            af[rg] = *(const short8v*)&hA[(rg*16 + lr)*72 + ks*32 + lg*8];
        #pragma unroll
        for (int cf = 0; cf < 3; ++cf) {
            short8v bf = *(const short8v*)&Wt[(w*48 + cf*16 + lr)*72 + ks*32 + lg*8];
            #pragma unroll
            for (int rg = 0; rg < 4; ++rg)
                acc[rg][cf] = __builtin_amdgcn_mfma_f32_16x16x32_bf16(af[rg], bf, acc[rg][cf], 0, 0, 0);
        }
    }
    #pragma unroll
    for (int rg = 0; rg < 4; ++rg)
        #pragma unroll
        for (int cf = 0; cf < 3; ++cf)
            #pragma unroll
            for (int j = 0; j < 4; ++j) {
                int r = rg*16 + lg*4 + j, c = w*48 + cf*16 + lr;
                qkv[(size_t)(m0 + r) * 192 + c] = acc[rg][cf][j] + vb[c];
            }
}

// =====================================================================
// MHA core -> ao bf16
// =====================================================================
__global__ __launch_bounds__(256) void attn_kernel(
    const float* __restrict__ qkv, __hip_bfloat16* __restrict__ ao)
{
    const int b = blockIdx.x;
    const int h = threadIdx.x >> 6, l = threadIdx.x & 63;
    __shared__ float sq[4][24][16], sk[4][24][16], sv[4][24][16], sp[4][24][24];
    #pragma unroll
    for (int p = 0; p < 6; ++p) {
        int e = l + 64 * p; int ti = e >> 4, d = e & 15;
        size_t base = ((size_t)(b * TSEQ + ti)) * 192 + h * 16 + d;
        sq[h][ti][d] = qkv[base];
        sk[h][ti][d] = qkv[base + 64];
        sv[h][ti][d] = qkv[base + 128];
    }
    __syncthreads();
    #pragma unroll
    for (int p = 0; p < 9; ++p) {
        int e = l + 64 * p; int i = e / 24, j = e - i * 24;
        float s = 0.f;
        #pragma unroll
        for (int d = 0; d < 16; ++d) s += sq[h][i][d] * sk[h][j][d];
        sp[h][i][j] = s * 0.25f;
    }
    __syncthreads();
    if (l < 24) {
        float mx = -1e30f;
        for (int j = 0; j < 24; ++j) mx = fmaxf(mx, sp[h][l][j]);
        float s = 0.f;
        for (int j = 0; j < 24; ++j) { float e = expf(sp[h][l][j] - mx); sp[h][l][j] = e; s += e; }
        float inv = 1.f / s;
        for (int j = 0; j < 24; ++j) sp[h][l][j] *= inv;
    }
    __syncthreads();
    #pragma unroll
    for (int p = 0; p < 6; ++p) {
        int e = l + 64 * p; int ti = e >> 4, d = e & 15;
        float s = 0.f;
        #pragma unroll
        for (int j = 0; j < 24; ++j) s += sp[h][ti][j] * sv[h][j][d];
        ao[((size_t)(b * TSEQ + ti)) * 64 + h * 16 + d] = __float2bfloat16(s);
    }
}

// =====================================================================
// fused post-attn: ao@Wout+b -> GLU(pa) -> +temporal -> LN -> enriched
// =====================================================================
__global__ __launch_bounds__(256) void fused_pa_kernel(
    const __hip_bfloat16* __restrict__ ao, const float* __restrict__ res,
    const float* __restrict__ wout, const float* __restrict__ bout,
    const float* __restrict__ g1w, const float* __restrict__ g1b,
    const float* __restrict__ g2w, const float* __restrict__ g2b,
    const float* __restrict__ lng, const float* __restrict__ lnb,
    float* __restrict__ outf, __hip_bfloat16* __restrict__ outb)
{
    const int m0 = blockIdx.x * 64;
    const int t = threadIdx.x;
    const int w = t >> 6, l = t & 63, lr = l & 15, lg = l >> 4;
    __shared__ __align__(16) unsigned short hA[64 * 72];
    __shared__ __align__(16) unsigned char uS[18432];
    unsigned short* Wt0 = (unsigned short*)uS;
    unsigned short* Wt1 = (unsigned short*)(uS + 9216);
    float* yA = (float*)uS;
    __shared__ float vob[64], vg1b[64], vg2b[64], vlng[64], vlnb[64];

    if (t < 64) { vob[t] = bout[t]; vg1b[t] = g1b[t]; vg2b[t] = g2b[t]; vlng[t] = lng[t]; vlnb[t] = lnb[t]; }
    #pragma unroll
    for (int p = 0; p < 16; ++p) {
        int e = t + 256 * p; int r = e >> 6, d = e & 63;
        hA[r*72 + d] = *(const unsigned short*)&ao[(size_t)(m0 + r) * 64 + d];
    }
    #pragma unroll
    for (int p = 0; p < 16; ++p) {
        int e = t + 256 * p; int k = e >> 6, c = e & 63;
        Wt0[c*72 + k] = f2bf(wout[k*64 + c]);
    }
    __syncthreads();

    f32x4 acc1[4];
    #pragma unroll
    for (int rg = 0; rg < 4; ++rg) acc1[rg] = (f32x4){0.f,0.f,0.f,0.f};
    #pragma unroll
    for (int ks = 0; ks < 2; ++ks) {
        short8v bf = *(const short8v*)&Wt0[(w*16 + lr)*72 + ks*32 + lg*8];
        #pragma unroll
        for (int rg = 0; rg < 4; ++rg) {
            short8v af = *(const short8v*)&hA[(rg*16 + lr)*72 + ks*32 + lg*8];
            acc1[rg] = __builtin_amdgcn_mfma_f32_16x16x32_bf16(af, bf, acc1[rg], 0, 0, 0);
        }
    }
    #pragma unroll
    for (int p = 0; p < 16; ++p) {
        int e = t + 256 * p; int k = e >> 6, c = e & 63;
        Wt1[c*72 + k] = f2bf(g1w[k*64 + c]);
    }
    __syncthreads();

    #pragma unroll
    for (int rg = 0; rg < 4; ++rg)
        #pragma unroll
        for (int j = 0; j < 4; ++j) {
            int r = rg*16 + lg*4 + j, c = w*16 + lr;
            hA[r*72 + c] = f2bf(acc1[rg][j] + vob[c]);
        }
    #pragma unroll
    for (int p = 0; p < 16; ++p) {
        int e = t + 256 * p; int k = e >> 6, c = e & 63;
        Wt0[c*72 + k] = f2bf(g2w[k*64 + c]);
    }
    __syncthreads();

    f32x4 aA[4], aB[4];
    #pragma unroll
    for (int rg = 0; rg < 4; ++rg) { aA[rg] = (f32x4){0.f,0.f,0.f,0.f}; aB[rg] = (f32x4){0.f,0.f,0.f,0.f}; }
    #pragma unroll
    for (int ks = 0; ks < 2; ++ks) {
        short8v b1f = *(const short8v*)&Wt1[(w*16 + lr)*72 + ks*32 + lg*8];
        short8v b2f = *(const short8v*)&Wt0[(w*16 + lr)*72 + ks*32 + lg*8];
        #pragma unroll
        for (int rg = 0; rg < 4; ++rg) {
            short8v af = *(const short8v*)&hA[(rg*16 + lr)*72 + ks*32 + lg*8];
            aA[rg] = __builtin_amdgcn_mfma_f32_16x16x32_bf16(af, b1f, aA[rg], 0, 0, 0);
            aB[rg] = __builtin_amdgcn_mfma_f32_16x16x32_bf16(af, b2f, aB[rg], 0, 0, 0);
        }
    }
    __syncthreads();

    #pragma unroll
    for (int rg = 0; rg < 4; ++rg)
        #pragma unroll
        for (int j = 0; j < 4; ++j) {
            int r = rg*16 + lg*4 + j, c = w*16 + lr;
            float sg = sigmoidf_(aA[rg][j] + vg1b[c]);
            yA[r*68 + c] = sg * (aB[rg][j] + vg2b[c]) + res[(size_t)(m0 + r) * 64 + c];
        }
    __syncthreads();

    const int tr = t >> 4, tc = t & 15;
    #pragma unroll
    for (int a = 0; a < 4; ++a) {
        const int r = tr + 16*a;
        float vals[4]; float part = 0.f;
        #pragma unroll
        for (int b = 0; b < 4; ++b) { vals[b] = yA[r*68 + tc + 16*b]; part += vals[b]; }
        #pragma unroll
        for (int off = 1; off < 16; off <<= 1) part += __shfl_xor(part, off);
        const float mean = part * (1.f / 64.f);
        float vp = 0.f;
        #pragma unroll
        for (int b = 0; b < 4; ++b) { float d = vals[b] - mean; vp += d * d; }
        #pragma unroll
        for (int off = 1; off < 16; off <<= 1) vp += __shfl_xor(vp, off);
        const float inv = rsqrtf(vp * (1.f / 64.f) + LN_EPS);
        #pragma unroll
        for (int b = 0; b < 4; ++b) {
            const int c = tc + 16*b;
            float v = (vals[b] - mean) * inv * vlng[c] + vlnb[c];
            outf[(size_t)(m0 + r) * 64 + c] = v;
            outb[(size_t)(m0 + r) * 64 + c] = __float2bfloat16(v);
        }
    }
}

// =====================================================================
// fused FF GRN
// =====================================================================
__global__ __launch_bounds__(256) void fused_ff_kernel(
    const __hip_bfloat16* __restrict__ eb, const float* __restrict__ res,
    const float* __restrict__ w1, const float* __restrict__ b1,
    const float* __restrict__ w2, const float* __restrict__ b2,
    const float* __restrict__ g1w, const float* __restrict__ g1b,
    const float* __restrict__ g2w, const float* __restrict__ g2b,
    const float* __restrict__ lng, const float* __restrict__ lnb,
    float* __restrict__ outf)
{
    const int m0 = blockIdx.x * 64;
    const int t = threadIdx.x;
    const int w = t >> 6, l = t & 63, lr = l & 15, lg = l >> 4;
    __shared__ __align__(16) unsigned short hA[64 * 72];
    __shared__ __align__(16) unsigned short hB[64 * 136];
    __shared__ __align__(16) unsigned char U1[18432];
    __shared__ __align__(16) unsigned char U2[17408];
    __shared__ float vb1[128], vb2[64], vg1b[64], vg2b[64], vlng[64], vlnb[64];

    unsigned short* W1t = (unsigned short*)U1;
    unsigned short* W2t = (unsigned short*)U2;
    unsigned short* G1t = (unsigned short*)U1;
    unsigned short* G2t = (unsigned short*)(U1 + 9216);
    float* yA = (float*)U2;

    if (t < 128) vb1[t] = b1[t];
    if (t < 64) { vb2[t] = b2[t]; vg1b[t] = g1b[t]; vg2b[t] = g2b[t]; vlng[t] = lng[t]; vlnb[t] = lnb[t]; }
    #pragma unroll
    for (int p = 0; p < 16; ++p) {
        int e = t + 256 * p; int r = e >> 6, d = e & 63;
        hA[r*72 + d] = *(const unsigned short*)&eb[(size_t)(m0 + r) * 64 + d];
    }
    #pragma unroll
    for (int p = 0; p < 32; ++p) {
        int e = t + 256 * p; int k = e >> 7, c = e & 127;
        W1t[c*72 + k] = f2bf(w1[(size_t)k * 128 + c]);
    }
    #pragma unroll
    for (int p = 0; p < 32; ++p) {
        int e = t + 256 * p; int k = e >> 6, c = e & 63;
        W2t[c*136 + k] = f2bf(w2[(size_t)k * 64 + c]);
    }
    __syncthreads();

    f32x4 acc1[4][2];
    #pragma unroll
    for (int rg = 0; rg < 4; ++rg)
        #pragma unroll
        for (int cf = 0; cf < 2; ++cf) acc1[rg][cf] = (f32x4){0.f,0.f,0.f,0.f};
    #pragma unroll
    for (int ks = 0; ks < 2; ++ks) {
        short8v af[4];
        #pragma unroll
        for (int rg = 0; rg < 4; ++rg)
            af[rg] = *(const short8v*)&hA[(rg*16 + lr)*72 + ks*32 + lg*8];
        #pragma unroll
        for (int cf = 0; cf < 2; ++cf) {
            short8v bf = *(const short8v*)&W1t[(w*32 + cf*16 + lr)*72 + ks*32 + lg*8];
            #pragma unroll
            for (int rg = 0; rg < 4; ++rg)
                acc1[rg][cf] = __builtin_amdgcn_mfma_f32_16x16x32_bf16(af[rg], bf, acc1[rg][cf], 0, 0, 0);
        }
    }
    #pragma unroll
    for (int rg = 0; rg < 4; ++rg)
        #pragma unroll
        for (int cf = 0; cf < 2; ++cf)
            #pragma unroll
            for (int j = 0; j < 4; ++j) {
                int r = rg*16 + lg*4 + j, c = w*32 + cf*16 + lr;
                hB[r*136 + c] = f2bf(eluf_(acc1[rg][cf][j] + vb1[c]));
            }
    __syncthreads();

    #pragma unroll
    for (int p = 0; p < 16; ++p) {
        int e = t + 256 * p; int k = e >> 6, c = e & 63;
        G1t[c*72 + k] = f2bf(g1w[k*64 + c]);
        G2t[c*72 + k] = f2bf(g2w[k*64 + c]);
    }
    __syncthreads();

    f32x4 acc2[4];
    #pragma unroll
    for (int rg = 0; rg < 4; ++rg) acc2[rg] = (f32x4){0.f,0.f,0.f,0.f};
    #pragma unroll
    for (int ks = 0; ks < 4; ++ks) {
        short8v bf = *(const short8v*)&W2t[(w*16 + lr)*136 + ks*32 + lg*8];
        #pragma unroll
        for (int rg = 0; rg < 4; ++rg) {
            short8v af = *(const short8v*)&hB[(rg*16 + lr)*136 + ks*32 + lg*8];
            acc2[rg] = __builtin_amdgcn_mfma_f32_16x16x32_bf16(af, bf, acc2[rg], 0, 0, 0);
        }
    }
    #pragma unroll
    for (int rg = 0; rg < 4; ++rg)
        #pragma unroll
        for (int j = 0; j < 4; ++j) {
            int r = rg*16 + lg*4 + j, c = w*16 + lr;
            hA[r*72 + c] = f2bf(acc2[rg][j] + vb2[c]);
        }
    __syncthreads();

    f32x4 aA[4], aB[4];
    #pragma unroll
    for (int rg = 0; rg < 4; ++rg) { aA[rg] = (f32x4){0.f,0.f,0.f,0.f}; aB[rg] = (f32x4){0.f,0.f,0.f,0.f}; }
    #pragma unroll
    for (int ks = 0; ks < 2; ++ks) {
        short8v b1f = *(const short8v*)&G1t[(w*16 + lr)*72 + ks*32 + lg*8];
        short8v b2f = *(const short8v*)&G2t[(w*16 + lr)*72 + ks*32 + lg*8];
        #pragma unroll
        for (int rg = 0; rg < 4; ++rg) {
            short8v af = *(const short8v*)&hA[(rg*16 + lr)*72 + ks*32 + lg*8];
            aA[rg] = __builtin_amdgcn_mfma_f32_16x16x32_bf16(af, b1f, aA[rg], 0, 0, 0);
            aB[rg] = __builtin_amdgcn_mfma_f32_16x16x32_bf16(af, b2f, aB[rg], 0, 0, 0);
        }
    }
    __syncthreads();

    #pragma unroll
    for (int rg = 0; rg < 4; ++rg)
        #pragma unroll
        for (int j = 0; j < 4; ++j) {
            int r = rg*16 + lg*4 + j, c = w*16 + lr;
            float sg = sigmoidf_(aA[rg][j] + vg1b[c]);
            yA[r*68 + c] = sg * (aB[rg][j] + vg2b[c]) + res[(size_t)(m0 + r) * 64 + c];
        }
    __syncthreads();

    const int tr = t >> 4, tc = t & 15;
    #pragma unroll
    for (int a = 0; a < 4; ++a) {
        const int r = tr + 16*a;
        float vals[4]; float part = 0.f;
        #pragma unroll
        for (int b = 0; b < 4; ++b) { vals[b] = yA[r*68 + tc + 16*b]; part += vals[b]; }
        #pragma unroll
        for (int off = 1; off < 16; off <<= 1) part += __shfl_xor(part, off);
        const float mean = part * (1.f / 64.f);
        float vp = 0.f;
        #pragma unroll
        for (int b = 0; b < 4; ++b) { float d = vals[b] - mean; vp += d * d; }
        #pragma unroll
        for (int off = 1; off < 16; off <<= 1) vp += __shfl_xor(vp, off);
        const float inv = rsqrtf(vp * (1.f / 64.f) + LN_EPS);
        #pragma unroll
        for (int b = 0; b < 4; ++b) {
            const int c = tc + 16*b;
            outf[(size_t)(m0 + r) * 64 + c] = (vals[b] - mean) * inv * vlng[c] + vlnb[c];
        }
    }
}

// =====================================================================
// head: mean over T -> fc1+relu -> fc2
// =====================================================================
__global__ __launch_bounds__(64) void head_kernel(
    const float* __restrict__ outln,
    const float* __restrict__ fc1_w, const float* __restrict__ fc1_b,
    const float* __restrict__ fc2_w, const float* __restrict__ fc2_b,
    float* __restrict__ out)
{
    const int b = blockIdx.x, l = threadIdx.x;
    __shared__ float sp[64];
    float s = 0.f;
    #pragma unroll
    for (int tt = 0; tt < TSEQ; ++tt) s += outln[((size_t)(b * TSEQ + tt)) * 64 + l];
    sp[l] = s * (1.f / 24.f);
    __syncthreads();
    float a = fc1_b[l];
    for (int k = 0; k < 64; ++k) a += sp[k] * fc1_w[k*64 + l];
    float f1 = fmaxf(a, 0.f);
    #pragma unroll
    for (int j = 0; j < 6; ++j) {
        float p = f1 * fc2_w[l*6 + j];
        #pragma unroll
        for (int off = 32; off; off >>= 1) p += __shfl_xor(p, off);
        if (l == 0) out[b*6 + j] = p + fc2_b[j];
    }
}

// =====================================================================
extern "C" void kernel_launch(void* const* d_in, const int* in_sizes, int n_in,
                              void* d_out, int out_size, void* d_ws, size_t ws_size,
                              hipStream_t stream)
{
    const float* x        = (const float*)d_in[0];
    const float* f_w1     = (const float*)d_in[1];
    const float* f_b1     = (const float*)d_in[2];
    const float* f_w2     = (const float*)d_in[3];
    const float* f_b2     = (const float*)d_in[4];
    const float* f_g1w    = (const float*)d_in[5];
    const float* f_g1b    = (const float*)d_in[6];
    const float* f_g2w    = (const float*)d_in[7];
    const float* f_g2b    = (const float*)d_in[8];
    const float* f_skw    = (const float*)d_in[9];
    const float* f_skb    = (const float*)d_in[10];
    const float* f_lng    = (const float*)d_in[11];
    const float* f_lnb    = (const float*)d_in[12];
    const float* w_w1     = (const float*)d_in[13];
    const float* w_b1     = (const float*)d_in[14];
    const float* w_w2     = (const float*)d_in[15];
    const float* w_b2     = (const float*)d_in[16];
    const float* w_g1w    = (const float*)d_in[17];
    const float* w_g1b    = (const float*)d_in[18];
    const float* w_g2w    = (const float*)d_in[19];
    const float* w_g2b    = (const float*)d_in[20];
    const float* w_skw    = (const float*)d_in[21];
    const float* w_skb    = (const float*)d_in[22];
    const float* w_lng    = (const float*)d_in[23];
    const float* w_lnb    = (const float*)d_in[24];
    const float* lstm_wih = (const float*)d_in[25];
    const float* lstm_whh = (const float*)d_in[26];
    const float* lstm_bih = (const float*)d_in[27];
    const float* lstm_bhh = (const float*)d_in[28];
    const float* pl_g1w   = (const float*)d_in[29];
    const float* pl_g1b   = (const float*)d_in[30];
    const float* pl_g2w   = (const float*)d_in[31];
    const float* pl_g2b   = (const float*)d_in[32];
    const float* pl_lng   = (const float*)d_in[33];
    const float* pl_lnb   = (const float*)d_in[34];
    const float* attn_in_w  = (const float*)d_in[35];
    const float* attn_in_b  = (const float*)d_in[36];
    const float* attn_out_w = (const float*)d_in[37];
    const float* attn_out_b = (const float*)d_in[38];
    const float* pa_g1w   = (const float*)d_in[39];
    const float* pa_g1b   = (const float*)d_in[40];
    const float* pa_g2w   = (const float*)d_in[41];
    const float* pa_g2b   = (const float*)d_in[42];
    const float* pa_lng   = (const float*)d_in[43];
    const float* pa_lnb   = (const float*)d_in[44];
    const float* ff_w1    = (const float*)d_in[45];
    const float* ff_b1    = (const float*)d_in[46];
    const float* ff_w2    = (const float*)d_in[47];
    const float* ff_b2    = (const float*)d_in[48];
    const float* ff_g1w   = (const float*)d_in[49];
    const float* ff_g1b   = (const float*)d_in[50];
    const float* ff_g2w   = (const float*)d_in[51];
    const float* ff_g2b   = (const float*)d_in[52];
    const float* ff_lng   = (const float*)d_in[53];
    const float* ff_lnb   = (const float*)d_in[54];
    const float* fc1_w    = (const float*)d_in[55];
    const float* fc1_b    = (const float*)d_in[56];
    const float* fc2_w    = (const float*)d_in[57];
    const float* fc2_b    = (const float*)d_in[58];

    float* ws = (float*)d_ws;

    // ---------------- phase-2 union (fixed offsets) ----------------------
    size_t o = 0;
    const size_t o_S0   = o; o += (size_t)MTOT * 256;   // xW / qkv
    const size_t o_A    = o; o += (size_t)MTOT * 64;    // lstm_out
    const size_t o_Bf   = o; o += (size_t)MTOT * 64;    // enriched f32
    const size_t o_Cf   = o; o += (size_t)MTOT * 64;    // outln f32
    const size_t o_Df   = o; o += (size_t)MTOT * 64;    // temporal f32
    const size_t o_F    = o; o += (size_t)MTOT * 128;   // bf16 trio: tb/ab/eb
    const size_t o_whhT = o; o += 16384;
    const size_t unionP2 = o;                            // 7,880,704 floats

    const size_t o_tb = o_F;
    const size_t o_ab = o_F + (size_t)MTOT * 32;
    const size_t o_eb = o_F + (size_t)MTOT * 64;

    // ---------------- adaptive M-chunk selection --------------------------
    // persist: sel f32 (64) + selb bf16 (32) + xT f32 (81) = MTOT*177 floats
    const size_t persist = (size_t)MTOT * 177;
    int mc = 0;
    {
        const int cands[4] = {12288, 6144, 3072, 1536};
        for (int ci = 0; ci < 4; ++ci) {
            const size_t c = (size_t)cands[ci];
            size_t overlay = c * FDIM / 2 + (size_t)KS * c * NW + c * 81
                           + (size_t)NW * FDIM / 2;
            size_t A = overlay > unionP2 ? overlay : unionP2;
            if ((A + persist) * sizeof(float) <= ws_size) { mc = cands[ci]; break; }
        }
        if (mc == 0) return;                             // workspace too small
    }
    const size_t ovl_partial = (size_t)mc * FDIM / 2;
    const size_t ovl_w81     = ovl_partial + (size_t)KS * mc * NW;
    const size_t ovl_wcat    = ovl_w81 + (size_t)mc * 81;
    const size_t ovl_end     = ovl_wcat + (size_t)NW * FDIM / 2;
    const size_t regA        = ovl_end > unionP2 ? ovl_end : unionP2;
    const size_t o_sel  = regA;
    const size_t o_selb = o_sel + (size_t)MTOT * 64;
    const size_t o_xt   = o_selb + (size_t)MTOT * 32;

    const dim3 blk(256);

    // 0) transpose x ; pack weight-head matrices to bf16
    xt_kernel<<<dim3((NF * MTOT + 255) / 256), blk, 0, stream>>>(x, ws + o_xt);
    wprep_kernel<<<dim3((FDIM + 255) / 256, NW), blk, 0, stream>>>(
        w_w1, w_skw, (unsigned short*)(ws + ovl_wcat));

    // ---------------- phase 1: VSN + weight-GRN, chunked over M ----------
    for (int mb = 0; mb < MTOT; mb += mc) {
        __hip_bfloat16* chunk = (__hip_bfloat16*)ws;
        vsn_kernel<<<dim3(NF, (mc / 64) / NT), blk, 0, stream>>>(
            ws + o_xt + mb, f_w1, f_b1, f_w2, f_b2, f_g1w, f_g1b,
            f_g2w, f_g2b, f_skw, f_skb, f_lng, f_lnb, chunk);
        wgemm_kernel<<<dim3(mc / 32, KS), dim3(64), 0, stream>>>(
            chunk, (const unsigned short*)(ws + ovl_wcat), ws + ovl_partial, mc);
        wtail_kernel<<<dim3(mc / 16), blk, 0, stream>>>(
            ws + ovl_partial, w_b1, w_skb, w_w2, w_b2, w_g1w, w_g1b,
            w_g2w, w_g2b, w_lng, w_lnb, ws + ovl_w81, mc);
        selected_kernel<<<dim3(mc), blk, 0, stream>>>(
            chunk, ws + ovl_w81, ws + o_sel + (size_t)mb * 64,
            (__hip_bfloat16*)(ws + o_selb) + (size_t)mb * 64);
    }

    // ---------------- phase 2: LSTM -> attention -> head -----------------
    lstm_prep_kernel<<<dim3(64), blk, 0, stream>>>(lstm_whh, ws + o_whhT);
    xw_kernel<<<dim3(MTOT / 64), blk, 0, stream>>>(
        (const __hip_bfloat16*)(ws + o_selb), lstm_wih, lstm_bih, lstm_bhh, ws + o_S0);
    lstm_kernel<<<dim3(BB), blk, 0, stream>>>(ws + o_S0, ws + o_whhT, ws + o_A);
    fused_pl_kernel<<<dim3(MTOT / 64), blk, 0, stream>>>(
        ws + o_A, ws + o_sel, pl_g1w, pl_g1b, pl_g2w, pl_g2b, pl_lng, pl_lnb,
        ws + o_Df, (__hip_bfloat16*)(ws + o_tb));
    qkv_kernel<<<dim3(MTOT / 64), blk, 0, stream>>>(
        (const __hip_bfloat16*)(ws + o_tb), attn_in_w, attn_in_b, ws + o_S0);
    attn_kernel<<<dim3(BB), blk, 0, stream>>>(
        ws + o_S0, (__hip_bfloat16*)(ws + o_ab));
    fused_pa_kernel<<<dim3(MTOT / 64), blk, 0, stream>>>(
        (const __hip_bfloat16*)(ws + o_ab), ws + o_Df,
        attn_out_w, attn_out_b, pa_g1w, pa_g1b, pa_g2w, pa_g2b, pa_lng, pa_lnb,
        ws + o_Bf, (__hip_bfloat16*)(ws + o_eb));
    fused_ff_kernel<<<dim3(MTOT / 64), blk, 0, stream>>>(
        (const __hip_bfloat16*)(ws + o_eb), ws + o_Bf,
        ff_w1, ff_b1, ff_w2, ff_b2, ff_g1w, ff_g1b, ff_g2w, ff_g2b,
        ff_lng, ff_lnb, ws + o_Cf);
    head_kernel<<<dim3(BB), dim3(64), 0, stream>>>(
        ws + o_Cf, fc1_w, fc1_b, fc2_w, fc2_b, (float*)d_out);
}

// Round 9
// 489.952 us; speedup vs baseline: 23.2030x; 1.1772x over previous
//
#include <hip/hip_runtime.h>
#include <hip/hip_bf16.h>
#include <math.h>

// ---------------- problem constants ----------------
constexpr int BB   = 512;
constexpr int TSEQ = 24;
constexpr int NF   = 81;
constexpr int DD   = 64;
constexpr int MTOT = BB * TSEQ;      // 12288
constexpr int FDIM = NF * DD;        // 5184
constexpr int KS   = 9;              // split-K groups for weight-head GEMM
constexpr int NW   = 160;            // padded combined N: 64 (wh1) + 81 (sk) + 15 pad
constexpr int NT   = 6;              // m-tiles per VSN block
constexpr float LN_EPS = 1e-5f;

typedef __attribute__((ext_vector_type(8))) short short8v;   // 8 bf16 (4 VGPRs)
typedef __attribute__((ext_vector_type(4))) float f32x4;     // MFMA C/D

// ---- fast transcendentals (native v_exp_f32 / v_rcp_f32; ~1-2 ulp) ----
static __device__ __forceinline__ float sigmoidf_(float x) {
    return __builtin_amdgcn_rcpf(1.f + __expf(-x));
}
static __device__ __forceinline__ float eluf_(float x) {
    return x > 0.f ? x : (__expf(x) - 1.f);
}
static __device__ __forceinline__ float ftanh_(float x) {
    // tanh(x) = 1 - 2/(exp(2x)+1); saturates correctly at +-inf
    float e = __expf(2.f * x);
    return 1.f - 2.f * __builtin_amdgcn_rcpf(e + 1.f);
}
static __device__ __forceinline__ unsigned short f2bf(float x) {
    __hip_bfloat16 h = __float2bfloat16(x);
    return *reinterpret_cast<unsigned short*>(&h);
}

// =====================================================================
// x transpose: xT[f][m] = x[m][f]
// =====================================================================
__global__ void xt_kernel(const float* __restrict__ x, float* __restrict__ xT)
{
    int id = blockIdx.x * 256 + threadIdx.x;
    if (id >= NF * MTOT) return;
    int f = id / MTOT, m = id - f * MTOT;
    xT[id] = x[(size_t)m * NF + f];
}

// =====================================================================
// Kernel 1: VSN v5 — persistent weight LDS, fast transcendentals,
// grid (m-tiles, NF) so same-feature blocks are ID-adjacent (L2 reuse).
// =====================================================================
__global__ __launch_bounds__(256) void vsn_kernel(
    const float* __restrict__ xT,   // xT + mb ; feature stride MTOT
    const float* __restrict__ f_w1,  const float* __restrict__ f_b1,
    const float* __restrict__ f_w2,  const float* __restrict__ f_b2,
    const float* __restrict__ f_g1w, const float* __restrict__ f_g1b,
    const float* __restrict__ f_g2w, const float* __restrict__ f_g2b,
    const float* __restrict__ f_skw, const float* __restrict__ f_skb,
    const float* __restrict__ f_lng, const float* __restrict__ f_lnb,
    __hip_bfloat16* __restrict__ stacked)
{
    const int f  = blockIdx.y;
    const int t  = threadIdx.x;
    const int w  = t >> 6;
    const int l  = t & 63;
    const int lr = l & 15;
    const int lg = l >> 4;

    __shared__ __align__(16) unsigned short W2t[64 * 72];
    __shared__ __align__(16) unsigned short G1t[64 * 72];
    __shared__ __align__(16) unsigned short G2t[64 * 72];
    __shared__ __align__(16) unsigned char  U[17408];      // hA (9216) ∪ yA (17408)
    unsigned short* hA = (unsigned short*)U;               // [64][72] bf16
    float*          yA = (float*)U;                        // [64][68] f32
    __shared__ float vw1[64], vb1[64], vb2[64], vg1b[64], vg2b[64];
    __shared__ float vskw[64], vskb[64], vlng[64], vlnb[64], xv[64];

    if (t < 64) {
        vw1[t]  = f_w1 [f*64 + t];  vb1[t]  = f_b1 [f*64 + t];
        vb2[t]  = f_b2 [f*64 + t];
        vg1b[t] = f_g1b[f*64 + t];  vg2b[t] = f_g2b[f*64 + t];
        vskw[t] = f_skw[f*64 + t];  vskb[t] = f_skb[f*64 + t];
        vlng[t] = f_lng[f*64 + t];  vlnb[t] = f_lnb[f*64 + t];
        xv[t]   = xT[(size_t)f * MTOT + blockIdx.x * (NT * 64) + t];
    }
    {
        const float* w2p = f_w2  + (size_t)f * 4096;
        const float* g1p = f_g1w + (size_t)f * 4096;
        const float* g2p = f_g2w + (size_t)f * 4096;
        #pragma unroll
        for (int p = 0; p < 16; ++p) {
            int e = t + 256 * p; int k = e >> 6, c = e & 63;
            W2t[c*72 + k] = f2bf(w2p[k*64 + c]);
            G1t[c*72 + k] = f2bf(g1p[k*64 + c]);
            G2t[c*72 + k] = f2bf(g2p[k*64 + c]);
        }
    }
    __syncthreads();   // bar0: weights + params + xv(tile0)

    for (int it = 0; it < NT; ++it) {
        const int m0 = (blockIdx.x * NT + it) * 64;

        // A: h0 = elu(x*w1 + b1) -> hA
        #pragma unroll
        for (int p = 0; p < 16; ++p) {
            int e = t + 256 * p; int r = e >> 6, d = e & 63;
            hA[r*72 + d] = f2bf(eluf_(xv[r] * vw1[d] + vb1[d]));
        }
        __syncthreads();   // bar1

        // B: mm1 h1 = h0 @ w2
        f32x4 acc1[4];
        #pragma unroll
        for (int rg = 0; rg < 4; ++rg) acc1[rg] = (f32x4){0.f, 0.f, 0.f, 0.f};
        #pragma unroll
        for (int ks = 0; ks < 2; ++ks) {
            short8v bf = *(const short8v*)&W2t[(w*16 + lr)*72 + ks*32 + lg*8];
            #pragma unroll
            for (int rg = 0; rg < 4; ++rg) {
                short8v af = *(const short8v*)&hA[(rg*16 + lr)*72 + ks*32 + lg*8];
                acc1[rg] = __builtin_amdgcn_mfma_f32_16x16x32_bf16(af, bf, acc1[rg], 0, 0, 0);
            }
        }
        __syncthreads();   // bar2: mm1 reads of hA done

        // C: write h1 (+b2) -> hA
        #pragma unroll
        for (int rg = 0; rg < 4; ++rg)
            #pragma unroll
            for (int j = 0; j < 4; ++j) {
                int r = rg*16 + lg*4 + j, c = w*16 + lr;
                hA[r*72 + c] = f2bf(acc1[rg][j] + vb2[c]);
            }
        __syncthreads();   // bar3: hA(h1) ready

        // D: mm2/mm3 + GLU+skip into registers
        f32x4 aA[4], aB[4];
        #pragma unroll
        for (int rg = 0; rg < 4; ++rg) { aA[rg] = (f32x4){0.f,0.f,0.f,0.f}; aB[rg] = (f32x4){0.f,0.f,0.f,0.f}; }
        #pragma unroll
        for (int ks = 0; ks < 2; ++ks) {
            short8v b1f = *(const short8v*)&G1t[(w*16 + lr)*72 + ks*32 + lg*8];
            short8v b2f = *(const short8v*)&G2t[(w*16 + lr)*72 + ks*32 + lg*8];
            #pragma unroll
            for (int rg = 0; rg < 4; ++rg) {
                short8v af = *(const short8v*)&hA[(rg*16 + lr)*72 + ks*32 + lg*8];
                aA[rg] = __builtin_amdgcn_mfma_f32_16x16x32_bf16(af, b1f, aA[rg], 0, 0, 0);
                aB[rg] = __builtin_amdgcn_mfma_f32_16x16x32_bf16(af, b2f, aB[rg], 0, 0, 0);
            }
        }
        float yv[4][4];
        #pragma unroll
        for (int rg = 0; rg < 4; ++rg)
            #pragma unroll
            for (int j = 0; j < 4; ++j) {
                int r = rg*16 + lg*4 + j, c = w*16 + lr;
                float sg = sigmoidf_(aA[rg][j] + vg1b[c]);
                yv[rg][j] = sg * (aB[rg][j] + vg2b[c]) + xv[r] * vskw[c] + vskb[c];
            }
        __syncthreads();   // bar4: all hA + xv reads done

        // E: write yA (overlays hA) ; stage next tile's xv
        #pragma unroll
        for (int rg = 0; rg < 4; ++rg)
            #pragma unroll
            for (int j = 0; j < 4; ++j) {
                int r = rg*16 + lg*4 + j, c = w*16 + lr;
                yA[r*68 + c] = yv[rg][j];
            }
        if (t < 64 && it + 1 < NT)
            xv[t] = xT[(size_t)f * MTOT + m0 + 64 + t];
        __syncthreads();   // bar5: yA ready

        // F: LayerNorm(64) + vectorized bf16 store (lane owns 4 consecutive c)
        const int tr = t >> 4, tc = t & 15;
        #pragma unroll
        for (int a = 0; a < 4; ++a) {
            const int r = tr + 16*a;
            float4 v4 = *(const float4*)&yA[r*68 + tc*4];
            float part = v4.x + v4.y + v4.z + v4.w;
            #pragma unroll
            for (int off = 1; off < 16; off <<= 1) part += __shfl_xor(part, off);
            const float mean = part * (1.f / 64.f);
            float d0 = v4.x - mean, d1 = v4.y - mean, d2 = v4.z - mean, d3 = v4.w - mean;
            float vp = d0*d0 + d1*d1 + d2*d2 + d3*d3;
            #pragma unroll
            for (int off = 1; off < 16; off <<= 1) vp += __shfl_xor(vp, off);
            const float inv = rsqrtf(vp * (1.f / 64.f) + LN_EPS);
            const int c0 = tc * 4;
            ushort4 o;
            o.x = f2bf(d0 * inv * vlng[c0+0] + vlnb[c0+0]);
            o.y = f2bf(d1 * inv * vlng[c0+1] + vlnb[c0+1]);
            o.z = f2bf(d2 * inv * vlng[c0+2] + vlnb[c0+2]);
            o.w = f2bf(d3 * inv * vlng[c0+3] + vlnb[c0+3]);
            *(ushort4*)&stacked[(size_t)(m0 + r) * FDIM + f*64 + c0] = o;
        }
        __syncthreads();   // bar6: yA reads done before next tile's hA writes
    }
}

// =====================================================================
// Pack w_w1 / w_skw into bf16 WcatT[160][FDIM]
// =====================================================================
__global__ void wprep_kernel(
    const float* __restrict__ w_w1, const float* __restrict__ w_skw,
    unsigned short* __restrict__ WcatT)
{
    const int c = blockIdx.y;
    const int k = blockIdx.x * 256 + threadIdx.x;
    if (k >= FDIM) return;
    float v = 0.f;
    if (c < 64)       v = w_w1[(size_t)k * 64 + c];
    else if (c < 145) v = w_skw[(size_t)k * 81 + (c - 64)];
    WcatT[(size_t)c * FDIM + k] = f2bf(v);
}

// =====================================================================
// Split-K fused weight-head GEMM (MFMA, LDS-free), MR=2 (32 rows/block)
// =====================================================================
__global__ __launch_bounds__(64) void wgemm_kernel(
    const __hip_bfloat16* __restrict__ stacked,
    const unsigned short* __restrict__ WcatT,
    float* __restrict__ partial, int mc)
{
    const int m0 = blockIdx.x * 32;
    const int ks = blockIdx.y;
    const int l  = threadIdx.x;
    const int lr = l & 15, lg = l >> 4;

    f32x4 acc[2][10];
    #pragma unroll
    for (int h = 0; h < 2; ++h)
        #pragma unroll
        for (int n = 0; n < 10; ++n) acc[h][n] = (f32x4){0.f, 0.f, 0.f, 0.f};

    const size_t a0r = (size_t)(m0 + lr) * FDIM;
    const size_t a1r = (size_t)(m0 + 16 + lr) * FDIM;
    const int k0base = ks * 576;
    for (int kk = 0; kk < 576; kk += 32) {
        const int k = k0base + kk + lg * 8;
        short8v a0 = *(const short8v*)(stacked + a0r + k);
        short8v a1 = *(const short8v*)(stacked + a1r + k);
        #pragma unroll
        for (int n = 0; n < 10; ++n) {
            short8v bf = *(const short8v*)(WcatT + (size_t)(n*16 + lr) * FDIM + k);
            acc[0][n] = __builtin_amdgcn_mfma_f32_16x16x32_bf16(a0, bf, acc[0][n], 0, 0, 0);
            acc[1][n] = __builtin_amdgcn_mfma_f32_16x16x32_bf16(a1, bf, acc[1][n], 0, 0, 0);
        }
    }
    #pragma unroll
    for (int h = 0; h < 2; ++h)
        #pragma unroll
        for (int n = 0; n < 10; ++n)
            #pragma unroll
            for (int j = 0; j < 4; ++j) {
                const int m = m0 + h*16 + lg*4 + j;
                partial[((size_t)ks * mc + m) * NW + n*16 + lr] = acc[h][n][j];
            }
}

// =====================================================================
// Weight-GRN tail: LDS-staged weights, 16 rows/block, mc-parameterized
// =====================================================================
__global__ __launch_bounds__(256) void wtail_kernel(
    const float* __restrict__ partial,
    const float* __restrict__ w_b1,  const float* __restrict__ w_skb,
    const float* __restrict__ w_w2,  const float* __restrict__ w_b2,
    const float* __restrict__ w_g1w, const float* __restrict__ w_g1b,
    const float* __restrict__ w_g2w, const float* __restrict__ w_g2b,
    const float* __restrict__ w_lng, const float* __restrict__ w_lnb,
    float* __restrict__ w81, int mc)
{
    __shared__ float w2s[5184];
    __shared__ float g1s[6561];
    __shared__ float g2s[6561];
    __shared__ float sWh[16][64];
    __shared__ float sW2[16][96];

    const int t  = threadIdx.x;
    const int wv = t >> 6, l = t & 63;
    const int m0 = blockIdx.x * 16;
    const bool v1 = (l < 17);

    for (int e = t; e < 5184; e += 256) w2s[e] = w_w2[e];
    for (int e = t; e < 6561; e += 256) { g1s[e] = w_g1w[e]; g2s[e] = w_g2w[e]; }

    float s0[4], sk0[4], sk1[4];
    {
        const float b1v = w_b1[l], skb0 = w_skb[l], skb1 = v1 ? w_skb[64 + l] : 0.f;
        #pragma unroll
        for (int rr = 0; rr < 4; ++rr) { s0[rr] = b1v; sk0[rr] = skb0; sk1[rr] = skb1; }
    }
    #pragma unroll
    for (int ks = 0; ks < KS; ++ks) {
        #pragma unroll
        for (int rr = 0; rr < 4; ++rr) {
            const float* pr = partial + ((size_t)ks * mc + (m0 + wv*4 + rr)) * NW;
            s0[rr]  += pr[l];
            sk0[rr] += pr[64 + l];
            if (v1) sk1[rr] += pr[128 + l];
        }
    }
    #pragma unroll
    for (int rr = 0; rr < 4; ++rr) sWh[wv*4 + rr][l] = eluf_(s0[rr]);
    __syncthreads();

    float a0[4], a1[4];
    {
        const float b0 = w_b2[l], b1v = v1 ? w_b2[64 + l] : 0.f;
        #pragma unroll
        for (int rr = 0; rr < 4; ++rr) { a0[rr] = b0; a1[rr] = b1v; }
    }
    #pragma unroll 4
    for (int i = 0; i < 64; ++i) {
        const float wl = w2s[i*81 + l];
        const float wh = v1 ? w2s[i*81 + 64 + l] : 0.f;
        #pragma unroll
        for (int rr = 0; rr < 4; ++rr) {
            const float h = sWh[wv*4 + rr][i];
            a0[rr] += h * wl;
            a1[rr] += h * wh;
        }
    }
    #pragma unroll
    for (int rr = 0; rr < 4; ++rr) {
        sW2[wv*4 + rr][l] = a0[rr];
        if (v1) sW2[wv*4 + rr][64 + l] = a1[rr];
    }
    __syncthreads();

    float g10[4], g20[4], g11[4], g21[4];
    {
        const float c10 = w_g1b[l], c20 = w_g2b[l];
        const float c11 = v1 ? w_g1b[64 + l] : 0.f, c21 = v1 ? w_g2b[64 + l] : 0.f;
        #pragma unroll
        for (int rr = 0; rr < 4; ++rr) { g10[rr] = c10; g20[rr] = c20; g11[rr] = c11; g21[rr] = c21; }
    }
    #pragma unroll 3
    for (int i = 0; i < 81; ++i) {
        const float w1l = g1s[i*81 + l],            w2l = g2s[i*81 + l];
        const float w1h = v1 ? g1s[i*81 + 64 + l] : 0.f;
        const float w2h = v1 ? g2s[i*81 + 64 + l] : 0.f;
        #pragma unroll
        for (int rr = 0; rr < 4; ++rr) {
            const float h = sW2[wv*4 + rr][i];
            g10[rr] += h * w1l; g20[rr] += h * w2l;
            g11[rr] += h * w1h; g21[rr] += h * w2h;
        }
    }

    #pragma unroll
    for (int rr = 0; rr < 4; ++rr) {
        const int m = m0 + wv*4 + rr;
        float y0 = sigmoidf_(g10[rr]) * g20[rr] + sk0[rr];
        float y1 = v1 ? (sigmoidf_(g11[rr]) * g21[rr] + sk1[rr]) : 0.f;

        float s = y0 + (v1 ? y1 : 0.f);
        #pragma unroll
        for (int off = 32; off; off >>= 1) s += __shfl_xor(s, off);
        const float mean = s / 81.f;
        float d0 = y0 - mean, d1 = v1 ? (y1 - mean) : 0.f;
        float vs = d0*d0 + (v1 ? d1*d1 : 0.f);
        #pragma unroll
        for (int off = 32; off; off >>= 1) vs += __shfl_xor(vs, off);
        const float inv = rsqrtf(vs / 81.f + LN_EPS);
        float wn0 = d0 * inv * w_lng[l] + w_lnb[l];
        float wn1 = v1 ? (d1 * inv * w_lng[64 + l] + w_lnb[64 + l]) : -1e30f;

        float mx = fmaxf(wn0, wn1);
        #pragma unroll
        for (int off = 32; off; off >>= 1) mx = fmaxf(mx, __shfl_xor(mx, off));
        float e0 = __expf(wn0 - mx), e1 = v1 ? __expf(wn1 - mx) : 0.f;
        float es = e0 + e1;
        #pragma unroll
        for (int off = 32; off; off >>= 1) es += __shfl_xor(es, off);
        const float r = __builtin_amdgcn_rcpf(es);
        w81[(size_t)m * 81 + l] = e0 * r;
        if (v1) w81[(size_t)m * 81 + 64 + l] = e1 * r;
    }
}

// =====================================================================
// selected: f32 + bf16 outputs
// =====================================================================
__global__ __launch_bounds__(256) void selected_kernel(
    const __hip_bfloat16* __restrict__ stacked, const float* __restrict__ w81,
    float* __restrict__ sel, __hip_bfloat16* __restrict__ selb)
{
    const int m = blockIdx.x;
    const int d = threadIdx.x & 63, fg = threadIdx.x >> 6;
    __shared__ float red[4][64];
    __shared__ float wsh[81];
    if (threadIdx.x < 81) wsh[threadIdx.x] = w81[(size_t)m * 81 + threadIdx.x];
    __syncthreads();
    float acc = 0.f;
    for (int f = fg; f < 81; f += 4)
        acc += __bfloat162float(stacked[(size_t)m * FDIM + f*64 + d]) * wsh[f];
    red[fg][d] = acc;
    __syncthreads();
    if (fg == 0) {
        float v = red[0][d] + red[1][d] + red[2][d] + red[3][d];
        sel[(size_t)m * 64 + d]  = v;
        selb[(size_t)m * 64 + d] = __float2bfloat16(v);
    }
}

// =====================================================================
// xW = selb @ wih^T + (bih+bhh)    MFMA, grid MTOT/64 blocks, 256 thr
// =====================================================================
__global__ __launch_bounds__(256) void xw_kernel(
    const __hip_bfloat16* __restrict__ selb,
    const float* __restrict__ wih,
    const float* __restrict__ bih, const float* __restrict__ bhh,
    float* __restrict__ xW)
{
    const int m0 = blockIdx.x * 64;
    const int t = threadIdx.x;
    const int w = t >> 6, l = t & 63, lr = l & 15, lg = l >> 4;
    __shared__ __align__(16) unsigned short hA[64 * 72];
    __shared__ __align__(16) unsigned short Wt[256 * 72];
    __shared__ float vbs[256];

    vbs[t] = bih[t] + bhh[t];
    #pragma unroll
    for (int p = 0; p < 16; ++p) {
        int e = t + 256 * p; int r = e >> 6, d = e & 63;
        hA[r*72 + d] = *(const unsigned short*)&selb[(size_t)(m0 + r) * 64 + d];
    }
    #pragma unroll
    for (int p = 0; p < 64; ++p) {
        int e = t + 256 * p; int c = e >> 6, k = e & 63;
        Wt[c*72 + k] = f2bf(wih[c*64 + k]);
    }
    __syncthreads();

    f32x4 acc[4][4];
    #pragma unroll
    for (int rg = 0; rg < 4; ++rg)
        #pragma unroll
        for (int cf = 0; cf < 4; ++cf) acc[rg][cf] = (f32x4){0.f,0.f,0.f,0.f};
    #pragma unroll
    for (int ks = 0; ks < 2; ++ks) {
        short8v af[4];
        #pragma unroll
        for (int rg = 0; rg < 4; ++rg)
            af[rg] = *(const short8v*)&hA[(rg*16 + lr)*72 + ks*32 + lg*8];
        #pragma unroll
        for (int cf = 0; cf < 4; ++cf) {
            short8v bf = *(const short8v*)&Wt[(w*64 + cf*16 + lr)*72 + ks*32 + lg*8];
            #pragma unroll
            for (int rg = 0; rg < 4; ++rg)
                acc[rg][cf] = __builtin_amdgcn_mfma_f32_16x16x32_bf16(af[rg], bf, acc[rg][cf], 0, 0, 0);
        }
    }
    #pragma unroll
    for (int rg = 0; rg < 4; ++rg)
        #pragma unroll
        for (int cf = 0; cf < 4; ++cf)
            #pragma unroll
            for (int j = 0; j < 4; ++j) {
                int r = rg*16 + lg*4 + j, c = w*64 + cf*16 + lr;
                xW[(size_t)(m0 + r) * 256 + c] = acc[rg][cf][j] + vbs[c];
            }
}

// =====================================================================
// LSTM prep: transpose whh ([4H,64] -> [64,4H])
// =====================================================================
__global__ void lstm_prep_kernel(
    const float* __restrict__ whh, float* __restrict__ whhT)
{
    int id = blockIdx.x * 256 + threadIdx.x;
    if (id < 16384) {
        int i = id >> 8, j = id & 255;
        whhT[id] = whh[j*64 + i];
    }
}

// =====================================================================
// LSTM recurrence v3: 1 batch row per block (grid BB=512), 256 threads.
// =====================================================================
__global__ __launch_bounds__(256) void lstm_kernel(
    const float* __restrict__ xW, const float* __restrict__ whhT,
    float* __restrict__ out)
{
    __shared__ float sh[64];
    __shared__ float sg[256];
    const int t = threadIdx.x;
    const int b = blockIdx.x;

    float wreg[64];
    #pragma unroll
    for (int i = 0; i < 64; ++i) wreg[i] = whhT[i*256 + t];

    if (t < 64) sh[t] = 0.f;
    float c_reg = 0.f;

    float xnext = xW[((size_t)b * TSEQ + 0) * 256 + t];
    __syncthreads();

    for (int tt = 0; tt < TSEQ; ++tt) {
        float acc = xnext;
        if (tt + 1 < TSEQ)
            xnext = xW[((size_t)b * TSEQ + tt + 1) * 256 + t];
        #pragma unroll
        for (int i = 0; i < 64; ++i) acc += sh[i] * wreg[i];
        sg[t] = acc;
        __syncthreads();
        if (t < 64) {
            float gi = sg[t], gf = sg[64 + t], gg = sg[128 + t], go = sg[192 + t];
            c_reg = sigmoidf_(gf) * c_reg + sigmoidf_(gi) * ftanh_(gg);
            float hn = sigmoidf_(go) * ftanh_(c_reg);
            sh[t] = hn;
            out[((size_t)b * TSEQ + tt) * 64 + t] = hn;
        }
        __syncthreads();
    }
}

// =====================================================================
// fused GLU pair + residual + LN (post-LSTM)
// =====================================================================
__global__ __launch_bounds__(256) void fused_pl_kernel(
    const float* __restrict__ in, const float* __restrict__ res,
    const float* __restrict__ g1w, const float* __restrict__ g1b,
    const float* __restrict__ g2w, const float* __restrict__ g2b,
    const float* __restrict__ lng, const float* __restrict__ lnb,
    float* __restrict__ outf, __hip_bfloat16* __restrict__ outb)
{
    const int m0 = blockIdx.x * 64;
    const int t = threadIdx.x;
    const int w = t >> 6, l = t & 63, lr = l & 15, lg = l >> 4;
    __shared__ __align__(16) unsigned short hA[64 * 72];
    __shared__ __align__(16) unsigned char uS[18432];
    unsigned short* Wt0 = (unsigned short*)uS;
    unsigned short* Wt1 = (unsigned short*)(uS + 9216);
    float* yA = (float*)uS;
    __shared__ float vg1b[64], vg2b[64], vlng[64], vlnb[64];

    if (t < 64) { vg1b[t] = g1b[t]; vg2b[t] = g2b[t]; vlng[t] = lng[t]; vlnb[t] = lnb[t]; }
    #pragma unroll
    for (int p = 0; p < 16; ++p) {
        int e = t + 256 * p; int r = e >> 6, d = e & 63;
        hA[r*72 + d] = f2bf(in[(size_t)(m0 + r) * 64 + d]);
    }
    #pragma unroll
    for (int p = 0; p < 16; ++p) {
        int e = t + 256 * p; int k = e >> 6, c = e & 63;
        Wt0[c*72 + k] = f2bf(g1w[k*64 + c]);
        Wt1[c*72 + k] = f2bf(g2w[k*64 + c]);
    }
    __syncthreads();

    f32x4 aA[4], aB[4];
    #pragma unroll
    for (int rg = 0; rg < 4; ++rg) { aA[rg] = (f32x4){0.f,0.f,0.f,0.f}; aB[rg] = (f32x4){0.f,0.f,0.f,0.f}; }
    #pragma unroll
    for (int ks = 0; ks < 2; ++ks) {
        short8v b0f = *(const short8v*)&Wt0[(w*16 + lr)*72 + ks*32 + lg*8];
        short8v b1f = *(const short8v*)&Wt1[(w*16 + lr)*72 + ks*32 + lg*8];
        #pragma unroll
        for (int rg = 0; rg < 4; ++rg) {
            short8v af = *(const short8v*)&hA[(rg*16 + lr)*72 + ks*32 + lg*8];
            aA[rg] = __builtin_amdgcn_mfma_f32_16x16x32_bf16(af, b0f, aA[rg], 0, 0, 0);
            aB[rg] = __builtin_amdgcn_mfma_f32_16x16x32_bf16(af, b1f, aB[rg], 0, 0, 0);
        }
    }
    __syncthreads();

    #pragma unroll
    for (int rg = 0; rg < 4; ++rg)
        #pragma unroll
        for (int j = 0; j < 4; ++j) {
            int r = rg*16 + lg*4 + j, c = w*16 + lr;
            float sg = sigmoidf_(aA[rg][j] + vg1b[c]);
            yA[r*68 + c] = sg * (aB[rg][j] + vg2b[c]) + res[(size_t)(m0 + r) * 64 + c];
        }
    __syncthreads();

    const int tr = t >> 4, tc = t & 15;
    #pragma unroll
    for (int a = 0; a < 4; ++a) {
        const int r = tr + 16*a;
        float vals[4]; float part = 0.f;
        #pragma unroll
        for (int b = 0; b < 4; ++b) { vals[b] = yA[r*68 + tc + 16*b]; part += vals[b]; }
        #pragma unroll
        for (int off = 1; off < 16; off <<= 1) part += __shfl_xor(part, off);
        const float mean = part * (1.f / 64.f);
        float vp = 0.f;
        #pragma unroll
        for (int b = 0; b < 4; ++b) { float d = vals[b] - mean; vp += d * d; }
        #pragma unroll
        for (int off = 1; off < 16; off <<= 1) vp += __shfl_xor(vp, off);
        const float inv = rsqrtf(vp * (1.f / 64.f) + LN_EPS);
        #pragma unroll
        for (int b = 0; b < 4; ++b) {
            const int c = tc + 16*b;
            float v = (vals[b] - mean) * inv * vlng[c] + vlnb[c];
            outf[(size_t)(m0 + r) * 64 + c] = v;
            outb[(size_t)(m0 + r) * 64 + c] = __float2bfloat16(v);
        }
    }
}

// =====================================================================
// qkv = temporal_bf16 @ attn_in_w[64,192] + b
// =====================================================================
__global__ __launch_bounds__(256) void qkv_kernel(
    const __hip_bfloat16* __restrict__ tb,
    const float* __restrict__ wqkv, const float* __restrict__ bqkv,
    float* __restrict__ qkv)
{
    const int m0 = blockIdx.x * 64;
    const int t = threadIdx.x;
    const int w = t >> 6, l = t & 63, lr = l & 15, lg = l >> 4;
    __shared__ __align__(16) unsigned short hA[64 * 72];
    __shared__ __align__(16) unsigned short Wt[192 * 72];
    __shared__ float vb[192];

    if (t < 192) vb[t] = bqkv[t];
    #pragma unroll
    for (int p = 0; p < 16; ++p) {
        int e = t + 256 * p; int r = e >> 6, d = e & 63;
        hA[r*72 + d] = *(const unsigned short*)&tb[(size_t)(m0 + r) * 64 + d];
    }
    #pragma unroll
    for (int p = 0; p < 48; ++p) {
        int e = t + 256 * p; int c = e >> 6, k = e & 63;
        Wt[c*72 + k] = f2bf(wqkv[(size_t)k * 192 + c]);
    }
    __syncthreads();

    f32x4 acc[4][3];
    #pragma unroll
    for (int rg = 0; rg < 4; ++rg)
        #pragma unroll
        for (int cf = 0; cf < 3; ++cf) acc[rg][cf] = (f32x4){0.f,0.f,0.f,0.f};
    #pragma unroll
    for (int ks = 0; ks < 2; ++ks) {
        short8v af[4];
        #pragma unroll
        for (int rg = 0; rg < 4; ++rg)
            af[rg] = *(const short8v*)&hA[(rg*16 + lr)*72 + ks*32 + lg*8];
        #pragma unroll
        for (int cf = 0; cf < 3; ++cf) {
            short8v bf = *(const short8v*)&Wt[(w*48 + cf*16 + lr)*72 + ks*32 + lg*8];
            #pragma unroll
            for (int rg = 0; rg < 4; ++rg)
                acc[rg][cf] = __builtin_amdgcn_mfma_f32_16x16x32_bf16(af[rg], bf, acc[rg][cf], 0, 0, 0);
        }
    }
    #pragma unroll
    for (int rg = 0; rg < 4; ++rg)
        #pragma unroll
        for (int cf = 0; cf < 3; ++cf)
            #pragma unroll
            for (int j = 0; j < 4; ++j) {
                int r = rg*16 + lg*4 + j, c = w*48 + cf*16 + lr;
                qkv[(size_t)(m0 + r) * 192 + c] = acc[rg][cf][j] + vb[c];
            }
}

// =====================================================================
// MHA core -> ao bf16
// =====================================================================
__global__ __launch_bounds__(256) void attn_kernel(
    const float* __restrict__ qkv, __hip_bfloat16* __restrict__ ao)
{
    const int b = blockIdx.x;
    const int h = threadIdx.x >> 6, l = threadIdx.x & 63;
    __shared__ float sq[4][24][16], sk[4][24][16], sv[4][24][16], sp[4][24][24];
    #pragma unroll
    for (int p = 0; p < 6; ++p) {
        int e = l + 64 * p; int ti = e >> 4, d = e & 15;
        size_t base = ((size_t)(b * TSEQ + ti)) * 192 + h * 16 + d;
        sq[h][ti][d] = qkv[base];
        sk[h][ti][d] = qkv[base + 64];
        sv[h][ti][d] = qkv[base + 128];
    }
    __syncthreads();
    #pragma unroll
    for (int p = 0; p < 9; ++p) {
        int e = l + 64 * p; int i = e / 24, j = e - i * 24;
        float s = 0.f;
        #pragma unroll
        for (int d = 0; d < 16; ++d) s += sq[h][i][d] * sk[h][j][d];
        sp[h][i][j] = s * 0.25f;
    }
    __syncthreads();
    if (l < 24) {
        float mx = -1e30f;
        for (int j = 0; j < 24; ++j) mx = fmaxf(mx, sp[h][l][j]);
        float s = 0.f;
        for (int j = 0; j < 24; ++j) { float e = __expf(sp[h][l][j] - mx); sp[h][l][j] = e; s += e; }
        float inv = __builtin_amdgcn_rcpf(s);
        for (int j = 0; j < 24; ++j) sp[h][l][j] *= inv;
    }
    __syncthreads();
    #pragma unroll
    for (int p = 0; p < 6; ++p) {
        int e = l + 64 * p; int ti = e >> 4, d = e & 15;
        float s = 0.f;
        #pragma unroll
        for (int j = 0; j < 24; ++j) s += sp[h][ti][j] * sv[h][j][d];
        ao[((size_t)(b * TSEQ + ti)) * 64 + h * 16 + d] = __float2bfloat16(s);
    }
}

// =====================================================================
// fused post-attn: ao@Wout+b -> GLU(pa) -> +temporal -> LN -> enriched
// =====================================================================
__global__ __launch_bounds__(256) void fused_pa_kernel(
    const __hip_bfloat16* __restrict__ ao, const float* __restrict__ res,
    const float* __restrict__ wout, const float* __restrict__ bout,
    const float* __restrict__ g1w, const float* __restrict__ g1b,
    const float* __restrict__ g2w, const float* __restrict__ g2b,
    const float* __restrict__ lng, const float* __restrict__ lnb,
    float* __restrict__ outf, __hip_bfloat16* __restrict__ outb)
{
    const int m0 = blockIdx.x * 64;
    const int t = threadIdx.x;
    const int w = t >> 6, l = t & 63, lr = l & 15, lg = l >> 4;
    __shared__ __align__(16) unsigned short hA[64 * 72];
    __shared__ __align__(16) unsigned char uS[18432];
    unsigned short* Wt0 = (unsigned short*)uS;
    unsigned short* Wt1 = (unsigned short*)(uS + 9216);
    float* yA = (float*)uS;
    __shared__ float vob[64], vg1b[64], vg2b[64], vlng[64], vlnb[64];

    if (t < 64) { vob[t] = bout[t]; vg1b[t] = g1b[t]; vg2b[t] = g2b[t]; vlng[t] = lng[t]; vlnb[t] = lnb[t]; }
    #pragma unroll
    for (int p = 0; p < 16; ++p) {
        int e = t + 256 * p; int r = e >> 6, d = e & 63;
        hA[r*72 + d] = *(const unsigned short*)&ao[(size_t)(m0 + r) * 64 + d];
    }
    #pragma unroll
    for (int p = 0; p < 16; ++p) {
        int e = t + 256 * p; int k = e >> 6, c = e & 63;
        Wt0[c*72 + k] = f2bf(wout[k*64 + c]);
    }
    __syncthreads();

    f32x4 acc1[4];
    #pragma unroll
    for (int rg = 0; rg < 4; ++rg) acc1[rg] = (f32x4){0.f,0.f,0.f,0.f};
    #pragma unroll
    for (int ks = 0; ks < 2; ++ks) {
        short8v bf = *(const short8v*)&Wt0[(w*16 + lr)*72 + ks*32 + lg*8];
        #pragma unroll
        for (int rg = 0; rg < 4; ++rg) {
            short8v af = *(const short8v*)&hA[(rg*16 + lr)*72 + ks*32 + lg*8];
            acc1[rg] = __builtin_amdgcn_mfma_f32_16x16x32_bf16(af, bf, acc1[rg], 0, 0, 0);
        }
    }
    #pragma unroll
    for (int p = 0; p < 16; ++p) {
        int e = t + 256 * p; int k = e >> 6, c = e & 63;
        Wt1[c*72 + k] = f2bf(g1w[k*64 + c]);
    }
    __syncthreads();

    #pragma unroll
    for (int rg = 0; rg < 4; ++rg)
        #pragma unroll
        for (int j = 0; j < 4; ++j) {
            int r = rg*16 + lg*4 + j, c = w*16 + lr;
            hA[r*72 + c] = f2bf(acc1[rg][j] + vob[c]);
        }
    #pragma unroll
    for (int p = 0; p < 16; ++p) {
        int e = t + 256 * p; int k = e >> 6, c = e & 63;
        Wt0[c*72 + k] = f2bf(g2w[k*64 + c]);
    }
    __syncthreads();

    f32x4 aA[4], aB[4];
    #pragma unroll
    for (int rg = 0; rg < 4; ++rg) { aA[rg] = (f32x4){0.f,0.f,0.f,0.f}; aB[rg] = (f32x4){0.f,0.f,0.f,0.f}; }
    #pragma unroll
    for (int ks = 0; ks < 2; ++ks) {
        short8v b1f = *(const short8v*)&Wt1[(w*16 + lr)*72 + ks*32 + lg*8];
        short8v b2f = *(const short8v*)&Wt0[(w*16 + lr)*72 + ks*32 + lg*8];
        #pragma unroll
        for (int rg = 0; rg < 4; ++rg) {
            short8v af = *(const short8v*)&hA[(rg*16 + lr)*72 + ks*32 + lg*8];
            aA[rg] = __builtin_amdgcn_mfma_f32_16x16x32_bf16(af, b1f, aA[rg], 0, 0, 0);
            aB[rg] = __builtin_amdgcn_mfma_f32_16x16x32_bf16(af, b2f, aB[rg], 0, 0, 0);
        }
    }
    __syncthreads();

    #pragma unroll
    for (int rg = 0; rg < 4; ++rg)
        #pragma unroll
        for (int j = 0; j < 4; ++j) {
            int r = rg*16 + lg*4 + j, c = w*16 + lr;
            float sg = sigmoidf_(aA[rg][j] + vg1b[c]);
            yA[r*68 + c] = sg * (aB[rg][j] + vg2b[c]) + res[(size_t)(m0 + r) * 64 + c];
        }
    __syncthreads();

    const int tr = t >> 4, tc = t & 15;
    #pragma unroll
    for (int a = 0; a < 4; ++a) {
        const int r = tr + 16*a;
        float vals[4]; float part = 0.f;
        #pragma unroll
        for (int b = 0; b < 4; ++b) { vals[b] = yA[r*68 + tc + 16*b]; part += vals[b]; }
        #pragma unroll
        for (int off = 1; off < 16; off <<= 1) part += __shfl_xor(part, off);
        const float mean = part * (1.f / 64.f);
        float vp = 0.f;
        #pragma unroll
        for (int b = 0; b < 4; ++b) { float d = vals[b] - mean; vp += d * d; }
        #pragma unroll
        for (int off = 1; off < 16; off <<= 1) vp += __shfl_xor(vp, off);
        const float inv = rsqrtf(vp * (1.f / 64.f) + LN_EPS);
        #pragma unroll
        for (int b = 0; b < 4; ++b) {
            const int c = tc + 16*b;
            float v = (vals[b] - mean) * inv * vlng[c] + vlnb[c];
            outf[(size_t)(m0 + r) * 64 + c] = v;
            outb[(size_t)(m0 + r) * 64 + c] = __float2bfloat16(v);
        }
    }
}

// =====================================================================
// fused FF GRN
// =====================================================================
__global__ __launch_bounds__(256) void fused_ff_kernel(
    const __hip_bfloat16* __restrict__ eb, const float* __restrict__ res,
    const float* __restrict__ w1, const float* __restrict__ b1,
    const float* __restrict__ w2, const float* __restrict__ b2,
    const float* __restrict__ g1w, const float* __restrict__ g1b,
    const float* __restrict__ g2w, const float* __restrict__ g2b,
    const float* __restrict__ lng, const float* __restrict__ lnb,
    float* __restrict__ outf)
{
    const int m0 = blockIdx.x * 64;
    const int t = threadIdx.x;
    const int w = t >> 6, l = t & 63, lr = l & 15, lg = l >> 4;
    __shared__ __align__(16) unsigned short hA[64 * 72];
    __shared__ __align__(16) unsigned short hB[64 * 136];
    __shared__ __align__(16) unsigned char U1[18432];
    __shared__ __align__(16) unsigned char U2[17408];
    __shared__ float vb1[128], vb2[64], vg1b[64], vg2b[64], vlng[64], vlnb[64];

    unsigned short* W1t = (unsigned short*)U1;
    unsigned short* W2t = (unsigned short*)U2;
    unsigned short* G1t = (unsigned short*)U1;
    unsigned short* G2t = (unsigned short*)(U1 + 9216);
    float* yA = (float*)U2;

    if (t < 128) vb1[t] = b1[t];
    if (t < 64) { vb2[t] = b2[t]; vg1b[t] = g1b[t]; vg2b[t] = g2b[t]; vlng[t] = lng[t]; vlnb[t] = lnb[t]; }
    #pragma unroll
    for (int p = 0; p < 16; ++p) {
        int e = t + 256 * p; int r = e >> 6, d = e & 63;
        hA[r*72 + d] = *(const unsigned short*)&eb[(size_t)(m0 + r) * 64 + d];
    }
    #pragma unroll
    for (int p = 0; p < 32; ++p) {
        int e = t + 256 * p; int k = e >> 7, c = e & 127;
        W1t[c*72 + k] = f2bf(w1[(size_t)k * 128 + c]);
    }
    #pragma unroll
    for (int p = 0; p < 32; ++p) {
        int e = t + 256 * p; int k = e >> 6, c = e & 63;
        W2t[c*136 + k] = f2bf(w2[(size_t)k * 64 + c]);
    }
    __syncthreads();

    f32x4 acc1[4][2];
    #pragma unroll
    for (int rg = 0; rg < 4; ++rg)
        #pragma unroll
        for (int cf = 0; cf < 2; ++cf) acc1[rg][cf] = (f32x4){0.f,0.f,0.f,0.f};
    #pragma unroll
    for (int ks = 0; ks < 2; ++ks) {
        short8v af[4];
        #pragma unroll
        for (int rg = 0; rg < 4; ++rg)
            af[rg] = *(const short8v*)&hA[(rg*16 + lr)*72 + ks*32 + lg*8];
        #pragma unroll
        for (int cf = 0; cf < 2; ++cf) {
            short8v bf = *(const short8v*)&W1t[(w*32 + cf*16 + lr)*72 + ks*32 + lg*8];
            #pragma unroll
            for (int rg = 0; rg < 4; ++rg)
                acc1[rg][cf] = __builtin_amdgcn_mfma_f32_16x16x32_bf16(af[rg], bf, acc1[rg][cf], 0, 0, 0);
        }
    }
    #pragma unroll
    for (int rg = 0; rg < 4; ++rg)
        #pragma unroll
        for (int cf = 0; cf < 2; ++cf)
            #pragma unroll
            for (int j = 0; j < 4; ++j) {
                int r = rg*16 + lg*4 + j, c = w*32 + cf*16 + lr;
                hB[r*136 + c] = f2bf(eluf_(acc1[rg][cf][j] + vb1[c]));
            }
    __syncthreads();

    #pragma unroll
    for (int p = 0; p < 16; ++p) {
        int e = t + 256 * p; int k = e >> 6, c = e & 63;
        G1t[c*72 + k] = f2bf(g1w[k*64 + c]);
        G2t[c*72 + k] = f2bf(g2w[k*64 + c]);
    }
    __syncthreads();

    f32x4 acc2[4];
    #pragma unroll
    for (int rg = 0; rg < 4; ++rg) acc2[rg] = (f32x4){0.f,0.f,0.f,0.f};
    #pragma unroll
    for (int ks = 0; ks < 4; ++ks) {
        short8v bf = *(const short8v*)&W2t[(w*16 + lr)*136 + ks*32 + lg*8];
        #pragma unroll
        for (int rg = 0; rg < 4; ++rg) {
            short8v af = *(const short8v*)&hB[(rg*16 + lr)*136 + ks*32 + lg*8];
            acc2[rg] = __builtin_amdgcn_mfma_f32_16x16x32_bf16(af, bf, acc2[rg], 0, 0, 0);
        }
    }
    #pragma unroll
    for (int rg = 0; rg < 4; ++rg)
        #pragma unroll
        for (int j = 0; j < 4; ++j) {
            int r = rg*16 + lg*4 + j, c = w*16 + lr;
            hA[r*72 + c] = f2bf(acc2[rg][j] + vb2[c]);
        }
    __syncthreads();

    f32x4 aA[4], aB[4];
    #pragma unroll
    for (int rg = 0; rg < 4; ++rg) { aA[rg] = (f32x4){0.f,0.f,0.f,0.f}; aB[rg] = (f32x4){0.f,0.f,0.f,0.f}; }
    #pragma unroll
    for (int ks = 0; ks < 2; ++ks) {
        short8v b1f = *(const short8v*)&G1t[(w*16 + lr)*72 + ks*32 + lg*8];
        short8v b2f = *(const short8v*)&G2t[(w*16 + lr)*72 + ks*32 + lg*8];
        #pragma unroll
        for (int rg = 0; rg < 4; ++rg) {
            short8v af = *(const short8v*)&hA[(rg*16 + lr)*72 + ks*32 + lg*8];
            aA[rg] = __builtin_amdgcn_mfma_f32_16x16x32_bf16(af, b1f, aA[rg], 0, 0, 0);
            aB[rg] = __builtin_amdgcn_mfma_f32_16x16x32_bf16(af, b2f, aB[rg], 0, 0, 0);
        }
    }
    __syncthreads();

    #pragma unroll
    for (int rg = 0; rg < 4; ++rg)
        #pragma unroll
        for (int j = 0; j < 4; ++j) {
            int r = rg*16 + lg*4 + j, c = w*16 + lr;
            float sg = sigmoidf_(aA[rg][j] + vg1b[c]);
            yA[r*68 + c] = sg * (aB[rg][j] + vg2b[c]) + res[(size_t)(m0 + r) * 64 + c];
        }
    __syncthreads();

    const int tr = t >> 4, tc = t & 15;
    #pragma unroll
    for (int a = 0; a < 4; ++a) {
        const int r = tr + 16*a;
        float vals[4]; float part = 0.f;
        #pragma unroll
        for (int b = 0; b < 4; ++b) { vals[b] = yA[r*68 + tc + 16*b]; part += vals[b]; }
        #pragma unroll
        for (int off = 1; off < 16; off <<= 1) part += __shfl_xor(part, off);
        const float mean = part * (1.f / 64.f);
        float vp = 0.f;
        #pragma unroll
        for (int b = 0; b < 4; ++b) { float d = vals[b] - mean; vp += d * d; }
        #pragma unroll
        for (int off = 1; off < 16; off <<= 1) vp += __shfl_xor(vp, off);
        const float inv = rsqrtf(vp * (1.f / 64.f) + LN_EPS);
        #pragma unroll
        for (int b = 0; b < 4; ++b) {
            const int c = tc + 16*b;
            outf[(size_t)(m0 + r) * 64 + c] = (vals[b] - mean) * inv * vlng[c] + vlnb[c];
        }
    }
}

// =====================================================================
// head: mean over T -> fc1+relu -> fc2
// =====================================================================
__global__ __launch_bounds__(64) void head_kernel(
    const float* __restrict__ outln,
    const float* __restrict__ fc1_w, const float* __restrict__ fc1_b,
    const float* __restrict__ fc2_w, const float* __restrict__ fc2_b,
    float* __restrict__ out)
{
    const int b = blockIdx.x, l = threadIdx.x;
    __shared__ float sp[64];
    float s = 0.f;
    #pragma unroll
    for (int tt = 0; tt < TSEQ; ++tt) s += outln[((size_t)(b * TSEQ + tt)) * 64 + l];
    sp[l] = s * (1.f / 24.f);
    __syncthreads();
    float a = fc1_b[l];
    for (int k = 0; k < 64; ++k) a += sp[k] * fc1_w[k*64 + l];
    float f1 = fmaxf(a, 0.f);
    #pragma unroll
    for (int j = 0; j < 6; ++j) {
        float p = f1 * fc2_w[l*6 + j];
        #pragma unroll
        for (int off = 32; off; off >>= 1) p += __shfl_xor(p, off);
        if (l == 0) out[b*6 + j] = p + fc2_b[j];
    }
}

// =====================================================================
extern "C" void kernel_launch(void* const* d_in, const int* in_sizes, int n_in,
                              void* d_out, int out_size, void* d_ws, size_t ws_size,
                              hipStream_t stream)
{
    const float* x        = (const float*)d_in[0];
    const float* f_w1     = (const float*)d_in[1];
    const float* f_b1     = (const float*)d_in[2];
    const float* f_w2     = (const float*)d_in[3];
    const float* f_b2     = (const float*)d_in[4];
    const float* f_g1w    = (const float*)d_in[5];
    const float* f_g1b    = (const float*)d_in[6];
    const float* f_g2w    = (const float*)d_in[7];
    const float* f_g2b    = (const float*)d_in[8];
    const float* f_skw    = (const float*)d_in[9];
    const float* f_skb    = (const float*)d_in[10];
    const float* f_lng    = (const float*)d_in[11];
    const float* f_lnb    = (const float*)d_in[12];
    const float* w_w1     = (const float*)d_in[13];
    const float* w_b1     = (const float*)d_in[14];
    const float* w_w2     = (const float*)d_in[15];
    const float* w_b2     = (const float*)d_in[16];
    const float* w_g1w    = (const float*)d_in[17];
    const float* w_g1b    = (const float*)d_in[18];
    const float* w_g2w    = (const float*)d_in[19];
    const float* w_g2b    = (const float*)d_in[20];
    const float* w_skw    = (const float*)d_in[21];
    const float* w_skb    = (const float*)d_in[22];
    const float* w_lng    = (const float*)d_in[23];
    const float* w_lnb    = (const float*)d_in[24];
    const float* lstm_wih = (const float*)d_in[25];
    const float* lstm_whh = (const float*)d_in[26];
    const float* lstm_bih = (const float*)d_in[27];
    const float* lstm_bhh = (const float*)d_in[28];
    const float* pl_g1w   = (const float*)d_in[29];
    const float* pl_g1b   = (const float*)d_in[30];
    const float* pl_g2w   = (const float*)d_in[31];
    const float* pl_g2b   = (const float*)d_in[32];
    const float* pl_lng   = (const float*)d_in[33];
    const float* pl_lnb   = (const float*)d_in[34];
    const float* attn_in_w  = (const float*)d_in[35];
    const float* attn_in_b  = (const float*)d_in[36];
    const float* attn_out_w = (const float*)d_in[37];
    const float* attn_out_b = (const float*)d_in[38];
    const float* pa_g1w   = (const float*)d_in[39];
    const float* pa_g1b   = (const float*)d_in[40];
    const float* pa_g2w   = (const float*)d_in[41];
    const float* pa_g2b   = (const float*)d_in[42];
    const float* pa_lng   = (const float*)d_in[43];
    const float* pa_lnb   = (const float*)d_in[44];
    const float* ff_w1    = (const float*)d_in[45];
    const float* ff_b1    = (const float*)d_in[46];
    const float* ff_w2    = (const float*)d_in[47];
    const float* ff_b2    = (const float*)d_in[48];
    const float* ff_g1w   = (const float*)d_in[49];
    const float* ff_g1b   = (const float*)d_in[50];
    const float* ff_g2w   = (const float*)d_in[51];
    const float* ff_g2b   = (const float*)d_in[52];
    const float* ff_lng   = (const float*)d_in[53];
    const float* ff_lnb   = (const float*)d_in[54];
    const float* fc1_w    = (const float*)d_in[55];
    const float* fc1_b    = (const float*)d_in[56];
    const float* fc2_w    = (const float*)d_in[57];
    const float* fc2_b    = (const float*)d_in[58];

    float* ws = (float*)d_ws;

    // ---------------- phase-2 union (fixed offsets) ----------------------
    size_t o = 0;
    const size_t o_S0   = o; o += (size_t)MTOT * 256;   // xW / qkv
    const size_t o_A    = o; o += (size_t)MTOT * 64;    // lstm_out
    const size_t o_Bf   = o; o += (size_t)MTOT * 64;    // enriched f32
    const size_t o_Cf   = o; o += (size_t)MTOT * 64;    // outln f32
    const size_t o_Df   = o; o += (size_t)MTOT * 64;    // temporal f32
    const size_t o_F    = o; o += (size_t)MTOT * 128;   // bf16 trio: tb/ab/eb
    const size_t o_whhT = o; o += 16384;
    const size_t unionP2 = o;                            // 7,880,704 floats

    const size_t o_tb = o_F;
    const size_t o_ab = o_F + (size_t)MTOT * 32;
    const size_t o_eb = o_F + (size_t)MTOT * 64;

    // ---------------- adaptive M-chunk selection --------------------------
    const size_t persist = (size_t)MTOT * 177;           // sel + selb + xT
    int mc = 0;
    {
        const int cands[4] = {12288, 6144, 3072, 1536};
        for (int ci = 0; ci < 4; ++ci) {
            const size_t c = (size_t)cands[ci];
            size_t overlay = c * FDIM / 2 + (size_t)KS * c * NW + c * 81
                           + (size_t)NW * FDIM / 2;
            size_t A = overlay > unionP2 ? overlay : unionP2;
            if ((A + persist) * sizeof(float) <= ws_size) { mc = cands[ci]; break; }
        }
        if (mc == 0) return;                             // workspace too small
    }
    const size_t ovl_partial = (size_t)mc * FDIM / 2;
    const size_t ovl_w81     = ovl_partial + (size_t)KS * mc * NW;
    const size_t ovl_wcat    = ovl_w81 + (size_t)mc * 81;
    const size_t ovl_end     = ovl_wcat + (size_t)NW * FDIM / 2;
    const size_t regA        = ovl_end > unionP2 ? ovl_end : unionP2;
    const size_t o_sel  = regA;
    const size_t o_selb = o_sel + (size_t)MTOT * 64;
    const size_t o_xt   = o_selb + (size_t)MTOT * 32;

    const dim3 blk(256);

    // 0) transpose x ; pack weight-head matrices to bf16
    xt_kernel<<<dim3((NF * MTOT + 255) / 256), blk, 0, stream>>>(x, ws + o_xt);
    wprep_kernel<<<dim3((FDIM + 255) / 256, NW), blk, 0, stream>>>(
        w_w1, w_skw, (unsigned short*)(ws + ovl_wcat));

    // ---------------- phase 1: VSN + weight-GRN, chunked over M ----------
    for (int mb = 0; mb < MTOT; mb += mc) {
        __hip_bfloat16* chunk = (__hip_bfloat16*)ws;
        vsn_kernel<<<dim3((mc / 64) / NT, NF), blk, 0, stream>>>(
            ws + o_xt + mb, f_w1, f_b1, f_w2, f_b2, f_g1w, f_g1b,
            f_g2w, f_g2b, f_skw, f_skb, f_lng, f_lnb, chunk);
        wgemm_kernel<<<dim3(mc / 32, KS), dim3(64), 0, stream>>>(
            chunk, (const unsigned short*)(ws + ovl_wcat), ws + ovl_partial, mc);
        wtail_kernel<<<dim3(mc / 16), blk, 0, stream>>>(
            ws + ovl_partial, w_b1, w_skb, w_w2, w_b2, w_g1w, w_g1b,
            w_g2w, w_g2b, w_lng, w_lnb, ws + ovl_w81, mc);
        selected_kernel<<<dim3(mc), blk, 0, stream>>>(
            chunk, ws + ovl_w81, ws + o_sel + (size_t)mb * 64,
            (__hip_bfloat16*)(ws + o_selb) + (size_t)mb * 64);
    }

    // ---------------- phase 2: LSTM -> attention -> head -----------------
    lstm_prep_kernel<<<dim3(64), blk, 0, stream>>>(lstm_whh, ws + o_whhT);
    xw_kernel<<<dim3(MTOT / 64), blk, 0, stream>>>(
        (const __hip_bfloat16*)(ws + o_selb), lstm_wih, lstm_bih, lstm_bhh, ws + o_S0);
    lstm_kernel<<<dim3(BB), blk, 0, stream>>>(ws + o_S0, ws + o_whhT, ws + o_A);
    fused_pl_kernel<<<dim3(MTOT / 64), blk, 0, stream>>>(
        ws + o_A, ws + o_sel, pl_g1w, pl_g1b, pl_g2w, pl_g2b, pl_lng, pl_lnb,
        ws + o_Df, (__hip_bfloat16*)(ws + o_tb));
    qkv_kernel<<<dim3(MTOT / 64), blk, 0, stream>>>(
        (const __hip_bfloat16*)(ws + o_tb), attn_in_w, attn_in_b, ws + o_S0);
    attn_kernel<<<dim3(BB), blk, 0, stream>>>(
        ws + o_S0, (__hip_bfloat16*)(ws + o_ab));
    fused_pa_kernel<<<dim3(MTOT / 64), blk, 0, stream>>>(
        (const __hip_bfloat16*)(ws + o_ab), ws + o_Df,
        attn_out_w, attn_out_b, pa_g1w, pa_g1b, pa_g2w, pa_g2b, pa_lng, pa_lnb,
        ws + o_Bf, (__hip_bfloat16*)(ws + o_eb));
    fused_ff_kernel<<<dim3(MTOT / 64), blk, 0, stream>>>(
        (const __hip_bfloat16*)(ws + o_eb), ws + o_Bf,
        ff_w1, ff_b1, ff_w2, ff_b2, ff_g1w, ff_g1b, ff_g2w, ff_g2b,
        ff_lng, ff_lnb, ws + o_Cf);
    head_kernel<<<dim3(BB), dim3(64), 0, stream>>>(
        ws + o_Cf, fc1_w, fc1_b, fc2_w, fc2_b, (float*)d_out);
}

// Round 10
// 431.464 us; speedup vs baseline: 26.3483x; 1.1356x over previous
//
#include <hip/hip_runtime.h>
#include <hip/hip_bf16.h>
#include <math.h>

// ---------------- problem constants ----------------
constexpr int BB   = 512;
constexpr int TSEQ = 24;
constexpr int NF   = 81;
constexpr int DD   = 64;
constexpr int MTOT = BB * TSEQ;      // 12288
constexpr int FDIM = NF * DD;        // 5184
constexpr int KS   = 6;              // split-K groups (5184/6 = 864 = 27*32)
constexpr int KSL  = 864;            // K-slice length
constexpr int NW   = 160;            // padded combined N: 64 (wh1) + 81 (sk) + pad
constexpr int NT   = 6;              // m-tiles per VSN block
constexpr float LN_EPS = 1e-5f;

typedef __attribute__((ext_vector_type(8))) short short8v;   // 8 bf16 (4 VGPRs)
typedef __attribute__((ext_vector_type(4))) float f32x4;     // MFMA C/D

// ---- fast transcendentals (native v_exp_f32 / v_rcp_f32; ~1-2 ulp) ----
static __device__ __forceinline__ float sigmoidf_(float x) {
    return __builtin_amdgcn_rcpf(1.f + __expf(-x));
}
static __device__ __forceinline__ float eluf_(float x) {
    return x > 0.f ? x : (__expf(x) - 1.f);
}
static __device__ __forceinline__ float ftanh_(float x) {
    float e = __expf(2.f * x);
    return 1.f - 2.f * __builtin_amdgcn_rcpf(e + 1.f);
}
static __device__ __forceinline__ unsigned short f2bf(float x) {
    __hip_bfloat16 h = __float2bfloat16(x);
    return *reinterpret_cast<unsigned short*>(&h);
}

// =====================================================================
// x transpose v2: LDS-tiled, both sides coalesced. grid MTOT/128.
// =====================================================================
__global__ __launch_bounds__(256) void xt_kernel(
    const float* __restrict__ x, float* __restrict__ xT)
{
    __shared__ float tile[128 * 81];
    const int m0 = blockIdx.x * 128;
    const int t  = threadIdx.x;
    for (int e = t; e < 128 * 81; e += 256)
        tile[e] = x[(size_t)m0 * NF + e];
    __syncthreads();
    for (int e = t; e < 128 * 81; e += 256) {
        int f = e >> 7, r = e & 127;
        xT[(size_t)f * MTOT + m0 + r] = tile[r * 81 + f];
    }
}

// =====================================================================
// Kernel 1: VSN v5 (unchanged from round 9 — verified)
// =====================================================================
__global__ __launch_bounds__(256) void vsn_kernel(
    const float* __restrict__ xT,
    const float* __restrict__ f_w1,  const float* __restrict__ f_b1,
    const float* __restrict__ f_w2,  const float* __restrict__ f_b2,
    const float* __restrict__ f_g1w, const float* __restrict__ f_g1b,
    const float* __restrict__ f_g2w, const float* __restrict__ f_g2b,
    const float* __restrict__ f_skw, const float* __restrict__ f_skb,
    const float* __restrict__ f_lng, const float* __restrict__ f_lnb,
    __hip_bfloat16* __restrict__ stacked)
{
    const int f  = blockIdx.y;
    const int t  = threadIdx.x;
    const int w  = t >> 6;
    const int l  = t & 63;
    const int lr = l & 15;
    const int lg = l >> 4;

    __shared__ __align__(16) unsigned short W2t[64 * 72];
    __shared__ __align__(16) unsigned short G1t[64 * 72];
    __shared__ __align__(16) unsigned short G2t[64 * 72];
    __shared__ __align__(16) unsigned char  U[17408];
    unsigned short* hA = (unsigned short*)U;
    float*          yA = (float*)U;
    __shared__ float vw1[64], vb1[64], vb2[64], vg1b[64], vg2b[64];
    __shared__ float vskw[64], vskb[64], vlng[64], vlnb[64], xv[64];

    if (t < 64) {
        vw1[t]  = f_w1 [f*64 + t];  vb1[t]  = f_b1 [f*64 + t];
        vb2[t]  = f_b2 [f*64 + t];
        vg1b[t] = f_g1b[f*64 + t];  vg2b[t] = f_g2b[f*64 + t];
        vskw[t] = f_skw[f*64 + t];  vskb[t] = f_skb[f*64 + t];
        vlng[t] = f_lng[f*64 + t];  vlnb[t] = f_lnb[f*64 + t];
        xv[t]   = xT[(size_t)f * MTOT + blockIdx.x * (NT * 64) + t];
    }
    {
        const float* w2p = f_w2  + (size_t)f * 4096;
        const float* g1p = f_g1w + (size_t)f * 4096;
        const float* g2p = f_g2w + (size_t)f * 4096;
        #pragma unroll
        for (int p = 0; p < 16; ++p) {
            int e = t + 256 * p; int k = e >> 6, c = e & 63;
            W2t[c*72 + k] = f2bf(w2p[k*64 + c]);
            G1t[c*72 + k] = f2bf(g1p[k*64 + c]);
            G2t[c*72 + k] = f2bf(g2p[k*64 + c]);
        }
    }
    __syncthreads();

    for (int it = 0; it < NT; ++it) {
        const int m0 = (blockIdx.x * NT + it) * 64;

        #pragma unroll
        for (int p = 0; p < 16; ++p) {
            int e = t + 256 * p; int r = e >> 6, d = e & 63;
            hA[r*72 + d] = f2bf(eluf_(xv[r] * vw1[d] + vb1[d]));
        }
        __syncthreads();

        f32x4 acc1[4];
        #pragma unroll
        for (int rg = 0; rg < 4; ++rg) acc1[rg] = (f32x4){0.f, 0.f, 0.f, 0.f};
        #pragma unroll
        for (int ks = 0; ks < 2; ++ks) {
            short8v bf = *(const short8v*)&W2t[(w*16 + lr)*72 + ks*32 + lg*8];
            #pragma unroll
            for (int rg = 0; rg < 4; ++rg) {
                short8v af = *(const short8v*)&hA[(rg*16 + lr)*72 + ks*32 + lg*8];
                acc1[rg] = __builtin_amdgcn_mfma_f32_16x16x32_bf16(af, bf, acc1[rg], 0, 0, 0);
            }
        }
        __syncthreads();

        #pragma unroll
        for (int rg = 0; rg < 4; ++rg)
            #pragma unroll
            for (int j = 0; j < 4; ++j) {
                int r = rg*16 + lg*4 + j, c = w*16 + lr;
                hA[r*72 + c] = f2bf(acc1[rg][j] + vb2[c]);
            }
        __syncthreads();

        f32x4 aA[4], aB[4];
        #pragma unroll
        for (int rg = 0; rg < 4; ++rg) { aA[rg] = (f32x4){0.f,0.f,0.f,0.f}; aB[rg] = (f32x4){0.f,0.f,0.f,0.f}; }
        #pragma unroll
        for (int ks = 0; ks < 2; ++ks) {
            short8v b1f = *(const short8v*)&G1t[(w*16 + lr)*72 + ks*32 + lg*8];
            short8v b2f = *(const short8v*)&G2t[(w*16 + lr)*72 + ks*32 + lg*8];
            #pragma unroll
            for (int rg = 0; rg < 4; ++rg) {
                short8v af = *(const short8v*)&hA[(rg*16 + lr)*72 + ks*32 + lg*8];
                aA[rg] = __builtin_amdgcn_mfma_f32_16x16x32_bf16(af, b1f, aA[rg], 0, 0, 0);
                aB[rg] = __builtin_amdgcn_mfma_f32_16x16x32_bf16(af, b2f, aB[rg], 0, 0, 0);
            }
        }
        float yv[4][4];
        #pragma unroll
        for (int rg = 0; rg < 4; ++rg)
            #pragma unroll
            for (int j = 0; j < 4; ++j) {
                int r = rg*16 + lg*4 + j, c = w*16 + lr;
                float sg = sigmoidf_(aA[rg][j] + vg1b[c]);
                yv[rg][j] = sg * (aB[rg][j] + vg2b[c]) + xv[r] * vskw[c] + vskb[c];
            }
        __syncthreads();

        #pragma unroll
        for (int rg = 0; rg < 4; ++rg)
            #pragma unroll
            for (int j = 0; j < 4; ++j) {
                int r = rg*16 + lg*4 + j, c = w*16 + lr;
                yA[r*68 + c] = yv[rg][j];
            }
        if (t < 64 && it + 1 < NT)
            xv[t] = xT[(size_t)f * MTOT + m0 + 64 + t];
        __syncthreads();

        const int tr = t >> 4, tc = t & 15;
        #pragma unroll
        for (int a = 0; a < 4; ++a) {
            const int r = tr + 16*a;
            float4 v4 = *(const float4*)&yA[r*68 + tc*4];
            float part = v4.x + v4.y + v4.z + v4.w;
            #pragma unroll
            for (int off = 1; off < 16; off <<= 1) part += __shfl_xor(part, off);
            const float mean = part * (1.f / 64.f);
            float d0 = v4.x - mean, d1 = v4.y - mean, d2 = v4.z - mean, d3 = v4.w - mean;
            float vp = d0*d0 + d1*d1 + d2*d2 + d3*d3;
            #pragma unroll
            for (int off = 1; off < 16; off <<= 1) vp += __shfl_xor(vp, off);
            const float inv = rsqrtf(vp * (1.f / 64.f) + LN_EPS);
            const int c0 = tc * 4;
            ushort4 o;
            o.x = f2bf(d0 * inv * vlng[c0+0] + vlnb[c0+0]);
            o.y = f2bf(d1 * inv * vlng[c0+1] + vlnb[c0+1]);
            o.z = f2bf(d2 * inv * vlng[c0+2] + vlnb[c0+2]);
            o.w = f2bf(d3 * inv * vlng[c0+3] + vlnb[c0+3]);
            *(ushort4*)&stacked[(size_t)(m0 + r) * FDIM + f*64 + c0] = o;
        }
        __syncthreads();
    }
}

// =====================================================================
// Pack w_w1 / w_skw into bf16 WcatT[160][FDIM]
// =====================================================================
__global__ void wprep_kernel(
    const float* __restrict__ w_w1, const float* __restrict__ w_skw,
    unsigned short* __restrict__ WcatT)
{
    const int c = blockIdx.y;
    const int k = blockIdx.x * 256 + threadIdx.x;
    if (k >= FDIM) return;
    float v = 0.f;
    if (c < 64)       v = w_w1[(size_t)k * 64 + c];
    else if (c < 145) v = w_skw[(size_t)k * 81 + (c - 64)];
    WcatT[(size_t)c * FDIM + k] = f2bf(v);
}

// =====================================================================
// Split-K fused weight-head GEMM (MFMA, LDS-free), MR=2, KS=6
// =====================================================================
__global__ __launch_bounds__(64) void wgemm_kernel(
    const __hip_bfloat16* __restrict__ stacked,
    const unsigned short* __restrict__ WcatT,
    float* __restrict__ partial, int mc)
{
    const int m0 = blockIdx.x * 32;
    const int ks = blockIdx.y;
    const int l  = threadIdx.x;
    const int lr = l & 15, lg = l >> 4;

    f32x4 acc[2][10];
    #pragma unroll
    for (int h = 0; h < 2; ++h)
        #pragma unroll
        for (int n = 0; n < 10; ++n) acc[h][n] = (f32x4){0.f, 0.f, 0.f, 0.f};

    const size_t a0r = (size_t)(m0 + lr) * FDIM;
    const size_t a1r = (size_t)(m0 + 16 + lr) * FDIM;
    const int k0base = ks * KSL;
    for (int kk = 0; kk < KSL; kk += 32) {
        const int k = k0base + kk + lg * 8;
        short8v a0 = *(const short8v*)(stacked + a0r + k);
        short8v a1 = *(const short8v*)(stacked + a1r + k);
        #pragma unroll
        for (int n = 0; n < 10; ++n) {
            short8v bf = *(const short8v*)(WcatT + (size_t)(n*16 + lr) * FDIM + k);
            acc[0][n] = __builtin_amdgcn_mfma_f32_16x16x32_bf16(a0, bf, acc[0][n], 0, 0, 0);
            acc[1][n] = __builtin_amdgcn_mfma_f32_16x16x32_bf16(a1, bf, acc[1][n], 0, 0, 0);
        }
    }
    #pragma unroll
    for (int h = 0; h < 2; ++h)
        #pragma unroll
        for (int n = 0; n < 10; ++n)
            #pragma unroll
            for (int j = 0; j < 4; ++j) {
                const int m = m0 + h*16 + lg*4 + j;
                partial[((size_t)ks * mc + m) * NW + n*16 + lr] = acc[h][n][j];
            }
}

// =====================================================================
// Weight-GRN tail: LDS-staged weights, 16 rows/block
// =====================================================================
__global__ __launch_bounds__(256) void wtail_kernel(
    const float* __restrict__ partial,
    const float* __restrict__ w_b1,  const float* __restrict__ w_skb,
    const float* __restrict__ w_w2,  const float* __restrict__ w_b2,
    const float* __restrict__ w_g1w, const float* __restrict__ w_g1b,
    const float* __restrict__ w_g2w, const float* __restrict__ w_g2b,
    const float* __restrict__ w_lng, const float* __restrict__ w_lnb,
    float* __restrict__ w81, int mc)
{
    __shared__ float w2s[5184];
    __shared__ float g1s[6561];
    __shared__ float g2s[6561];
    __shared__ float sWh[16][64];
    __shared__ float sW2[16][96];

    const int t  = threadIdx.x;
    const int wv = t >> 6, l = t & 63;
    const int m0 = blockIdx.x * 16;
    const bool v1 = (l < 17);

    for (int e = t; e < 5184; e += 256) w2s[e] = w_w2[e];
    for (int e = t; e < 6561; e += 256) { g1s[e] = w_g1w[e]; g2s[e] = w_g2w[e]; }

    float s0[4], sk0[4], sk1[4];
    {
        const float b1v = w_b1[l], skb0 = w_skb[l], skb1 = v1 ? w_skb[64 + l] : 0.f;
        #pragma unroll
        for (int rr = 0; rr < 4; ++rr) { s0[rr] = b1v; sk0[rr] = skb0; sk1[rr] = skb1; }
    }
    #pragma unroll
    for (int ks = 0; ks < KS; ++ks) {
        #pragma unroll
        for (int rr = 0; rr < 4; ++rr) {
            const float* pr = partial + ((size_t)ks * mc + (m0 + wv*4 + rr)) * NW;
            s0[rr]  += pr[l];
            sk0[rr] += pr[64 + l];
            if (v1) sk1[rr] += pr[128 + l];
        }
    }
    #pragma unroll
    for (int rr = 0; rr < 4; ++rr) sWh[wv*4 + rr][l] = eluf_(s0[rr]);
    __syncthreads();

    float a0[4], a1[4];
    {
        const float b0 = w_b2[l], b1v = v1 ? w_b2[64 + l] : 0.f;
        #pragma unroll
        for (int rr = 0; rr < 4; ++rr) { a0[rr] = b0; a1[rr] = b1v; }
    }
    #pragma unroll 4
    for (int i = 0; i < 64; ++i) {
        const float wl = w2s[i*81 + l];
        const float wh = v1 ? w2s[i*81 + 64 + l] : 0.f;
        #pragma unroll
        for (int rr = 0; rr < 4; ++rr) {
            const float h = sWh[wv*4 + rr][i];
            a0[rr] += h * wl;
            a1[rr] += h * wh;
        }
    }
    #pragma unroll
    for (int rr = 0; rr < 4; ++rr) {
        sW2[wv*4 + rr][l] = a0[rr];
        if (v1) sW2[wv*4 + rr][64 + l] = a1[rr];
    }
    __syncthreads();

    float g10[4], g20[4], g11[4], g21[4];
    {
        const float c10 = w_g1b[l], c20 = w_g2b[l];
        const float c11 = v1 ? w_g1b[64 + l] : 0.f, c21 = v1 ? w_g2b[64 + l] : 0.f;
        #pragma unroll
        for (int rr = 0; rr < 4; ++rr) { g10[rr] = c10; g20[rr] = c20; g11[rr] = c11; g21[rr] = c21; }
    }
    #pragma unroll 3
    for (int i = 0; i < 81; ++i) {
        const float w1l = g1s[i*81 + l],            w2l = g2s[i*81 + l];
        const float w1h = v1 ? g1s[i*81 + 64 + l] : 0.f;
        const float w2h = v1 ? g2s[i*81 + 64 + l] : 0.f;
        #pragma unroll
        for (int rr = 0; rr < 4; ++rr) {
            const float h = sW2[wv*4 + rr][i];
            g10[rr] += h * w1l; g20[rr] += h * w2l;
            g11[rr] += h * w1h; g21[rr] += h * w2h;
        }
    }

    #pragma unroll
    for (int rr = 0; rr < 4; ++rr) {
        const int m = m0 + wv*4 + rr;
        float y0 = sigmoidf_(g10[rr]) * g20[rr] + sk0[rr];
        float y1 = v1 ? (sigmoidf_(g11[rr]) * g21[rr] + sk1[rr]) : 0.f;

        float s = y0 + (v1 ? y1 : 0.f);
        #pragma unroll
        for (int off = 32; off; off >>= 1) s += __shfl_xor(s, off);
        const float mean = s / 81.f;
        float d0 = y0 - mean, d1 = v1 ? (y1 - mean) : 0.f;
        float vs = d0*d0 + (v1 ? d1*d1 : 0.f);
        #pragma unroll
        for (int off = 32; off; off >>= 1) vs += __shfl_xor(vs, off);
        const float inv = rsqrtf(vs / 81.f + LN_EPS);
        float wn0 = d0 * inv * w_lng[l] + w_lnb[l];
        float wn1 = v1 ? (d1 * inv * w_lng[64 + l] + w_lnb[64 + l]) : -1e30f;

        float mx = fmaxf(wn0, wn1);
        #pragma unroll
        for (int off = 32; off; off >>= 1) mx = fmaxf(mx, __shfl_xor(mx, off));
        float e0 = __expf(wn0 - mx), e1 = v1 ? __expf(wn1 - mx) : 0.f;
        float es = e0 + e1;
        #pragma unroll
        for (int off = 32; off; off >>= 1) es += __shfl_xor(es, off);
        const float r = __builtin_amdgcn_rcpf(es);
        w81[(size_t)m * 81 + l] = e0 * r;
        if (v1) w81[(size_t)m * 81 + 64 + l] = e1 * r;
    }
}

// =====================================================================
// selected: f32 + bf16 outputs
// =====================================================================
__global__ __launch_bounds__(256) void selected_kernel(
    const __hip_bfloat16* __restrict__ stacked, const float* __restrict__ w81,
    float* __restrict__ sel, __hip_bfloat16* __restrict__ selb)
{
    const int m = blockIdx.x;
    const int d = threadIdx.x & 63, fg = threadIdx.x >> 6;
    __shared__ float red[4][64];
    __shared__ float wsh[81];
    if (threadIdx.x < 81) wsh[threadIdx.x] = w81[(size_t)m * 81 + threadIdx.x];
    __syncthreads();
    float acc = 0.f;
    for (int f = fg; f < 81; f += 4)
        acc += __bfloat162float(stacked[(size_t)m * FDIM + f*64 + d]) * wsh[f];
    red[fg][d] = acc;
    __syncthreads();
    if (fg == 0) {
        float v = red[0][d] + red[1][d] + red[2][d] + red[3][d];
        sel[(size_t)m * 64 + d]  = v;
        selb[(size_t)m * 64 + d] = __float2bfloat16(v);
    }
}

// =====================================================================
// xW = selb @ wih^T + (bih+bhh)
// =====================================================================
__global__ __launch_bounds__(256) void xw_kernel(
    const __hip_bfloat16* __restrict__ selb,
    const float* __restrict__ wih,
    const float* __restrict__ bih, const float* __restrict__ bhh,
    float* __restrict__ xW)
{
    const int m0 = blockIdx.x * 64;
    const int t = threadIdx.x;
    const int w = t >> 6, l = t & 63, lr = l & 15, lg = l >> 4;
    __shared__ __align__(16) unsigned short hA[64 * 72];
    __shared__ __align__(16) unsigned short Wt[256 * 72];
    __shared__ float vbs[256];

    vbs[t] = bih[t] + bhh[t];
    #pragma unroll
    for (int p = 0; p < 16; ++p) {
        int e = t + 256 * p; int r = e >> 6, d = e & 63;
        hA[r*72 + d] = *(const unsigned short*)&selb[(size_t)(m0 + r) * 64 + d];
    }
    #pragma unroll
    for (int p = 0; p < 64; ++p) {
        int e = t + 256 * p; int c = e >> 6, k = e & 63;
        Wt[c*72 + k] = f2bf(wih[c*64 + k]);
    }
    __syncthreads();

    f32x4 acc[4][4];
    #pragma unroll
    for (int rg = 0; rg < 4; ++rg)
        #pragma unroll
        for (int cf = 0; cf < 4; ++cf) acc[rg][cf] = (f32x4){0.f,0.f,0.f,0.f};
    #pragma unroll
    for (int ks = 0; ks < 2; ++ks) {
        short8v af[4];
        #pragma unroll
        for (int rg = 0; rg < 4; ++rg)
            af[rg] = *(const short8v*)&hA[(rg*16 + lr)*72 + ks*32 + lg*8];
        #pragma unroll
        for (int cf = 0; cf < 4; ++cf) {
            short8v bf = *(const short8v*)&Wt[(w*64 + cf*16 + lr)*72 + ks*32 + lg*8];
            #pragma unroll
            for (int rg = 0; rg < 4; ++rg)
                acc[rg][cf] = __builtin_amdgcn_mfma_f32_16x16x32_bf16(af[rg], bf, acc[rg][cf], 0, 0, 0);
        }
    }
    #pragma unroll
    for (int rg = 0; rg < 4; ++rg)
        #pragma unroll
        for (int cf = 0; cf < 4; ++cf)
            #pragma unroll
            for (int j = 0; j < 4; ++j) {
                int r = rg*16 + lg*4 + j, c = w*64 + cf*16 + lr;
                xW[(size_t)(m0 + r) * 256 + c] = acc[rg][cf][j] + vbs[c];
            }
}

// =====================================================================
// LSTM prep + recurrence (unchanged)
// =====================================================================
__global__ void lstm_prep_kernel(
    const float* __restrict__ whh, float* __restrict__ whhT)
{
    int id = blockIdx.x * 256 + threadIdx.x;
    if (id < 16384) {
        int i = id >> 8, j = id & 255;
        whhT[id] = whh[j*64 + i];
    }
}

__global__ __launch_bounds__(256) void lstm_kernel(
    const float* __restrict__ xW, const float* __restrict__ whhT,
    float* __restrict__ out)
{
    __shared__ float sh[64];
    __shared__ float sg[256];
    const int t = threadIdx.x;
    const int b = blockIdx.x;

    float wreg[64];
    #pragma unroll
    for (int i = 0; i < 64; ++i) wreg[i] = whhT[i*256 + t];

    if (t < 64) sh[t] = 0.f;
    float c_reg = 0.f;

    float xnext = xW[((size_t)b * TSEQ + 0) * 256 + t];
    __syncthreads();

    for (int tt = 0; tt < TSEQ; ++tt) {
        float acc = xnext;
        if (tt + 1 < TSEQ)
            xnext = xW[((size_t)b * TSEQ + tt + 1) * 256 + t];
        #pragma unroll
        for (int i = 0; i < 64; ++i) acc += sh[i] * wreg[i];
        sg[t] = acc;
        __syncthreads();
        if (t < 64) {
            float gi = sg[t], gf = sg[64 + t], gg = sg[128 + t], go = sg[192 + t];
            c_reg = sigmoidf_(gf) * c_reg + sigmoidf_(gi) * ftanh_(gg);
            float hn = sigmoidf_(go) * ftanh_(c_reg);
            sh[t] = hn;
            out[((size_t)b * TSEQ + tt) * 64 + t] = hn;
        }
        __syncthreads();
    }
}

// =====================================================================
// fused post-LSTM GLU+res+LN -> temporal (f32 global) -> QKV projection
// grid MTOT/64, 256 thr. LDS ~38 KB -> 4 blocks/CU.
// =====================================================================
__global__ __launch_bounds__(256) void fused_pl_qkv_kernel(
    const float* __restrict__ in, const float* __restrict__ res,
    const float* __restrict__ g1w, const float* __restrict__ g1b,
    const float* __restrict__ g2w, const float* __restrict__ g2b,
    const float* __restrict__ lng, const float* __restrict__ lnb,
    const float* __restrict__ wqkv, const float* __restrict__ bqkv,
    float* __restrict__ outf, float* __restrict__ qkv)
{
    const int m0 = blockIdx.x * 64;
    const int t = threadIdx.x;
    const int w = t >> 6, l = t & 63, lr = l & 15, lg = l >> 4;
    __shared__ __align__(16) unsigned short hA[64 * 72];     // 9216 B
    __shared__ __align__(16) unsigned char U[27648];         // Wt pair ∪ yA ∪ Wq[192][72]
    unsigned short* Wt0 = (unsigned short*)U;
    unsigned short* Wt1 = (unsigned short*)(U + 9216);
    float* yA = (float*)U;
    unsigned short* Wq = (unsigned short*)U;
    __shared__ float vg1b[64], vg2b[64], vlng[64], vlnb[64], vbq[192];

    if (t < 64) { vg1b[t] = g1b[t]; vg2b[t] = g2b[t]; vlng[t] = lng[t]; vlnb[t] = lnb[t]; }
    if (t < 192) vbq[t] = bqkv[t];
    #pragma unroll
    for (int p = 0; p < 16; ++p) {
        int e = t + 256 * p; int r = e >> 6, d = e & 63;
        hA[r*72 + d] = f2bf(in[(size_t)(m0 + r) * 64 + d]);
    }
    #pragma unroll
    for (int p = 0; p < 16; ++p) {
        int e = t + 256 * p; int k = e >> 6, c = e & 63;
        Wt0[c*72 + k] = f2bf(g1w[k*64 + c]);
        Wt1[c*72 + k] = f2bf(g2w[k*64 + c]);
    }
    __syncthreads();   // bar0

    f32x4 aA[4], aB[4];
    #pragma unroll
    for (int rg = 0; rg < 4; ++rg) { aA[rg] = (f32x4){0.f,0.f,0.f,0.f}; aB[rg] = (f32x4){0.f,0.f,0.f,0.f}; }
    #pragma unroll
    for (int ks = 0; ks < 2; ++ks) {
        short8v b0f = *(const short8v*)&Wt0[(w*16 + lr)*72 + ks*32 + lg*8];
        short8v b1f = *(const short8v*)&Wt1[(w*16 + lr)*72 + ks*32 + lg*8];
        #pragma unroll
        for (int rg = 0; rg < 4; ++rg) {
            short8v af = *(const short8v*)&hA[(rg*16 + lr)*72 + ks*32 + lg*8];
            aA[rg] = __builtin_amdgcn_mfma_f32_16x16x32_bf16(af, b0f, aA[rg], 0, 0, 0);
            aB[rg] = __builtin_amdgcn_mfma_f32_16x16x32_bf16(af, b1f, aB[rg], 0, 0, 0);
        }
    }
    float yv[4][4];
    #pragma unroll
    for (int rg = 0; rg < 4; ++rg)
        #pragma unroll
        for (int j = 0; j < 4; ++j) {
            int r = rg*16 + lg*4 + j, c = w*16 + lr;
            float sg = sigmoidf_(aA[rg][j] + vg1b[c]);
            yv[rg][j] = sg * (aB[rg][j] + vg2b[c]) + res[(size_t)(m0 + r) * 64 + c];
        }
    __syncthreads();   // bar1: Wt + hA reads done

    #pragma unroll
    for (int rg = 0; rg < 4; ++rg)
        #pragma unroll
        for (int j = 0; j < 4; ++j) {
            int r = rg*16 + lg*4 + j, c = w*16 + lr;
            yA[r*68 + c] = yv[rg][j];
        }
    __syncthreads();   // bar2: yA ready

    // LN -> temporal: f32 global + bf16 into hA (row-major, coalesced)
    const int tr = t >> 4, tc = t & 15;
    #pragma unroll
    for (int a = 0; a < 4; ++a) {
        const int r = tr + 16*a;
        float4 v4 = *(const float4*)&yA[r*68 + tc*4];
        float part = v4.x + v4.y + v4.z + v4.w;
        #pragma unroll
        for (int off = 1; off < 16; off <<= 1) part += __shfl_xor(part, off);
        const float mean = part * (1.f / 64.f);
        float d0 = v4.x - mean, d1 = v4.y - mean, d2 = v4.z - mean, d3 = v4.w - mean;
        float vp = d0*d0 + d1*d1 + d2*d2 + d3*d3;
        #pragma unroll
        for (int off = 1; off < 16; off <<= 1) vp += __shfl_xor(vp, off);
        const float inv = rsqrtf(vp * (1.f / 64.f) + LN_EPS);
        const int c0 = tc * 4;
        float4 ov;
        ov.x = d0 * inv * vlng[c0+0] + vlnb[c0+0];
        ov.y = d1 * inv * vlng[c0+1] + vlnb[c0+1];
        ov.z = d2 * inv * vlng[c0+2] + vlnb[c0+2];
        ov.w = d3 * inv * vlng[c0+3] + vlnb[c0+3];
        *(float4*)&outf[(size_t)(m0 + r) * 64 + c0] = ov;
        ushort4 ob;
        ob.x = f2bf(ov.x); ob.y = f2bf(ov.y); ob.z = f2bf(ov.z); ob.w = f2bf(ov.w);
        *(ushort4*)&hA[r*72 + c0] = ob;
    }
    __syncthreads();   // bar3: yA reads done; hA(temporal bf16) ready

    // stage Wqkv [192][72]
    #pragma unroll
    for (int p = 0; p < 48; ++p) {
        int e = t + 256 * p; int c = e >> 6, k = e & 63;
        Wq[c*72 + k] = f2bf(wqkv[(size_t)k * 192 + c]);
    }
    __syncthreads();   // bar4

    f32x4 acc[4][3];
    #pragma unroll
    for (int rg = 0; rg < 4; ++rg)
        #pragma unroll
        for (int cf = 0; cf < 3; ++cf) acc[rg][cf] = (f32x4){0.f,0.f,0.f,0.f};
    #pragma unroll
    for (int ks = 0; ks < 2; ++ks) {
        short8v af[4];
        #pragma unroll
        for (int rg = 0; rg < 4; ++rg)
            af[rg] = *(const short8v*)&hA[(rg*16 + lr)*72 + ks*32 + lg*8];
        #pragma unroll
        for (int cf = 0; cf < 3; ++cf) {
            short8v bf = *(const short8v*)&Wq[(w*48 + cf*16 + lr)*72 + ks*32 + lg*8];
            #pragma unroll
            for (int rg = 0; rg < 4; ++rg)
                acc[rg][cf] = __builtin_amdgcn_mfma_f32_16x16x32_bf16(af[rg], bf, acc[rg][cf], 0, 0, 0);
        }
    }
    #pragma unroll
    for (int rg = 0; rg < 4; ++rg)
        #pragma unroll
        for (int cf = 0; cf < 3; ++cf)
            #pragma unroll
            for (int j = 0; j < 4; ++j) {
                int r = rg*16 + lg*4 + j, c = w*48 + cf*16 + lr;
                qkv[(size_t)(m0 + r) * 192 + c] = acc[rg][cf][j] + vbq[c];
            }
}

// =====================================================================
// MHA core -> ao bf16
// =====================================================================
__global__ __launch_bounds__(256) void attn_kernel(
    const float* __restrict__ qkv, __hip_bfloat16* __restrict__ ao)
{
    const int b = blockIdx.x;
    const int h = threadIdx.x >> 6, l = threadIdx.x & 63;
    __shared__ float sq[4][24][16], sk[4][24][16], sv[4][24][16], sp[4][24][24];
    #pragma unroll
    for (int p = 0; p < 6; ++p) {
        int e = l + 64 * p; int ti = e >> 4, d = e & 15;
        size_t base = ((size_t)(b * TSEQ + ti)) * 192 + h * 16 + d;
        sq[h][ti][d] = qkv[base];
        sk[h][ti][d] = qkv[base + 64];
        sv[h][ti][d] = qkv[base + 128];
    }
    __syncthreads();
    #pragma unroll
    for (int p = 0; p < 9; ++p) {
        int e = l + 64 * p; int i = e / 24, j = e - i * 24;
        float s = 0.f;
        #pragma unroll
        for (int d = 0; d < 16; ++d) s += sq[h][i][d] * sk[h][j][d];
        sp[h][i][j] = s * 0.25f;
    }
    __syncthreads();
    if (l < 24) {
        float mx = -1e30f;
        for (int j = 0; j < 24; ++j) mx = fmaxf(mx, sp[h][l][j]);
        float s = 0.f;
        for (int j = 0; j < 24; ++j) { float e = __expf(sp[h][l][j] - mx); sp[h][l][j] = e; s += e; }
        float inv = __builtin_amdgcn_rcpf(s);
        for (int j = 0; j < 24; ++j) sp[h][l][j] *= inv;
    }
    __syncthreads();
    #pragma unroll
    for (int p = 0; p < 6; ++p) {
        int e = l + 64 * p; int ti = e >> 4, d = e & 15;
        float s = 0.f;
        #pragma unroll
        for (int j = 0; j < 24; ++j) s += sp[h][ti][j] * sv[h][j][d];
        ao[((size_t)(b * TSEQ + ti)) * 64 + h * 16 + d] = __float2bfloat16(s);
    }
}

// =====================================================================
// fused post-attn + FF GRN:
// ao@Wout+b -> GLU(pa) -> +temporal -> LN -> enriched (f32 via escratch)
// -> elu(e@W1+b1) -> @W2+b2 -> GLU(ff) -> +enriched -> LN -> outln
// grid MTOT/64, 256 thr, ~65 KB LDS -> 2 blocks/CU.
// =====================================================================
__global__ __launch_bounds__(256) void fused_paff_kernel(
    const __hip_bfloat16* __restrict__ ao, const float* __restrict__ res_t,
    const float* __restrict__ wout, const float* __restrict__ bout,
    const float* __restrict__ pg1w, const float* __restrict__ pg1b,
    const float* __restrict__ pg2w, const float* __restrict__ pg2b,
    const float* __restrict__ plng, const float* __restrict__ plnb,
    const float* __restrict__ fw1, const float* __restrict__ fb1,
    const float* __restrict__ fw2, const float* __restrict__ fb2,
    const float* __restrict__ fg1w, const float* __restrict__ fg1b,
    const float* __restrict__ fg2w, const float* __restrict__ fg2b,
    const float* __restrict__ flng, const float* __restrict__ flnb,
    float* __restrict__ escratch, float* __restrict__ outln)
{
    const int m0 = blockIdx.x * 64;
    const int t = threadIdx.x;
    const int w = t >> 6, l = t & 63, lr = l & 15, lg = l >> 4;
    __shared__ __align__(16) unsigned short hA[64 * 72];     // 9216
    __shared__ __align__(16) unsigned short hB[64 * 136];    // 17408
    __shared__ __align__(16) unsigned char U1[18432];        // Wt pair / W1t[128][72]
    __shared__ __align__(16) unsigned char U2[17408];        // W2t[64][136] ∪ yA
    unsigned short* Wt0 = (unsigned short*)U1;
    unsigned short* Wt1 = (unsigned short*)(U1 + 9216);
    unsigned short* W1t = (unsigned short*)U1;
    unsigned short* W2t = (unsigned short*)U2;
    float* yA = (float*)U2;
    __shared__ float vob[64], vp1b[64], vp2b[64], vplg[64], vplb[64];
    __shared__ float vf1b[128], vf2b[64], vfg1b[64], vfg2b[64], vflg[64], vflb[64];

    if (t < 64) {
        vob[t] = bout[t]; vp1b[t] = pg1b[t]; vp2b[t] = pg2b[t];
        vplg[t] = plng[t]; vplb[t] = plnb[t];
        vf2b[t] = fb2[t]; vfg1b[t] = fg1b[t]; vfg2b[t] = fg2b[t];
        vflg[t] = flng[t]; vflb[t] = flnb[t];
    }
    if (t < 128) vf1b[t] = fb1[t];
    #pragma unroll
    for (int p = 0; p < 16; ++p) {
        int e = t + 256 * p; int r = e >> 6, d = e & 63;
        hA[r*72 + d] = *(const unsigned short*)&ao[(size_t)(m0 + r) * 64 + d];
    }
    #pragma unroll
    for (int p = 0; p < 16; ++p) {
        int e = t + 256 * p; int k = e >> 6, c = e & 63;
        Wt0[c*72 + k] = f2bf(wout[k*64 + c]);
    }
    __syncthreads();   // bar0

    // pa mm1: attn_out
    f32x4 acc1[4];
    #pragma unroll
    for (int rg = 0; rg < 4; ++rg) acc1[rg] = (f32x4){0.f,0.f,0.f,0.f};
    #pragma unroll
    for (int ks = 0; ks < 2; ++ks) {
        short8v bf = *(const short8v*)&Wt0[(w*16 + lr)*72 + ks*32 + lg*8];
        #pragma unroll
        for (int rg = 0; rg < 4; ++rg) {
            short8v af = *(const short8v*)&hA[(rg*16 + lr)*72 + ks*32 + lg*8];
            acc1[rg] = __builtin_amdgcn_mfma_f32_16x16x32_bf16(af, bf, acc1[rg], 0, 0, 0);
        }
    }
    #pragma unroll
    for (int p = 0; p < 16; ++p) {
        int e = t + 256 * p; int k = e >> 6, c = e & 63;
        Wt1[c*72 + k] = f2bf(pg1w[k*64 + c]);
    }
    __syncthreads();   // bar1

    #pragma unroll
    for (int rg = 0; rg < 4; ++rg)
        #pragma unroll
        for (int j = 0; j < 4; ++j) {
            int r = rg*16 + lg*4 + j, c = w*16 + lr;
            hA[r*72 + c] = f2bf(acc1[rg][j] + vob[c]);
        }
    #pragma unroll
    for (int p = 0; p < 16; ++p) {
        int e = t + 256 * p; int k = e >> 6, c = e & 63;
        Wt0[c*72 + k] = f2bf(pg2w[k*64 + c]);
    }
    __syncthreads();   // bar2

    // pa GLU pair + residual(temporal)
    f32x4 aA[4], aB[4];
    #pragma unroll
    for (int rg = 0; rg < 4; ++rg) { aA[rg] = (f32x4){0.f,0.f,0.f,0.f}; aB[rg] = (f32x4){0.f,0.f,0.f,0.f}; }
    #pragma unroll
    for (int ks = 0; ks < 2; ++ks) {
        short8v b1f = *(const short8v*)&Wt1[(w*16 + lr)*72 + ks*32 + lg*8];
        short8v b2f = *(const short8v*)&Wt0[(w*16 + lr)*72 + ks*32 + lg*8];
        #pragma unroll
        for (int rg = 0; rg < 4; ++rg) {
            short8v af = *(const short8v*)&hA[(rg*16 + lr)*72 + ks*32 + lg*8];
            aA[rg] = __builtin_amdgcn_mfma_f32_16x16x32_bf16(af, b1f, aA[rg], 0, 0, 0);
            aB[rg] = __builtin_amdgcn_mfma_f32_16x16x32_bf16(af, b2f, aB[rg], 0, 0, 0);
        }
    }
    float yv[4][4];
    #pragma unroll
    for (int rg = 0; rg < 4; ++rg)
        #pragma unroll
        for (int j = 0; j < 4; ++j) {
            int r = rg*16 + lg*4 + j, c = w*16 + lr;
            float sg = sigmoidf_(aA[rg][j] + vp1b[c]);
            yv[rg][j] = sg * (aB[rg][j] + vp2b[c]) + res_t[(size_t)(m0 + r) * 64 + c];
        }
    __syncthreads();   // bar3: hA/U1 reads done

    #pragma unroll
    for (int rg = 0; rg < 4; ++rg)
        #pragma unroll
        for (int j = 0; j < 4; ++j) {
            int r = rg*16 + lg*4 + j, c = w*16 + lr;
            yA[r*68 + c] = yv[rg][j];
        }
    __syncthreads();   // bar4: yA ready

    // pa-LN -> enriched: f32 to escratch, bf16 into hA
    const int tr = t >> 4, tc = t & 15;
    #pragma unroll
    for (int a = 0; a < 4; ++a) {
        const int r = tr + 16*a;
        float4 v4 = *(const float4*)&yA[r*68 + tc*4];
        float part = v4.x + v4.y + v4.z + v4.w;
        #pragma unroll
        for (int off = 1; off < 16; off <<= 1) part += __shfl_xor(part, off);
        const float mean = part * (1.f / 64.f);
        float d0 = v4.x - mean, d1 = v4.y - mean, d2 = v4.z - mean, d3 = v4.w - mean;
        float vp = d0*d0 + d1*d1 + d2*d2 + d3*d3;
        #pragma unroll
        for (int off = 1; off < 16; off <<= 1) vp += __shfl_xor(vp, off);
        const float inv = rsqrtf(vp * (1.f / 64.f) + LN_EPS);
        const int c0 = tc * 4;
        float4 ov;
        ov.x = d0 * inv * vplg[c0+0] + vplb[c0+0];
        ov.y = d1 * inv * vplg[c0+1] + vplb[c0+1];
        ov.z = d2 * inv * vplg[c0+2] + vplb[c0+2];
        ov.w = d3 * inv * vplg[c0+3] + vplb[c0+3];
        *(float4*)&escratch[(size_t)(m0 + r) * 64 + c0] = ov;
        ushort4 ob;
        ob.x = f2bf(ov.x); ob.y = f2bf(ov.y); ob.z = f2bf(ov.z); ob.w = f2bf(ov.w);
        *(ushort4*)&hA[r*72 + c0] = ob;
    }
    __syncthreads();   // bar5: yA reads done; hA(enriched) ready

    // stage ff W1t [128][72]
    #pragma unroll
    for (int p = 0; p < 32; ++p) {
        int e = t + 256 * p; int k = e >> 7, c = e & 127;
        W1t[c*72 + k] = f2bf(fw1[(size_t)k * 128 + c]);
    }
    __syncthreads();   // bar6

    // ff mm1: h = elu(e@W1+b1), N=128 -> hB
    f32x4 accf[4][2];
    #pragma unroll
    for (int rg = 0; rg < 4; ++rg)
        #pragma unroll
        for (int cf = 0; cf < 2; ++cf) accf[rg][cf] = (f32x4){0.f,0.f,0.f,0.f};
    #pragma unroll
    for (int ks = 0; ks < 2; ++ks) {
        short8v af[4];
        #pragma unroll
        for (int rg = 0; rg < 4; ++rg)
            af[rg] = *(const short8v*)&hA[(rg*16 + lr)*72 + ks*32 + lg*8];
        #pragma unroll
        for (int cf = 0; cf < 2; ++cf) {
            short8v bf = *(const short8v*)&W1t[(w*32 + cf*16 + lr)*72 + ks*32 + lg*8];
            #pragma unroll
            for (int rg = 0; rg < 4; ++rg)
                accf[rg][cf] = __builtin_amdgcn_mfma_f32_16x16x32_bf16(af[rg], bf, accf[rg][cf], 0, 0, 0);
        }
    }
    #pragma unroll
    for (int rg = 0; rg < 4; ++rg)
        #pragma unroll
        for (int cf = 0; cf < 2; ++cf)
            #pragma unroll
            for (int j = 0; j < 4; ++j) {
                int r = rg*16 + lg*4 + j, c = w*32 + cf*16 + lr;
                hB[r*136 + c] = f2bf(eluf_(accf[rg][cf][j] + vf1b[c]));
            }
    __syncthreads();   // bar7: W1t + hA(enriched) reads done; hB ready

    // stage ff W2t [64][136] + ff GLU weights into U1
    #pragma unroll
    for (int p = 0; p < 32; ++p) {
        int e = t + 256 * p; int k = e >> 6, c = e & 63;
        W2t[c*136 + k] = f2bf(fw2[(size_t)k * 64 + c]);
    }
    #pragma unroll
    for (int p = 0; p < 16; ++p) {
        int e = t + 256 * p; int k = e >> 6, c = e & 63;
        Wt0[c*72 + k] = f2bf(fg1w[k*64 + c]);
        Wt1[c*72 + k] = f2bf(fg2w[k*64 + c]);
    }
    __syncthreads();   // bar8

    // ff mm2: h2 = h@W2+b2 (K=128) -> hA
    f32x4 acc2[4];
    #pragma unroll
    for (int rg = 0; rg < 4; ++rg) acc2[rg] = (f32x4){0.f,0.f,0.f,0.f};
    #pragma unroll
    for (int ks = 0; ks < 4; ++ks) {
        short8v bf = *(const short8v*)&W2t[(w*16 + lr)*136 + ks*32 + lg*8];
        #pragma unroll
        for (int rg = 0; rg < 4; ++rg) {
            short8v af = *(const short8v*)&hB[(rg*16 + lr)*136 + ks*32 + lg*8];
            acc2[rg] = __builtin_amdgcn_mfma_f32_16x16x32_bf16(af, bf, acc2[rg], 0, 0, 0);
        }
    }
    #pragma unroll
    for (int rg = 0; rg < 4; ++rg)
        #pragma unroll
        for (int j = 0; j < 4; ++j) {
            int r = rg*16 + lg*4 + j, c = w*16 + lr;
            hA[r*72 + c] = f2bf(acc2[rg][j] + vf2b[c]);
        }
    __syncthreads();   // bar9: hA(h2) ready; W2t reads done

    // ff GLU pair + residual(enriched via escratch)
    #pragma unroll
    for (int rg = 0; rg < 4; ++rg) { aA[rg] = (f32x4){0.f,0.f,0.f,0.f}; aB[rg] = (f32x4){0.f,0.f,0.f,0.f}; }
    #pragma unroll
    for (int ks = 0; ks < 2; ++ks) {
        short8v b1f = *(const short8v*)&Wt0[(w*16 + lr)*72 + ks*32 + lg*8];
        short8v b2f = *(const short8v*)&Wt1[(w*16 + lr)*72 + ks*32 + lg*8];
        #pragma unroll
        for (int rg = 0; rg < 4; ++rg) {
            short8v af = *(const short8v*)&hA[(rg*16 + lr)*72 + ks*32 + lg*8];
            aA[rg] = __builtin_amdgcn_mfma_f32_16x16x32_bf16(af, b1f, aA[rg], 0, 0, 0);
            aB[rg] = __builtin_amdgcn_mfma_f32_16x16x32_bf16(af, b2f, aB[rg], 0, 0, 0);
        }
    }
    #pragma unroll
    for (int rg = 0; rg < 4; ++rg)
        #pragma unroll
        for (int j = 0; j < 4; ++j) {
            int r = rg*16 + lg*4 + j, c = w*16 + lr;
            float sg = sigmoidf_(aA[rg][j] + vfg1b[c]);
            yv[rg][j] = sg * (aB[rg][j] + vfg2b[c]) + escratch[(size_t)(m0 + r) * 64 + c];
        }
    __syncthreads();   // bar10: W2t(U2) reads long done; safe to overlay yA

    #pragma unroll
    for (int rg = 0; rg < 4; ++rg)
        #pragma unroll
        for (int j = 0; j < 4; ++j) {
            int r = rg*16 + lg*4 + j, c = w*16 + lr;
            yA[r*68 + c] = yv[rg][j];
        }
    __syncthreads();   // bar11: yA ready

    // ff-LN -> outln
    #pragma unroll
    for (int a = 0; a < 4; ++a) {
        const int r = tr + 16*a;
        float4 v4 = *(const float4*)&yA[r*68 + tc*4];
        float part = v4.x + v4.y + v4.z + v4.w;
        #pragma unroll
        for (int off = 1; off < 16; off <<= 1) part += __shfl_xor(part, off);
        const float mean = part * (1.f / 64.f);
        float d0 = v4.x - mean, d1 = v4.y - mean, d2 = v4.z - mean, d3 = v4.w - mean;
        float vp = d0*d0 + d1*d1 + d2*d2 + d3*d3;
        #pragma unroll
        for (int off = 1; off < 16; off <<= 1) vp += __shfl_xor(vp, off);
        const float inv = rsqrtf(vp * (1.f / 64.f) + LN_EPS);
        const int c0 = tc * 4;
        float4 ov;
        ov.x = d0 * inv * vflg[c0+0] + vflb[c0+0];
        ov.y = d1 * inv * vflg[c0+1] + vflb[c0+1];
        ov.z = d2 * inv * vflg[c0+2] + vflb[c0+2];
        ov.w = d3 * inv * vflg[c0+3] + vflb[c0+3];
        *(float4*)&outln[(size_t)(m0 + r) * 64 + c0] = ov;
    }
}

// =====================================================================
// head: mean over T -> fc1+relu -> fc2
// =====================================================================
__global__ __launch_bounds__(64) void head_kernel(
    const float* __restrict__ outln,
    const float* __restrict__ fc1_w, const float* __restrict__ fc1_b,
    const float* __restrict__ fc2_w, const float* __restrict__ fc2_b,
    float* __restrict__ out)
{
    const int b = blockIdx.x, l = threadIdx.x;
    __shared__ float sp[64];
    float s = 0.f;
    #pragma unroll
    for (int tt = 0; tt < TSEQ; ++tt) s += outln[((size_t)(b * TSEQ + tt)) * 64 + l];
    sp[l] = s * (1.f / 24.f);
    __syncthreads();
    float a = fc1_b[l];
    for (int k = 0; k < 64; ++k) a += sp[k] * fc1_w[k*64 + l];
    float f1 = fmaxf(a, 0.f);
    #pragma unroll
    for (int j = 0; j < 6; ++j) {
        float p = f1 * fc2_w[l*6 + j];
        #pragma unroll
        for (int off = 32; off; off >>= 1) p += __shfl_xor(p, off);
        if (l == 0) out[b*6 + j] = p + fc2_b[j];
    }
}

// =====================================================================
extern "C" void kernel_launch(void* const* d_in, const int* in_sizes, int n_in,
                              void* d_out, int out_size, void* d_ws, size_t ws_size,
                              hipStream_t stream)
{
    const float* x        = (const float*)d_in[0];
    const float* f_w1     = (const float*)d_in[1];
    const float* f_b1     = (const float*)d_in[2];
    const float* f_w2     = (const float*)d_in[3];
    const float* f_b2     = (const float*)d_in[4];
    const float* f_g1w    = (const float*)d_in[5];
    const float* f_g1b    = (const float*)d_in[6];
    const float* f_g2w    = (const float*)d_in[7];
    const float* f_g2b    = (const float*)d_in[8];
    const float* f_skw    = (const float*)d_in[9];
    const float* f_skb    = (const float*)d_in[10];
    const float* f_lng    = (const float*)d_in[11];
    const float* f_lnb    = (const float*)d_in[12];
    const float* w_w1     = (const float*)d_in[13];
    const float* w_b1     = (const float*)d_in[14];
    const float* w_w2     = (const float*)d_in[15];
    const float* w_b2     = (const float*)d_in[16];
    const float* w_g1w    = (const float*)d_in[17];
    const float* w_g1b    = (const float*)d_in[18];
    const float* w_g2w    = (const float*)d_in[19];
    const float* w_g2b    = (const float*)d_in[20];
    const float* w_skw    = (const float*)d_in[21];
    const float* w_skb    = (const float*)d_in[22];
    const float* w_lng    = (const float*)d_in[23];
    const float* w_lnb    = (const float*)d_in[24];
    const float* lstm_wih = (const float*)d_in[25];
    const float* lstm_whh = (const float*)d_in[26];
    const float* lstm_bih = (const float*)d_in[27];
    const float* lstm_bhh = (const float*)d_in[28];
    const float* pl_g1w   = (const float*)d_in[29];
    const float* pl_g1b   = (const float*)d_in[30];
    const float* pl_g2w   = (const float*)d_in[31];
    const float* pl_g2b   = (const float*)d_in[32];
    const float* pl_lng   = (const float*)d_in[33];
    const float* pl_lnb   = (const float*)d_in[34];
    const float* attn_in_w  = (const float*)d_in[35];
    const float* attn_in_b  = (const float*)d_in[36];
    const float* attn_out_w = (const float*)d_in[37];
    const float* attn_out_b = (const float*)d_in[38];
    const float* pa_g1w   = (const float*)d_in[39];
    const float* pa_g1b   = (const float*)d_in[40];
    const float* pa_g2w   = (const float*)d_in[41];
    const float* pa_g2b   = (const float*)d_in[42];
    const float* pa_lng   = (const float*)d_in[43];
    const float* pa_lnb   = (const float*)d_in[44];
    const float* ff_w1    = (const float*)d_in[45];
    const float* ff_b1    = (const float*)d_in[46];
    const float* ff_w2    = (const float*)d_in[47];
    const float* ff_b2    = (const float*)d_in[48];
    const float* ff_g1w   = (const float*)d_in[49];
    const float* ff_g1b   = (const float*)d_in[50];
    const float* ff_g2w   = (const float*)d_in[51];
    const float* ff_g2b   = (const float*)d_in[52];
    const float* ff_lng   = (const float*)d_in[53];
    const float* ff_lnb   = (const float*)d_in[54];
    const float* fc1_w    = (const float*)d_in[55];
    const float* fc1_b    = (const float*)d_in[56];
    const float* fc2_w    = (const float*)d_in[57];
    const float* fc2_b    = (const float*)d_in[58];

    float* ws = (float*)d_ws;

    // ---------------- phase-2 union (fixed offsets) ----------------------
    size_t o = 0;
    const size_t o_S0   = o; o += (size_t)MTOT * 256;   // xW / qkv
    const size_t o_A    = o; o += (size_t)MTOT * 64;    // lstm_out
    const size_t o_Bf   = o; o += (size_t)MTOT * 64;    // enriched f32 scratch
    const size_t o_Cf   = o; o += (size_t)MTOT * 64;    // outln f32
    const size_t o_Df   = o; o += (size_t)MTOT * 64;    // temporal f32
    const size_t o_F    = o; o += (size_t)MTOT * 128;   // ao bf16 lives here
    const size_t o_whhT = o; o += 16384;
    const size_t unionP2 = o;                            // 7,880,704 floats

    const size_t o_ab = o_F;                             // ao bf16

    // ---------------- adaptive M-chunk selection --------------------------
    const size_t persist = (size_t)MTOT * 177;           // sel + selb + xT
    int mc = 0;
    {
        const int cands[4] = {12288, 6144, 3072, 1536};
        for (int ci = 0; ci < 4; ++ci) {
            const size_t c = (size_t)cands[ci];
            size_t overlay = c * FDIM / 2 + (size_t)KS * c * NW + c * 81
                           + (size_t)NW * FDIM / 2;
            size_t A = overlay > unionP2 ? overlay : unionP2;
            if ((A + persist) * sizeof(float) <= ws_size) { mc = cands[ci]; break; }
        }
        if (mc == 0) return;                             // workspace too small
    }
    const size_t ovl_partial = (size_t)mc * FDIM / 2;
    const size_t ovl_w81     = ovl_partial + (size_t)KS * mc * NW;
    const size_t ovl_wcat    = ovl_w81 + (size_t)mc * 81;
    const size_t ovl_end     = ovl_wcat + (size_t)NW * FDIM / 2;
    const size_t regA        = ovl_end > unionP2 ? ovl_end : unionP2;
    const size_t o_sel  = regA;
    const size_t o_selb = o_sel + (size_t)MTOT * 64;
    const size_t o_xt   = o_selb + (size_t)MTOT * 32;

    const dim3 blk(256);

    // 0) transpose x (tiled) ; pack weight-head matrices to bf16
    xt_kernel<<<dim3(MTOT / 128), blk, 0, stream>>>(x, ws + o_xt);
    wprep_kernel<<<dim3((FDIM + 255) / 256, NW), blk, 0, stream>>>(
        w_w1, w_skw, (unsigned short*)(ws + ovl_wcat));

    // ---------------- phase 1: VSN + weight-GRN, chunked over M ----------
    for (int mb = 0; mb < MTOT; mb += mc) {
        __hip_bfloat16* chunk = (__hip_bfloat16*)ws;
        vsn_kernel<<<dim3((mc / 64) / NT, NF), blk, 0, stream>>>(
            ws + o_xt + mb, f_w1, f_b1, f_w2, f_b2, f_g1w, f_g1b,
            f_g2w, f_g2b, f_skw, f_skb, f_lng, f_lnb, chunk);
        wgemm_kernel<<<dim3(mc / 32, KS), dim3(64), 0, stream>>>(
            chunk, (const unsigned short*)(ws + ovl_wcat), ws + ovl_partial, mc);
        wtail_kernel<<<dim3(mc / 16), blk, 0, stream>>>(
            ws + ovl_partial, w_b1, w_skb, w_w2, w_b2, w_g1w, w_g1b,
            w_g2w, w_g2b, w_lng, w_lnb, ws + ovl_w81, mc);
        selected_kernel<<<dim3(mc), blk, 0, stream>>>(
            chunk, ws + ovl_w81, ws + o_sel + (size_t)mb * 64,
            (__hip_bfloat16*)(ws + o_selb) + (size_t)mb * 64);
    }

    // ---------------- phase 2: LSTM -> attention -> head -----------------
    lstm_prep_kernel<<<dim3(64), blk, 0, stream>>>(lstm_whh, ws + o_whhT);
    xw_kernel<<<dim3(MTOT / 64), blk, 0, stream>>>(
        (const __hip_bfloat16*)(ws + o_selb), lstm_wih, lstm_bih, lstm_bhh, ws + o_S0);
    lstm_kernel<<<dim3(BB), blk, 0, stream>>>(ws + o_S0, ws + o_whhT, ws + o_A);
    fused_pl_qkv_kernel<<<dim3(MTOT / 64), blk, 0, stream>>>(
        ws + o_A, ws + o_sel, pl_g1w, pl_g1b, pl_g2w, pl_g2b, pl_lng, pl_lnb,
        attn_in_w, attn_in_b, ws + o_Df, ws + o_S0);
    attn_kernel<<<dim3(BB), blk, 0, stream>>>(
        ws + o_S0, (__hip_bfloat16*)(ws + o_ab));
    fused_paff_kernel<<<dim3(MTOT / 64), blk, 0, stream>>>(
        (const __hip_bfloat16*)(ws + o_ab), ws + o_Df,
        attn_out_w, attn_out_b, pa_g1w, pa_g1b, pa_g2w, pa_g2b, pa_lng, pa_lnb,
        ff_w1, ff_b1, ff_w2, ff_b2, ff_g1w, ff_g1b, ff_g2w, ff_g2b,
        ff_lng, ff_lnb, ws + o_Bf, ws + o_Cf);
    head_kernel<<<dim3(BB), dim3(64), 0, stream>>>(
        ws + o_Cf, fc1_w, fc1_b, fc2_w, fc2_b, (float*)d_out);
}